// Round 2
// baseline (842.368 us; speedup 1.0000x reference)
//
#include <hip/hip_runtime.h>
#include <hip/hip_bf16.h>
#include <stdint.h>

typedef unsigned short u16;
typedef __attribute__((ext_vector_type(8))) short bf16x8;
typedef __attribute__((ext_vector_type(4))) float f32x4;

#define DEV static __device__ __forceinline__

DEV u16 f2bf(float f){
  union { float f; unsigned u; } x; x.f = f;
  unsigned r = x.u + 0x7fffu + ((x.u >> 16) & 1u);
  return (u16)(r >> 16);
}

DEV void g2l16(const void* g, void* l){
  __builtin_amdgcn_global_load_lds((const __attribute__((address_space(1))) unsigned int*)g,
                                   (__attribute__((address_space(3))) unsigned int*)l,
                                   16, 0, 0);
}

// ---------------- f32 -> bf16 straight convert ----------------
__global__ __launch_bounds__(256)
void f2bf_k(const float* __restrict__ in, u16* __restrict__ out){
  int idx = blockIdx.x*256 + threadIdx.x;
  float4 v = *(const float4*)&in[(size_t)idx*4];
  u16 a = f2bf(v.x), b = f2bf(v.y), c = f2bf(v.z), d = f2bf(v.w);
  ushort4 o4; o4.x=a; o4.y=b; o4.z=c; o4.w=d;
  *(ushort4*)&out[(size_t)idx*4] = o4;
}

// ---------------- f32 [R][C] -> bf16 [C][R] transpose ----------------
__global__ __launch_bounds__(256)
void transp_k(const float* __restrict__ in, u16* __restrict__ out, int R, int C){
  __shared__ float tile[32][33];
  const int c0 = blockIdx.x*32, r0 = blockIdx.y*32;
  const int x = threadIdx.x & 31, y0 = threadIdx.x >> 5;
#pragma unroll
  for (int j=0;j<4;j++){
    int r = y0 + j*8;
    tile[r][x] = in[(size_t)(r0+r)*C + c0 + x];
  }
  __syncthreads();
#pragma unroll
  for (int j=0;j<4;j++){
    int cc = y0 + j*8;
    out[(size_t)(c0+cc)*R + r0 + x] = f2bf(tile[x][cc]);
  }
}

// ---------------- bf16 GEMM: A[M,K] (row, lda), B^T[N,K] (row, ldb) -> C[M,N] ----------------
template<bool OBF>
__global__ __launch_bounds__(256)
void gemm_k(const u16* __restrict__ A, const u16* __restrict__ B, void* __restrict__ Cp,
            int K, int lda, int ldb, int ldc){
  __shared__ u16 As[128*32];
  __shared__ u16 Bs[128*32];
  const int m0 = blockIdx.y*128, n0 = blockIdx.x*128;
  const int tid = threadIdx.x;
  const int lane = tid & 63, wave = tid >> 6;
  const int wr = wave >> 1, wc = wave & 1;
  const int lr = lane & 15, kg = lane >> 4;
  const f32x4 vzero = {0.f,0.f,0.f,0.f};
  f32x4 acc[4][4];
#pragma unroll
  for (int a=0;a<4;a++)
#pragma unroll
    for (int b=0;b<4;b++) acc[a][b] = vzero;
  const int r0 = tid>>2, s0 = tid&3;
  for (int k0=0;k0<K;k0+=32){
    __syncthreads();
    g2l16(A + (size_t)(m0+r0)*lda + k0 + s0*8, (u16*)As + (size_t)tid*8);
    g2l16(B + (size_t)(n0+r0)*ldb + k0 + s0*8, (u16*)Bs + (size_t)tid*8);
    g2l16(A + (size_t)(m0+r0+64)*lda + k0 + s0*8, (u16*)As + (size_t)(tid+256)*8);
    g2l16(B + (size_t)(n0+r0+64)*ldb + k0 + s0*8, (u16*)Bs + (size_t)(tid+256)*8);
    __syncthreads();
    bf16x8 af[4], bfv[4];
#pragma unroll
    for (int mi=0;mi<4;mi++) af[mi]  = *(const bf16x8*)(As + (wr*64+mi*16+lr)*32 + kg*8);
#pragma unroll
    for (int ni=0;ni<4;ni++) bfv[ni] = *(const bf16x8*)(Bs + (wc*64+ni*16+lr)*32 + kg*8);
#pragma unroll
    for (int mi=0;mi<4;mi++)
#pragma unroll
      for (int ni=0;ni<4;ni++)
        acc[mi][ni] = __builtin_amdgcn_mfma_f32_16x16x32_bf16(af[mi], bfv[ni], acc[mi][ni], 0, 0, 0);
  }
#pragma unroll
  for (int mi=0;mi<4;mi++)
#pragma unroll
    for (int ni=0;ni<4;ni++)
#pragma unroll
      for (int vv=0;vv<4;vv++){
        int row = m0 + wr*64 + mi*16 + kg*4 + vv;
        int col = n0 + wc*64 + ni*16 + lr;
        float val = acc[mi][ni][vv];
        if (OBF) ((u16*)Cp)[(size_t)row*ldc + col] = f2bf(val);
        else     ((float*)Cp)[(size_t)row*ldc + col] = val;
      }
}

// ---------------- beta = sigmoid(h @ Wb), per-t block ----------------
__global__ __launch_bounds__(256)
void beta_k(const float* __restrict__ h, const float* __restrict__ Wb, float* __restrict__ betab){
  __shared__ float hrow[2048];
  __shared__ float red[16][5];
  const int t = blockIdx.x, tid = threadIdx.x;
#pragma unroll
  for (int j=0;j<8;j++) hrow[tid + j*256] = h[(size_t)t*2048 + tid + j*256];
  __syncthreads();
  float part[16];
#pragma unroll
  for (int n=0;n<16;n++) part[n]=0.f;
  for (int j=0;j<8;j++){
    int kk = tid + j*256;
    float hv = hrow[kk];
    const float4* wr4 = (const float4*)&Wb[(size_t)kk*16];
    float4 w0=wr4[0], w1=wr4[1], w2=wr4[2], w3=wr4[3];
    part[0]+=hv*w0.x; part[1]+=hv*w0.y; part[2]+=hv*w0.z; part[3]+=hv*w0.w;
    part[4]+=hv*w1.x; part[5]+=hv*w1.y; part[6]+=hv*w1.z; part[7]+=hv*w1.w;
    part[8]+=hv*w2.x; part[9]+=hv*w2.y; part[10]+=hv*w2.z; part[11]+=hv*w2.w;
    part[12]+=hv*w3.x; part[13]+=hv*w3.y; part[14]+=hv*w3.z; part[15]+=hv*w3.w;
  }
#pragma unroll
  for (int n=0;n<16;n++){
    float s = part[n];
#pragma unroll
    for (int off=1;off<64;off<<=1) s += __shfl_xor(s, off);
    if ((tid&63)==0) red[n][tid>>6] = s;
  }
  __syncthreads();
  if (tid < 16){
    float s = red[tid][0]+red[tid][1]+red[tid][2]+red[tid][3];
    betab[t*16+tid] = 1.f/(1.f+__expf(-s));
  }
}

// ---------------- causal conv4 + silu on concatenated qkvw ----------------
__global__ __launch_bounds__(256)
void conv_k(const float* __restrict__ raw, const float* __restrict__ cq,
            const float* __restrict__ ck, const float* __restrict__ cv,
            float* __restrict__ qo, float* __restrict__ ko,
            float* __restrict__ vo, float* __restrict__ wo){
  int idx = blockIdx.x*256 + threadIdx.x;
  int cgl = idx & 8191, tb = idx >> 13;
  int which = cgl >> 11, cc = cgl & 2047;
  const float* wt = (which==0)?cq:((which==1)?ck:cv);   // w-branch (3) uses cv (faithful to ref)
  float4 w4 = *(const float4*)&wt[cc*4];
  float* out = (which==0)?qo:((which==1)?ko:((which==2)?vo:wo));
  int t0 = tb*4;
  float x[7];
#pragma unroll
  for (int j=0;j<7;j++){
    int t = t0 - 3 + j;
    x[j] = (t >= 0) ? raw[(size_t)t*8192 + cgl] : 0.f;
  }
#pragma unroll
  for (int j=0;j<4;j++){
    float y = x[j]*w4.x + x[j+1]*w4.y + x[j+2]*w4.z + x[j+3]*w4.w;
    y = y / (1.f + __expf(-y));           // silu
    out[(size_t)(t0+j)*2048 + cc] = y;
  }
}

// ---------------- l2norm over M + beta scale: bw ----------------
__global__ __launch_bounds__(256)
void l2bw_k(const float* __restrict__ wconv, const float* __restrict__ betab,
            float* __restrict__ bwout){
  int row = blockIdx.x*4 + (threadIdx.x>>6);
  int lane = threadIdx.x & 63;
  int t = row >> 4, h = row & 15;
  size_t base = (size_t)t*2048 + h*128;
  float a0 = wconv[base+lane], a1 = wconv[base+64+lane];
  float ss = a0*a0 + a1*a1;
#pragma unroll
  for (int off=1;off<64;off<<=1) ss += __shfl_xor(ss, off);
  float r = rsqrtf(ss + 1e-6f) * betab[t*16+h];
  bwout[base+lane]    = a0*r;
  bwout[base+64+lane] = a1*r;
}

// ---------------- per-chunk inclusive cumsum of logsigmoid(gpre) ----------------
__global__ __launch_bounds__(256)
void cg_k(const float* __restrict__ gpre, float* __restrict__ cg){
  int idx = blockIdx.x*256 + threadIdx.x;   // 32768 = c*2048 + h*128 + m
  int m = idx & 127, h = (idx>>7) & 15, c = idx >> 11;
  size_t base = (size_t)h*128 + m;
  float run = 0.f;
  for (int i2=0;i2<64;i2++){
    size_t t = (size_t)c*64 + i2;
    float x = gpre[t*2048 + base];
    float lg = (x >= 0.f) ? (-log1pf(__expf(-x))) : (x - log1pf(__expf(x)));
    run += lg;
    cg[t*2048 + base] = run;
  }
}

// ---------------- Phase A: per-chunk state deltas (register-blocked 4x16) ----------------
__global__ __launch_bounds__(256)
void phaseA_k(const float* __restrict__ k, const float* __restrict__ v,
              const float* __restrict__ bw, const float* __restrict__ cg,
              float* __restrict__ DSk, float* __restrict__ DSv){
  __shared__ float Ks[64][133];
  __shared__ float Vs[64][133];
  __shared__ float Us[64][133];
  __shared__ float Gt[128];
  const int bx=blockIdx.x, h=bx&15, c=bx>>4, tid=threadIdx.x;
  if (tid < 128) Gt[tid] = cg[(size_t)(c*64+63)*2048 + h*128 + tid];
#pragma unroll
  for (int j=0;j<8;j++){
    int f4=tid+j*256, r=f4>>5, c4=(f4&31)<<2;
    size_t g=(size_t)(c*64+r)*2048 + h*128 + c4;
    *(float4*)&Ks[r][c4] = *(const float4*)&k[g];
    *(float4*)&Vs[r][c4] = *(const float4*)&v[g];
  }
  __syncthreads();
#pragma unroll
  for (int j=0;j<8;j++){
    int f4=tid+j*256, r=f4>>5, c4=(f4&31)<<2;
    size_t g=(size_t)(c*64+r)*2048 + h*128 + c4;
    float4 bv=*(const float4*)&bw[g];
    float4 cgv=*(const float4*)&cg[g];
    float4 u;
    u.x=bv.x*__expf(Gt[c4+0]-cgv.x);
    u.y=bv.y*__expf(Gt[c4+1]-cgv.y);
    u.z=bv.z*__expf(Gt[c4+2]-cgv.z);
    u.w=bv.w*__expf(Gt[c4+3]-cgv.w);
    *(float4*)&Us[r][c4]=u;
  }
  __syncthreads();
  const int d0 = tid>>3, p = tid&7;   // rows {d0+32j}, cols {4p+32jj+x}
  // GEMM1: DSk[d][m] = sum_s K[s][d]*U[s][m]
  {
    float acc[4][16];
#pragma unroll
    for (int j=0;j<4;j++)
#pragma unroll
      for (int e=0;e<16;e++) acc[j][e]=0.f;
    for (int s=0;s<64;s++){
      float kv[4];
#pragma unroll
      for (int j=0;j<4;j++) kv[j] = Ks[s][d0+32*j];
#pragma unroll
      for (int jj=0;jj<4;jj++){
        float4 u4 = *(float4*)&Us[s][4*p+32*jj];
#pragma unroll
        for (int j=0;j<4;j++){
          acc[j][jj*4+0]+=kv[j]*u4.x; acc[j][jj*4+1]+=kv[j]*u4.y;
          acc[j][jj*4+2]+=kv[j]*u4.z; acc[j][jj*4+3]+=kv[j]*u4.w;
        }
      }
    }
#pragma unroll
    for (int j=0;j<4;j++)
#pragma unroll
      for (int jj=0;jj<4;jj++){
        float4 st = {acc[j][jj*4+0],acc[j][jj*4+1],acc[j][jj*4+2],acc[j][jj*4+3]};
        *(float4*)&DSk[(size_t)bx*16384 + (size_t)(d0+32*j)*128 + 4*p+32*jj] = st;
      }
  }
  // GEMM2: DSv[m][v] = sum_s U[s][m]*V[s][v]
  {
    float acc[4][16];
#pragma unroll
    for (int j=0;j<4;j++)
#pragma unroll
      for (int e=0;e<16;e++) acc[j][e]=0.f;
    for (int s=0;s<64;s++){
      float uv[4];
#pragma unroll
      for (int j=0;j<4;j++) uv[j] = Us[s][d0+32*j];
#pragma unroll
      for (int jj=0;jj<4;jj++){
        float4 v4 = *(float4*)&Vs[s][4*p+32*jj];
#pragma unroll
        for (int j=0;j<4;j++){
          acc[j][jj*4+0]+=uv[j]*v4.x; acc[j][jj*4+1]+=uv[j]*v4.y;
          acc[j][jj*4+2]+=uv[j]*v4.z; acc[j][jj*4+3]+=uv[j]*v4.w;
        }
      }
    }
#pragma unroll
    for (int j=0;j<4;j++)
#pragma unroll
      for (int jj=0;jj<4;jj++){
        float4 st = {acc[j][jj*4+0],acc[j][jj*4+1],acc[j][jj*4+2],acc[j][jj*4+3]};
        *(float4*)&DSv[(size_t)bx*16384 + (size_t)(d0+32*j)*128 + 4*p+32*jj] = st;
      }
  }
}

// ---------------- Phase B: sequential cross-chunk state combine ----------------
__global__ __launch_bounds__(256)
void phaseB_k(const float* __restrict__ DSk, const float* __restrict__ DSv,
              const float* __restrict__ cg, float* __restrict__ Sk0, float* __restrict__ Sv0){
  unsigned idx = blockIdx.x*256u + threadIdx.x;   // 524288 total
  int sel  = idx >> 18;
  int h    = (idx >> 14) & 15;
  int flat = idx & 16383;                 // d*128+m (Sk) or m*128+v (Sv)
  int mdec = sel ? (flat >> 7) : (flat & 127);
  const float* DS = sel ? DSv : DSk;
  float* S = sel ? Sv0 : Sk0;
  float cur = 0.f;
  for (int c=0;c<16;c++){
    size_t sb = ((size_t)(c*16+h))*16384 + flat;
    S[sb] = cur;                           // state BEFORE chunk c
    float gd = __expf(cg[(size_t)(c*64+63)*2048 + h*128 + mdec]);
    cur = cur*gd + DS[sb];
  }
}

// ---------------- Phase C: per-chunk outputs (register-blocked 4-row) ----------------
__global__ __launch_bounds__(256)
void phaseC_k(const float* __restrict__ q, const float* __restrict__ k,
              const float* __restrict__ v, const float* __restrict__ bw,
              const float* __restrict__ cg, const float* __restrict__ Sk0,
              const float* __restrict__ Sv0, float* __restrict__ o){
  __shared__ float Qs[64][133];   // Q, later A'
  __shared__ float Ks[64][133];   // K, later V
  __shared__ float Bws[64][133];  // bw * e^{cgm - cg_s}
  __shared__ float Ss[64][69];    // sqk, later P (masked)
  __shared__ float St[32][133];   // Sk'/Sv' staging tiles
  __shared__ float cgm[128];
  __shared__ float ecgm[128];
  const int bx = blockIdx.x, h = bx&15, c = bx>>4;
  const int tid = threadIdx.x;
  const int i0 = tid>>4, p = tid&15;      // rows {i0+16j}
  const float SCALE = 0.088388347648318447f;   // 128^-0.5
  if (tid < 128){
    float cv_ = cg[(size_t)(c*64+31)*2048 + h*128 + tid];
    cgm[tid] = cv_; ecgm[tid] = __expf(cv_);
  }
#pragma unroll
  for (int j=0;j<8;j++){
    int f4=tid+j*256, r=f4>>5, c4=(f4&31)<<2;
    size_t g=(size_t)(c*64+r)*2048 + h*128 + c4;
    *(float4*)&Qs[r][c4] = *(const float4*)&q[g];
    *(float4*)&Ks[r][c4] = *(const float4*)&k[g];
  }
  __syncthreads();
  // Bws[i][m] = bw[i][m]*exp(cgm[m]-cg[i][m]); map: i2=tid>>2, cols pq*4+16*j8
  {
    const int i2 = tid>>2, pq = tid&3;
    size_t g0 = (size_t)(c*64+i2)*2048 + h*128 + pq*4;
#pragma unroll
    for (int j8=0;j8<8;j8++){
      int mb = pq*4 + 16*j8;
      float4 cgv = *(const float4*)&cg[g0 + 16*j8];
      float4 bwv = *(const float4*)&bw[g0 + 16*j8];
      float4 r4;
      r4.x = bwv.x*__expf(cgm[mb+0]-cgv.x);
      r4.y = bwv.y*__expf(cgm[mb+1]-cgv.y);
      r4.z = bwv.z*__expf(cgm[mb+2]-cgv.z);
      r4.w = bwv.w*__expf(cgm[mb+3]-cgv.w);
      *(float4*)&Bws[i2][mb] = r4;
    }
  }
  __syncthreads();
  // step1: sqk[i][s] = q_i . k_s (masked s<=i); thread: 4 rows x 4 s {p+16jj}
  {
    float a[4][4];
#pragma unroll
    for (int j=0;j<4;j++)
#pragma unroll
      for (int jj=0;jj<4;jj++) a[j][jj]=0.f;
    for (int d4=0; d4<32; ++d4){
      float4 qv[4];
#pragma unroll
      for (int j=0;j<4;j++) qv[j] = *(float4*)&Qs[i0+16*j][d4<<2];
#pragma unroll
      for (int jj=0;jj<4;jj++){
        float4 kv = *(float4*)&Ks[p+16*jj][d4<<2];
#pragma unroll
        for (int j=0;j<4;j++)
          a[j][jj] += qv[j].x*kv.x + qv[j].y*kv.y + qv[j].z*kv.z + qv[j].w*kv.w;
      }
    }
#pragma unroll
    for (int j=0;j<4;j++)
#pragma unroll
      for (int jj=0;jj<4;jj++){
        int s = p+16*jj, ii = i0+16*j;
        Ss[ii][s] = (s<=ii) ? a[j][jj] : 0.f;
      }
  }
  __syncthreads();
  // step2: z[i][m] = Q @ (Sk_start * e^{cgm[m]}); thread cols {4p+64jj+x}
  float z[4][8];
#pragma unroll
  for (int j=0;j<4;j++)
#pragma unroll
    for (int e=0;e<8;e++) z[j][e]=0.f;
  for (int dt=0; dt<4; ++dt){
    if (dt) __syncthreads();
#pragma unroll
    for (int j=0;j<4;j++){
      int f4=tid+j*256, r=f4>>5, c4=(f4&31)<<2;
      float4 sv0 = *(const float4*)&Sk0[(size_t)bx*16384 + (size_t)(dt*32+r)*128 + c4];
      float4 e;
      e.x=sv0.x*ecgm[c4+0]; e.y=sv0.y*ecgm[c4+1]; e.z=sv0.z*ecgm[c4+2]; e.w=sv0.w*ecgm[c4+3];
      *(float4*)&St[r][c4] = e;
    }
    __syncthreads();
    for (int dd=0; dd<32; ++dd){
      float qd[4];
#pragma unroll
      for (int j=0;j<4;j++) qd[j] = Qs[i0+16*j][dt*32+dd];
#pragma unroll
      for (int jj=0;jj<2;jj++){
        float4 s4 = *(float4*)&St[dd][4*p + 64*jj];
#pragma unroll
        for (int j=0;j<4;j++){
          z[j][jj*4+0]+=qd[j]*s4.x; z[j][jj*4+1]+=qd[j]*s4.y;
          z[j][jj*4+2]+=qd[j]*s4.z; z[j][jj*4+3]+=qd[j]*s4.w;
        }
      }
    }
  }
  // step3: z += tril(sqk) @ Bws
  for (int s=0;s<64;s++){
    float pv[4];
#pragma unroll
    for (int j=0;j<4;j++) pv[j] = Ss[i0+16*j][s];
#pragma unroll
    for (int jj=0;jj<2;jj++){
      float4 b4 = *(float4*)&Bws[s][4*p + 64*jj];
#pragma unroll
      for (int j=0;j<4;j++){
        z[j][jj*4+0]+=pv[j]*b4.x; z[j][jj*4+1]+=pv[j]*b4.y;
        z[j][jj*4+2]+=pv[j]*b4.z; z[j][jj*4+3]+=pv[j]*b4.w;
      }
    }
  }
  // dec[j][e] = exp(cg[i][m] - cgm[m]) for own (row, m) pairs
  float dec[4][8];
#pragma unroll
  for (int j=0;j<4;j++){
    size_t gr = (size_t)(c*64 + i0+16*j)*2048 + h*128;
#pragma unroll
    for (int jj=0;jj<2;jj++){
      int mb = 4*p + 64*jj;
      float4 cgv = *(const float4*)&cg[gr + mb];
      dec[j][jj*4+0] = __expf(cgv.x - cgm[mb+0]);
      dec[j][jj*4+1] = __expf(cgv.y - cgm[mb+1]);
      dec[j][jj*4+2] = __expf(cgv.z - cgm[mb+2]);
      dec[j][jj*4+3] = __expf(cgv.w - cgm[mb+3]);
    }
  }
  // softmax over m (per row): own 8 + shfl over p lanes (bits 0..3)
  float av_[4][8];
#pragma unroll
  for (int j=0;j<4;j++){
    float mx = -3.0e38f;
#pragma unroll
    for (int e=0;e<8;e++){ z[j][e] = SCALE*dec[j][e]*z[j][e]; mx = fmaxf(mx, z[j][e]); }
    mx = fmaxf(mx, __shfl_xor(mx,1)); mx = fmaxf(mx, __shfl_xor(mx,2));
    mx = fmaxf(mx, __shfl_xor(mx,4)); mx = fmaxf(mx, __shfl_xor(mx,8));
    float ssum = 0.f;
#pragma unroll
    for (int e=0;e<8;e++){ z[j][e] = __expf(z[j][e]-mx); ssum += z[j][e]; }
    ssum += __shfl_xor(ssum,1); ssum += __shfl_xor(ssum,2);
    ssum += __shfl_xor(ssum,4); ssum += __shfl_xor(ssum,8);
    float inv = 1.f/ssum;
#pragma unroll
    for (int e=0;e<8;e++) av_[j][e] = z[j][e]*inv*dec[j][e];   // A' = a * e^{cg_i - cgm}
  }
  __syncthreads();   // all threads done reading Qs (step2) and St
  // store A' into Qs; stage V into Ks (K dead since step1)
#pragma unroll
  for (int j=0;j<4;j++)
#pragma unroll
    for (int jj=0;jj<2;jj++){
      float4 a4 = {av_[j][jj*4+0],av_[j][jj*4+1],av_[j][jj*4+2],av_[j][jj*4+3]};
      *(float4*)&Qs[i0+16*j][4*p + 64*jj] = a4;
    }
#pragma unroll
  for (int j=0;j<8;j++){
    int f4=tid+j*256, r=f4>>5, c4=(f4&31)<<2;
    *(float4*)&Ks[r][c4] = *(const float4*)&v[(size_t)(c*64+r)*2048 + h*128 + c4];
  }
  __syncthreads();
  // step4: P[i][s] = A'[i,:] . Bws[s,:]  (masked) -> Ss
  {
    float a[4][4];
#pragma unroll
    for (int j=0;j<4;j++)
#pragma unroll
      for (int jj=0;jj<4;jj++) a[j][jj]=0.f;
    for (int m4=0;m4<32;m4++){
      float4 avv[4];
#pragma unroll
      for (int j=0;j<4;j++) avv[j] = *(float4*)&Qs[i0+16*j][m4<<2];
#pragma unroll
      for (int jj=0;jj<4;jj++){
        float4 b4 = *(float4*)&Bws[p+16*jj][m4<<2];
#pragma unroll
        for (int j=0;j<4;j++)
          a[j][jj] += avv[j].x*b4.x + avv[j].y*b4.y + avv[j].z*b4.z + avv[j].w*b4.w;
      }
    }
#pragma unroll
    for (int j=0;j<4;j++)
#pragma unroll
      for (int jj=0;jj<4;jj++){
        int s = p+16*jj, ii = i0+16*j;
        Ss[ii][s] = (s<=ii) ? a[j][jj] : 0.f;
      }
  }
  __syncthreads();
  // step5: o = P @ V
#pragma unroll
  for (int j=0;j<4;j++)
#pragma unroll
    for (int e=0;e<8;e++) z[j][e]=0.f;
  for (int s=0;s<64;s++){
    float pv[4];
#pragma unroll
    for (int j=0;j<4;j++) pv[j] = Ss[i0+16*j][s];
#pragma unroll
    for (int jj=0;jj<2;jj++){
      float4 v4 = *(float4*)&Ks[s][4*p + 64*jj];
#pragma unroll
      for (int j=0;j<4;j++){
        z[j][jj*4+0]+=pv[j]*v4.x; z[j][jj*4+1]+=pv[j]*v4.y;
        z[j][jj*4+2]+=pv[j]*v4.z; z[j][jj*4+3]+=pv[j]*v4.w;
      }
    }
  }
  // step6: o += A' @ (e^{cgm[m]} * Sv_start)
  for (int mt=0; mt<4; ++mt){
    __syncthreads();
#pragma unroll
    for (int j=0;j<4;j++){
      int f4=tid+j*256, r=f4>>5, c4=(f4&31)<<2;
      float4 sv0 = *(const float4*)&Sv0[(size_t)bx*16384 + (size_t)(mt*32+r)*128 + c4];
      float em = ecgm[mt*32+r];
      float4 e = {sv0.x*em, sv0.y*em, sv0.z*em, sv0.w*em};
      *(float4*)&St[r][c4] = e;
    }
    __syncthreads();
    for (int mm=0;mm<32;mm++){
      float aa[4];
#pragma unroll
      for (int j=0;j<4;j++) aa[j] = Qs[i0+16*j][mt*32+mm];
#pragma unroll
      for (int jj=0;jj<2;jj++){
        float4 s4 = *(float4*)&St[mm][4*p + 64*jj];
#pragma unroll
        for (int j=0;j<4;j++){
          z[j][jj*4+0]+=aa[j]*s4.x; z[j][jj*4+1]+=aa[j]*s4.y;
          z[j][jj*4+2]+=aa[j]*s4.z; z[j][jj*4+3]+=aa[j]*s4.w;
        }
      }
    }
  }
#pragma unroll
  for (int j=0;j<4;j++){
    size_t ob = (size_t)(c*64 + i0+16*j)*2048 + h*128;
#pragma unroll
    for (int jj=0;jj<2;jj++){
      float4 ov = {z[j][jj*4+0], z[j][jj*4+1], z[j][jj*4+2], z[j][jj*4+3]};
      *(float4*)&o[ob + 4*p + 64*jj] = ov;
    }
  }
}

// ---------------- gated RMSNorm -> bf16 ----------------
__global__ __launch_bounds__(256)
void norm_k(const float* __restrict__ o, const float* __restrict__ gate,
            const float* __restrict__ bg2, const float* __restrict__ nw,
            u16* __restrict__ Obf){
  int row = blockIdx.x*4 + (threadIdx.x>>6);
  int lane = threadIdx.x & 63;
  int t = row >> 4, h = row & 15;
  size_t base = (size_t)t*2048 + h*128;
  float o0 = o[base+lane], o1 = o[base+64+lane];
  float ss = o0*o0 + o1*o1;
#pragma unroll
  for (int off=1;off<64;off<<=1) ss += __shfl_xor(ss, off);
  float r = rsqrtf(ss*(1.f/128.f) + 1e-5f);
  int hv0 = h*128+lane, hv1 = hv0+64;
  float g0 = gate[base+lane]    + bg2[hv0];
  float g1 = gate[base+64+lane] + bg2[hv1];
  float v0 = o0*r*nw[lane]   *(1.f/(1.f+__expf(-g0)));
  float v1 = o1*r*nw[lane+64]*(1.f/(1.f+__expf(-g1)));
  Obf[base+lane]    = f2bf(v0);
  Obf[base+64+lane] = f2bf(v1);
}

extern "C" void kernel_launch(void* const* d_in, const int* in_sizes, int n_in,
                              void* d_out, int out_size, void* d_ws, size_t ws_size,
                              hipStream_t stream){
  (void)in_sizes; (void)n_in; (void)out_size; (void)ws_size;
  const float* hX   = (const float*)d_in[0];
  const float* Wq   = (const float*)d_in[1];
  const float* Wk   = (const float*)d_in[2];
  const float* Wv   = (const float*)d_in[3];
  const float* Ww   = (const float*)d_in[4];
  const float* cq   = (const float*)d_in[5];
  const float* ck   = (const float*)d_in[6];
  const float* cv   = (const float*)d_in[7];
  const float* Wf1  = (const float*)d_in[8];
  const float* Wf2  = (const float*)d_in[9];
  const float* Wb   = (const float*)d_in[10];
  const float* Wg1  = (const float*)d_in[11];
  const float* Wg2  = (const float*)d_in[12];
  const float* bg2  = (const float*)d_in[13];
  const float* nw   = (const float*)d_in[14];
  const float* Wo   = (const float*)d_in[15];
  char* ws = (char*)d_ws;
  u16*   h_bf  = (u16*)  (ws + 0);
  u16*   WcatT = (u16*)  (ws + 4194304);
  float* Sk0   = (float*)(ws + 4194304);            // reuses WcatT after G1
  float* Sv0   = (float*)(ws + 4194304 + 16777216);
  u16*   WoT   = (u16*)  (ws + 37748736);
  u16*   WfgT  = (u16*)  (ws + 46137344);
  u16*   Wf2T  = (u16*)  (ws + 47185920);
  u16*   Wg2T  = (u16*)  (ws + 47710208);
  float* qkvw  = (float*)(ws + 48234496);
  float* DSk   = (float*)(ws + 48234496);           // reuses qkvw after conv
  float* DSv   = (float*)(ws + 48234496 + 16777216);
  float* qb    = (float*)(ws + 81788928);
  float* kb    = (float*)(ws + 90177536);
  float* vb    = (float*)(ws + 98566144);
  float* wcv   = (float*)(ws + 106954752);
  float* osc   = wcv;                               // reuses wconv after l2bw
  float* bwb   = (float*)(ws + 115343360);
  u16*   f1g1  = (u16*)  (ws + 123731968);
  float* gpre  = (float*)(ws + 124256256);
  float* gateb = gpre;                              // reuses gpre after cg
  float* cgb   = (float*)(ws + 132644864);
  float* betab = (float*)(ws + 141033472);
  u16*   Obf   = (u16*)  (ws + 141099008);
  float* outp  = (float*)d_out;

  // conversions
  f2bf_k<<<2048,256,0,stream>>>(hX, h_bf);
  transp_k<<<dim3(64,64),256,0,stream>>>(Wq, WcatT + (size_t)0*2048*2048, 2048, 2048);
  transp_k<<<dim3(64,64),256,0,stream>>>(Wk, WcatT + (size_t)1*2048*2048, 2048, 2048);
  transp_k<<<dim3(64,64),256,0,stream>>>(Wv, WcatT + (size_t)2*2048*2048, 2048, 2048);
  transp_k<<<dim3(64,64),256,0,stream>>>(Ww, WcatT + (size_t)3*2048*2048, 2048, 2048);
  transp_k<<<dim3(64,64),256,0,stream>>>(Wo, WoT, 2048, 2048);
  transp_k<<<dim3(4,64), 256,0,stream>>>(Wf1, WfgT, 2048, 128);
  transp_k<<<dim3(4,64), 256,0,stream>>>(Wg1, WfgT + (size_t)128*2048, 2048, 128);
  transp_k<<<dim3(64,4), 256,0,stream>>>(Wf2, Wf2T, 128, 2048);
  transp_k<<<dim3(64,4), 256,0,stream>>>(Wg2, Wg2T, 128, 2048);

  // projections
  gemm_k<false><<<dim3(64,8),256,0,stream>>>(h_bf, WcatT, qkvw, 2048, 2048, 2048, 8192);
  gemm_k<true ><<<dim3(2,8), 256,0,stream>>>(h_bf, WfgT, f1g1, 2048, 2048, 2048, 256);
  gemm_k<false><<<dim3(16,8),256,0,stream>>>(f1g1, Wf2T, gpre, 128, 256, 128, 2048);
  beta_k<<<1024,256,0,stream>>>(hX, Wb, betab);

  // conv + silu, l2norm*beta, chunk cumsum of logsigmoid
  conv_k<<<8192,256,0,stream>>>(qkvw, cq, ck, cv, qb, kb, vb, wcv);
  l2bw_k<<<4096,256,0,stream>>>(wcv, betab, bwb);
  cg_k<<<128,256,0,stream>>>(gpre, cgb);

  // gate GEMM (into gpre buffer, safe after cg)
  gemm_k<false><<<dim3(16,8),256,0,stream>>>(f1g1 + 128, Wg2T, gateb, 128, 256, 128, 2048);

  // chunked scan
  phaseA_k<<<256,256,0,stream>>>(kb, vb, bwb, cgb, DSk, DSv);
  phaseB_k<<<2048,256,0,stream>>>(DSk, DSv, cgb, Sk0, Sv0);
  phaseC_k<<<256,256,0,stream>>>(qb, kb, vb, bwb, cgb, Sk0, Sv0, osc);

  // gated RMSNorm + output projection
  norm_k<<<4096,256,0,stream>>>(osc, gateb, bg2, nw, Obf);
  gemm_k<false><<<dim3(16,8),256,0,stream>>>(Obf, WoT, outp, 2048, 2048, 2048, 2048);
}

// Round 3
// 379.968 us; speedup vs baseline: 2.2169x; 2.2169x over previous
//
#include <hip/hip_runtime.h>
#include <hip/hip_bf16.h>
#include <stdint.h>

typedef unsigned short u16;
typedef __attribute__((ext_vector_type(8))) short bf16x8;
typedef __attribute__((ext_vector_type(4))) float f32x4;

#define DEV static __device__ __forceinline__

DEV u16 f2bf(float f){
  union { float f; unsigned u; } x; x.f = f;
  unsigned r = x.u + 0x7fffu + ((x.u >> 16) & 1u);
  return (u16)(r >> 16);
}

DEV void g2l16(const void* g, void* l){
  __builtin_amdgcn_global_load_lds((const __attribute__((address_space(1))) unsigned int*)g,
                                   (__attribute__((address_space(3))) unsigned int*)l,
                                   16, 0, 0);
}

// ---------------- f32 -> bf16 straight convert ----------------
__global__ __launch_bounds__(256)
void f2bf_k(const float* __restrict__ in, u16* __restrict__ out){
  int idx = blockIdx.x*256 + threadIdx.x;
  float4 v = *(const float4*)&in[(size_t)idx*4];
  u16 a = f2bf(v.x), b = f2bf(v.y), c = f2bf(v.z), d = f2bf(v.w);
  ushort4 o4; o4.x=a; o4.y=b; o4.z=c; o4.w=d;
  *(ushort4*)&out[(size_t)idx*4] = o4;
}

// ---------------- f32 [R][C] -> bf16 [C][R] transpose ----------------
__global__ __launch_bounds__(256)
void transp_k(const float* __restrict__ in, u16* __restrict__ out, int R, int C){
  __shared__ float tile[32][33];
  const int c0 = blockIdx.x*32, r0 = blockIdx.y*32;
  const int x = threadIdx.x & 31, y0 = threadIdx.x >> 5;
#pragma unroll
  for (int j=0;j<4;j++){
    int r = y0 + j*8;
    tile[r][x] = in[(size_t)(r0+r)*C + c0 + x];
  }
  __syncthreads();
#pragma unroll
  for (int j=0;j<4;j++){
    int cc = y0 + j*8;
    out[(size_t)(c0+cc)*R + r0 + x] = f2bf(tile[x][cc]);
  }
}

// ---------------- bf16 GEMM: A[M,K] (row, lda), B^T[N,K] (row, ldb) -> C[M,N] ----------------
template<bool OBF>
__global__ __launch_bounds__(256)
void gemm_k(const u16* __restrict__ A, const u16* __restrict__ B, void* __restrict__ Cp,
            int K, int lda, int ldb, int ldc){
  __shared__ u16 As[128*32];
  __shared__ u16 Bs[128*32];
  const int m0 = blockIdx.y*128, n0 = blockIdx.x*128;
  const int tid = threadIdx.x;
  const int lane = tid & 63, wave = tid >> 6;
  const int wr = wave >> 1, wc = wave & 1;
  const int lr = lane & 15, kg = lane >> 4;
  const f32x4 vzero = {0.f,0.f,0.f,0.f};
  f32x4 acc[4][4];
#pragma unroll
  for (int a=0;a<4;a++)
#pragma unroll
    for (int b=0;b<4;b++) acc[a][b] = vzero;
  const int r0 = tid>>2, s0 = tid&3;
  for (int k0=0;k0<K;k0+=32){
    __syncthreads();
    g2l16(A + (size_t)(m0+r0)*lda + k0 + s0*8, (u16*)As + (size_t)tid*8);
    g2l16(B + (size_t)(n0+r0)*ldb + k0 + s0*8, (u16*)Bs + (size_t)tid*8);
    g2l16(A + (size_t)(m0+r0+64)*lda + k0 + s0*8, (u16*)As + (size_t)(tid+256)*8);
    g2l16(B + (size_t)(n0+r0+64)*ldb + k0 + s0*8, (u16*)Bs + (size_t)(tid+256)*8);
    __syncthreads();
    bf16x8 af[4], bfv[4];
#pragma unroll
    for (int mi=0;mi<4;mi++) af[mi]  = *(const bf16x8*)(As + (wr*64+mi*16+lr)*32 + kg*8);
#pragma unroll
    for (int ni=0;ni<4;ni++) bfv[ni] = *(const bf16x8*)(Bs + (wc*64+ni*16+lr)*32 + kg*8);
#pragma unroll
    for (int mi=0;mi<4;mi++)
#pragma unroll
      for (int ni=0;ni<4;ni++)
        acc[mi][ni] = __builtin_amdgcn_mfma_f32_16x16x32_bf16(af[mi], bfv[ni], acc[mi][ni], 0, 0, 0);
  }
#pragma unroll
  for (int mi=0;mi<4;mi++)
#pragma unroll
    for (int ni=0;ni<4;ni++)
#pragma unroll
      for (int vv=0;vv<4;vv++){
        int row = m0 + wr*64 + mi*16 + kg*4 + vv;
        int col = n0 + wc*64 + ni*16 + lr;
        float val = acc[mi][ni][vv];
        if (OBF) ((u16*)Cp)[(size_t)row*ldc + col] = f2bf(val);
        else     ((float*)Cp)[(size_t)row*ldc + col] = val;
      }
}

// ---------------- beta = sigmoid(h @ Wb), per-t block ----------------
__global__ __launch_bounds__(256)
void beta_k(const float* __restrict__ h, const float* __restrict__ Wb, float* __restrict__ betab){
  __shared__ float hrow[2048];
  __shared__ float red[16][5];
  const int t = blockIdx.x, tid = threadIdx.x;
#pragma unroll
  for (int j=0;j<8;j++) hrow[tid + j*256] = h[(size_t)t*2048 + tid + j*256];
  __syncthreads();
  float part[16];
#pragma unroll
  for (int n=0;n<16;n++) part[n]=0.f;
  for (int j=0;j<8;j++){
    int kk = tid + j*256;
    float hv = hrow[kk];
    const float4* wr4 = (const float4*)&Wb[(size_t)kk*16];
    float4 w0=wr4[0], w1=wr4[1], w2=wr4[2], w3=wr4[3];
    part[0]+=hv*w0.x; part[1]+=hv*w0.y; part[2]+=hv*w0.z; part[3]+=hv*w0.w;
    part[4]+=hv*w1.x; part[5]+=hv*w1.y; part[6]+=hv*w1.z; part[7]+=hv*w1.w;
    part[8]+=hv*w2.x; part[9]+=hv*w2.y; part[10]+=hv*w2.z; part[11]+=hv*w2.w;
    part[12]+=hv*w3.x; part[13]+=hv*w3.y; part[14]+=hv*w3.z; part[15]+=hv*w3.w;
  }
#pragma unroll
  for (int n=0;n<16;n++){
    float s = part[n];
#pragma unroll
    for (int off=1;off<64;off<<=1) s += __shfl_xor(s, off);
    if ((tid&63)==0) red[n][tid>>6] = s;
  }
  __syncthreads();
  if (tid < 16){
    float s = red[tid][0]+red[tid][1]+red[tid][2]+red[tid][3];
    betab[t*16+tid] = 1.f/(1.f+__expf(-s));
  }
}

// ---------------- causal conv4 + silu on concatenated qkvw ----------------
__global__ __launch_bounds__(256)
void conv_k(const float* __restrict__ raw, const float* __restrict__ cq,
            const float* __restrict__ ck, const float* __restrict__ cv,
            float* __restrict__ qo, float* __restrict__ ko,
            float* __restrict__ vo, float* __restrict__ wo){
  int idx = blockIdx.x*256 + threadIdx.x;
  int cgl = idx & 8191, tb = idx >> 13;
  int which = cgl >> 11, cc = cgl & 2047;
  const float* wt = (which==0)?cq:((which==1)?ck:cv);   // w-branch (3) uses cv (faithful to ref)
  float4 w4 = *(const float4*)&wt[cc*4];
  float* out = (which==0)?qo:((which==1)?ko:((which==2)?vo:wo));
  int t0 = tb*4;
  float x[7];
#pragma unroll
  for (int j=0;j<7;j++){
    int t = t0 - 3 + j;
    x[j] = (t >= 0) ? raw[(size_t)t*8192 + cgl] : 0.f;
  }
#pragma unroll
  for (int j=0;j<4;j++){
    float y = x[j]*w4.x + x[j+1]*w4.y + x[j+2]*w4.z + x[j+3]*w4.w;
    y = y / (1.f + __expf(-y));           // silu
    out[(size_t)(t0+j)*2048 + cc] = y;
  }
}

// ---------------- l2norm over M + beta scale: bw ----------------
__global__ __launch_bounds__(256)
void l2bw_k(const float* __restrict__ wconv, const float* __restrict__ betab,
            float* __restrict__ bwout){
  int row = blockIdx.x*4 + (threadIdx.x>>6);
  int lane = threadIdx.x & 63;
  int t = row >> 4, h = row & 15;
  size_t base = (size_t)t*2048 + h*128;
  float a0 = wconv[base+lane], a1 = wconv[base+64+lane];
  float ss = a0*a0 + a1*a1;
#pragma unroll
  for (int off=1;off<64;off<<=1) ss += __shfl_xor(ss, off);
  float r = rsqrtf(ss + 1e-6f) * betab[t*16+h];
  bwout[base+lane]    = a0*r;
  bwout[base+64+lane] = a1*r;
}

// ---------------- per-chunk inclusive cumsum of logsigmoid(gpre) ----------------
__global__ __launch_bounds__(256)
void cg_k(const float* __restrict__ gpre, float* __restrict__ cg){
  int idx = blockIdx.x*256 + threadIdx.x;   // 32768 = c*2048 + h*128 + m
  int m = idx & 127, h = (idx>>7) & 15, c = idx >> 11;
  size_t base = (size_t)h*128 + m;
  float run = 0.f;
  for (int i2=0;i2<64;i2++){
    size_t t = (size_t)c*64 + i2;
    float x = gpre[t*2048 + base];
    float lg = (x >= 0.f) ? (-log1pf(__expf(-x))) : (x - log1pf(__expf(x)));
    run += lg;
    cg[t*2048 + base] = run;
  }
}

// ---------------- Phase A: per-chunk state deltas (register-blocked 4x16) ----------------
__global__ __launch_bounds__(256)
void phaseA_k(const float* __restrict__ k, const float* __restrict__ v,
              const float* __restrict__ bw, const float* __restrict__ cg,
              float* __restrict__ DSk, float* __restrict__ DSv){
  __shared__ float Ks[64][132];
  __shared__ float Vs[64][132];
  __shared__ float Us[64][132];
  __shared__ float Gt[128];
  const int bx=blockIdx.x, h=bx&15, c=bx>>4, tid=threadIdx.x;
  if (tid < 128) Gt[tid] = cg[(size_t)(c*64+63)*2048 + h*128 + tid];
#pragma unroll
  for (int j=0;j<8;j++){
    int f4=tid+j*256, r=f4>>5, c4=(f4&31)<<2;
    size_t g=(size_t)(c*64+r)*2048 + h*128 + c4;
    *(float4*)&Ks[r][c4] = *(const float4*)&k[g];
    *(float4*)&Vs[r][c4] = *(const float4*)&v[g];
  }
  __syncthreads();
#pragma unroll
  for (int j=0;j<8;j++){
    int f4=tid+j*256, r=f4>>5, c4=(f4&31)<<2;
    size_t g=(size_t)(c*64+r)*2048 + h*128 + c4;
    float4 bv=*(const float4*)&bw[g];
    float4 cgv=*(const float4*)&cg[g];
    float4 u;
    u.x=bv.x*__expf(Gt[c4+0]-cgv.x);
    u.y=bv.y*__expf(Gt[c4+1]-cgv.y);
    u.z=bv.z*__expf(Gt[c4+2]-cgv.z);
    u.w=bv.w*__expf(Gt[c4+3]-cgv.w);
    *(float4*)&Us[r][c4]=u;
  }
  __syncthreads();
  const int d0 = tid>>3, p = tid&7;   // rows {d0+32j}, cols {4p+32jj+x}
  // GEMM1: DSk[d][m] = sum_s K[s][d]*U[s][m]
  {
    float acc[4][16];
#pragma unroll
    for (int j=0;j<4;j++)
#pragma unroll
      for (int e=0;e<16;e++) acc[j][e]=0.f;
    for (int s=0;s<64;s++){
      float kv[4];
#pragma unroll
      for (int j=0;j<4;j++) kv[j] = Ks[s][d0+32*j];
#pragma unroll
      for (int jj=0;jj<4;jj++){
        float4 u4 = *(float4*)&Us[s][4*p+32*jj];
#pragma unroll
        for (int j=0;j<4;j++){
          acc[j][jj*4+0]+=kv[j]*u4.x; acc[j][jj*4+1]+=kv[j]*u4.y;
          acc[j][jj*4+2]+=kv[j]*u4.z; acc[j][jj*4+3]+=kv[j]*u4.w;
        }
      }
    }
#pragma unroll
    for (int j=0;j<4;j++)
#pragma unroll
      for (int jj=0;jj<4;jj++){
        float4 st = {acc[j][jj*4+0],acc[j][jj*4+1],acc[j][jj*4+2],acc[j][jj*4+3]};
        *(float4*)&DSk[(size_t)bx*16384 + (size_t)(d0+32*j)*128 + 4*p+32*jj] = st;
      }
  }
  // GEMM2: DSv[m][v] = sum_s U[s][m]*V[s][v]
  {
    float acc[4][16];
#pragma unroll
    for (int j=0;j<4;j++)
#pragma unroll
      for (int e=0;e<16;e++) acc[j][e]=0.f;
    for (int s=0;s<64;s++){
      float uv[4];
#pragma unroll
      for (int j=0;j<4;j++) uv[j] = Us[s][d0+32*j];
#pragma unroll
      for (int jj=0;jj<4;jj++){
        float4 v4 = *(float4*)&Vs[s][4*p+32*jj];
#pragma unroll
        for (int j=0;j<4;j++){
          acc[j][jj*4+0]+=uv[j]*v4.x; acc[j][jj*4+1]+=uv[j]*v4.y;
          acc[j][jj*4+2]+=uv[j]*v4.z; acc[j][jj*4+3]+=uv[j]*v4.w;
        }
      }
    }
#pragma unroll
    for (int j=0;j<4;j++)
#pragma unroll
      for (int jj=0;jj<4;jj++){
        float4 st = {acc[j][jj*4+0],acc[j][jj*4+1],acc[j][jj*4+2],acc[j][jj*4+3]};
        *(float4*)&DSv[(size_t)bx*16384 + (size_t)(d0+32*j)*128 + 4*p+32*jj] = st;
      }
  }
}

// ---------------- Phase B: sequential cross-chunk state combine ----------------
__global__ __launch_bounds__(256)
void phaseB_k(const float* __restrict__ DSk, const float* __restrict__ DSv,
              const float* __restrict__ cg, float* __restrict__ Sk0, float* __restrict__ Sv0){
  unsigned idx = blockIdx.x*256u + threadIdx.x;   // 524288 total
  int sel  = idx >> 18;
  int h    = (idx >> 14) & 15;
  int flat = idx & 16383;                 // d*128+m (Sk) or m*128+v (Sv)
  int mdec = sel ? (flat >> 7) : (flat & 127);
  const float* DS = sel ? DSv : DSk;
  float* S = sel ? Sv0 : Sk0;
  float cur = 0.f;
  for (int c=0;c<16;c++){
    size_t sb = ((size_t)(c*16+h))*16384 + flat;
    S[sb] = cur;                           // state BEFORE chunk c
    float gd = __expf(cg[(size_t)(c*64+63)*2048 + h*128 + mdec]);
    cur = cur*gd + DS[sb];
  }
}

// ---------------- Phase C: per-chunk outputs (2-row x 16-col, spill-safe) ----------------
__global__ __launch_bounds__(256)
void phaseC_k(const float* __restrict__ q, const float* __restrict__ k,
              const float* __restrict__ v, const float* __restrict__ bw,
              const float* __restrict__ cg, const float* __restrict__ Sk0,
              const float* __restrict__ Sv0, float* __restrict__ o){
  __shared__ float Qs[64][132];   // Q, later A'
  __shared__ float Ks[64][132];   // K, later V
  __shared__ float Bws[64][132];  // bw * e^{cgm - cg_s}
  __shared__ float Ss[64][68];    // sqk, later P (masked)
  __shared__ float St[32][132];   // Sk'/Sv' staging tiles
  __shared__ float cgm[128];
  __shared__ float ecgm[128];
  const int bx = blockIdx.x, h = bx&15, c = bx>>4;
  const int tid = threadIdx.x;
  const int i0 = tid>>3, p = tid&7;       // 2-row x 16-col: rows {i0, i0+32}, cols {4p+32jj}
  const int r4 = tid>>4, p16 = tid&15;    // 4-row x 4-s map for steps 1/4
  const float SCALE = 0.088388347648318447f;   // 128^-0.5
  if (tid < 128){
    float cv_ = cg[(size_t)(c*64+31)*2048 + h*128 + tid];
    cgm[tid] = cv_; ecgm[tid] = __expf(cv_);
  }
#pragma unroll
  for (int j=0;j<8;j++){
    int f4=tid+j*256, r=f4>>5, c4=(f4&31)<<2;
    size_t g=(size_t)(c*64+r)*2048 + h*128 + c4;
    *(float4*)&Qs[r][c4] = *(const float4*)&q[g];
    *(float4*)&Ks[r][c4] = *(const float4*)&k[g];
  }
  __syncthreads();
  // Bws[i][m] = bw[i][m]*exp(cgm[m]-cg[i][m])
  {
    const int i2 = tid>>2, pq = tid&3;
    size_t g0 = (size_t)(c*64+i2)*2048 + h*128 + pq*4;
#pragma unroll
    for (int j8=0;j8<8;j8++){
      int mb = pq*4 + 16*j8;
      float4 cgv = *(const float4*)&cg[g0 + 16*j8];
      float4 bwv = *(const float4*)&bw[g0 + 16*j8];
      float4 r4v;
      r4v.x = bwv.x*__expf(cgm[mb+0]-cgv.x);
      r4v.y = bwv.y*__expf(cgm[mb+1]-cgv.y);
      r4v.z = bwv.z*__expf(cgm[mb+2]-cgv.z);
      r4v.w = bwv.w*__expf(cgm[mb+3]-cgv.w);
      *(float4*)&Bws[i2][mb] = r4v;
    }
  }
  __syncthreads();
  // step1: sqk[i][s] = q_i . k_s (masked s<=i); 4 rows {r4+16j} x 4 s {p16+16jj}
  {
    float a[4][4];
#pragma unroll
    for (int j=0;j<4;j++)
#pragma unroll
      for (int jj=0;jj<4;jj++) a[j][jj]=0.f;
    for (int d4=0; d4<32; ++d4){
      float4 qv[4];
#pragma unroll
      for (int j=0;j<4;j++) qv[j] = *(float4*)&Qs[r4+16*j][d4<<2];
#pragma unroll
      for (int jj=0;jj<4;jj++){
        float4 kv = *(float4*)&Ks[p16+16*jj][d4<<2];
#pragma unroll
        for (int j=0;j<4;j++)
          a[j][jj] += qv[j].x*kv.x + qv[j].y*kv.y + qv[j].z*kv.z + qv[j].w*kv.w;
      }
    }
#pragma unroll
    for (int j=0;j<4;j++)
#pragma unroll
      for (int jj=0;jj<4;jj++){
        int s = p16+16*jj, ii = r4+16*j;
        Ss[ii][s] = (s<=ii) ? a[j][jj] : 0.f;
      }
  }
  __syncthreads();
  // step2: z[i][m] = Q @ (Sk_start * e^{cgm[m]})
  float z[2][16];
#pragma unroll
  for (int j=0;j<2;j++)
#pragma unroll
    for (int e=0;e<16;e++) z[j][e]=0.f;
  for (int dt=0; dt<4; ++dt){
    if (dt) __syncthreads();
#pragma unroll
    for (int j=0;j<4;j++){
      int f4=tid+j*256, r=f4>>5, c4=(f4&31)<<2;
      float4 sv0 = *(const float4*)&Sk0[(size_t)bx*16384 + (size_t)(dt*32+r)*128 + c4];
      float4 e;
      e.x=sv0.x*ecgm[c4+0]; e.y=sv0.y*ecgm[c4+1]; e.z=sv0.z*ecgm[c4+2]; e.w=sv0.w*ecgm[c4+3];
      *(float4*)&St[r][c4] = e;
    }
    __syncthreads();
    for (int dd4=0; dd4<8; ++dd4){
      float4 qdv[2];
#pragma unroll
      for (int j=0;j<2;j++) qdv[j] = *(float4*)&Qs[i0+32*j][dt*32+4*dd4];
#pragma unroll
      for (int x=0;x<4;x++){
        float qd[2] = { ((float*)&qdv[0])[x], ((float*)&qdv[1])[x] };
#pragma unroll
        for (int jj=0;jj<4;jj++){
          float4 s4 = *(float4*)&St[4*dd4+x][4*p + 32*jj];
#pragma unroll
          for (int j=0;j<2;j++){
            z[j][jj*4+0]+=qd[j]*s4.x; z[j][jj*4+1]+=qd[j]*s4.y;
            z[j][jj*4+2]+=qd[j]*s4.z; z[j][jj*4+3]+=qd[j]*s4.w;
          }
        }
      }
    }
  }
  // step3: z += tril(sqk) @ Bws
  for (int s4_=0; s4_<16; ++s4_){
    float4 pv4[2];
#pragma unroll
    for (int j=0;j<2;j++) pv4[j] = *(float4*)&Ss[i0+32*j][s4_<<2];
#pragma unroll
    for (int x=0;x<4;x++){
      float pv[2] = { ((float*)&pv4[0])[x], ((float*)&pv4[1])[x] };
#pragma unroll
      for (int jj=0;jj<4;jj++){
        float4 b4 = *(float4*)&Bws[(s4_<<2)+x][4*p + 32*jj];
#pragma unroll
        for (int j=0;j<2;j++){
          z[j][jj*4+0]+=pv[j]*b4.x; z[j][jj*4+1]+=pv[j]*b4.y;
          z[j][jj*4+2]+=pv[j]*b4.z; z[j][jj*4+3]+=pv[j]*b4.w;
        }
      }
    }
  }
  // dec[j][e] = exp(cg[i][m] - cgm[m])
  float dec[2][16];
#pragma unroll
  for (int j=0;j<2;j++){
    size_t gr = (size_t)(c*64 + i0+32*j)*2048 + h*128;
#pragma unroll
    for (int jj=0;jj<4;jj++){
      int mb = 4*p + 32*jj;
      float4 cgv = *(const float4*)&cg[gr + mb];
      dec[j][jj*4+0] = __expf(cgv.x - cgm[mb+0]);
      dec[j][jj*4+1] = __expf(cgv.y - cgm[mb+1]);
      dec[j][jj*4+2] = __expf(cgv.z - cgm[mb+2]);
      dec[j][jj*4+3] = __expf(cgv.w - cgm[mb+3]);
    }
  }
  // softmax over m per row: own 16 + shfl over 8 p-lanes
#pragma unroll
  for (int j=0;j<2;j++){
    float mx = -3.0e38f;
#pragma unroll
    for (int e=0;e<16;e++){ z[j][e] = SCALE*dec[j][e]*z[j][e]; mx = fmaxf(mx, z[j][e]); }
    mx = fmaxf(mx, __shfl_xor(mx,1)); mx = fmaxf(mx, __shfl_xor(mx,2));
    mx = fmaxf(mx, __shfl_xor(mx,4));
    float ssum = 0.f;
#pragma unroll
    for (int e=0;e<16;e++){ z[j][e] = __expf(z[j][e]-mx); ssum += z[j][e]; }
    ssum += __shfl_xor(ssum,1); ssum += __shfl_xor(ssum,2);
    ssum += __shfl_xor(ssum,4);
    float inv = 1.f/ssum;
#pragma unroll
    for (int e=0;e<16;e++) z[j][e] *= inv;   // a (normalized)
  }
  __syncthreads();   // all threads done reading Qs (step2) and St
  // store A' = a*dec into Qs; stage V into Ks (K dead since step1)
#pragma unroll
  for (int j=0;j<2;j++)
#pragma unroll
    for (int jj=0;jj<4;jj++){
      float4 a4 = {z[j][jj*4+0]*dec[j][jj*4+0], z[j][jj*4+1]*dec[j][jj*4+1],
                   z[j][jj*4+2]*dec[j][jj*4+2], z[j][jj*4+3]*dec[j][jj*4+3]};
      *(float4*)&Qs[i0+32*j][4*p + 32*jj] = a4;
    }
#pragma unroll
  for (int j=0;j<8;j++){
    int f4=tid+j*256, r=f4>>5, c4=(f4&31)<<2;
    *(float4*)&Ks[r][c4] = *(const float4*)&v[(size_t)(c*64+r)*2048 + h*128 + c4];
  }
  __syncthreads();
  // step4: P[i][s] = A'[i,:] . Bws[s,:]  (masked) -> Ss; 4-row map
  {
    float a[4][4];
#pragma unroll
    for (int j=0;j<4;j++)
#pragma unroll
      for (int jj=0;jj<4;jj++) a[j][jj]=0.f;
    for (int m4=0;m4<32;m4++){
      float4 avv[4];
#pragma unroll
      for (int j=0;j<4;j++) avv[j] = *(float4*)&Qs[r4+16*j][m4<<2];
#pragma unroll
      for (int jj=0;jj<4;jj++){
        float4 b4 = *(float4*)&Bws[p16+16*jj][m4<<2];
#pragma unroll
        for (int j=0;j<4;j++)
          a[j][jj] += avv[j].x*b4.x + avv[j].y*b4.y + avv[j].z*b4.z + avv[j].w*b4.w;
      }
    }
#pragma unroll
    for (int j=0;j<4;j++)
#pragma unroll
      for (int jj=0;jj<4;jj++){
        int s = p16+16*jj, ii = r4+16*j;
        Ss[ii][s] = (s<=ii) ? a[j][jj] : 0.f;
      }
  }
  __syncthreads();
  // step5: o = P @ V
#pragma unroll
  for (int j=0;j<2;j++)
#pragma unroll
    for (int e=0;e<16;e++) z[j][e]=0.f;
  for (int s4_=0; s4_<16; ++s4_){
    float4 pv4[2];
#pragma unroll
    for (int j=0;j<2;j++) pv4[j] = *(float4*)&Ss[i0+32*j][s4_<<2];
#pragma unroll
    for (int x=0;x<4;x++){
      float pv[2] = { ((float*)&pv4[0])[x], ((float*)&pv4[1])[x] };
#pragma unroll
      for (int jj=0;jj<4;jj++){
        float4 v4 = *(float4*)&Ks[(s4_<<2)+x][4*p + 32*jj];
#pragma unroll
        for (int j=0;j<2;j++){
          z[j][jj*4+0]+=pv[j]*v4.x; z[j][jj*4+1]+=pv[j]*v4.y;
          z[j][jj*4+2]+=pv[j]*v4.z; z[j][jj*4+3]+=pv[j]*v4.w;
        }
      }
    }
  }
  // step6: o += A' @ (e^{cgm[m]} * Sv_start)
  for (int mt=0; mt<4; ++mt){
    __syncthreads();
#pragma unroll
    for (int j=0;j<4;j++){
      int f4=tid+j*256, r=f4>>5, c4=(f4&31)<<2;
      float4 sv0 = *(const float4*)&Sv0[(size_t)bx*16384 + (size_t)(mt*32+r)*128 + c4];
      float em = ecgm[mt*32+r];
      float4 e = {sv0.x*em, sv0.y*em, sv0.z*em, sv0.w*em};
      *(float4*)&St[r][c4] = e;
    }
    __syncthreads();
    for (int mm4=0; mm4<8; ++mm4){
      float4 adv[2];
#pragma unroll
      for (int j=0;j<2;j++) adv[j] = *(float4*)&Qs[i0+32*j][mt*32+4*mm4];
#pragma unroll
      for (int x=0;x<4;x++){
        float aa[2] = { ((float*)&adv[0])[x], ((float*)&adv[1])[x] };
#pragma unroll
        for (int jj=0;jj<4;jj++){
          float4 s4 = *(float4*)&St[4*mm4+x][4*p + 32*jj];
#pragma unroll
          for (int j=0;j<2;j++){
            z[j][jj*4+0]+=aa[j]*s4.x; z[j][jj*4+1]+=aa[j]*s4.y;
            z[j][jj*4+2]+=aa[j]*s4.z; z[j][jj*4+3]+=aa[j]*s4.w;
          }
        }
      }
    }
  }
#pragma unroll
  for (int j=0;j<2;j++){
    size_t ob = (size_t)(c*64 + i0+32*j)*2048 + h*128;
#pragma unroll
    for (int jj=0;jj<4;jj++){
      float4 ov = {z[j][jj*4+0], z[j][jj*4+1], z[j][jj*4+2], z[j][jj*4+3]};
      *(float4*)&o[ob + 4*p + 32*jj] = ov;
    }
  }
}

// ---------------- gated RMSNorm -> bf16 ----------------
__global__ __launch_bounds__(256)
void norm_k(const float* __restrict__ o, const float* __restrict__ gate,
            const float* __restrict__ bg2, const float* __restrict__ nw,
            u16* __restrict__ Obf){
  int row = blockIdx.x*4 + (threadIdx.x>>6);
  int lane = threadIdx.x & 63;
  int t = row >> 4, h = row & 15;
  size_t base = (size_t)t*2048 + h*128;
  float o0 = o[base+lane], o1 = o[base+64+lane];
  float ss = o0*o0 + o1*o1;
#pragma unroll
  for (int off=1;off<64;off<<=1) ss += __shfl_xor(ss, off);
  float r = rsqrtf(ss*(1.f/128.f) + 1e-5f);
  int hv0 = h*128+lane, hv1 = hv0+64;
  float g0 = gate[base+lane]    + bg2[hv0];
  float g1 = gate[base+64+lane] + bg2[hv1];
  float v0 = o0*r*nw[lane]   *(1.f/(1.f+__expf(-g0)));
  float v1 = o1*r*nw[lane+64]*(1.f/(1.f+__expf(-g1)));
  Obf[base+lane]    = f2bf(v0);
  Obf[base+64+lane] = f2bf(v1);
}

extern "C" void kernel_launch(void* const* d_in, const int* in_sizes, int n_in,
                              void* d_out, int out_size, void* d_ws, size_t ws_size,
                              hipStream_t stream){
  (void)in_sizes; (void)n_in; (void)out_size; (void)ws_size;
  const float* hX   = (const float*)d_in[0];
  const float* Wq   = (const float*)d_in[1];
  const float* Wk   = (const float*)d_in[2];
  const float* Wv   = (const float*)d_in[3];
  const float* Ww   = (const float*)d_in[4];
  const float* cq   = (const float*)d_in[5];
  const float* ck   = (const float*)d_in[6];
  const float* cv   = (const float*)d_in[7];
  const float* Wf1  = (const float*)d_in[8];
  const float* Wf2  = (const float*)d_in[9];
  const float* Wb   = (const float*)d_in[10];
  const float* Wg1  = (const float*)d_in[11];
  const float* Wg2  = (const float*)d_in[12];
  const float* bg2  = (const float*)d_in[13];
  const float* nw   = (const float*)d_in[14];
  const float* Wo   = (const float*)d_in[15];
  char* ws = (char*)d_ws;
  u16*   h_bf  = (u16*)  (ws + 0);
  u16*   WcatT = (u16*)  (ws + 4194304);
  float* Sk0   = (float*)(ws + 4194304);            // reuses WcatT after G1
  float* Sv0   = (float*)(ws + 4194304 + 16777216);
  u16*   WoT   = (u16*)  (ws + 37748736);
  u16*   WfgT  = (u16*)  (ws + 46137344);
  u16*   Wf2T  = (u16*)  (ws + 47185920);
  u16*   Wg2T  = (u16*)  (ws + 47710208);
  float* qkvw  = (float*)(ws + 48234496);
  float* DSk   = (float*)(ws + 48234496);           // reuses qkvw after conv
  float* DSv   = (float*)(ws + 48234496 + 16777216);
  float* qb    = (float*)(ws + 81788928);
  float* kb    = (float*)(ws + 90177536);
  float* vb    = (float*)(ws + 98566144);
  float* wcv   = (float*)(ws + 106954752);
  float* osc   = wcv;                               // reuses wconv after l2bw
  float* bwb   = (float*)(ws + 115343360);
  u16*   f1g1  = (u16*)  (ws + 123731968);
  float* gpre  = (float*)(ws + 124256256);
  float* gateb = gpre;                              // reuses gpre after cg
  float* cgb   = (float*)(ws + 132644864);
  float* betab = (float*)(ws + 141033472);
  u16*   Obf   = (u16*)  (ws + 141099008);
  float* outp  = (float*)d_out;

  // conversions
  f2bf_k<<<2048,256,0,stream>>>(hX, h_bf);
  transp_k<<<dim3(64,64),256,0,stream>>>(Wq, WcatT + (size_t)0*2048*2048, 2048, 2048);
  transp_k<<<dim3(64,64),256,0,stream>>>(Wk, WcatT + (size_t)1*2048*2048, 2048, 2048);
  transp_k<<<dim3(64,64),256,0,stream>>>(Wv, WcatT + (size_t)2*2048*2048, 2048, 2048);
  transp_k<<<dim3(64,64),256,0,stream>>>(Ww, WcatT + (size_t)3*2048*2048, 2048, 2048);
  transp_k<<<dim3(64,64),256,0,stream>>>(Wo, WoT, 2048, 2048);
  transp_k<<<dim3(4,64), 256,0,stream>>>(Wf1, WfgT, 2048, 128);
  transp_k<<<dim3(4,64), 256,0,stream>>>(Wg1, WfgT + (size_t)128*2048, 2048, 128);
  transp_k<<<dim3(64,4), 256,0,stream>>>(Wf2, Wf2T, 128, 2048);
  transp_k<<<dim3(64,4), 256,0,stream>>>(Wg2, Wg2T, 128, 2048);

  // projections
  gemm_k<false><<<dim3(64,8),256,0,stream>>>(h_bf, WcatT, qkvw, 2048, 2048, 2048, 8192);
  gemm_k<true ><<<dim3(2,8), 256,0,stream>>>(h_bf, WfgT, f1g1, 2048, 2048, 2048, 256);
  gemm_k<false><<<dim3(16,8),256,0,stream>>>(f1g1, Wf2T, gpre, 128, 256, 128, 2048);
  beta_k<<<1024,256,0,stream>>>(hX, Wb, betab);

  // conv + silu, l2norm*beta, chunk cumsum of logsigmoid
  conv_k<<<8192,256,0,stream>>>(qkvw, cq, ck, cv, qb, kb, vb, wcv);
  l2bw_k<<<4096,256,0,stream>>>(wcv, betab, bwb);
  cg_k<<<128,256,0,stream>>>(gpre, cgb);

  // gate GEMM (into gpre buffer, safe after cg)
  gemm_k<false><<<dim3(16,8),256,0,stream>>>(f1g1 + 128, Wg2T, gateb, 128, 256, 128, 2048);

  // chunked scan
  phaseA_k<<<256,256,0,stream>>>(kb, vb, bwb, cgb, DSk, DSv);
  phaseB_k<<<2048,256,0,stream>>>(DSk, DSv, cgb, Sk0, Sv0);
  phaseC_k<<<256,256,0,stream>>>(qb, kb, vb, bwb, cgb, Sk0, Sv0, osc);

  // gated RMSNorm + output projection
  norm_k<<<4096,256,0,stream>>>(osc, gateb, bg2, nw, Obf);
  gemm_k<false><<<dim3(16,8),256,0,stream>>>(Obf, WoT, outp, 2048, 2048, 2048, 2048);
}

// Round 4
// 332.320 us; speedup vs baseline: 2.5348x; 1.1434x over previous
//
#include <hip/hip_runtime.h>
#include <hip/hip_bf16.h>
#include <stdint.h>

typedef unsigned short u16;
typedef __attribute__((ext_vector_type(8))) short bf16x8;
typedef __attribute__((ext_vector_type(4))) short bf16x4;
typedef __attribute__((ext_vector_type(4))) float f32x4;

#define DEV static __device__ __forceinline__

DEV u16 f2bf(float f){
  union { float f; unsigned u; } x; x.f = f;
  unsigned r = x.u + 0x7fffu + ((x.u >> 16) & 1u);
  return (u16)(r >> 16);
}

DEV bf16x8 ldfrag(const u16* p){           // two ds_read_b64 (8B-aligned rows)
  bf16x4 a = *(const bf16x4*)p;
  bf16x4 b = *(const bf16x4*)(p+4);
  bf16x8 r;
  r[0]=a[0]; r[1]=a[1]; r[2]=a[2]; r[3]=a[3];
  r[4]=b[0]; r[5]=b[1]; r[6]=b[2]; r[7]=b[3];
  return r;
}

DEV bf16x4 cvt4(float a, float b, float c, float d){
  bf16x4 r; r[0]=(short)f2bf(a); r[1]=(short)f2bf(b); r[2]=(short)f2bf(c); r[3]=(short)f2bf(d);
  return r;
}

DEV void g2l16(const void* g, void* l){
  __builtin_amdgcn_global_load_lds((const __attribute__((address_space(1))) unsigned int*)g,
                                   (__attribute__((address_space(3))) unsigned int*)l,
                                   16, 0, 0);
}

// ---------------- f32 -> bf16 straight convert ----------------
__global__ __launch_bounds__(256)
void f2bf_k(const float* __restrict__ in, u16* __restrict__ out){
  int idx = blockIdx.x*256 + threadIdx.x;
  float4 v = *(const float4*)&in[(size_t)idx*4];
  u16 a = f2bf(v.x), b = f2bf(v.y), c = f2bf(v.z), d = f2bf(v.w);
  ushort4 o4; o4.x=a; o4.y=b; o4.z=c; o4.w=d;
  *(ushort4*)&out[(size_t)idx*4] = o4;
}

// ---------------- f32 [R][C] -> bf16 [C][R] transpose ----------------
__global__ __launch_bounds__(256)
void transp_k(const float* __restrict__ in, u16* __restrict__ out, int R, int C){
  __shared__ float tile[32][33];
  const int c0 = blockIdx.x*32, r0 = blockIdx.y*32;
  const int x = threadIdx.x & 31, y0 = threadIdx.x >> 5;
#pragma unroll
  for (int j=0;j<4;j++){
    int r = y0 + j*8;
    tile[r][x] = in[(size_t)(r0+r)*C + c0 + x];
  }
  __syncthreads();
#pragma unroll
  for (int j=0;j<4;j++){
    int cc = y0 + j*8;
    out[(size_t)(c0+cc)*R + r0 + x] = f2bf(tile[x][cc]);
  }
}

// ---------------- bf16 GEMM: A[M,K] (row, lda), B^T[N,K] (row, ldb) -> C[M,N] ----------------
template<bool OBF>
__global__ __launch_bounds__(256)
void gemm_k(const u16* __restrict__ A, const u16* __restrict__ B, void* __restrict__ Cp,
            int K, int lda, int ldb, int ldc){
  __shared__ u16 As[128*32];
  __shared__ u16 Bs[128*32];
  const int m0 = blockIdx.y*128, n0 = blockIdx.x*128;
  const int tid = threadIdx.x;
  const int lane = tid & 63, wave = tid >> 6;
  const int wr = wave >> 1, wc = wave & 1;
  const int lr = lane & 15, kg = lane >> 4;
  const f32x4 vzero = {0.f,0.f,0.f,0.f};
  f32x4 acc[4][4];
#pragma unroll
  for (int a=0;a<4;a++)
#pragma unroll
    for (int b=0;b<4;b++) acc[a][b] = vzero;
  const int r0 = tid>>2, s0 = tid&3;
  for (int k0=0;k0<K;k0+=32){
    __syncthreads();
    g2l16(A + (size_t)(m0+r0)*lda + k0 + s0*8, (u16*)As + (size_t)tid*8);
    g2l16(B + (size_t)(n0+r0)*ldb + k0 + s0*8, (u16*)Bs + (size_t)tid*8);
    g2l16(A + (size_t)(m0+r0+64)*lda + k0 + s0*8, (u16*)As + (size_t)(tid+256)*8);
    g2l16(B + (size_t)(n0+r0+64)*ldb + k0 + s0*8, (u16*)Bs + (size_t)(tid+256)*8);
    __syncthreads();
    bf16x8 af[4], bfv[4];
#pragma unroll
    for (int mi=0;mi<4;mi++) af[mi]  = *(const bf16x8*)(As + (wr*64+mi*16+lr)*32 + kg*8);
#pragma unroll
    for (int ni=0;ni<4;ni++) bfv[ni] = *(const bf16x8*)(Bs + (wc*64+ni*16+lr)*32 + kg*8);
#pragma unroll
    for (int mi=0;mi<4;mi++)
#pragma unroll
      for (int ni=0;ni<4;ni++)
        acc[mi][ni] = __builtin_amdgcn_mfma_f32_16x16x32_bf16(af[mi], bfv[ni], acc[mi][ni], 0, 0, 0);
  }
#pragma unroll
  for (int mi=0;mi<4;mi++)
#pragma unroll
    for (int ni=0;ni<4;ni++)
#pragma unroll
      for (int vv=0;vv<4;vv++){
        int row = m0 + wr*64 + mi*16 + kg*4 + vv;
        int col = n0 + wc*64 + ni*16 + lr;
        float val = acc[mi][ni][vv];
        if (OBF) ((u16*)Cp)[(size_t)row*ldc + col] = f2bf(val);
        else     ((float*)Cp)[(size_t)row*ldc + col] = val;
      }
}

// ---------------- beta = sigmoid(h @ Wb), per-t block ----------------
__global__ __launch_bounds__(256)
void beta_k(const float* __restrict__ h, const float* __restrict__ Wb, float* __restrict__ betab){
  __shared__ float hrow[2048];
  __shared__ float red[16][5];
  const int t = blockIdx.x, tid = threadIdx.x;
#pragma unroll
  for (int j=0;j<8;j++) hrow[tid + j*256] = h[(size_t)t*2048 + tid + j*256];
  __syncthreads();
  float part[16];
#pragma unroll
  for (int n=0;n<16;n++) part[n]=0.f;
  for (int j=0;j<8;j++){
    int kk = tid + j*256;
    float hv = hrow[kk];
    const float4* wr4 = (const float4*)&Wb[(size_t)kk*16];
    float4 w0=wr4[0], w1=wr4[1], w2=wr4[2], w3=wr4[3];
    part[0]+=hv*w0.x; part[1]+=hv*w0.y; part[2]+=hv*w0.z; part[3]+=hv*w0.w;
    part[4]+=hv*w1.x; part[5]+=hv*w1.y; part[6]+=hv*w1.z; part[7]+=hv*w1.w;
    part[8]+=hv*w2.x; part[9]+=hv*w2.y; part[10]+=hv*w2.z; part[11]+=hv*w2.w;
    part[12]+=hv*w3.x; part[13]+=hv*w3.y; part[14]+=hv*w3.z; part[15]+=hv*w3.w;
  }
#pragma unroll
  for (int n=0;n<16;n++){
    float s = part[n];
#pragma unroll
    for (int off=1;off<64;off<<=1) s += __shfl_xor(s, off);
    if ((tid&63)==0) red[n][tid>>6] = s;
  }
  __syncthreads();
  if (tid < 16){
    float s = red[tid][0]+red[tid][1]+red[tid][2]+red[tid][3];
    betab[t*16+tid] = 1.f/(1.f+__expf(-s));
  }
}

// ---------------- causal conv4 + silu on concatenated qkvw ----------------
__global__ __launch_bounds__(256)
void conv_k(const float* __restrict__ raw, const float* __restrict__ cq,
            const float* __restrict__ ck, const float* __restrict__ cv,
            float* __restrict__ qo, float* __restrict__ ko,
            float* __restrict__ vo, float* __restrict__ wo){
  int idx = blockIdx.x*256 + threadIdx.x;
  int cgl = idx & 8191, tb = idx >> 13;
  int which = cgl >> 11, cc = cgl & 2047;
  const float* wt = (which==0)?cq:((which==1)?ck:cv);   // w-branch (3) uses cv (faithful to ref)
  float4 w4 = *(const float4*)&wt[cc*4];
  float* out = (which==0)?qo:((which==1)?ko:((which==2)?vo:wo));
  int t0 = tb*4;
  float x[7];
#pragma unroll
  for (int j=0;j<7;j++){
    int t = t0 - 3 + j;
    x[j] = (t >= 0) ? raw[(size_t)t*8192 + cgl] : 0.f;
  }
#pragma unroll
  for (int j=0;j<4;j++){
    float y = x[j]*w4.x + x[j+1]*w4.y + x[j+2]*w4.z + x[j+3]*w4.w;
    y = y / (1.f + __expf(-y));           // silu
    out[(size_t)(t0+j)*2048 + cc] = y;
  }
}

// ---------------- l2norm over M + beta scale: bw ----------------
__global__ __launch_bounds__(256)
void l2bw_k(const float* __restrict__ wconv, const float* __restrict__ betab,
            float* __restrict__ bwout){
  int row = blockIdx.x*4 + (threadIdx.x>>6);
  int lane = threadIdx.x & 63;
  int t = row >> 4, h = row & 15;
  size_t base = (size_t)t*2048 + h*128;
  float a0 = wconv[base+lane], a1 = wconv[base+64+lane];
  float ss = a0*a0 + a1*a1;
#pragma unroll
  for (int off=1;off<64;off<<=1) ss += __shfl_xor(ss, off);
  float r = rsqrtf(ss + 1e-6f) * betab[t*16+h];
  bwout[base+lane]    = a0*r;
  bwout[base+64+lane] = a1*r;
}

// ---------------- per-chunk inclusive cumsum of logsigmoid(gpre) ----------------
__global__ __launch_bounds__(256)
void cg_k(const float* __restrict__ gpre, float* __restrict__ cg){
  int idx = blockIdx.x*256 + threadIdx.x;   // 32768 = c*2048 + h*128 + m
  int m = idx & 127, h = (idx>>7) & 15, c = idx >> 11;
  size_t base = (size_t)h*128 + m;
  float run = 0.f;
  for (int i2=0;i2<64;i2++){
    size_t t = (size_t)c*64 + i2;
    float x = gpre[t*2048 + base];
    float lg = (x >= 0.f) ? (-log1pf(__expf(-x))) : (x - log1pf(__expf(x)));
    run += lg;
    cg[t*2048 + base] = run;
  }
}

// ---------------- Phase A (MFMA): DSkT[m][d] = U^T K ; DSvT[v][m] = V^T U ----------------
__global__ __launch_bounds__(256)
void phaseA_k(const float* __restrict__ k, const float* __restrict__ v,
              const float* __restrict__ bw, const float* __restrict__ cg,
              float* __restrict__ DSkT, float* __restrict__ DSvT){
  __shared__ u16 UT[128*68];
  __shared__ u16 KT[128*68];
  __shared__ u16 VT[128*68];
  __shared__ float Gt[128];
  const int bx=blockIdx.x, h=bx&15, c=bx>>4, tid=threadIdx.x;
  const int w=tid>>6, lane=tid&63, lr=lane&15, kg=lane>>4;
  if (tid<128) Gt[tid] = cg[(size_t)(c*64+63)*2048 + h*128 + tid];
  __syncthreads();
#pragma unroll
  for (int j=0;j<8;j++){
    int f4=tid+j*256, r=f4>>5, c4=(f4&31)<<2;
    size_t g=(size_t)(c*64+r)*2048 + h*128 + c4;
    float4 kv=*(const float4*)&k[g];
    float4 vv=*(const float4*)&v[g];
    float4 bv=*(const float4*)&bw[g];
    float4 cv=*(const float4*)&cg[g];
    float u0=bv.x*__expf(Gt[c4+0]-cv.x);
    float u1=bv.y*__expf(Gt[c4+1]-cv.y);
    float u2=bv.z*__expf(Gt[c4+2]-cv.z);
    float u3=bv.w*__expf(Gt[c4+3]-cv.w);
    KT[(c4+0)*68+r]=f2bf(kv.x); KT[(c4+1)*68+r]=f2bf(kv.y);
    KT[(c4+2)*68+r]=f2bf(kv.z); KT[(c4+3)*68+r]=f2bf(kv.w);
    VT[(c4+0)*68+r]=f2bf(vv.x); VT[(c4+1)*68+r]=f2bf(vv.y);
    VT[(c4+2)*68+r]=f2bf(vv.z); VT[(c4+3)*68+r]=f2bf(vv.w);
    UT[(c4+0)*68+r]=f2bf(u0);   UT[(c4+1)*68+r]=f2bf(u1);
    UT[(c4+2)*68+r]=f2bf(u2);   UT[(c4+3)*68+r]=f2bf(u3);
  }
  __syncthreads();
  const f32x4 vz = {0.f,0.f,0.f,0.f};
  // DSkT: A=UT (rows m), B=KT (rows d), K-dim = s (64)
  {
    f32x4 acc[2][8];
#pragma unroll
    for (int a=0;a<2;a++)
#pragma unroll
      for (int b=0;b<8;b++) acc[a][b]=vz;
#pragma unroll
    for (int ks=0;ks<2;ks++){
      bf16x8 a0=ldfrag(&UT[(w*32   +lr)*68 + ks*32+kg*8]);
      bf16x8 a1=ldfrag(&UT[(w*32+16+lr)*68 + ks*32+kg*8]);
#pragma unroll
      for (int nj=0;nj<8;nj++){
        bf16x8 b=ldfrag(&KT[(nj*16+lr)*68 + ks*32+kg*8]);
        acc[0][nj]=__builtin_amdgcn_mfma_f32_16x16x32_bf16(a0,b,acc[0][nj],0,0,0);
        acc[1][nj]=__builtin_amdgcn_mfma_f32_16x16x32_bf16(a1,b,acc[1][nj],0,0,0);
      }
    }
#pragma unroll
    for (int mi2=0;mi2<2;mi2++)
#pragma unroll
      for (int nj=0;nj<8;nj++)
#pragma unroll
        for (int vv2=0;vv2<4;vv2++)
          DSkT[(size_t)bx*16384 + (size_t)(w*32+mi2*16+kg*4+vv2)*128 + nj*16+lr] = acc[mi2][nj][vv2];
  }
  // DSvT: A=VT (rows v), B=UT (rows m), K-dim = s (64)
  {
    f32x4 acc[2][8];
#pragma unroll
    for (int a=0;a<2;a++)
#pragma unroll
      for (int b=0;b<8;b++) acc[a][b]=vz;
#pragma unroll
    for (int ks=0;ks<2;ks++){
      bf16x8 a0=ldfrag(&VT[(w*32   +lr)*68 + ks*32+kg*8]);
      bf16x8 a1=ldfrag(&VT[(w*32+16+lr)*68 + ks*32+kg*8]);
#pragma unroll
      for (int nj=0;nj<8;nj++){
        bf16x8 b=ldfrag(&UT[(nj*16+lr)*68 + ks*32+kg*8]);
        acc[0][nj]=__builtin_amdgcn_mfma_f32_16x16x32_bf16(a0,b,acc[0][nj],0,0,0);
        acc[1][nj]=__builtin_amdgcn_mfma_f32_16x16x32_bf16(a1,b,acc[1][nj],0,0,0);
      }
    }
#pragma unroll
    for (int mi2=0;mi2<2;mi2++)
#pragma unroll
      for (int nj=0;nj<8;nj++)
#pragma unroll
        for (int vv2=0;vv2<4;vv2++)
          DSvT[(size_t)bx*16384 + (size_t)(w*32+mi2*16+kg*4+vv2)*128 + nj*16+lr] = acc[mi2][nj][vv2];
  }
}

// ---------------- Phase B: sequential cross-chunk state combine (transposed layouts) ----------------
__global__ __launch_bounds__(256)
void phaseB_k(const float* __restrict__ DSk, const float* __restrict__ DSv,
              const float* __restrict__ cg, float* __restrict__ Sk0, float* __restrict__ Sv0){
  unsigned idx = blockIdx.x*256u + threadIdx.x;   // 524288 total
  int sel  = idx >> 18;
  int h    = (idx >> 14) & 15;
  int flat = idx & 16383;                 // SkT: m*128+d ; SvT: v*128+m
  int mdec = sel ? (flat & 127) : (flat >> 7);
  const float* DS = sel ? DSv : DSk;
  float* S = sel ? Sv0 : Sk0;
  float cur = 0.f;
  for (int c=0;c<16;c++){
    size_t sb = ((size_t)(c*16+h))*16384 + flat;
    S[sb] = cur;                           // state BEFORE chunk c
    float gd = __expf(cg[(size_t)(c*64+63)*2048 + h*128 + mdec]);
    cur = cur*gd + DS[sb];
  }
}

// ---------------- Phase C (MFMA): per-chunk outputs ----------------
__global__ __launch_bounds__(256)
void phaseC_k(const float* __restrict__ q, const float* __restrict__ k,
              const float* __restrict__ v, const float* __restrict__ bw,
              const float* __restrict__ cg, const float* __restrict__ SkT,
              const float* __restrict__ SvT, float* __restrict__ o){
  __shared__ u16 Qb[64*132];     // Q, then A' (wave-private rows after prep)
  __shared__ u16 KV[8704];       // K[64][132], then VT[128][68]
  __shared__ u16 Bws[64*132];    // bw*e^{cgm-cg} natural [s][m]
  __shared__ u16 BwT[128*68];    // transposed [m][s]
  __shared__ u16 Ssb[64*68];     // sqk, then P (wave-private rows)
  __shared__ u16 SkL[128*132];   // Sk'^T * e^{cgm[m]}  [m][d]
  __shared__ u16 SvL[128*132];   // Sv'^T * e^{cgm[m]}  [v][m]
  __shared__ float cgm[128];
  __shared__ float ecgm[128];
  const int bx=blockIdx.x, h=bx&15, c=bx>>4, tid=threadIdx.x;
  const int w=tid>>6, lane=tid&63, lr=lane&15, kg=lane>>4;
  const float SCALE = 0.088388347648318447f;   // 128^-0.5
  const f32x4 vz = {0.f,0.f,0.f,0.f};
  if (tid<128){ float t=cg[(size_t)(c*64+31)*2048 + h*128 + tid]; cgm[tid]=t; ecgm[tid]=__expf(t); }
  __syncthreads();
  // ---- stage Q, K, Bws, BwT
#pragma unroll
  for (int j=0;j<8;j++){
    int f4=tid+j*256, r=f4>>5, c4=(f4&31)<<2;
    size_t g=(size_t)(c*64+r)*2048 + h*128 + c4;
    float4 qv=*(const float4*)&q[g];
    float4 kv=*(const float4*)&k[g];
    *(bf16x4*)&Qb[r*132+c4] = cvt4(qv.x,qv.y,qv.z,qv.w);
    *(bf16x4*)&KV[r*132+c4] = cvt4(kv.x,kv.y,kv.z,kv.w);
    float4 bv=*(const float4*)&bw[g];
    float4 cv=*(const float4*)&cg[g];
    float b0=bv.x*__expf(cgm[c4+0]-cv.x);
    float b1=bv.y*__expf(cgm[c4+1]-cv.y);
    float b2=bv.z*__expf(cgm[c4+2]-cv.z);
    float b3=bv.w*__expf(cgm[c4+3]-cv.w);
    bf16x4 bb = cvt4(b0,b1,b2,b3);
    *(bf16x4*)&Bws[r*132+c4] = bb;
    BwT[(c4+0)*68+r]=(u16)bb[0]; BwT[(c4+1)*68+r]=(u16)bb[1];
    BwT[(c4+2)*68+r]=(u16)bb[2]; BwT[(c4+3)*68+r]=(u16)bb[3];
  }
  __syncthreads();
  // ---- step1: sqk[i][s] = Q.K^T (rows w*16.., masked s<=i) -> Ssb
  {
    f32x4 acc1[4];
#pragma unroll
    for (int a=0;a<4;a++) acc1[a]=vz;
#pragma unroll
    for (int ks=0;ks<4;ks++){
      bf16x8 aq = ldfrag(&Qb[(w*16+lr)*132 + ks*32+kg*8]);
#pragma unroll
      for (int ni=0;ni<4;ni++){
        bf16x8 bk = ldfrag(&KV[(ni*16+lr)*132 + ks*32+kg*8]);
        acc1[ni]=__builtin_amdgcn_mfma_f32_16x16x32_bf16(aq,bk,acc1[ni],0,0,0);
      }
    }
#pragma unroll
    for (int ni=0;ni<4;ni++)
#pragma unroll
      for (int vv2=0;vv2<4;vv2++){
        int row=w*16+kg*4+vv2, col=ni*16+lr;
        Ssb[row*68+col] = (col<=row) ? f2bf(acc1[ni][vv2]) : (u16)0;
      }
  }
  __syncthreads();   // all K reads done -> KV reusable for VT
  // ---- stage VT (into KV), SkL, SvL
#pragma unroll
  for (int j=0;j<8;j++){
    int f4=tid+j*256, r=f4>>5, c4=(f4&31)<<2;
    float4 vv=*(const float4*)&v[(size_t)(c*64+r)*2048 + h*128 + c4];
    KV[(c4+0)*68+r]=f2bf(vv.x); KV[(c4+1)*68+r]=f2bf(vv.y);
    KV[(c4+2)*68+r]=f2bf(vv.z); KV[(c4+3)*68+r]=f2bf(vv.w);
  }
#pragma unroll
  for (int j=0;j<16;j++){
    int f4=tid+j*256, r=f4>>5, c4=(f4&31)<<2;
    float4 s4=*(const float4*)&SkT[(size_t)bx*16384 + (size_t)r*128 + c4];
    float em=ecgm[r];
    *(bf16x4*)&SkL[r*132+c4]=cvt4(s4.x*em, s4.y*em, s4.z*em, s4.w*em);
  }
#pragma unroll
  for (int j=0;j<16;j++){
    int f4=tid+j*256, r=f4>>5, c4=(f4&31)<<2;
    float4 s4=*(const float4*)&SvT[(size_t)bx*16384 + (size_t)r*128 + c4];
    *(bf16x4*)&SvL[r*132+c4]=cvt4(s4.x*ecgm[c4+0], s4.y*ecgm[c4+1], s4.z*ecgm[c4+2], s4.w*ecgm[c4+3]);
  }
  // ---- step3: z += tril(sqk) @ Bws   (B-operand = BwT rows m)
  f32x4 zac[8];
#pragma unroll
  for (int a=0;a<8;a++) zac[a]=vz;
#pragma unroll
  for (int ks=0;ks<2;ks++){
    bf16x8 as_ = ldfrag(&Ssb[(w*16+lr)*68 + ks*32+kg*8]);
#pragma unroll
    for (int ni=0;ni<8;ni++){
      bf16x8 bb = ldfrag(&BwT[(ni*16+lr)*68 + ks*32+kg*8]);
      zac[ni]=__builtin_amdgcn_mfma_f32_16x16x32_bf16(as_,bb,zac[ni],0,0,0);
    }
  }
  __syncthreads();   // SkL/SvL/VT staged & visible
  // ---- step2: z += Q @ SkL
#pragma unroll
  for (int dt=0;dt<4;dt++){
    bf16x8 aq = ldfrag(&Qb[(w*16+lr)*132 + dt*32+kg*8]);
#pragma unroll
    for (int ni=0;ni<8;ni++){
      bf16x8 bs = ldfrag(&SkL[(ni*16+lr)*132 + dt*32+kg*8]);
      zac[ni]=__builtin_amdgcn_mfma_f32_16x16x32_bf16(aq,bs,zac[ni],0,0,0);
    }
  }
  // ---- softmax over m (per row, in-wave: 8 in-lane cols x 16 lr lanes)
  float dec[4][8], zz[4][8];
#pragma unroll
  for (int vv2=0;vv2<4;vv2++)
#pragma unroll
    for (int ni=0;ni<8;ni++) zz[vv2][ni]=zac[ni][vv2];
#pragma unroll
  for (int vv2=0;vv2<4;vv2++){
    size_t gr=(size_t)(c*64+w*16+kg*4+vv2)*2048 + h*128;
#pragma unroll
    for (int ni=0;ni<8;ni++){
      float cgv = cg[gr + ni*16+lr];
      dec[vv2][ni] = __expf(cgv - cgm[ni*16+lr]);
    }
  }
#pragma unroll
  for (int vv2=0;vv2<4;vv2++){
    float mx=-3.0e38f;
#pragma unroll
    for (int ni=0;ni<8;ni++){ zz[vv2][ni] *= SCALE*dec[vv2][ni]; mx=fmaxf(mx,zz[vv2][ni]); }
    mx=fmaxf(mx,__shfl_xor(mx,1)); mx=fmaxf(mx,__shfl_xor(mx,2));
    mx=fmaxf(mx,__shfl_xor(mx,4)); mx=fmaxf(mx,__shfl_xor(mx,8));
    float sum=0.f;
#pragma unroll
    for (int ni=0;ni<8;ni++){ zz[vv2][ni]=__expf(zz[vv2][ni]-mx); sum+=zz[vv2][ni]; }
    sum+=__shfl_xor(sum,1); sum+=__shfl_xor(sum,2);
    sum+=__shfl_xor(sum,4); sum+=__shfl_xor(sum,8);
    float inv=1.f/sum;
#pragma unroll
    for (int ni=0;ni<8;ni++) zz[vv2][ni] *= inv*dec[vv2][ni];   // A' = a * e^{cg-cgm}
  }
  // A' -> Qb (wave-private rows; own-wave step2 reads complete in program order)
#pragma unroll
  for (int vv2=0;vv2<4;vv2++)
#pragma unroll
    for (int ni=0;ni<8;ni++)
      Qb[(w*16+kg*4+vv2)*132 + ni*16+lr] = f2bf(zz[vv2][ni]);
  // ---- step4: P[i][s] = A' . Bws[s][:]  (masked) -> Ssb (wave-private)
  {
    f32x4 acc4[4];
#pragma unroll
    for (int a=0;a<4;a++) acc4[a]=vz;
#pragma unroll
    for (int ks=0;ks<4;ks++){
      bf16x8 aa = ldfrag(&Qb[(w*16+lr)*132 + ks*32+kg*8]);
#pragma unroll
      for (int ni=0;ni<4;ni++){
        bf16x8 bb = ldfrag(&Bws[(ni*16+lr)*132 + ks*32+kg*8]);
        acc4[ni]=__builtin_amdgcn_mfma_f32_16x16x32_bf16(aa,bb,acc4[ni],0,0,0);
      }
    }
#pragma unroll
    for (int ni=0;ni<4;ni++)
#pragma unroll
      for (int vv2=0;vv2<4;vv2++){
        int row=w*16+kg*4+vv2, col=ni*16+lr;
        Ssb[row*68+col] = (col<=row) ? f2bf(acc4[ni][vv2]) : (u16)0;
      }
  }
  // ---- step5: o = P @ V (VT in KV)
  f32x4 oac[8];
#pragma unroll
  for (int a=0;a<8;a++) oac[a]=vz;
#pragma unroll
  for (int ks=0;ks<2;ks++){
    bf16x8 ap = ldfrag(&Ssb[(w*16+lr)*68 + ks*32+kg*8]);
#pragma unroll
    for (int ni=0;ni<8;ni++){
      bf16x8 bv2 = ldfrag(&KV[(ni*16+lr)*68 + ks*32+kg*8]);
      oac[ni]=__builtin_amdgcn_mfma_f32_16x16x32_bf16(ap,bv2,oac[ni],0,0,0);
    }
  }
  // ---- step6: o += A' @ SvL
#pragma unroll
  for (int mt=0;mt<4;mt++){
    bf16x8 aa = ldfrag(&Qb[(w*16+lr)*132 + mt*32+kg*8]);
#pragma unroll
    for (int ni=0;ni<8;ni++){
      bf16x8 bs = ldfrag(&SvL[(ni*16+lr)*132 + mt*32+kg*8]);
      oac[ni]=__builtin_amdgcn_mfma_f32_16x16x32_bf16(aa,bs,oac[ni],0,0,0);
    }
  }
  // ---- write o
#pragma unroll
  for (int ni=0;ni<8;ni++)
#pragma unroll
    for (int vv2=0;vv2<4;vv2++)
      o[(size_t)(c*64+w*16+kg*4+vv2)*2048 + h*128 + ni*16+lr] = oac[ni][vv2];
}

// ---------------- gated RMSNorm -> bf16 ----------------
__global__ __launch_bounds__(256)
void norm_k(const float* __restrict__ o, const float* __restrict__ gate,
            const float* __restrict__ bg2, const float* __restrict__ nw,
            u16* __restrict__ Obf){
  int row = blockIdx.x*4 + (threadIdx.x>>6);
  int lane = threadIdx.x & 63;
  int t = row >> 4, h = row & 15;
  size_t base = (size_t)t*2048 + h*128;
  float o0 = o[base+lane], o1 = o[base+64+lane];
  float ss = o0*o0 + o1*o1;
#pragma unroll
  for (int off=1;off<64;off<<=1) ss += __shfl_xor(ss, off);
  float r = rsqrtf(ss*(1.f/128.f) + 1e-5f);
  int hv0 = h*128+lane, hv1 = hv0+64;
  float g0 = gate[base+lane]    + bg2[hv0];
  float g1 = gate[base+64+lane] + bg2[hv1];
  float v0 = o0*r*nw[lane]   *(1.f/(1.f+__expf(-g0)));
  float v1 = o1*r*nw[lane+64]*(1.f/(1.f+__expf(-g1)));
  Obf[base+lane]    = f2bf(v0);
  Obf[base+64+lane] = f2bf(v1);
}

extern "C" void kernel_launch(void* const* d_in, const int* in_sizes, int n_in,
                              void* d_out, int out_size, void* d_ws, size_t ws_size,
                              hipStream_t stream){
  (void)in_sizes; (void)n_in; (void)out_size; (void)ws_size;
  const float* hX   = (const float*)d_in[0];
  const float* Wq   = (const float*)d_in[1];
  const float* Wk   = (const float*)d_in[2];
  const float* Wv   = (const float*)d_in[3];
  const float* Ww   = (const float*)d_in[4];
  const float* cq   = (const float*)d_in[5];
  const float* ck   = (const float*)d_in[6];
  const float* cv   = (const float*)d_in[7];
  const float* Wf1  = (const float*)d_in[8];
  const float* Wf2  = (const float*)d_in[9];
  const float* Wb   = (const float*)d_in[10];
  const float* Wg1  = (const float*)d_in[11];
  const float* Wg2  = (const float*)d_in[12];
  const float* bg2  = (const float*)d_in[13];
  const float* nw   = (const float*)d_in[14];
  const float* Wo   = (const float*)d_in[15];
  char* ws = (char*)d_ws;
  u16*   h_bf  = (u16*)  (ws + 0);
  u16*   WcatT = (u16*)  (ws + 4194304);
  float* Sk0   = (float*)(ws + 4194304);            // reuses WcatT after G1
  float* Sv0   = (float*)(ws + 4194304 + 16777216);
  u16*   WoT   = (u16*)  (ws + 37748736);
  u16*   WfgT  = (u16*)  (ws + 46137344);
  u16*   Wf2T  = (u16*)  (ws + 47185920);
  u16*   Wg2T  = (u16*)  (ws + 47710208);
  float* qkvw  = (float*)(ws + 48234496);
  float* DSk   = (float*)(ws + 48234496);           // reuses qkvw after conv
  float* DSv   = (float*)(ws + 48234496 + 16777216);
  float* qb    = (float*)(ws + 81788928);
  float* kb    = (float*)(ws + 90177536);
  float* vb    = (float*)(ws + 98566144);
  float* wcv   = (float*)(ws + 106954752);
  float* osc   = wcv;                               // reuses wconv after l2bw
  float* bwb   = (float*)(ws + 115343360);
  u16*   f1g1  = (u16*)  (ws + 123731968);
  float* gpre  = (float*)(ws + 124256256);
  float* gateb = gpre;                              // reuses gpre after cg
  float* cgb   = (float*)(ws + 132644864);
  float* betab = (float*)(ws + 141033472);
  u16*   Obf   = (u16*)  (ws + 141099008);
  float* outp  = (float*)d_out;

  // conversions
  f2bf_k<<<2048,256,0,stream>>>(hX, h_bf);
  transp_k<<<dim3(64,64),256,0,stream>>>(Wq, WcatT + (size_t)0*2048*2048, 2048, 2048);
  transp_k<<<dim3(64,64),256,0,stream>>>(Wk, WcatT + (size_t)1*2048*2048, 2048, 2048);
  transp_k<<<dim3(64,64),256,0,stream>>>(Wv, WcatT + (size_t)2*2048*2048, 2048, 2048);
  transp_k<<<dim3(64,64),256,0,stream>>>(Ww, WcatT + (size_t)3*2048*2048, 2048, 2048);
  transp_k<<<dim3(64,64),256,0,stream>>>(Wo, WoT, 2048, 2048);
  transp_k<<<dim3(4,64), 256,0,stream>>>(Wf1, WfgT, 2048, 128);
  transp_k<<<dim3(4,64), 256,0,stream>>>(Wg1, WfgT + (size_t)128*2048, 2048, 128);
  transp_k<<<dim3(64,4), 256,0,stream>>>(Wf2, Wf2T, 128, 2048);
  transp_k<<<dim3(64,4), 256,0,stream>>>(Wg2, Wg2T, 128, 2048);

  // projections
  gemm_k<false><<<dim3(64,8),256,0,stream>>>(h_bf, WcatT, qkvw, 2048, 2048, 2048, 8192);
  gemm_k<true ><<<dim3(2,8), 256,0,stream>>>(h_bf, WfgT, f1g1, 2048, 2048, 2048, 256);
  gemm_k<false><<<dim3(16,8),256,0,stream>>>(f1g1, Wf2T, gpre, 128, 256, 128, 2048);
  beta_k<<<1024,256,0,stream>>>(hX, Wb, betab);

  // conv + silu, l2norm*beta, chunk cumsum of logsigmoid
  conv_k<<<8192,256,0,stream>>>(qkvw, cq, ck, cv, qb, kb, vb, wcv);
  l2bw_k<<<4096,256,0,stream>>>(wcv, betab, bwb);
  cg_k<<<128,256,0,stream>>>(gpre, cgb);

  // gate GEMM (into gpre buffer, safe after cg)
  gemm_k<false><<<dim3(16,8),256,0,stream>>>(f1g1 + 128, Wg2T, gateb, 128, 256, 128, 2048);

  // chunked scan
  phaseA_k<<<256,256,0,stream>>>(kb, vb, bwb, cgb, DSk, DSv);
  phaseB_k<<<2048,256,0,stream>>>(DSk, DSv, cgb, Sk0, Sv0);
  phaseC_k<<<256,256,0,stream>>>(qb, kb, vb, bwb, cgb, Sk0, Sv0, osc);

  // gated RMSNorm + output projection
  norm_k<<<4096,256,0,stream>>>(osc, gateb, bg2, nw, Obf);
  gemm_k<false><<<dim3(16,8),256,0,stream>>>(Obf, WoT, outp, 2048, 2048, 2048, 2048);
}

// Round 5
// 245.209 us; speedup vs baseline: 3.4353x; 1.3553x over previous
//
#include <hip/hip_runtime.h>
#include <hip/hip_bf16.h>
#include <stdint.h>

typedef unsigned short u16;
typedef __attribute__((ext_vector_type(8))) short bf16x8;
typedef __attribute__((ext_vector_type(4))) short bf16x4;
typedef __attribute__((ext_vector_type(4))) float f32x4;

#define DEV static __device__ __forceinline__

DEV u16 f2bf(float f){
  union { float f; unsigned u; } x; x.f = f;
  unsigned r = x.u + 0x7fffu + ((x.u >> 16) & 1u);
  return (u16)(r >> 16);
}

DEV float bf2f(u16 u){
  union { unsigned u; float f; } x; x.u = ((unsigned)u) << 16; return x.f;
}

DEV bf16x8 ldfrag(const u16* p){           // two ds_read_b64 (8B-aligned rows)
  bf16x4 a = *(const bf16x4*)p;
  bf16x4 b = *(const bf16x4*)(p+4);
  bf16x8 r;
  r[0]=a[0]; r[1]=a[1]; r[2]=a[2]; r[3]=a[3];
  r[4]=b[0]; r[5]=b[1]; r[6]=b[2]; r[7]=b[3];
  return r;
}

DEV bf16x4 cvt4(float a, float b, float c, float d){
  bf16x4 r; r[0]=(short)f2bf(a); r[1]=(short)f2bf(b); r[2]=(short)f2bf(c); r[3]=(short)f2bf(d);
  return r;
}

DEV void g2l16(const void* g, void* l){
  __builtin_amdgcn_global_load_lds((const __attribute__((address_space(1))) unsigned int*)g,
                                   (__attribute__((address_space(3))) unsigned int*)l,
                                   16, 0, 0);
}

// ---------------- f32 -> bf16 straight convert ----------------
__global__ __launch_bounds__(256)
void f2bf_k(const float* __restrict__ in, u16* __restrict__ out){
  int idx = blockIdx.x*256 + threadIdx.x;
  float4 v = *(const float4*)&in[(size_t)idx*4];
  u16 a = f2bf(v.x), b = f2bf(v.y), c = f2bf(v.z), d = f2bf(v.w);
  ushort4 o4; o4.x=a; o4.y=b; o4.z=c; o4.w=d;
  *(ushort4*)&out[(size_t)idx*4] = o4;
}

// ---------------- fused 2048x2048 f32 -> bf16 transposes (Wq,Wk,Wv,Ww,Wo) ----------------
__global__ __launch_bounds__(256)
void transp64_k(const float* __restrict__ Wq, const float* __restrict__ Wk,
                const float* __restrict__ Wv, const float* __restrict__ Ww,
                const float* __restrict__ Wo, u16* __restrict__ WcatT, u16* __restrict__ WoT){
  __shared__ float tile[64][65];
  const int z = blockIdx.z;
  const float* src = (z==0)?Wq:((z==1)?Wk:((z==2)?Wv:((z==3)?Ww:Wo)));
  u16* dst = (z<4) ? (WcatT + (size_t)z*4194304) : WoT;
  const int c0 = blockIdx.x*64, r0 = blockIdx.y*64;
#pragma unroll
  for (int p=0;p<4;p++){
    int i = threadIdx.x + p*256;
    int r = i>>4, c4 = (i&15)<<2;
    *(float4*)&tile[r][c4] = *(const float4*)&src[(size_t)(r0+r)*2048 + c0 + c4];
  }
  __syncthreads();
#pragma unroll
  for (int p=0;p<4;p++){
    int i = threadIdx.x + p*256;
    int cc = i>>4, r4 = (i&15)<<2;
    ushort4 o;
    o.x = f2bf(tile[r4+0][cc]); o.y = f2bf(tile[r4+1][cc]);
    o.z = f2bf(tile[r4+2][cc]); o.w = f2bf(tile[r4+3][cc]);
    *(ushort4*)&dst[(size_t)(c0+cc)*2048 + r0 + r4] = o;
  }
}

// ---------------- f32 [R][C] -> bf16 [C][R] transpose (small mats) ----------------
__global__ __launch_bounds__(256)
void transp_k(const float* __restrict__ in, u16* __restrict__ out, int R, int C){
  __shared__ float tile[32][33];
  const int c0 = blockIdx.x*32, r0 = blockIdx.y*32;
  const int x = threadIdx.x & 31, y0 = threadIdx.x >> 5;
#pragma unroll
  for (int j=0;j<4;j++){
    int r = y0 + j*8;
    tile[r][x] = in[(size_t)(r0+r)*C + c0 + x];
  }
  __syncthreads();
#pragma unroll
  for (int j=0;j<4;j++){
    int cc = y0 + j*8;
    out[(size_t)(c0+cc)*R + r0 + x] = f2bf(tile[x][cc]);
  }
}

// ---------------- big GEMM: 128x256 tile, BK=64, 8 waves, dbuf, T2 swizzle ----------------
// A[M,K] row (lda), B^T[N,K] row (ldb) -> C[M,N] bf16 (ldc)
__global__ __launch_bounds__(512)
void gemm8_k(const u16* __restrict__ A, const u16* __restrict__ B, u16* __restrict__ C,
             int K, int lda, int ldb, int ldc){
  __shared__ u16 As[2][128*64];
  __shared__ u16 Bs[2][256*64];
  const int m0 = blockIdx.y*128, n0 = blockIdx.x*256;
  const int tid = threadIdx.x;
  const int wave = tid>>6, lane = tid&63, lr = lane&15, kg = lane>>4;
  const int wm = wave>>2, wn = wave&3;
  const f32x4 vz = {0.f,0.f,0.f,0.f};
  f32x4 acc[4][4];
#pragma unroll
  for (int a=0;a<4;a++)
#pragma unroll
    for (int b=0;b<4;b++) acc[a][b]=vz;

#define STAGE8(buf, k0) do { \
    _Pragma("unroll") \
    for (int p=0;p<2;p++){ \
      int chunk = tid + p*512, r_ = chunk>>3, ci = chunk&7; \
      g2l16(A + (size_t)(m0+r_)*lda + (k0) + ((ci^(r_&7))<<3), &As[buf][chunk*8]); \
    } \
    _Pragma("unroll") \
    for (int p=0;p<4;p++){ \
      int chunk = tid + p*512, r_ = chunk>>3, ci = chunk&7; \
      g2l16(B + (size_t)(n0+r_)*ldb + (k0) + ((ci^(r_&7))<<3), &Bs[buf][chunk*8]); \
    } \
  } while(0)

  STAGE8(0, 0);
  __syncthreads();
  const int nt = K>>6;
  for (int t=0; t<nt; ++t){
    const int buf = t&1;
    if (t+1 < nt) STAGE8(buf^1, (t+1)<<6);
#pragma unroll
    for (int ks=0; ks<2; ++ks){
      bf16x8 af[4], bfv[4];
#pragma unroll
      for (int mi=0;mi<4;mi++){
        int r = wm*64+mi*16+lr;
        af[mi] = *(const bf16x8*)&As[buf][r*64 + (((ks*4+kg)^(r&7))<<3)];
      }
#pragma unroll
      for (int ni=0;ni<4;ni++){
        int r = wn*64+ni*16+lr;
        bfv[ni] = *(const bf16x8*)&Bs[buf][r*64 + (((ks*4+kg)^(r&7))<<3)];
      }
#pragma unroll
      for (int mi=0;mi<4;mi++)
#pragma unroll
        for (int ni=0;ni<4;ni++)
          acc[mi][ni] = __builtin_amdgcn_mfma_f32_16x16x32_bf16(af[mi], bfv[ni], acc[mi][ni], 0, 0, 0);
    }
    __syncthreads();
  }
#undef STAGE8
#pragma unroll
  for (int mi=0;mi<4;mi++)
#pragma unroll
    for (int ni=0;ni<4;ni++)
#pragma unroll
      for (int vv=0;vv<4;vv++){
        int row = m0 + wm*64 + mi*16 + kg*4 + vv;
        int col = n0 + wn*64 + ni*16 + lr;
        C[(size_t)row*ldc + col] = f2bf(acc[mi][ni][vv]);
      }
}

// ---------------- bf16 GEMM (128^2, BK=32): EPI 0=none 1=logsigmoid ----------------
template<bool OBF, int EPI>
__global__ __launch_bounds__(256)
void gemm_k(const u16* __restrict__ A, const u16* __restrict__ B, void* __restrict__ Cp,
            int K, int lda, int ldb, int ldc){
  __shared__ u16 As[128*32];
  __shared__ u16 Bs[128*32];
  const int m0 = blockIdx.y*128, n0 = blockIdx.x*128;
  const int tid = threadIdx.x;
  const int lane = tid & 63, wave = tid >> 6;
  const int wr = wave >> 1, wc = wave & 1;
  const int lr = lane & 15, kg = lane >> 4;
  const f32x4 vzero = {0.f,0.f,0.f,0.f};
  f32x4 acc[4][4];
#pragma unroll
  for (int a=0;a<4;a++)
#pragma unroll
    for (int b=0;b<4;b++) acc[a][b] = vzero;
  const int r0 = tid>>2, s0 = tid&3;
  for (int k0=0;k0<K;k0+=32){
    __syncthreads();
    g2l16(A + (size_t)(m0+r0)*lda + k0 + s0*8, (u16*)As + (size_t)tid*8);
    g2l16(B + (size_t)(n0+r0)*ldb + k0 + s0*8, (u16*)Bs + (size_t)tid*8);
    g2l16(A + (size_t)(m0+r0+64)*lda + k0 + s0*8, (u16*)As + (size_t)(tid+256)*8);
    g2l16(B + (size_t)(n0+r0+64)*ldb + k0 + s0*8, (u16*)Bs + (size_t)(tid+256)*8);
    __syncthreads();
    bf16x8 af[4], bfv[4];
#pragma unroll
    for (int mi=0;mi<4;mi++) af[mi]  = *(const bf16x8*)(As + (wr*64+mi*16+lr)*32 + kg*8);
#pragma unroll
    for (int ni=0;ni<4;ni++) bfv[ni] = *(const bf16x8*)(Bs + (wc*64+ni*16+lr)*32 + kg*8);
#pragma unroll
    for (int mi=0;mi<4;mi++)
#pragma unroll
      for (int ni=0;ni<4;ni++)
        acc[mi][ni] = __builtin_amdgcn_mfma_f32_16x16x32_bf16(af[mi], bfv[ni], acc[mi][ni], 0, 0, 0);
  }
#pragma unroll
  for (int mi=0;mi<4;mi++)
#pragma unroll
    for (int ni=0;ni<4;ni++)
#pragma unroll
      for (int vv=0;vv<4;vv++){
        int row = m0 + wr*64 + mi*16 + kg*4 + vv;
        int col = n0 + wc*64 + ni*16 + lr;
        float val = acc[mi][ni][vv];
        if (EPI==1) val = fminf(val,0.f) - __logf(1.f + __expf(-fabsf(val)));
        if (OBF) ((u16*)Cp)[(size_t)row*ldc + col] = f2bf(val);
        else     ((float*)Cp)[(size_t)row*ldc + col] = val;
      }
}

// ---------------- split-K GEMM for f1g1 (N=256, K=2048 in 8 chunks) ----------------
__global__ __launch_bounds__(256)
void gemmsk_k(const u16* __restrict__ A, const u16* __restrict__ B, float* __restrict__ P,
              int lda, int ldb){
  __shared__ u16 As[128*32];
  __shared__ u16 Bs[128*32];
  const int m0 = blockIdx.y*128, n0 = blockIdx.x*128;
  const int kbase = blockIdx.z*256;
  const int tid = threadIdx.x;
  const int lane = tid & 63, wave = tid >> 6;
  const int wr = wave >> 1, wc = wave & 1;
  const int lr = lane & 15, kg = lane >> 4;
  const f32x4 vzero = {0.f,0.f,0.f,0.f};
  f32x4 acc[4][4];
#pragma unroll
  for (int a=0;a<4;a++)
#pragma unroll
    for (int b=0;b<4;b++) acc[a][b] = vzero;
  const int r0 = tid>>2, s0 = tid&3;
  for (int k0=kbase;k0<kbase+256;k0+=32){
    __syncthreads();
    g2l16(A + (size_t)(m0+r0)*lda + k0 + s0*8, (u16*)As + (size_t)tid*8);
    g2l16(B + (size_t)(n0+r0)*ldb + k0 + s0*8, (u16*)Bs + (size_t)tid*8);
    g2l16(A + (size_t)(m0+r0+64)*lda + k0 + s0*8, (u16*)As + (size_t)(tid+256)*8);
    g2l16(B + (size_t)(n0+r0+64)*ldb + k0 + s0*8, (u16*)Bs + (size_t)(tid+256)*8);
    __syncthreads();
    bf16x8 af[4], bfv[4];
#pragma unroll
    for (int mi=0;mi<4;mi++) af[mi]  = *(const bf16x8*)(As + (wr*64+mi*16+lr)*32 + kg*8);
#pragma unroll
    for (int ni=0;ni<4;ni++) bfv[ni] = *(const bf16x8*)(Bs + (wc*64+ni*16+lr)*32 + kg*8);
#pragma unroll
    for (int mi=0;mi<4;mi++)
#pragma unroll
      for (int ni=0;ni<4;ni++)
        acc[mi][ni] = __builtin_amdgcn_mfma_f32_16x16x32_bf16(af[mi], bfv[ni], acc[mi][ni], 0, 0, 0);
  }
#pragma unroll
  for (int mi=0;mi<4;mi++)
#pragma unroll
    for (int ni=0;ni<4;ni++)
#pragma unroll
      for (int vv=0;vv<4;vv++){
        int row = m0 + wr*64 + mi*16 + kg*4 + vv;
        int col = n0 + wc*64 + ni*16 + lr;
        P[(size_t)blockIdx.z*262144 + (size_t)row*256 + col] = acc[mi][ni][vv];
      }
}

__global__ __launch_bounds__(256)
void reduce8_k(const float* __restrict__ P, u16* __restrict__ out){
  int i = (blockIdx.x*256 + threadIdx.x)*4;
  float4 s = *(const float4*)&P[i];
#pragma unroll
  for (int z=1;z<8;z++){
    float4 p = *(const float4*)&P[(size_t)z*262144 + i];
    s.x+=p.x; s.y+=p.y; s.z+=p.z; s.w+=p.w;
  }
  ushort4 o; o.x=f2bf(s.x); o.y=f2bf(s.y); o.z=f2bf(s.z); o.w=f2bf(s.w);
  *(ushort4*)&out[i] = o;
}

// ---------------- beta = sigmoid(h @ Wb), per-t block ----------------
__global__ __launch_bounds__(256)
void beta_k(const float* __restrict__ h, const float* __restrict__ Wb, float* __restrict__ betab){
  __shared__ float hrow[2048];
  __shared__ float red[16][5];
  const int t = blockIdx.x, tid = threadIdx.x;
#pragma unroll
  for (int j=0;j<8;j++) hrow[tid + j*256] = h[(size_t)t*2048 + tid + j*256];
  __syncthreads();
  float part[16];
#pragma unroll
  for (int n=0;n<16;n++) part[n]=0.f;
  for (int j=0;j<8;j++){
    int kk = tid + j*256;
    float hv = hrow[kk];
    const float4* wr4 = (const float4*)&Wb[(size_t)kk*16];
    float4 w0=wr4[0], w1=wr4[1], w2=wr4[2], w3=wr4[3];
    part[0]+=hv*w0.x; part[1]+=hv*w0.y; part[2]+=hv*w0.z; part[3]+=hv*w0.w;
    part[4]+=hv*w1.x; part[5]+=hv*w1.y; part[6]+=hv*w1.z; part[7]+=hv*w1.w;
    part[8]+=hv*w2.x; part[9]+=hv*w2.y; part[10]+=hv*w2.z; part[11]+=hv*w2.w;
    part[12]+=hv*w3.x; part[13]+=hv*w3.y; part[14]+=hv*w3.z; part[15]+=hv*w3.w;
  }
#pragma unroll
  for (int n=0;n<16;n++){
    float s = part[n];
#pragma unroll
    for (int off=1;off<64;off<<=1) s += __shfl_xor(s, off);
    if ((tid&63)==0) red[n][tid>>6] = s;
  }
  __syncthreads();
  if (tid < 16){
    float s = red[tid][0]+red[tid][1]+red[tid][2]+red[tid][3];
    betab[t*16+tid] = 1.f/(1.f+__expf(-s));
  }
}

// ---------------- causal conv4 + silu on concatenated qkvw (bf16 in) ----------------
__global__ __launch_bounds__(256)
void conv_k(const u16* __restrict__ raw, const float* __restrict__ cq,
            const float* __restrict__ ck, const float* __restrict__ cv,
            float* __restrict__ qo, float* __restrict__ ko,
            float* __restrict__ vo, float* __restrict__ wo){
  int idx = blockIdx.x*256 + threadIdx.x;
  int cgl = idx & 8191, tb = idx >> 13;
  int which = cgl >> 11, cc = cgl & 2047;
  const float* wt = (which==0)?cq:((which==1)?ck:cv);   // w-branch (3) uses cv (faithful to ref)
  float4 w4 = *(const float4*)&wt[cc*4];
  float* out = (which==0)?qo:((which==1)?ko:((which==2)?vo:wo));
  int t0 = tb*4;
  float x[7];
#pragma unroll
  for (int j=0;j<7;j++){
    int t = t0 - 3 + j;
    x[j] = (t >= 0) ? bf2f(raw[(size_t)t*8192 + cgl]) : 0.f;
  }
#pragma unroll
  for (int j=0;j<4;j++){
    float y = x[j]*w4.x + x[j+1]*w4.y + x[j+2]*w4.z + x[j+3]*w4.w;
    y = y / (1.f + __expf(-y));           // silu
    out[(size_t)(t0+j)*2048 + cc] = y;
  }
}

// ---------------- l2norm over M + beta scale: bw ----------------
__global__ __launch_bounds__(256)
void l2bw_k(const float* __restrict__ wconv, const float* __restrict__ betab,
            float* __restrict__ bwout){
  int row = blockIdx.x*4 + (threadIdx.x>>6);
  int lane = threadIdx.x & 63;
  int t = row >> 4, h = row & 15;
  size_t base = (size_t)t*2048 + h*128;
  float a0 = wconv[base+lane], a1 = wconv[base+64+lane];
  float ss = a0*a0 + a1*a1;
#pragma unroll
  for (int off=1;off<64;off<<=1) ss += __shfl_xor(ss, off);
  float r = rsqrtf(ss + 1e-6f) * betab[t*16+h];
  bwout[base+lane]    = a0*r;
  bwout[base+64+lane] = a1*r;
}

// ---------------- per-chunk inclusive cumsum (gpre already = logsigmoid) ----------------
__global__ __launch_bounds__(256)
void cg_k(const float* __restrict__ gpre, float* __restrict__ cg){
  int idx = blockIdx.x*256 + threadIdx.x;   // 32768 = c*2048 + h*128 + m
  int c = idx >> 11;
  size_t base = (size_t)(idx & 2047);
  float run = 0.f;
  for (int i2=0;i2<64;i2++){
    size_t t = (size_t)c*64 + i2;
    run += gpre[t*2048 + base];
    cg[t*2048 + base] = run;
  }
}

// ---------------- Phase A (MFMA): DSkT[m][d] = U^T K ; DSvT[v][m] = V^T U ----------------
__global__ __launch_bounds__(256)
void phaseA_k(const float* __restrict__ k, const float* __restrict__ v,
              const float* __restrict__ bw, const float* __restrict__ cg,
              float* __restrict__ DSkT, float* __restrict__ DSvT){
  __shared__ u16 UT[128*68];
  __shared__ u16 KT[128*68];
  __shared__ u16 VT[128*68];
  __shared__ float Gt[128];
  const int bx=blockIdx.x, h=bx&15, c=bx>>4, tid=threadIdx.x;
  const int w=tid>>6, lane=tid&63, lr=lane&15, kg=lane>>4;
  if (tid<128) Gt[tid] = cg[(size_t)(c*64+63)*2048 + h*128 + tid];
  __syncthreads();
#pragma unroll
  for (int j=0;j<8;j++){
    int f4=tid+j*256, r=f4>>5, c4=(f4&31)<<2;
    size_t g=(size_t)(c*64+r)*2048 + h*128 + c4;
    float4 kv=*(const float4*)&k[g];
    float4 vv=*(const float4*)&v[g];
    float4 bv=*(const float4*)&bw[g];
    float4 cv=*(const float4*)&cg[g];
    float u0=bv.x*__expf(Gt[c4+0]-cv.x);
    float u1=bv.y*__expf(Gt[c4+1]-cv.y);
    float u2=bv.z*__expf(Gt[c4+2]-cv.z);
    float u3=bv.w*__expf(Gt[c4+3]-cv.w);
    KT[(c4+0)*68+r]=f2bf(kv.x); KT[(c4+1)*68+r]=f2bf(kv.y);
    KT[(c4+2)*68+r]=f2bf(kv.z); KT[(c4+3)*68+r]=f2bf(kv.w);
    VT[(c4+0)*68+r]=f2bf(vv.x); VT[(c4+1)*68+r]=f2bf(vv.y);
    VT[(c4+2)*68+r]=f2bf(vv.z); VT[(c4+3)*68+r]=f2bf(vv.w);
    UT[(c4+0)*68+r]=f2bf(u0);   UT[(c4+1)*68+r]=f2bf(u1);
    UT[(c4+2)*68+r]=f2bf(u2);   UT[(c4+3)*68+r]=f2bf(u3);
  }
  __syncthreads();
  const f32x4 vz = {0.f,0.f,0.f,0.f};
  {
    f32x4 acc[2][8];
#pragma unroll
    for (int a=0;a<2;a++)
#pragma unroll
      for (int b=0;b<8;b++) acc[a][b]=vz;
#pragma unroll
    for (int ks=0;ks<2;ks++){
      bf16x8 a0=ldfrag(&UT[(w*32   +lr)*68 + ks*32+kg*8]);
      bf16x8 a1=ldfrag(&UT[(w*32+16+lr)*68 + ks*32+kg*8]);
#pragma unroll
      for (int nj=0;nj<8;nj++){
        bf16x8 b=ldfrag(&KT[(nj*16+lr)*68 + ks*32+kg*8]);
        acc[0][nj]=__builtin_amdgcn_mfma_f32_16x16x32_bf16(a0,b,acc[0][nj],0,0,0);
        acc[1][nj]=__builtin_amdgcn_mfma_f32_16x16x32_bf16(a1,b,acc[1][nj],0,0,0);
      }
    }
#pragma unroll
    for (int mi2=0;mi2<2;mi2++)
#pragma unroll
      for (int nj=0;nj<8;nj++)
#pragma unroll
        for (int vv2=0;vv2<4;vv2++)
          DSkT[(size_t)bx*16384 + (size_t)(w*32+mi2*16+kg*4+vv2)*128 + nj*16+lr] = acc[mi2][nj][vv2];
  }
  {
    f32x4 acc[2][8];
#pragma unroll
    for (int a=0;a<2;a++)
#pragma unroll
      for (int b=0;b<8;b++) acc[a][b]=vz;
#pragma unroll
    for (int ks=0;ks<2;ks++){
      bf16x8 a0=ldfrag(&VT[(w*32   +lr)*68 + ks*32+kg*8]);
      bf16x8 a1=ldfrag(&VT[(w*32+16+lr)*68 + ks*32+kg*8]);
#pragma unroll
      for (int nj=0;nj<8;nj++){
        bf16x8 b=ldfrag(&UT[(nj*16+lr)*68 + ks*32+kg*8]);
        acc[0][nj]=__builtin_amdgcn_mfma_f32_16x16x32_bf16(a0,b,acc[0][nj],0,0,0);
        acc[1][nj]=__builtin_amdgcn_mfma_f32_16x16x32_bf16(a1,b,acc[1][nj],0,0,0);
      }
    }
#pragma unroll
    for (int mi2=0;mi2<2;mi2++)
#pragma unroll
      for (int nj=0;nj<8;nj++)
#pragma unroll
        for (int vv2=0;vv2<4;vv2++)
          DSvT[(size_t)bx*16384 + (size_t)(w*32+mi2*16+kg*4+vv2)*128 + nj*16+lr] = acc[mi2][nj][vv2];
  }
}

// ---------------- Phase B: sequential cross-chunk state combine (transposed layouts) ----------------
__global__ __launch_bounds__(256)
void phaseB_k(const float* __restrict__ DSk, const float* __restrict__ DSv,
              const float* __restrict__ cg, float* __restrict__ Sk0, float* __restrict__ Sv0){
  unsigned idx = blockIdx.x*256u + threadIdx.x;   // 524288 total
  int sel  = idx >> 18;
  int h    = (idx >> 14) & 15;
  int flat = idx & 16383;                 // SkT: m*128+d ; SvT: v*128+m
  int mdec = sel ? (flat & 127) : (flat >> 7);
  const float* DS = sel ? DSv : DSk;
  float* S = sel ? Sv0 : Sk0;
  float cur = 0.f;
  for (int c=0;c<16;c++){
    size_t sb = ((size_t)(c*16+h))*16384 + flat;
    S[sb] = cur;                           // state BEFORE chunk c
    float gd = __expf(cg[(size_t)(c*64+63)*2048 + h*128 + mdec]);
    cur = cur*gd + DS[sb];
  }
}

// ---------------- Phase C (MFMA): per-chunk outputs ----------------
__global__ __launch_bounds__(256)
void phaseC_k(const float* __restrict__ q, const float* __restrict__ k,
              const float* __restrict__ v, const float* __restrict__ bw,
              const float* __restrict__ cg, const float* __restrict__ SkT,
              const float* __restrict__ SvT, float* __restrict__ o){
  __shared__ u16 Qb[64*132];     // Q, then A' (wave-private rows after prep)
  __shared__ u16 KV[8704];       // K[64][132], then VT[128][68]
  __shared__ u16 Bws[64*132];    // bw*e^{cgm-cg} natural [s][m]
  __shared__ u16 BwT[128*68];    // transposed [m][s]
  __shared__ u16 Ssb[64*68];     // sqk, then P (wave-private rows)
  __shared__ u16 SkL[128*132];   // Sk'^T * e^{cgm[m]}  [m][d]
  __shared__ u16 SvL[128*132];   // Sv'^T * e^{cgm[m]}  [v][m]
  __shared__ float cgm[128];
  __shared__ float ecgm[128];
  const int bx=blockIdx.x, h=bx&15, c=bx>>4, tid=threadIdx.x;
  const int w=tid>>6, lane=tid&63, lr=lane&15, kg=lane>>4;
  const float SCALE = 0.088388347648318447f;   // 128^-0.5
  const f32x4 vz = {0.f,0.f,0.f,0.f};
  if (tid<128){ float t=cg[(size_t)(c*64+31)*2048 + h*128 + tid]; cgm[tid]=t; ecgm[tid]=__expf(t); }
  __syncthreads();
#pragma unroll
  for (int j=0;j<8;j++){
    int f4=tid+j*256, r=f4>>5, c4=(f4&31)<<2;
    size_t g=(size_t)(c*64+r)*2048 + h*128 + c4;
    float4 qv=*(const float4*)&q[g];
    float4 kv=*(const float4*)&k[g];
    *(bf16x4*)&Qb[r*132+c4] = cvt4(qv.x,qv.y,qv.z,qv.w);
    *(bf16x4*)&KV[r*132+c4] = cvt4(kv.x,kv.y,kv.z,kv.w);
    float4 bv=*(const float4*)&bw[g];
    float4 cv=*(const float4*)&cg[g];
    float b0=bv.x*__expf(cgm[c4+0]-cv.x);
    float b1=bv.y*__expf(cgm[c4+1]-cv.y);
    float b2=bv.z*__expf(cgm[c4+2]-cv.z);
    float b3=bv.w*__expf(cgm[c4+3]-cv.w);
    bf16x4 bb = cvt4(b0,b1,b2,b3);
    *(bf16x4*)&Bws[r*132+c4] = bb;
    BwT[(c4+0)*68+r]=(u16)bb[0]; BwT[(c4+1)*68+r]=(u16)bb[1];
    BwT[(c4+2)*68+r]=(u16)bb[2]; BwT[(c4+3)*68+r]=(u16)bb[3];
  }
  __syncthreads();
  {
    f32x4 acc1[4];
#pragma unroll
    for (int a=0;a<4;a++) acc1[a]=vz;
#pragma unroll
    for (int ks=0;ks<4;ks++){
      bf16x8 aq = ldfrag(&Qb[(w*16+lr)*132 + ks*32+kg*8]);
#pragma unroll
      for (int ni=0;ni<4;ni++){
        bf16x8 bk = ldfrag(&KV[(ni*16+lr)*132 + ks*32+kg*8]);
        acc1[ni]=__builtin_amdgcn_mfma_f32_16x16x32_bf16(aq,bk,acc1[ni],0,0,0);
      }
    }
#pragma unroll
    for (int ni=0;ni<4;ni++)
#pragma unroll
      for (int vv2=0;vv2<4;vv2++){
        int row=w*16+kg*4+vv2, col=ni*16+lr;
        Ssb[row*68+col] = (col<=row) ? f2bf(acc1[ni][vv2]) : (u16)0;
      }
  }
  __syncthreads();   // all K reads done -> KV reusable for VT
#pragma unroll
  for (int j=0;j<8;j++){
    int f4=tid+j*256, r=f4>>5, c4=(f4&31)<<2;
    float4 vv=*(const float4*)&v[(size_t)(c*64+r)*2048 + h*128 + c4];
    KV[(c4+0)*68+r]=f2bf(vv.x); KV[(c4+1)*68+r]=f2bf(vv.y);
    KV[(c4+2)*68+r]=f2bf(vv.z); KV[(c4+3)*68+r]=f2bf(vv.w);
  }
#pragma unroll
  for (int j=0;j<16;j++){
    int f4=tid+j*256, r=f4>>5, c4=(f4&31)<<2;
    float4 s4=*(const float4*)&SkT[(size_t)bx*16384 + (size_t)r*128 + c4];
    float em=ecgm[r];
    *(bf16x4*)&SkL[r*132+c4]=cvt4(s4.x*em, s4.y*em, s4.z*em, s4.w*em);
  }
#pragma unroll
  for (int j=0;j<16;j++){
    int f4=tid+j*256, r=f4>>5, c4=(f4&31)<<2;
    float4 s4=*(const float4*)&SvT[(size_t)bx*16384 + (size_t)r*128 + c4];
    *(bf16x4*)&SvL[r*132+c4]=cvt4(s4.x*ecgm[c4+0], s4.y*ecgm[c4+1], s4.z*ecgm[c4+2], s4.w*ecgm[c4+3]);
  }
  f32x4 zac[8];
#pragma unroll
  for (int a=0;a<8;a++) zac[a]=vz;
#pragma unroll
  for (int ks=0;ks<2;ks++){
    bf16x8 as_ = ldfrag(&Ssb[(w*16+lr)*68 + ks*32+kg*8]);
#pragma unroll
    for (int ni=0;ni<8;ni++){
      bf16x8 bb = ldfrag(&BwT[(ni*16+lr)*68 + ks*32+kg*8]);
      zac[ni]=__builtin_amdgcn_mfma_f32_16x16x32_bf16(as_,bb,zac[ni],0,0,0);
    }
  }
  __syncthreads();   // SkL/SvL/VT staged & visible
#pragma unroll
  for (int dt=0;dt<4;dt++){
    bf16x8 aq = ldfrag(&Qb[(w*16+lr)*132 + dt*32+kg*8]);
#pragma unroll
    for (int ni=0;ni<8;ni++){
      bf16x8 bs = ldfrag(&SkL[(ni*16+lr)*132 + dt*32+kg*8]);
      zac[ni]=__builtin_amdgcn_mfma_f32_16x16x32_bf16(aq,bs,zac[ni],0,0,0);
    }
  }
  float dec[4][8], zz[4][8];
#pragma unroll
  for (int vv2=0;vv2<4;vv2++)
#pragma unroll
    for (int ni=0;ni<8;ni++) zz[vv2][ni]=zac[ni][vv2];
#pragma unroll
  for (int vv2=0;vv2<4;vv2++){
    size_t gr=(size_t)(c*64+w*16+kg*4+vv2)*2048 + h*128;
#pragma unroll
    for (int ni=0;ni<8;ni++){
      float cgv = cg[gr + ni*16+lr];
      dec[vv2][ni] = __expf(cgv - cgm[ni*16+lr]);
    }
  }
#pragma unroll
  for (int vv2=0;vv2<4;vv2++){
    float mx=-3.0e38f;
#pragma unroll
    for (int ni=0;ni<8;ni++){ zz[vv2][ni] *= SCALE*dec[vv2][ni]; mx=fmaxf(mx,zz[vv2][ni]); }
    mx=fmaxf(mx,__shfl_xor(mx,1)); mx=fmaxf(mx,__shfl_xor(mx,2));
    mx=fmaxf(mx,__shfl_xor(mx,4)); mx=fmaxf(mx,__shfl_xor(mx,8));
    float sum=0.f;
#pragma unroll
    for (int ni=0;ni<8;ni++){ zz[vv2][ni]=__expf(zz[vv2][ni]-mx); sum+=zz[vv2][ni]; }
    sum+=__shfl_xor(sum,1); sum+=__shfl_xor(sum,2);
    sum+=__shfl_xor(sum,4); sum+=__shfl_xor(sum,8);
    float inv=1.f/sum;
#pragma unroll
    for (int ni=0;ni<8;ni++) zz[vv2][ni] *= inv*dec[vv2][ni];   // A' = a * e^{cg-cgm}
  }
#pragma unroll
  for (int vv2=0;vv2<4;vv2++)
#pragma unroll
    for (int ni=0;ni<8;ni++)
      Qb[(w*16+kg*4+vv2)*132 + ni*16+lr] = f2bf(zz[vv2][ni]);
  {
    f32x4 acc4[4];
#pragma unroll
    for (int a=0;a<4;a++) acc4[a]=vz;
#pragma unroll
    for (int ks=0;ks<4;ks++){
      bf16x8 aa = ldfrag(&Qb[(w*16+lr)*132 + ks*32+kg*8]);
#pragma unroll
      for (int ni=0;ni<4;ni++){
        bf16x8 bb = ldfrag(&Bws[(ni*16+lr)*132 + ks*32+kg*8]);
        acc4[ni]=__builtin_amdgcn_mfma_f32_16x16x32_bf16(aa,bb,acc4[ni],0,0,0);
      }
    }
#pragma unroll
    for (int ni=0;ni<4;ni++)
#pragma unroll
      for (int vv2=0;vv2<4;vv2++){
        int row=w*16+kg*4+vv2, col=ni*16+lr;
        Ssb[row*68+col] = (col<=row) ? f2bf(acc4[ni][vv2]) : (u16)0;
      }
  }
  f32x4 oac[8];
#pragma unroll
  for (int a=0;a<8;a++) oac[a]=vz;
#pragma unroll
  for (int ks=0;ks<2;ks++){
    bf16x8 ap = ldfrag(&Ssb[(w*16+lr)*68 + ks*32+kg*8]);
#pragma unroll
    for (int ni=0;ni<8;ni++){
      bf16x8 bv2 = ldfrag(&KV[(ni*16+lr)*68 + ks*32+kg*8]);
      oac[ni]=__builtin_amdgcn_mfma_f32_16x16x32_bf16(ap,bv2,oac[ni],0,0,0);
    }
  }
#pragma unroll
  for (int mt=0;mt<4;mt++){
    bf16x8 aa = ldfrag(&Qb[(w*16+lr)*132 + mt*32+kg*8]);
#pragma unroll
    for (int ni=0;ni<8;ni++){
      bf16x8 bs = ldfrag(&SvL[(ni*16+lr)*132 + mt*32+kg*8]);
      oac[ni]=__builtin_amdgcn_mfma_f32_16x16x32_bf16(aa,bs,oac[ni],0,0,0);
    }
  }
#pragma unroll
  for (int ni=0;ni<8;ni++)
#pragma unroll
    for (int vv2=0;vv2<4;vv2++)
      o[(size_t)(c*64+w*16+kg*4+vv2)*2048 + h*128 + ni*16+lr] = oac[ni][vv2];
}

// ---------------- gated RMSNorm -> bf16 ----------------
__global__ __launch_bounds__(256)
void norm_k(const float* __restrict__ o, const float* __restrict__ gate,
            const float* __restrict__ bg2, const float* __restrict__ nw,
            u16* __restrict__ Obf){
  int row = blockIdx.x*4 + (threadIdx.x>>6);
  int lane = threadIdx.x & 63;
  int t = row >> 4, h = row & 15;
  size_t base = (size_t)t*2048 + h*128;
  float o0 = o[base+lane], o1 = o[base+64+lane];
  float ss = o0*o0 + o1*o1;
#pragma unroll
  for (int off=1;off<64;off<<=1) ss += __shfl_xor(ss, off);
  float r = rsqrtf(ss*(1.f/128.f) + 1e-5f);
  int hv0 = h*128+lane, hv1 = hv0+64;
  float g0 = gate[base+lane]    + bg2[hv0];
  float g1 = gate[base+64+lane] + bg2[hv1];
  float v0 = o0*r*nw[lane]   *(1.f/(1.f+__expf(-g0)));
  float v1 = o1*r*nw[lane+64]*(1.f/(1.f+__expf(-g1)));
  Obf[base+lane]    = f2bf(v0);
  Obf[base+64+lane] = f2bf(v1);
}

extern "C" void kernel_launch(void* const* d_in, const int* in_sizes, int n_in,
                              void* d_out, int out_size, void* d_ws, size_t ws_size,
                              hipStream_t stream){
  (void)in_sizes; (void)n_in; (void)out_size; (void)ws_size;
  const float* hX   = (const float*)d_in[0];
  const float* Wq   = (const float*)d_in[1];
  const float* Wk   = (const float*)d_in[2];
  const float* Wv   = (const float*)d_in[3];
  const float* Ww   = (const float*)d_in[4];
  const float* cq   = (const float*)d_in[5];
  const float* ck   = (const float*)d_in[6];
  const float* cv   = (const float*)d_in[7];
  const float* Wf1  = (const float*)d_in[8];
  const float* Wf2  = (const float*)d_in[9];
  const float* Wb   = (const float*)d_in[10];
  const float* Wg1  = (const float*)d_in[11];
  const float* Wg2  = (const float*)d_in[12];
  const float* bg2  = (const float*)d_in[13];
  const float* nw   = (const float*)d_in[14];
  const float* Wo   = (const float*)d_in[15];
  char* ws = (char*)d_ws;
  u16*   h_bf  = (u16*)  (ws + 0);
  u16*   WcatT = (u16*)  (ws + 4194304);
  float* Sk0   = (float*)(ws + 4194304);            // reuses WcatT after GEMMs
  float* Sv0   = (float*)(ws + 20971520);
  u16*   WoT   = (u16*)  (ws + 37748736);
  u16*   WfgT  = (u16*)  (ws + 46137344);
  u16*   Wf2T  = (u16*)  (ws + 47185920);
  u16*   Wg2T  = (u16*)  (ws + 47710208);
  u16*   qkvw  = (u16*)  (ws + 48234496);           // bf16 [1024][8192]
  float* DSk   = (float*)(ws + 48234496);           // reuses qkvw after conv
  float* DSv   = (float*)(ws + 65011712);
  float* qb    = (float*)(ws + 81788928);
  float* kb    = (float*)(ws + 90177536);
  float* vb    = (float*)(ws + 98566144);
  float* wcv   = (float*)(ws + 106954752);
  float* P8    = wcv;                               // split-K partials (before conv)
  float* osc   = wcv;                               // reuses wconv after l2bw
  float* bwb   = (float*)(ws + 115343360);
  u16*   f1g1  = (u16*)  (ws + 123731968);
  float* gpre  = (float*)(ws + 124256256);
  float* gateb = gpre;                              // reuses gpre after cg
  float* cgb   = (float*)(ws + 132644864);
  float* betab = (float*)(ws + 141033472);
  u16*   Obf   = (u16*)  (ws + 141099008);
  float* outp  = (float*)d_out;

  // conversions
  f2bf_k<<<2048,256,0,stream>>>(hX, h_bf);
  transp64_k<<<dim3(32,32,5),256,0,stream>>>(Wq, Wk, Wv, Ww, Wo, WcatT, WoT);
  transp_k<<<dim3(4,64), 256,0,stream>>>(Wf1, WfgT, 2048, 128);
  transp_k<<<dim3(4,64), 256,0,stream>>>(Wg1, WfgT + (size_t)128*2048, 2048, 128);
  transp_k<<<dim3(64,4), 256,0,stream>>>(Wf2, Wf2T, 128, 2048);
  transp_k<<<dim3(64,4), 256,0,stream>>>(Wg2, Wg2T, 128, 2048);

  // projections
  gemm8_k<<<dim3(32,8),512,0,stream>>>(h_bf, WcatT, qkvw, 2048, 2048, 2048, 8192);
  gemmsk_k<<<dim3(2,8,8),256,0,stream>>>(h_bf, WfgT, P8, 2048, 2048);
  reduce8_k<<<256,256,0,stream>>>(P8, f1g1);
  gemm_k<false,1><<<dim3(16,8),256,0,stream>>>(f1g1, Wf2T, gpre, 128, 256, 128, 2048);
  beta_k<<<1024,256,0,stream>>>(hX, Wb, betab);

  // conv + silu, l2norm*beta, chunk cumsum
  conv_k<<<8192,256,0,stream>>>(qkvw, cq, ck, cv, qb, kb, vb, wcv);
  l2bw_k<<<4096,256,0,stream>>>(wcv, betab, bwb);
  cg_k<<<128,256,0,stream>>>(gpre, cgb);

  // gate GEMM (into gpre buffer, safe after cg)
  gemm_k<false,0><<<dim3(16,8),256,0,stream>>>(f1g1 + 128, Wg2T, gateb, 128, 256, 128, 2048);

  // chunked scan
  phaseA_k<<<256,256,0,stream>>>(kb, vb, bwb, cgb, DSk, DSv);
  phaseB_k<<<2048,256,0,stream>>>(DSk, DSv, cgb, Sk0, Sv0);
  phaseC_k<<<256,256,0,stream>>>(qb, kb, vb, bwb, cgb, Sk0, Sv0, osc);

  // gated RMSNorm + output projection
  norm_k<<<4096,256,0,stream>>>(osc, gateb, bg2, nw, Obf);
  gemm_k<false,0><<<dim3(16,8),256,0,stream>>>(Obf, WoT, outp, 2048, 2048, 2048, 2048);
}

// Round 6
// 242.734 us; speedup vs baseline: 3.4703x; 1.0102x over previous
//
#include <hip/hip_runtime.h>
#include <hip/hip_bf16.h>
#include <stdint.h>

typedef unsigned short u16;
typedef __attribute__((ext_vector_type(8))) short bf16x8;
typedef __attribute__((ext_vector_type(4))) short bf16x4;
typedef __attribute__((ext_vector_type(4))) float f32x4;

#define DEV static __device__ __forceinline__

DEV u16 f2bf(float f){
  union { float f; unsigned u; } x; x.f = f;
  unsigned r = x.u + 0x7fffu + ((x.u >> 16) & 1u);
  return (u16)(r >> 16);
}

DEV float bf2f(u16 u){
  union { unsigned u; float f; } x; x.u = ((unsigned)u) << 16; return x.f;
}

DEV bf16x8 ldfrag(const u16* p){           // two ds_read_b64 (8B-aligned rows)
  bf16x4 a = *(const bf16x4*)p;
  bf16x4 b = *(const bf16x4*)(p+4);
  bf16x8 r;
  r[0]=a[0]; r[1]=a[1]; r[2]=a[2]; r[3]=a[3];
  r[4]=b[0]; r[5]=b[1]; r[6]=b[2]; r[7]=b[3];
  return r;
}

DEV bf16x4 cvt4(float a, float b, float c, float d){
  bf16x4 r; r[0]=(short)f2bf(a); r[1]=(short)f2bf(b); r[2]=(short)f2bf(c); r[3]=(short)f2bf(d);
  return r;
}

DEV void g2l16(const void* g, void* l){
  __builtin_amdgcn_global_load_lds((const __attribute__((address_space(1))) unsigned int*)g,
                                   (__attribute__((address_space(3))) unsigned int*)l,
                                   16, 0, 0);
}

// ---------------- f32 -> bf16 straight convert ----------------
__global__ __launch_bounds__(256)
void f2bf_k(const float* __restrict__ in, u16* __restrict__ out){
  int idx = blockIdx.x*256 + threadIdx.x;
  float4 v = *(const float4*)&in[(size_t)idx*4];
  u16 a = f2bf(v.x), b = f2bf(v.y), c = f2bf(v.z), d = f2bf(v.w);
  ushort4 o4; o4.x=a; o4.y=b; o4.z=c; o4.w=d;
  *(ushort4*)&out[(size_t)idx*4] = o4;
}

// ---------------- fused 2048x2048 f32 -> bf16 transposes (Wq,Wk,Wv,Ww,Wo) ----------------
__global__ __launch_bounds__(256)
void transp64_k(const float* __restrict__ Wq, const float* __restrict__ Wk,
                const float* __restrict__ Wv, const float* __restrict__ Ww,
                const float* __restrict__ Wo, u16* __restrict__ WcatT, u16* __restrict__ WoT){
  __shared__ float tile[64][65];
  const int z = blockIdx.z;
  const float* src = (z==0)?Wq:((z==1)?Wk:((z==2)?Wv:((z==3)?Ww:Wo)));
  u16* dst = (z<4) ? (WcatT + (size_t)z*4194304) : WoT;
  const int c0 = blockIdx.x*64, r0 = blockIdx.y*64;
#pragma unroll
  for (int p=0;p<4;p++){
    int i = threadIdx.x + p*256;
    int r = i>>4, c4 = (i&15)<<2;
    *(float4*)&tile[r][c4] = *(const float4*)&src[(size_t)(r0+r)*2048 + c0 + c4];
  }
  __syncthreads();
#pragma unroll
  for (int p=0;p<4;p++){
    int i = threadIdx.x + p*256;
    int cc = i>>4, r4 = (i&15)<<2;
    ushort4 o;
    o.x = f2bf(tile[r4+0][cc]); o.y = f2bf(tile[r4+1][cc]);
    o.z = f2bf(tile[r4+2][cc]); o.w = f2bf(tile[r4+3][cc]);
    *(ushort4*)&dst[(size_t)(c0+cc)*2048 + r0 + r4] = o;
  }
}

// ---------------- f32 [R][C] -> bf16 [C][R] transpose (small mats) ----------------
__global__ __launch_bounds__(256)
void transp_k(const float* __restrict__ in, u16* __restrict__ out, int R, int C){
  __shared__ float tile[32][33];
  const int c0 = blockIdx.x*32, r0 = blockIdx.y*32;
  const int x = threadIdx.x & 31, y0 = threadIdx.x >> 5;
#pragma unroll
  for (int j=0;j<4;j++){
    int r = y0 + j*8;
    tile[r][x] = in[(size_t)(r0+r)*C + c0 + x];
  }
  __syncthreads();
#pragma unroll
  for (int j=0;j<4;j++){
    int cc = y0 + j*8;
    out[(size_t)(c0+cc)*R + r0 + x] = f2bf(tile[x][cc]);
  }
}

// ---------------- big GEMM: 128x256, BK=64, 8 waves, dbuf + counted vmcnt (T4) ----------------
// A[M,K] row (lda), B^T[N,K] row (ldb) -> C[M,N] bf16 (ldc)
__global__ __launch_bounds__(512)
void gemm8_k(const u16* __restrict__ A, const u16* __restrict__ B, u16* __restrict__ C,
             int K, int lda, int ldb, int ldc){
  __shared__ u16 As[2][128*64];
  __shared__ u16 Bs[2][256*64];
  const int m0 = blockIdx.y*128, n0 = blockIdx.x*256;
  const int tid = threadIdx.x;
  const int wave = tid>>6, lane = tid&63, lr = lane&15, kg = lane>>4;
  const int wm = wave>>2, wn = wave&3;
  const f32x4 vz = {0.f,0.f,0.f,0.f};
  f32x4 acc[4][4];
#pragma unroll
  for (int a=0;a<4;a++)
#pragma unroll
    for (int b=0;b<4;b++) acc[a][b]=vz;

#define STAGE8(buf, k0) do { \
    _Pragma("unroll") \
    for (int p=0;p<2;p++){ \
      int chunk = tid + p*512, r_ = chunk>>3, ci = chunk&7; \
      g2l16(A + (size_t)(m0+r_)*lda + (k0) + ((ci^(r_&7))<<3), &As[buf][chunk*8]); \
    } \
    _Pragma("unroll") \
    for (int p=0;p<4;p++){ \
      int chunk = tid + p*512, r_ = chunk>>3, ci = chunk&7; \
      g2l16(B + (size_t)(n0+r_)*ldb + (k0) + ((ci^(r_&7))<<3), &Bs[buf][chunk*8]); \
    } \
  } while(0)

  const int nt = K>>6;          // >= 2 required (K=2048 -> 32)
  STAGE8(0, 0);
  STAGE8(1, 64);
  for (int t=0; t<nt; ++t){
    const int buf = t&1;
    // wait for THIS wave's 6 loads of buf t (6 newer stay in flight), then block barrier
    if (t < nt-1) asm volatile("s_waitcnt vmcnt(6)" ::: "memory");
    else          asm volatile("s_waitcnt vmcnt(0)" ::: "memory");
    asm volatile("s_barrier" ::: "memory");
    __builtin_amdgcn_sched_barrier(0);
#pragma unroll
    for (int ks=0; ks<2; ++ks){
      bf16x8 af[4], bfv[4];
#pragma unroll
      for (int mi=0;mi<4;mi++){
        int r = wm*64+mi*16+lr;
        af[mi] = *(const bf16x8*)&As[buf][r*64 + (((ks*4+kg)^(r&7))<<3)];
      }
#pragma unroll
      for (int ni=0;ni<4;ni++){
        int r = wn*64+ni*16+lr;
        bfv[ni] = *(const bf16x8*)&Bs[buf][r*64 + (((ks*4+kg)^(r&7))<<3)];
      }
#pragma unroll
      for (int mi=0;mi<4;mi++)
#pragma unroll
        for (int ni=0;ni<4;ni++)
          acc[mi][ni] = __builtin_amdgcn_mfma_f32_16x16x32_bf16(af[mi], bfv[ni], acc[mi][ni], 0, 0, 0);
    }
    __builtin_amdgcn_sched_barrier(0);
    asm volatile("s_barrier" ::: "memory");   // all waves done reading buf -> safe to overwrite
    if (t+2 < nt) STAGE8(buf, (t+2)<<6);
  }
#undef STAGE8
#pragma unroll
  for (int mi=0;mi<4;mi++)
#pragma unroll
    for (int ni=0;ni<4;ni++)
#pragma unroll
      for (int vv=0;vv<4;vv++){
        int row = m0 + wm*64 + mi*16 + kg*4 + vv;
        int col = n0 + wn*64 + ni*16 + lr;
        C[(size_t)row*ldc + col] = f2bf(acc[mi][ni][vv]);
      }
}

// ---------------- bf16 GEMM (128^2, BK=32): EPI 0=none 1=logsigmoid ----------------
template<bool OBF, int EPI>
__global__ __launch_bounds__(256)
void gemm_k(const u16* __restrict__ A, const u16* __restrict__ B, void* __restrict__ Cp,
            int K, int lda, int ldb, int ldc){
  __shared__ u16 As[128*32];
  __shared__ u16 Bs[128*32];
  const int m0 = blockIdx.y*128, n0 = blockIdx.x*128;
  const int tid = threadIdx.x;
  const int lane = tid & 63, wave = tid >> 6;
  const int wr = wave >> 1, wc = wave & 1;
  const int lr = lane & 15, kg = lane >> 4;
  const f32x4 vzero = {0.f,0.f,0.f,0.f};
  f32x4 acc[4][4];
#pragma unroll
  for (int a=0;a<4;a++)
#pragma unroll
    for (int b=0;b<4;b++) acc[a][b] = vzero;
  const int r0 = tid>>2, s0 = tid&3;
  for (int k0=0;k0<K;k0+=32){
    __syncthreads();
    g2l16(A + (size_t)(m0+r0)*lda + k0 + s0*8, (u16*)As + (size_t)tid*8);
    g2l16(B + (size_t)(n0+r0)*ldb + k0 + s0*8, (u16*)Bs + (size_t)tid*8);
    g2l16(A + (size_t)(m0+r0+64)*lda + k0 + s0*8, (u16*)As + (size_t)(tid+256)*8);
    g2l16(B + (size_t)(n0+r0+64)*ldb + k0 + s0*8, (u16*)Bs + (size_t)(tid+256)*8);
    __syncthreads();
    bf16x8 af[4], bfv[4];
#pragma unroll
    for (int mi=0;mi<4;mi++) af[mi]  = *(const bf16x8*)(As + (wr*64+mi*16+lr)*32 + kg*8);
#pragma unroll
    for (int ni=0;ni<4;ni++) bfv[ni] = *(const bf16x8*)(Bs + (wc*64+ni*16+lr)*32 + kg*8);
#pragma unroll
    for (int mi=0;mi<4;mi++)
#pragma unroll
      for (int ni=0;ni<4;ni++)
        acc[mi][ni] = __builtin_amdgcn_mfma_f32_16x16x32_bf16(af[mi], bfv[ni], acc[mi][ni], 0, 0, 0);
  }
#pragma unroll
  for (int mi=0;mi<4;mi++)
#pragma unroll
    for (int ni=0;ni<4;ni++)
#pragma unroll
      for (int vv=0;vv<4;vv++){
        int row = m0 + wr*64 + mi*16 + kg*4 + vv;
        int col = n0 + wc*64 + ni*16 + lr;
        float val = acc[mi][ni][vv];
        if (EPI==1) val = fminf(val,0.f) - __logf(1.f + __expf(-fabsf(val)));
        if (OBF) ((u16*)Cp)[(size_t)row*ldc + col] = f2bf(val);
        else     ((float*)Cp)[(size_t)row*ldc + col] = val;
      }
}

// ---------------- split-K GEMM for f1g1 (N=256, K=2048 in 8 chunks) ----------------
__global__ __launch_bounds__(256)
void gemmsk_k(const u16* __restrict__ A, const u16* __restrict__ B, float* __restrict__ P,
              int lda, int ldb){
  __shared__ u16 As[128*32];
  __shared__ u16 Bs[128*32];
  const int m0 = blockIdx.y*128, n0 = blockIdx.x*128;
  const int kbase = blockIdx.z*256;
  const int tid = threadIdx.x;
  const int lane = tid & 63, wave = tid >> 6;
  const int wr = wave >> 1, wc = wave & 1;
  const int lr = lane & 15, kg = lane >> 4;
  const f32x4 vzero = {0.f,0.f,0.f,0.f};
  f32x4 acc[4][4];
#pragma unroll
  for (int a=0;a<4;a++)
#pragma unroll
    for (int b=0;b<4;b++) acc[a][b] = vzero;
  const int r0 = tid>>2, s0 = tid&3;
  for (int k0=kbase;k0<kbase+256;k0+=32){
    __syncthreads();
    g2l16(A + (size_t)(m0+r0)*lda + k0 + s0*8, (u16*)As + (size_t)tid*8);
    g2l16(B + (size_t)(n0+r0)*ldb + k0 + s0*8, (u16*)Bs + (size_t)tid*8);
    g2l16(A + (size_t)(m0+r0+64)*lda + k0 + s0*8, (u16*)As + (size_t)(tid+256)*8);
    g2l16(B + (size_t)(n0+r0+64)*ldb + k0 + s0*8, (u16*)Bs + (size_t)(tid+256)*8);
    __syncthreads();
    bf16x8 af[4], bfv[4];
#pragma unroll
    for (int mi=0;mi<4;mi++) af[mi]  = *(const bf16x8*)(As + (wr*64+mi*16+lr)*32 + kg*8);
#pragma unroll
    for (int ni=0;ni<4;ni++) bfv[ni] = *(const bf16x8*)(Bs + (wc*64+ni*16+lr)*32 + kg*8);
#pragma unroll
    for (int mi=0;mi<4;mi++)
#pragma unroll
      for (int ni=0;ni<4;ni++)
        acc[mi][ni] = __builtin_amdgcn_mfma_f32_16x16x32_bf16(af[mi], bfv[ni], acc[mi][ni], 0, 0, 0);
  }
#pragma unroll
  for (int mi=0;mi<4;mi++)
#pragma unroll
    for (int ni=0;ni<4;ni++)
#pragma unroll
      for (int vv=0;vv<4;vv++){
        int row = m0 + wr*64 + mi*16 + kg*4 + vv;
        int col = n0 + wc*64 + ni*16 + lr;
        P[(size_t)blockIdx.z*262144 + (size_t)row*256 + col] = acc[mi][ni][vv];
      }
}

__global__ __launch_bounds__(256)
void reduce8_k(const float* __restrict__ P, u16* __restrict__ out){
  int i = (blockIdx.x*256 + threadIdx.x)*4;
  float4 s = *(const float4*)&P[i];
#pragma unroll
  for (int z=1;z<8;z++){
    float4 p = *(const float4*)&P[(size_t)z*262144 + i];
    s.x+=p.x; s.y+=p.y; s.z+=p.z; s.w+=p.w;
  }
  ushort4 o; o.x=f2bf(s.x); o.y=f2bf(s.y); o.z=f2bf(s.z); o.w=f2bf(s.w);
  *(ushort4*)&out[i] = o;
}

// ---------------- beta = sigmoid(h @ Wb), per-t block ----------------
__global__ __launch_bounds__(256)
void beta_k(const float* __restrict__ h, const float* __restrict__ Wb, float* __restrict__ betab){
  __shared__ float hrow[2048];
  __shared__ float red[16][5];
  const int t = blockIdx.x, tid = threadIdx.x;
#pragma unroll
  for (int j=0;j<8;j++) hrow[tid + j*256] = h[(size_t)t*2048 + tid + j*256];
  __syncthreads();
  float part[16];
#pragma unroll
  for (int n=0;n<16;n++) part[n]=0.f;
  for (int j=0;j<8;j++){
    int kk = tid + j*256;
    float hv = hrow[kk];
    const float4* wr4 = (const float4*)&Wb[(size_t)kk*16];
    float4 w0=wr4[0], w1=wr4[1], w2=wr4[2], w3=wr4[3];
    part[0]+=hv*w0.x; part[1]+=hv*w0.y; part[2]+=hv*w0.z; part[3]+=hv*w0.w;
    part[4]+=hv*w1.x; part[5]+=hv*w1.y; part[6]+=hv*w1.z; part[7]+=hv*w1.w;
    part[8]+=hv*w2.x; part[9]+=hv*w2.y; part[10]+=hv*w2.z; part[11]+=hv*w2.w;
    part[12]+=hv*w3.x; part[13]+=hv*w3.y; part[14]+=hv*w3.z; part[15]+=hv*w3.w;
  }
#pragma unroll
  for (int n=0;n<16;n++){
    float s = part[n];
#pragma unroll
    for (int off=1;off<64;off<<=1) s += __shfl_xor(s, off);
    if ((tid&63)==0) red[n][tid>>6] = s;
  }
  __syncthreads();
  if (tid < 16){
    float s = red[tid][0]+red[tid][1]+red[tid][2]+red[tid][3];
    betab[t*16+tid] = 1.f/(1.f+__expf(-s));
  }
}

// ---------------- causal conv4 + silu: q,k,v -> bf16 ; w -> f32 ----------------
__global__ __launch_bounds__(256)
void conv_k(const u16* __restrict__ raw, const float* __restrict__ cq,
            const float* __restrict__ ck, const float* __restrict__ cv,
            u16* __restrict__ qo, u16* __restrict__ ko,
            u16* __restrict__ vo, float* __restrict__ wo){
  int idx = blockIdx.x*256 + threadIdx.x;
  int cgl = idx & 8191, tb = idx >> 13;
  int which = cgl >> 11, cc = cgl & 2047;
  const float* wt = (which==0)?cq:((which==1)?ck:cv);   // w-branch (3) uses cv (faithful to ref)
  float4 w4 = *(const float4*)&wt[cc*4];
  u16* outb = (which==0)?qo:((which==1)?ko:vo);
  int t0 = tb*4;
  float x[7];
#pragma unroll
  for (int j=0;j<7;j++){
    int t = t0 - 3 + j;
    x[j] = (t >= 0) ? bf2f(raw[(size_t)t*8192 + cgl]) : 0.f;
  }
#pragma unroll
  for (int j=0;j<4;j++){
    float y = x[j]*w4.x + x[j+1]*w4.y + x[j+2]*w4.z + x[j+3]*w4.w;
    y = y / (1.f + __expf(-y));           // silu
    if (which==3) wo[(size_t)(t0+j)*2048 + cc] = y;
    else          outb[(size_t)(t0+j)*2048 + cc] = f2bf(y);
  }
}

// ---------------- l2norm over M + beta scale: bw ----------------
__global__ __launch_bounds__(256)
void l2bw_k(const float* __restrict__ wconv, const float* __restrict__ betab,
            float* __restrict__ bwout){
  int row = blockIdx.x*4 + (threadIdx.x>>6);
  int lane = threadIdx.x & 63;
  int t = row >> 4, h = row & 15;
  size_t base = (size_t)t*2048 + h*128;
  float a0 = wconv[base+lane], a1 = wconv[base+64+lane];
  float ss = a0*a0 + a1*a1;
#pragma unroll
  for (int off=1;off<64;off<<=1) ss += __shfl_xor(ss, off);
  float r = rsqrtf(ss + 1e-6f) * betab[t*16+h];
  bwout[base+lane]    = a0*r;
  bwout[base+64+lane] = a1*r;
}

// ---------------- per-chunk inclusive cumsum (gpre already = logsigmoid) ----------------
__global__ __launch_bounds__(256)
void cg_k(const float* __restrict__ gpre, float* __restrict__ cg){
  int idx = blockIdx.x*256 + threadIdx.x;   // 32768 = c*2048 + h*128 + m
  int c = idx >> 11;
  size_t base = (size_t)(idx & 2047);
  float run = 0.f;
  for (int i2=0;i2<64;i2++){
    size_t t = (size_t)c*64 + i2;
    run += gpre[t*2048 + base];
    cg[t*2048 + base] = run;
  }
}

// ---------------- Phase A (MFMA): DSkT[m][d] = U^T K ; DSvT[v][m] = V^T U ----------------
__global__ __launch_bounds__(256)
void phaseA_k(const u16* __restrict__ k, const u16* __restrict__ v,
              const float* __restrict__ bw, const float* __restrict__ cg,
              float* __restrict__ DSkT, float* __restrict__ DSvT){
  __shared__ u16 UT[128*68];
  __shared__ u16 KT[128*68];
  __shared__ u16 VT[128*68];
  __shared__ float Gt[128];
  const int bx=blockIdx.x, h=bx&15, c=bx>>4, tid=threadIdx.x;
  const int w=tid>>6, lane=tid&63, lr=lane&15, kg=lane>>4;
  if (tid<128) Gt[tid] = cg[(size_t)(c*64+63)*2048 + h*128 + tid];
  __syncthreads();
#pragma unroll
  for (int j=0;j<8;j++){
    int f4=tid+j*256, r=f4>>5, c4=(f4&31)<<2;
    size_t g=(size_t)(c*64+r)*2048 + h*128 + c4;
    ushort4 kv=*(const ushort4*)&k[g];
    ushort4 vv=*(const ushort4*)&v[g];
    float4 bv=*(const float4*)&bw[g];
    float4 cv=*(const float4*)&cg[g];
    float u0=bv.x*__expf(Gt[c4+0]-cv.x);
    float u1=bv.y*__expf(Gt[c4+1]-cv.y);
    float u2=bv.z*__expf(Gt[c4+2]-cv.z);
    float u3=bv.w*__expf(Gt[c4+3]-cv.w);
    KT[(c4+0)*68+r]=kv.x; KT[(c4+1)*68+r]=kv.y;
    KT[(c4+2)*68+r]=kv.z; KT[(c4+3)*68+r]=kv.w;
    VT[(c4+0)*68+r]=vv.x; VT[(c4+1)*68+r]=vv.y;
    VT[(c4+2)*68+r]=vv.z; VT[(c4+3)*68+r]=vv.w;
    UT[(c4+0)*68+r]=f2bf(u0);   UT[(c4+1)*68+r]=f2bf(u1);
    UT[(c4+2)*68+r]=f2bf(u2);   UT[(c4+3)*68+r]=f2bf(u3);
  }
  __syncthreads();
  const f32x4 vz = {0.f,0.f,0.f,0.f};
  {
    f32x4 acc[2][8];
#pragma unroll
    for (int a=0;a<2;a++)
#pragma unroll
      for (int b=0;b<8;b++) acc[a][b]=vz;
#pragma unroll
    for (int ks=0;ks<2;ks++){
      bf16x8 a0=ldfrag(&UT[(w*32   +lr)*68 + ks*32+kg*8]);
      bf16x8 a1=ldfrag(&UT[(w*32+16+lr)*68 + ks*32+kg*8]);
#pragma unroll
      for (int nj=0;nj<8;nj++){
        bf16x8 b=ldfrag(&KT[(nj*16+lr)*68 + ks*32+kg*8]);
        acc[0][nj]=__builtin_amdgcn_mfma_f32_16x16x32_bf16(a0,b,acc[0][nj],0,0,0);
        acc[1][nj]=__builtin_amdgcn_mfma_f32_16x16x32_bf16(a1,b,acc[1][nj],0,0,0);
      }
    }
#pragma unroll
    for (int mi2=0;mi2<2;mi2++)
#pragma unroll
      for (int nj=0;nj<8;nj++)
#pragma unroll
        for (int vv2=0;vv2<4;vv2++)
          DSkT[(size_t)bx*16384 + (size_t)(w*32+mi2*16+kg*4+vv2)*128 + nj*16+lr] = acc[mi2][nj][vv2];
  }
  {
    f32x4 acc[2][8];
#pragma unroll
    for (int a=0;a<2;a++)
#pragma unroll
      for (int b=0;b<8;b++) acc[a][b]=vz;
#pragma unroll
    for (int ks=0;ks<2;ks++){
      bf16x8 a0=ldfrag(&VT[(w*32   +lr)*68 + ks*32+kg*8]);
      bf16x8 a1=ldfrag(&VT[(w*32+16+lr)*68 + ks*32+kg*8]);
#pragma unroll
      for (int nj=0;nj<8;nj++){
        bf16x8 b=ldfrag(&UT[(nj*16+lr)*68 + ks*32+kg*8]);
        acc[0][nj]=__builtin_amdgcn_mfma_f32_16x16x32_bf16(a0,b,acc[0][nj],0,0,0);
        acc[1][nj]=__builtin_amdgcn_mfma_f32_16x16x32_bf16(a1,b,acc[1][nj],0,0,0);
      }
    }
#pragma unroll
    for (int mi2=0;mi2<2;mi2++)
#pragma unroll
      for (int nj=0;nj<8;nj++)
#pragma unroll
        for (int vv2=0;vv2<4;vv2++)
          DSvT[(size_t)bx*16384 + (size_t)(w*32+mi2*16+kg*4+vv2)*128 + nj*16+lr] = acc[mi2][nj][vv2];
  }
}

// ---------------- Phase B: sequential cross-chunk combine -> bf16 snapshots ----------------
__global__ __launch_bounds__(256)
void phaseB_k(const float* __restrict__ DSk, const float* __restrict__ DSv,
              const float* __restrict__ cg, u16* __restrict__ Sk0, u16* __restrict__ Sv0){
  unsigned idx = blockIdx.x*256u + threadIdx.x;   // 524288 total
  int sel  = idx >> 18;
  int h    = (idx >> 14) & 15;
  int flat = idx & 16383;                 // SkT: m*128+d ; SvT: v*128+m
  int mdec = sel ? (flat & 127) : (flat >> 7);
  const float* DS = sel ? DSv : DSk;
  u16* S = sel ? Sv0 : Sk0;
  float cur = 0.f;
  for (int c=0;c<16;c++){
    size_t sb = ((size_t)(c*16+h))*16384 + flat;
    S[sb] = f2bf(cur);                     // state BEFORE chunk c
    float gd = __expf(cg[(size_t)(c*64+63)*2048 + h*128 + mdec]);
    cur = cur*gd + DS[sb];
  }
}

// ---------------- Phase C (MFMA): per-chunk outputs ----------------
__global__ __launch_bounds__(256)
void phaseC_k(const u16* __restrict__ q, const u16* __restrict__ k,
              const u16* __restrict__ v, const float* __restrict__ bw,
              const float* __restrict__ cg, const u16* __restrict__ SkT,
              const u16* __restrict__ SvT, float* __restrict__ o){
  __shared__ u16 Qb[64*132];     // Q, then A' (wave-private rows after prep)
  __shared__ u16 KV[8704];       // K[64][132], then VT[128][68]
  __shared__ u16 Bws[64*132];    // bw*e^{cgm-cg} natural [s][m]
  __shared__ u16 BwT[128*68];    // transposed [m][s]
  __shared__ u16 Ssb[64*68];     // sqk, then P (wave-private rows)
  __shared__ u16 SkL[128*132];   // Sk'^T * e^{cgm[m]}  [m][d]
  __shared__ u16 SvL[128*132];   // Sv'^T * e^{cgm[m]}  [v][m]
  __shared__ float cgm[128];
  __shared__ float ecgm[128];
  const int bx=blockIdx.x, h=bx&15, c=bx>>4, tid=threadIdx.x;
  const int w=tid>>6, lane=tid&63, lr=lane&15, kg=lane>>4;
  const float SCALE = 0.088388347648318447f;   // 128^-0.5
  const f32x4 vz = {0.f,0.f,0.f,0.f};
  if (tid<128){ float t=cg[(size_t)(c*64+31)*2048 + h*128 + tid]; cgm[tid]=t; ecgm[tid]=__expf(t); }
  __syncthreads();
#pragma unroll
  for (int j=0;j<8;j++){
    int f4=tid+j*256, r=f4>>5, c4=(f4&31)<<2;
    size_t g=(size_t)(c*64+r)*2048 + h*128 + c4;
    *(ushort4*)&Qb[r*132+c4] = *(const ushort4*)&q[g];
    *(ushort4*)&KV[r*132+c4] = *(const ushort4*)&k[g];
    float4 bv=*(const float4*)&bw[g];
    float4 cv=*(const float4*)&cg[g];
    float b0=bv.x*__expf(cgm[c4+0]-cv.x);
    float b1=bv.y*__expf(cgm[c4+1]-cv.y);
    float b2=bv.z*__expf(cgm[c4+2]-cv.z);
    float b3=bv.w*__expf(cgm[c4+3]-cv.w);
    bf16x4 bb = cvt4(b0,b1,b2,b3);
    *(bf16x4*)&Bws[r*132+c4] = bb;
    BwT[(c4+0)*68+r]=(u16)bb[0]; BwT[(c4+1)*68+r]=(u16)bb[1];
    BwT[(c4+2)*68+r]=(u16)bb[2]; BwT[(c4+3)*68+r]=(u16)bb[3];
  }
  __syncthreads();
  {
    f32x4 acc1[4];
#pragma unroll
    for (int a=0;a<4;a++) acc1[a]=vz;
#pragma unroll
    for (int ks=0;ks<4;ks++){
      bf16x8 aq = ldfrag(&Qb[(w*16+lr)*132 + ks*32+kg*8]);
#pragma unroll
      for (int ni=0;ni<4;ni++){
        bf16x8 bk = ldfrag(&KV[(ni*16+lr)*132 + ks*32+kg*8]);
        acc1[ni]=__builtin_amdgcn_mfma_f32_16x16x32_bf16(aq,bk,acc1[ni],0,0,0);
      }
    }
#pragma unroll
    for (int ni=0;ni<4;ni++)
#pragma unroll
      for (int vv2=0;vv2<4;vv2++){
        int row=w*16+kg*4+vv2, col=ni*16+lr;
        Ssb[row*68+col] = (col<=row) ? f2bf(acc1[ni][vv2]) : (u16)0;
      }
  }
  __syncthreads();   // all K reads done -> KV reusable for VT
#pragma unroll
  for (int j=0;j<8;j++){
    int f4=tid+j*256, r=f4>>5, c4=(f4&31)<<2;
    ushort4 vv=*(const ushort4*)&v[(size_t)(c*64+r)*2048 + h*128 + c4];
    KV[(c4+0)*68+r]=vv.x; KV[(c4+1)*68+r]=vv.y;
    KV[(c4+2)*68+r]=vv.z; KV[(c4+3)*68+r]=vv.w;
  }
#pragma unroll
  for (int j=0;j<16;j++){
    int f4=tid+j*256, r=f4>>5, c4=(f4&31)<<2;
    ushort4 s4=*(const ushort4*)&SkT[(size_t)bx*16384 + (size_t)r*128 + c4];
    float em=ecgm[r];
    *(bf16x4*)&SkL[r*132+c4]=cvt4(bf2f(s4.x)*em, bf2f(s4.y)*em, bf2f(s4.z)*em, bf2f(s4.w)*em);
  }
#pragma unroll
  for (int j=0;j<16;j++){
    int f4=tid+j*256, r=f4>>5, c4=(f4&31)<<2;
    ushort4 s4=*(const ushort4*)&SvT[(size_t)bx*16384 + (size_t)r*128 + c4];
    *(bf16x4*)&SvL[r*132+c4]=cvt4(bf2f(s4.x)*ecgm[c4+0], bf2f(s4.y)*ecgm[c4+1],
                                  bf2f(s4.z)*ecgm[c4+2], bf2f(s4.w)*ecgm[c4+3]);
  }
  f32x4 zac[8];
#pragma unroll
  for (int a=0;a<8;a++) zac[a]=vz;
#pragma unroll
  for (int ks=0;ks<2;ks++){
    bf16x8 as_ = ldfrag(&Ssb[(w*16+lr)*68 + ks*32+kg*8]);
#pragma unroll
    for (int ni=0;ni<8;ni++){
      bf16x8 bb = ldfrag(&BwT[(ni*16+lr)*68 + ks*32+kg*8]);
      zac[ni]=__builtin_amdgcn_mfma_f32_16x16x32_bf16(as_,bb,zac[ni],0,0,0);
    }
  }
  __syncthreads();   // SkL/SvL/VT staged & visible
#pragma unroll
  for (int dt=0;dt<4;dt++){
    bf16x8 aq = ldfrag(&Qb[(w*16+lr)*132 + dt*32+kg*8]);
#pragma unroll
    for (int ni=0;ni<8;ni++){
      bf16x8 bs = ldfrag(&SkL[(ni*16+lr)*132 + dt*32+kg*8]);
      zac[ni]=__builtin_amdgcn_mfma_f32_16x16x32_bf16(aq,bs,zac[ni],0,0,0);
    }
  }
  float dec[4][8], zz[4][8];
#pragma unroll
  for (int vv2=0;vv2<4;vv2++)
#pragma unroll
    for (int ni=0;ni<8;ni++) zz[vv2][ni]=zac[ni][vv2];
#pragma unroll
  for (int vv2=0;vv2<4;vv2++){
    size_t gr=(size_t)(c*64+w*16+kg*4+vv2)*2048 + h*128;
#pragma unroll
    for (int ni=0;ni<8;ni++){
      float cgv = cg[gr + ni*16+lr];
      dec[vv2][ni] = __expf(cgv - cgm[ni*16+lr]);
    }
  }
#pragma unroll
  for (int vv2=0;vv2<4;vv2++){
    float mx=-3.0e38f;
#pragma unroll
    for (int ni=0;ni<8;ni++){ zz[vv2][ni] *= SCALE*dec[vv2][ni]; mx=fmaxf(mx,zz[vv2][ni]); }
    mx=fmaxf(mx,__shfl_xor(mx,1)); mx=fmaxf(mx,__shfl_xor(mx,2));
    mx=fmaxf(mx,__shfl_xor(mx,4)); mx=fmaxf(mx,__shfl_xor(mx,8));
    float sum=0.f;
#pragma unroll
    for (int ni=0;ni<8;ni++){ zz[vv2][ni]=__expf(zz[vv2][ni]-mx); sum+=zz[vv2][ni]; }
    sum+=__shfl_xor(sum,1); sum+=__shfl_xor(sum,2);
    sum+=__shfl_xor(sum,4); sum+=__shfl_xor(sum,8);
    float inv=1.f/sum;
#pragma unroll
    for (int ni=0;ni<8;ni++) zz[vv2][ni] *= inv*dec[vv2][ni];   // A' = a * e^{cg-cgm}
  }
#pragma unroll
  for (int vv2=0;vv2<4;vv2++)
#pragma unroll
    for (int ni=0;ni<8;ni++)
      Qb[(w*16+kg*4+vv2)*132 + ni*16+lr] = f2bf(zz[vv2][ni]);
  {
    f32x4 acc4[4];
#pragma unroll
    for (int a=0;a<4;a++) acc4[a]=vz;
#pragma unroll
    for (int ks=0;ks<4;ks++){
      bf16x8 aa = ldfrag(&Qb[(w*16+lr)*132 + ks*32+kg*8]);
#pragma unroll
      for (int ni=0;ni<4;ni++){
        bf16x8 bb = ldfrag(&Bws[(ni*16+lr)*132 + ks*32+kg*8]);
        acc4[ni]=__builtin_amdgcn_mfma_f32_16x16x32_bf16(aa,bb,acc4[ni],0,0,0);
      }
    }
#pragma unroll
    for (int ni=0;ni<4;ni++)
#pragma unroll
      for (int vv2=0;vv2<4;vv2++){
        int row=w*16+kg*4+vv2, col=ni*16+lr;
        Ssb[row*68+col] = (col<=row) ? f2bf(acc4[ni][vv2]) : (u16)0;
      }
  }
  f32x4 oac[8];
#pragma unroll
  for (int a=0;a<8;a++) oac[a]=vz;
#pragma unroll
  for (int ks=0;ks<2;ks++){
    bf16x8 ap = ldfrag(&Ssb[(w*16+lr)*68 + ks*32+kg*8]);
#pragma unroll
    for (int ni=0;ni<8;ni++){
      bf16x8 bv2 = ldfrag(&KV[(ni*16+lr)*68 + ks*32+kg*8]);
      oac[ni]=__builtin_amdgcn_mfma_f32_16x16x32_bf16(ap,bv2,oac[ni],0,0,0);
    }
  }
#pragma unroll
  for (int mt=0;mt<4;mt++){
    bf16x8 aa = ldfrag(&Qb[(w*16+lr)*132 + mt*32+kg*8]);
#pragma unroll
    for (int ni=0;ni<8;ni++){
      bf16x8 bs = ldfrag(&SvL[(ni*16+lr)*132 + mt*32+kg*8]);
      oac[ni]=__builtin_amdgcn_mfma_f32_16x16x32_bf16(aa,bs,oac[ni],0,0,0);
    }
  }
#pragma unroll
  for (int ni=0;ni<8;ni++)
#pragma unroll
    for (int vv2=0;vv2<4;vv2++)
      o[(size_t)(c*64+w*16+kg*4+vv2)*2048 + h*128 + ni*16+lr] = oac[ni][vv2];
}

// ---------------- gated RMSNorm -> bf16 ----------------
__global__ __launch_bounds__(256)
void norm_k(const float* __restrict__ o, const float* __restrict__ gate,
            const float* __restrict__ bg2, const float* __restrict__ nw,
            u16* __restrict__ Obf){
  int row = blockIdx.x*4 + (threadIdx.x>>6);
  int lane = threadIdx.x & 63;
  int t = row >> 4, h = row & 15;
  size_t base = (size_t)t*2048 + h*128;
  float o0 = o[base+lane], o1 = o[base+64+lane];
  float ss = o0*o0 + o1*o1;
#pragma unroll
  for (int off=1;off<64;off<<=1) ss += __shfl_xor(ss, off);
  float r = rsqrtf(ss*(1.f/128.f) + 1e-5f);
  int hv0 = h*128+lane, hv1 = hv0+64;
  float g0 = gate[base+lane]    + bg2[hv0];
  float g1 = gate[base+64+lane] + bg2[hv1];
  float v0 = o0*r*nw[lane]   *(1.f/(1.f+__expf(-g0)));
  float v1 = o1*r*nw[lane+64]*(1.f/(1.f+__expf(-g1)));
  Obf[base+lane]    = f2bf(v0);
  Obf[base+64+lane] = f2bf(v1);
}

extern "C" void kernel_launch(void* const* d_in, const int* in_sizes, int n_in,
                              void* d_out, int out_size, void* d_ws, size_t ws_size,
                              hipStream_t stream){
  (void)in_sizes; (void)n_in; (void)out_size; (void)ws_size;
  const float* hX   = (const float*)d_in[0];
  const float* Wq   = (const float*)d_in[1];
  const float* Wk   = (const float*)d_in[2];
  const float* Wv   = (const float*)d_in[3];
  const float* Ww   = (const float*)d_in[4];
  const float* cq   = (const float*)d_in[5];
  const float* ck   = (const float*)d_in[6];
  const float* cv   = (const float*)d_in[7];
  const float* Wf1  = (const float*)d_in[8];
  const float* Wf2  = (const float*)d_in[9];
  const float* Wb   = (const float*)d_in[10];
  const float* Wg1  = (const float*)d_in[11];
  const float* Wg2  = (const float*)d_in[12];
  const float* bg2  = (const float*)d_in[13];
  const float* nw   = (const float*)d_in[14];
  const float* Wo   = (const float*)d_in[15];
  char* ws = (char*)d_ws;
  u16*   h_bf  = (u16*)  (ws + 0);
  u16*   WcatT = (u16*)  (ws + 4194304);
  u16*   Sk0   = (u16*)  (ws + 4194304);            // reuses WcatT after GEMMs (bf16)
  u16*   Sv0   = (u16*)  (ws + 20971520);
  u16*   WoT   = (u16*)  (ws + 37748736);
  u16*   WfgT  = (u16*)  (ws + 46137344);
  u16*   Wf2T  = (u16*)  (ws + 47185920);
  u16*   Wg2T  = (u16*)  (ws + 47710208);
  u16*   qkvw  = (u16*)  (ws + 48234496);           // bf16 [1024][8192]
  float* DSk   = (float*)(ws + 48234496);           // reuses qkvw after conv
  float* DSv   = (float*)(ws + 65011712);
  u16*   qb    = (u16*)  (ws + 81788928);           // bf16 [1024][2048]
  u16*   kb    = (u16*)  (ws + 90177536);
  u16*   vb    = (u16*)  (ws + 98566144);
  float* wcv   = (float*)(ws + 106954752);
  float* P8    = wcv;                               // split-K partials (before conv)
  float* osc   = wcv;                               // reuses wconv after l2bw
  float* bwb   = (float*)(ws + 115343360);
  u16*   f1g1  = (u16*)  (ws + 123731968);
  float* gpre  = (float*)(ws + 124256256);
  float* gateb = gpre;                              // reuses gpre after cg
  float* cgb   = (float*)(ws + 132644864);
  float* betab = (float*)(ws + 141033472);
  u16*   Obf   = (u16*)  (ws + 141099008);
  float* outp  = (float*)d_out;

  // conversions
  f2bf_k<<<2048,256,0,stream>>>(hX, h_bf);
  transp64_k<<<dim3(32,32,5),256,0,stream>>>(Wq, Wk, Wv, Ww, Wo, WcatT, WoT);
  transp_k<<<dim3(4,64), 256,0,stream>>>(Wf1, WfgT, 2048, 128);
  transp_k<<<dim3(4,64), 256,0,stream>>>(Wg1, WfgT + (size_t)128*2048, 2048, 128);
  transp_k<<<dim3(64,4), 256,0,stream>>>(Wf2, Wf2T, 128, 2048);
  transp_k<<<dim3(64,4), 256,0,stream>>>(Wg2, Wg2T, 128, 2048);

  // projections
  gemm8_k<<<dim3(32,8),512,0,stream>>>(h_bf, WcatT, qkvw, 2048, 2048, 2048, 8192);
  gemmsk_k<<<dim3(2,8,8),256,0,stream>>>(h_bf, WfgT, P8, 2048, 2048);
  reduce8_k<<<256,256,0,stream>>>(P8, f1g1);
  gemm_k<false,1><<<dim3(16,8),256,0,stream>>>(f1g1, Wf2T, gpre, 128, 256, 128, 2048);
  beta_k<<<1024,256,0,stream>>>(hX, Wb, betab);

  // conv + silu, l2norm*beta, chunk cumsum
  conv_k<<<8192,256,0,stream>>>(qkvw, cq, ck, cv, qb, kb, vb, wcv);
  l2bw_k<<<4096,256,0,stream>>>(wcv, betab, bwb);
  cg_k<<<128,256,0,stream>>>(gpre, cgb);

  // gate GEMM (into gpre buffer, safe after cg)
  gemm_k<false,0><<<dim3(16,8),256,0,stream>>>(f1g1 + 128, Wg2T, gateb, 128, 256, 128, 2048);

  // chunked scan
  phaseA_k<<<256,256,0,stream>>>(kb, vb, bwb, cgb, DSk, DSv);
  phaseB_k<<<2048,256,0,stream>>>(DSk, DSv, cgb, Sk0, Sv0);
  phaseC_k<<<256,256,0,stream>>>(qb, kb, vb, bwb, cgb, Sk0, Sv0, osc);

  // gated RMSNorm + output projection
  norm_k<<<4096,256,0,stream>>>(osc, gateb, bg2, nw, Obf);
  gemm_k<false,0><<<dim3(16,8),256,0,stream>>>(Obf, WoT, outp, 2048, 2048, 2048, 2048);
}

// Round 7
// 217.191 us; speedup vs baseline: 3.8785x; 1.1176x over previous
//
#include <hip/hip_runtime.h>
#include <hip/hip_bf16.h>
#include <stdint.h>

typedef unsigned short u16;
typedef __attribute__((ext_vector_type(8))) short bf16x8;
typedef __attribute__((ext_vector_type(4))) short bf16x4;
typedef __attribute__((ext_vector_type(4))) float f32x4;

#define DEV static __device__ __forceinline__

DEV u16 f2bf(float f){
  union { float f; unsigned u; } x; x.f = f;
  unsigned r = x.u + 0x7fffu + ((x.u >> 16) & 1u);
  return (u16)(r >> 16);
}

DEV float bf2f(u16 u){
  union { unsigned u; float f; } x; x.u = ((unsigned)u) << 16; return x.f;
}

DEV bf16x8 ldfrag(const u16* p){           // two ds_read_b64 (8B-aligned rows)
  bf16x4 a = *(const bf16x4*)p;
  bf16x4 b = *(const bf16x4*)(p+4);
  bf16x8 r;
  r[0]=a[0]; r[1]=a[1]; r[2]=a[2]; r[3]=a[3];
  r[4]=b[0]; r[5]=b[1]; r[6]=b[2]; r[7]=b[3];
  return r;
}

DEV bf16x4 cvt4(float a, float b, float c, float d){
  bf16x4 r; r[0]=(short)f2bf(a); r[1]=(short)f2bf(b); r[2]=(short)f2bf(c); r[3]=(short)f2bf(d);
  return r;
}

DEV void g2l16(const void* g, void* l){
  __builtin_amdgcn_global_load_lds((const __attribute__((address_space(1))) unsigned int*)g,
                                   (__attribute__((address_space(3))) unsigned int*)l,
                                   16, 0, 0);
}

// ---------------- f32 -> bf16 straight convert ----------------
__global__ __launch_bounds__(256)
void f2bf_k(const float* __restrict__ in, u16* __restrict__ out){
  int idx = blockIdx.x*256 + threadIdx.x;
  float4 v = *(const float4*)&in[(size_t)idx*4];
  u16 a = f2bf(v.x), b = f2bf(v.y), c = f2bf(v.z), d = f2bf(v.w);
  ushort4 o4; o4.x=a; o4.y=b; o4.z=c; o4.w=d;
  *(ushort4*)&out[(size_t)idx*4] = o4;
}

// ---------------- fused 2048x2048 f32 -> bf16 transposes (Wq,Wk,Wv,Ww,Wo) ----------------
__global__ __launch_bounds__(256)
void transp64_k(const float* __restrict__ Wq, const float* __restrict__ Wk,
                const float* __restrict__ Wv, const float* __restrict__ Ww,
                const float* __restrict__ Wo, u16* __restrict__ WcatT, u16* __restrict__ WoT){
  __shared__ float tile[64][65];
  const int z = blockIdx.z;
  const float* src = (z==0)?Wq:((z==1)?Wk:((z==2)?Wv:((z==3)?Ww:Wo)));
  u16* dst = (z<4) ? (WcatT + (size_t)z*4194304) : WoT;
  const int c0 = blockIdx.x*64, r0 = blockIdx.y*64;
#pragma unroll
  for (int p=0;p<4;p++){
    int i = threadIdx.x + p*256;
    int r = i>>4, c4 = (i&15)<<2;
    *(float4*)&tile[r][c4] = *(const float4*)&src[(size_t)(r0+r)*2048 + c0 + c4];
  }
  __syncthreads();
#pragma unroll
  for (int p=0;p<4;p++){
    int i = threadIdx.x + p*256;
    int cc = i>>4, r4 = (i&15)<<2;
    ushort4 o;
    o.x = f2bf(tile[r4+0][cc]); o.y = f2bf(tile[r4+1][cc]);
    o.z = f2bf(tile[r4+2][cc]); o.w = f2bf(tile[r4+3][cc]);
    *(ushort4*)&dst[(size_t)(c0+cc)*2048 + r0 + r4] = o;
  }
}

// ---------------- f32 [R][C] -> bf16 [C][R] transpose (small mats) ----------------
__global__ __launch_bounds__(256)
void transp_k(const float* __restrict__ in, u16* __restrict__ out, int R, int C){
  __shared__ float tile[32][33];
  const int c0 = blockIdx.x*32, r0 = blockIdx.y*32;
  const int x = threadIdx.x & 31, y0 = threadIdx.x >> 5;
#pragma unroll
  for (int j=0;j<4;j++){
    int r = y0 + j*8;
    tile[r][x] = in[(size_t)(r0+r)*C + c0 + x];
  }
  __syncthreads();
#pragma unroll
  for (int j=0;j<4;j++){
    int cc = y0 + j*8;
    out[(size_t)(c0+cc)*R + r0 + x] = f2bf(tile[x][cc]);
  }
}

// ---------------- big GEMM: 128x256, BK=64, 8 waves, dbuf + phase schedule (T3+T4+T5) ----------------
// A[M,K] row (lda), B^T[N,K] row (ldb) -> C[M,N] bf16 (ldc)
__global__ __launch_bounds__(512)
void gemm8_k(const u16* __restrict__ A, const u16* __restrict__ B, u16* __restrict__ C,
             int K, int lda, int ldb, int ldc){
  __shared__ u16 As[2][128*64];
  __shared__ u16 Bs[2][256*64];
  const int m0 = blockIdx.y*128, n0 = blockIdx.x*256;
  const int tid = threadIdx.x;
  const int wave = tid>>6, lane = tid&63, lr = lane&15, kg = lane>>4;
  const int wm = wave>>2, wn = wave&3;
  const f32x4 vz = {0.f,0.f,0.f,0.f};
  f32x4 acc[4][4];
#pragma unroll
  for (int a=0;a<4;a++)
#pragma unroll
    for (int b=0;b<4;b++) acc[a][b]=vz;

#define STAGE8(buf, k0) do { \
    _Pragma("unroll") \
    for (int p=0;p<2;p++){ \
      int chunk = tid + p*512, r_ = chunk>>3, ci = chunk&7; \
      g2l16(A + (size_t)(m0+r_)*lda + (k0) + ((ci^(r_&7))<<3), &As[buf][chunk*8]); \
    } \
    _Pragma("unroll") \
    for (int p=0;p<4;p++){ \
      int chunk = tid + p*512, r_ = chunk>>3, ci = chunk&7; \
      g2l16(B + (size_t)(n0+r_)*ldb + (k0) + ((ci^(r_&7))<<3), &Bs[buf][chunk*8]); \
    } \
  } while(0)

  const int nt = K>>6;          // >= 2 required
  STAGE8(0, 0);
  STAGE8(1, 64);
  for (int t=0; t<nt; ++t){
    const int buf = t&1;
    if (t < nt-1) asm volatile("s_waitcnt vmcnt(6)" ::: "memory");
    else          asm volatile("s_waitcnt vmcnt(0)" ::: "memory");
    asm volatile("s_barrier" ::: "memory");   // buf t fully staged for all waves
#pragma unroll
    for (int ks=0; ks<2; ++ks){
      bf16x8 af[4], bfv[4];
#pragma unroll
      for (int mi=0;mi<4;mi++){
        int r = wm*64+mi*16+lr;
        af[mi] = *(const bf16x8*)&As[buf][r*64 + (((ks*4+kg)^(r&7))<<3)];
      }
#pragma unroll
      for (int ni=0;ni<4;ni++){
        int r = wn*64+ni*16+lr;
        bfv[ni] = *(const bf16x8*)&Bs[buf][r*64 + (((ks*4+kg)^(r&7))<<3)];
      }
      asm volatile("s_waitcnt lgkmcnt(0)" ::: "memory");
      __builtin_amdgcn_sched_barrier(0);
      __builtin_amdgcn_s_setprio(1);
#pragma unroll
      for (int mi=0;mi<4;mi++)
#pragma unroll
        for (int ni=0;ni<4;ni++)
          acc[mi][ni] = __builtin_amdgcn_mfma_f32_16x16x32_bf16(af[mi], bfv[ni], acc[mi][ni], 0, 0, 0);
      __builtin_amdgcn_s_setprio(0);
      __builtin_amdgcn_sched_barrier(0);
      asm volatile("s_barrier" ::: "memory");
    }
    if (t+2 < nt) STAGE8(buf, (t+2)<<6);
  }
#undef STAGE8
#pragma unroll
  for (int mi=0;mi<4;mi++)
#pragma unroll
    for (int ni=0;ni<4;ni++)
#pragma unroll
      for (int vv=0;vv<4;vv++){
        int row = m0 + wm*64 + mi*16 + kg*4 + vv;
        int col = n0 + wn*64 + ni*16 + lr;
        C[(size_t)row*ldc + col] = f2bf(acc[mi][ni][vv]);
      }
}

// ---------------- split-K pipelined GEMM: 128x128, BK=64, 4 waves -> f32 partials ----------------
__global__ __launch_bounds__(256)
void gemm4sk_k(const u16* __restrict__ A, const u16* __restrict__ B, float* __restrict__ P,
               int Khalf, int lda, int ldb, int ldc){
  __shared__ u16 As[2][128*64];
  __shared__ u16 Bs[2][128*64];
  const int m0 = blockIdx.y*128, n0 = blockIdx.x*128;
  const int kbase = blockIdx.z*Khalf;
  const int tid = threadIdx.x;
  const int wave = tid>>6, lane = tid&63, lr = lane&15, kg = lane>>4;
  const int wm = wave>>1, wn = wave&1;
  const f32x4 vz = {0.f,0.f,0.f,0.f};
  f32x4 acc[4][4];
#pragma unroll
  for (int a=0;a<4;a++)
#pragma unroll
    for (int b=0;b<4;b++) acc[a][b]=vz;

#define STAGE4(buf, k0) do { \
    _Pragma("unroll") \
    for (int p=0;p<4;p++){ \
      int chunk = tid + p*256, r_ = chunk>>3, ci = chunk&7; \
      g2l16(A + (size_t)(m0+r_)*lda + (k0) + ((ci^(r_&7))<<3), &As[buf][chunk*8]); \
    } \
    _Pragma("unroll") \
    for (int p=0;p<4;p++){ \
      int chunk = tid + p*256, r_ = chunk>>3, ci = chunk&7; \
      g2l16(B + (size_t)(n0+r_)*ldb + (k0) + ((ci^(r_&7))<<3), &Bs[buf][chunk*8]); \
    } \
  } while(0)

  const int nt = Khalf>>6;      // >= 2 required
  STAGE4(0, kbase);
  STAGE4(1, kbase+64);
  for (int t=0; t<nt; ++t){
    const int buf = t&1;
    if (t < nt-1) asm volatile("s_waitcnt vmcnt(8)" ::: "memory");
    else          asm volatile("s_waitcnt vmcnt(0)" ::: "memory");
    asm volatile("s_barrier" ::: "memory");
#pragma unroll
    for (int ks=0; ks<2; ++ks){
      bf16x8 af[4], bfv[4];
#pragma unroll
      for (int mi=0;mi<4;mi++){
        int r = wm*64+mi*16+lr;
        af[mi] = *(const bf16x8*)&As[buf][r*64 + (((ks*4+kg)^(r&7))<<3)];
      }
#pragma unroll
      for (int ni=0;ni<4;ni++){
        int r = wn*64+ni*16+lr;
        bfv[ni] = *(const bf16x8*)&Bs[buf][r*64 + (((ks*4+kg)^(r&7))<<3)];
      }
      asm volatile("s_waitcnt lgkmcnt(0)" ::: "memory");
      __builtin_amdgcn_sched_barrier(0);
      __builtin_amdgcn_s_setprio(1);
#pragma unroll
      for (int mi=0;mi<4;mi++)
#pragma unroll
        for (int ni=0;ni<4;ni++)
          acc[mi][ni] = __builtin_amdgcn_mfma_f32_16x16x32_bf16(af[mi], bfv[ni], acc[mi][ni], 0, 0, 0);
      __builtin_amdgcn_s_setprio(0);
      __builtin_amdgcn_sched_barrier(0);
      asm volatile("s_barrier" ::: "memory");
    }
    if (t+2 < nt) STAGE4(buf, kbase + ((t+2)<<6));
  }
#undef STAGE4
#pragma unroll
  for (int mi=0;mi<4;mi++)
#pragma unroll
    for (int ni=0;ni<4;ni++)
#pragma unroll
      for (int vv=0;vv<4;vv++){
        int row = m0 + wm*64 + mi*16 + kg*4 + vv;
        int col = n0 + wn*64 + ni*16 + lr;
        P[(size_t)blockIdx.z*2097152 + (size_t)row*ldc + col] = acc[mi][ni][vv];
      }
}

__global__ __launch_bounds__(256)
void addout_k(const float* __restrict__ P, float* __restrict__ out){
  int i = (blockIdx.x*256 + threadIdx.x)*4;
  float4 a = *(const float4*)&P[i];
  float4 b = *(const float4*)&P[2097152 + i];
  float4 s = {a.x+b.x, a.y+b.y, a.z+b.z, a.w+b.w};
  *(float4*)&out[i] = s;
}

// ---------------- bf16 GEMM (128^2, BK=32): EPI 0=none 1=logsigmoid ----------------
template<bool OBF, int EPI>
__global__ __launch_bounds__(256)
void gemm_k(const u16* __restrict__ A, const u16* __restrict__ B, void* __restrict__ Cp,
            int K, int lda, int ldb, int ldc){
  __shared__ u16 As[128*32];
  __shared__ u16 Bs[128*32];
  const int m0 = blockIdx.y*128, n0 = blockIdx.x*128;
  const int tid = threadIdx.x;
  const int lane = tid & 63, wave = tid >> 6;
  const int wr = wave >> 1, wc = wave & 1;
  const int lr = lane & 15, kg = lane >> 4;
  const f32x4 vzero = {0.f,0.f,0.f,0.f};
  f32x4 acc[4][4];
#pragma unroll
  for (int a=0;a<4;a++)
#pragma unroll
    for (int b=0;b<4;b++) acc[a][b] = vzero;
  const int r0 = tid>>2, s0 = tid&3;
  for (int k0=0;k0<K;k0+=32){
    __syncthreads();
    g2l16(A + (size_t)(m0+r0)*lda + k0 + s0*8, (u16*)As + (size_t)tid*8);
    g2l16(B + (size_t)(n0+r0)*ldb + k0 + s0*8, (u16*)Bs + (size_t)tid*8);
    g2l16(A + (size_t)(m0+r0+64)*lda + k0 + s0*8, (u16*)As + (size_t)(tid+256)*8);
    g2l16(B + (size_t)(n0+r0+64)*ldb + k0 + s0*8, (u16*)Bs + (size_t)(tid+256)*8);
    __syncthreads();
    bf16x8 af[4], bfv[4];
#pragma unroll
    for (int mi=0;mi<4;mi++) af[mi]  = *(const bf16x8*)(As + (wr*64+mi*16+lr)*32 + kg*8);
#pragma unroll
    for (int ni=0;ni<4;ni++) bfv[ni] = *(const bf16x8*)(Bs + (wc*64+ni*16+lr)*32 + kg*8);
#pragma unroll
    for (int mi=0;mi<4;mi++)
#pragma unroll
      for (int ni=0;ni<4;ni++)
        acc[mi][ni] = __builtin_amdgcn_mfma_f32_16x16x32_bf16(af[mi], bfv[ni], acc[mi][ni], 0, 0, 0);
  }
#pragma unroll
  for (int mi=0;mi<4;mi++)
#pragma unroll
    for (int ni=0;ni<4;ni++)
#pragma unroll
      for (int vv=0;vv<4;vv++){
        int row = m0 + wr*64 + mi*16 + kg*4 + vv;
        int col = n0 + wc*64 + ni*16 + lr;
        float val = acc[mi][ni][vv];
        if (EPI==1) val = fminf(val,0.f) - __logf(1.f + __expf(-fabsf(val)));
        if (OBF) ((u16*)Cp)[(size_t)row*ldc + col] = f2bf(val);
        else     ((float*)Cp)[(size_t)row*ldc + col] = val;
      }
}

// ---------------- split-K GEMM for f1g1 (N=256, K=2048 in 8 chunks) ----------------
__global__ __launch_bounds__(256)
void gemmsk_k(const u16* __restrict__ A, const u16* __restrict__ B, float* __restrict__ P,
              int lda, int ldb){
  __shared__ u16 As[128*32];
  __shared__ u16 Bs[128*32];
  const int m0 = blockIdx.y*128, n0 = blockIdx.x*128;
  const int kbase = blockIdx.z*256;
  const int tid = threadIdx.x;
  const int lane = tid & 63, wave = tid >> 6;
  const int wr = wave >> 1, wc = wave & 1;
  const int lr = lane & 15, kg = lane >> 4;
  const f32x4 vzero = {0.f,0.f,0.f,0.f};
  f32x4 acc[4][4];
#pragma unroll
  for (int a=0;a<4;a++)
#pragma unroll
    for (int b=0;b<4;b++) acc[a][b] = vzero;
  const int r0 = tid>>2, s0 = tid&3;
  for (int k0=kbase;k0<kbase+256;k0+=32){
    __syncthreads();
    g2l16(A + (size_t)(m0+r0)*lda + k0 + s0*8, (u16*)As + (size_t)tid*8);
    g2l16(B + (size_t)(n0+r0)*ldb + k0 + s0*8, (u16*)Bs + (size_t)tid*8);
    g2l16(A + (size_t)(m0+r0+64)*lda + k0 + s0*8, (u16*)As + (size_t)(tid+256)*8);
    g2l16(B + (size_t)(n0+r0+64)*ldb + k0 + s0*8, (u16*)Bs + (size_t)(tid+256)*8);
    __syncthreads();
    bf16x8 af[4], bfv[4];
#pragma unroll
    for (int mi=0;mi<4;mi++) af[mi]  = *(const bf16x8*)(As + (wr*64+mi*16+lr)*32 + kg*8);
#pragma unroll
    for (int ni=0;ni<4;ni++) bfv[ni] = *(const bf16x8*)(Bs + (wc*64+ni*16+lr)*32 + kg*8);
#pragma unroll
    for (int mi=0;mi<4;mi++)
#pragma unroll
      for (int ni=0;ni<4;ni++)
        acc[mi][ni] = __builtin_amdgcn_mfma_f32_16x16x32_bf16(af[mi], bfv[ni], acc[mi][ni], 0, 0, 0);
  }
#pragma unroll
  for (int mi=0;mi<4;mi++)
#pragma unroll
    for (int ni=0;ni<4;ni++)
#pragma unroll
      for (int vv=0;vv<4;vv++){
        int row = m0 + wr*64 + mi*16 + kg*4 + vv;
        int col = n0 + wc*64 + ni*16 + lr;
        P[(size_t)blockIdx.z*262144 + (size_t)row*256 + col] = acc[mi][ni][vv];
      }
}

__global__ __launch_bounds__(256)
void reduce8_k(const float* __restrict__ P, u16* __restrict__ out){
  int i = (blockIdx.x*256 + threadIdx.x)*4;
  float4 s = *(const float4*)&P[i];
#pragma unroll
  for (int z=1;z<8;z++){
    float4 p = *(const float4*)&P[(size_t)z*262144 + i];
    s.x+=p.x; s.y+=p.y; s.z+=p.z; s.w+=p.w;
  }
  ushort4 o; o.x=f2bf(s.x); o.y=f2bf(s.y); o.z=f2bf(s.z); o.w=f2bf(s.w);
  *(ushort4*)&out[i] = o;
}

// ---------------- beta = sigmoid(h @ Wb), per-t block ----------------
__global__ __launch_bounds__(256)
void beta_k(const float* __restrict__ h, const float* __restrict__ Wb, float* __restrict__ betab){
  __shared__ float hrow[2048];
  __shared__ float red[16][5];
  const int t = blockIdx.x, tid = threadIdx.x;
#pragma unroll
  for (int j=0;j<8;j++) hrow[tid + j*256] = h[(size_t)t*2048 + tid + j*256];
  __syncthreads();
  float part[16];
#pragma unroll
  for (int n=0;n<16;n++) part[n]=0.f;
  for (int j=0;j<8;j++){
    int kk = tid + j*256;
    float hv = hrow[kk];
    const float4* wr4 = (const float4*)&Wb[(size_t)kk*16];
    float4 w0=wr4[0], w1=wr4[1], w2=wr4[2], w3=wr4[3];
    part[0]+=hv*w0.x; part[1]+=hv*w0.y; part[2]+=hv*w0.z; part[3]+=hv*w0.w;
    part[4]+=hv*w1.x; part[5]+=hv*w1.y; part[6]+=hv*w1.z; part[7]+=hv*w1.w;
    part[8]+=hv*w2.x; part[9]+=hv*w2.y; part[10]+=hv*w2.z; part[11]+=hv*w2.w;
    part[12]+=hv*w3.x; part[13]+=hv*w3.y; part[14]+=hv*w3.z; part[15]+=hv*w3.w;
  }
#pragma unroll
  for (int n=0;n<16;n++){
    float s = part[n];
#pragma unroll
    for (int off=1;off<64;off<<=1) s += __shfl_xor(s, off);
    if ((tid&63)==0) red[n][tid>>6] = s;
  }
  __syncthreads();
  if (tid < 16){
    float s = red[tid][0]+red[tid][1]+red[tid][2]+red[tid][3];
    betab[t*16+tid] = 1.f/(1.f+__expf(-s));
  }
}

// ---------------- causal conv4 + silu: q,k,v -> bf16 ; w -> f32 ----------------
__global__ __launch_bounds__(256)
void conv_k(const u16* __restrict__ raw, const float* __restrict__ cq,
            const float* __restrict__ ck, const float* __restrict__ cv,
            u16* __restrict__ qo, u16* __restrict__ ko,
            u16* __restrict__ vo, float* __restrict__ wo){
  int idx = blockIdx.x*256 + threadIdx.x;
  int cgl = idx & 8191, tb = idx >> 13;
  int which = cgl >> 11, cc = cgl & 2047;
  const float* wt = (which==0)?cq:((which==1)?ck:cv);   // w-branch (3) uses cv (faithful to ref)
  float4 w4 = *(const float4*)&wt[cc*4];
  u16* outb = (which==0)?qo:((which==1)?ko:vo);
  int t0 = tb*4;
  float x[7];
#pragma unroll
  for (int j=0;j<7;j++){
    int t = t0 - 3 + j;
    x[j] = (t >= 0) ? bf2f(raw[(size_t)t*8192 + cgl]) : 0.f;
  }
#pragma unroll
  for (int j=0;j<4;j++){
    float y = x[j]*w4.x + x[j+1]*w4.y + x[j+2]*w4.z + x[j+3]*w4.w;
    y = y / (1.f + __expf(-y));           // silu
    if (which==3) wo[(size_t)(t0+j)*2048 + cc] = y;
    else          outb[(size_t)(t0+j)*2048 + cc] = f2bf(y);
  }
}

// ---------------- l2norm over M + beta scale: bw ----------------
__global__ __launch_bounds__(256)
void l2bw_k(const float* __restrict__ wconv, const float* __restrict__ betab,
            float* __restrict__ bwout){
  int row = blockIdx.x*4 + (threadIdx.x>>6);
  int lane = threadIdx.x & 63;
  int t = row >> 4, h = row & 15;
  size_t base = (size_t)t*2048 + h*128;
  float a0 = wconv[base+lane], a1 = wconv[base+64+lane];
  float ss = a0*a0 + a1*a1;
#pragma unroll
  for (int off=1;off<64;off<<=1) ss += __shfl_xor(ss, off);
  float r = rsqrtf(ss + 1e-6f) * betab[t*16+h];
  bwout[base+lane]    = a0*r;
  bwout[base+64+lane] = a1*r;
}

// ---------------- per-chunk inclusive cumsum (gpre already = logsigmoid) ----------------
__global__ __launch_bounds__(128)
void cg_k(const float* __restrict__ gpre, float* __restrict__ cg){
  int idx = blockIdx.x*128 + threadIdx.x;   // 32768 = c*2048 + h*128 + m
  int c = idx >> 11;
  size_t base = (size_t)(idx & 2047);
  float run = 0.f;
  for (int i2=0;i2<64;i2++){
    size_t t = (size_t)c*64 + i2;
    run += gpre[t*2048 + base];
    cg[t*2048 + base] = run;
  }
}

// ---------------- Phase A (MFMA): DSkT[m][d] = U^T K ; DSvT[v][m] = V^T U (bf16 out) ----------------
__global__ __launch_bounds__(256)
void phaseA_k(const u16* __restrict__ k, const u16* __restrict__ v,
              const float* __restrict__ bw, const float* __restrict__ cg,
              u16* __restrict__ DSkT, u16* __restrict__ DSvT){
  __shared__ u16 UT[128*68];
  __shared__ u16 KT[128*68];
  __shared__ u16 VT[128*68];
  __shared__ float Gt[128];
  const int bx=blockIdx.x, h=bx&15, c=bx>>4, tid=threadIdx.x;
  const int w=tid>>6, lane=tid&63, lr=lane&15, kg=lane>>4;
  if (tid<128) Gt[tid] = cg[(size_t)(c*64+63)*2048 + h*128 + tid];
  __syncthreads();
#pragma unroll
  for (int j=0;j<8;j++){
    int f4=tid+j*256, r=f4>>5, c4=(f4&31)<<2;
    size_t g=(size_t)(c*64+r)*2048 + h*128 + c4;
    ushort4 kv=*(const ushort4*)&k[g];
    ushort4 vv=*(const ushort4*)&v[g];
    float4 bv=*(const float4*)&bw[g];
    float4 cv=*(const float4*)&cg[g];
    float u0=bv.x*__expf(Gt[c4+0]-cv.x);
    float u1=bv.y*__expf(Gt[c4+1]-cv.y);
    float u2=bv.z*__expf(Gt[c4+2]-cv.z);
    float u3=bv.w*__expf(Gt[c4+3]-cv.w);
    KT[(c4+0)*68+r]=kv.x; KT[(c4+1)*68+r]=kv.y;
    KT[(c4+2)*68+r]=kv.z; KT[(c4+3)*68+r]=kv.w;
    VT[(c4+0)*68+r]=vv.x; VT[(c4+1)*68+r]=vv.y;
    VT[(c4+2)*68+r]=vv.z; VT[(c4+3)*68+r]=vv.w;
    UT[(c4+0)*68+r]=f2bf(u0);   UT[(c4+1)*68+r]=f2bf(u1);
    UT[(c4+2)*68+r]=f2bf(u2);   UT[(c4+3)*68+r]=f2bf(u3);
  }
  __syncthreads();
  const f32x4 vz = {0.f,0.f,0.f,0.f};
  {
    f32x4 acc[2][8];
#pragma unroll
    for (int a=0;a<2;a++)
#pragma unroll
      for (int b=0;b<8;b++) acc[a][b]=vz;
#pragma unroll
    for (int ks=0;ks<2;ks++){
      bf16x8 a0=ldfrag(&UT[(w*32   +lr)*68 + ks*32+kg*8]);
      bf16x8 a1=ldfrag(&UT[(w*32+16+lr)*68 + ks*32+kg*8]);
#pragma unroll
      for (int nj=0;nj<8;nj++){
        bf16x8 b=ldfrag(&KT[(nj*16+lr)*68 + ks*32+kg*8]);
        acc[0][nj]=__builtin_amdgcn_mfma_f32_16x16x32_bf16(a0,b,acc[0][nj],0,0,0);
        acc[1][nj]=__builtin_amdgcn_mfma_f32_16x16x32_bf16(a1,b,acc[1][nj],0,0,0);
      }
    }
#pragma unroll
    for (int mi2=0;mi2<2;mi2++)
#pragma unroll
      for (int nj=0;nj<8;nj++)
#pragma unroll
        for (int vv2=0;vv2<4;vv2++)
          DSkT[(size_t)bx*16384 + (size_t)(w*32+mi2*16+kg*4+vv2)*128 + nj*16+lr] = f2bf(acc[mi2][nj][vv2]);
  }
  {
    f32x4 acc[2][8];
#pragma unroll
    for (int a=0;a<2;a++)
#pragma unroll
      for (int b=0;b<8;b++) acc[a][b]=vz;
#pragma unroll
    for (int ks=0;ks<2;ks++){
      bf16x8 a0=ldfrag(&VT[(w*32   +lr)*68 + ks*32+kg*8]);
      bf16x8 a1=ldfrag(&VT[(w*32+16+lr)*68 + ks*32+kg*8]);
#pragma unroll
      for (int nj=0;nj<8;nj++){
        bf16x8 b=ldfrag(&UT[(nj*16+lr)*68 + ks*32+kg*8]);
        acc[0][nj]=__builtin_amdgcn_mfma_f32_16x16x32_bf16(a0,b,acc[0][nj],0,0,0);
        acc[1][nj]=__builtin_amdgcn_mfma_f32_16x16x32_bf16(a1,b,acc[1][nj],0,0,0);
      }
    }
#pragma unroll
    for (int mi2=0;mi2<2;mi2++)
#pragma unroll
      for (int nj=0;nj<8;nj++)
#pragma unroll
        for (int vv2=0;vv2<4;vv2++)
          DSvT[(size_t)bx*16384 + (size_t)(w*32+mi2*16+kg*4+vv2)*128 + nj*16+lr] = f2bf(acc[mi2][nj][vv2]);
  }
}

// ---------------- Phase B: sequential cross-chunk combine (bf16 in/out) ----------------
__global__ __launch_bounds__(256)
void phaseB_k(const u16* __restrict__ DSk, const u16* __restrict__ DSv,
              const float* __restrict__ cg, u16* __restrict__ Sk0, u16* __restrict__ Sv0){
  unsigned idx = blockIdx.x*256u + threadIdx.x;   // 524288 total
  int sel  = idx >> 18;
  int h    = (idx >> 14) & 15;
  int flat = idx & 16383;                 // SkT: m*128+d ; SvT: v*128+m
  int mdec = sel ? (flat & 127) : (flat >> 7);
  const u16* DS = sel ? DSv : DSk;
  u16* S = sel ? Sv0 : Sk0;
  float cur = 0.f;
  for (int c=0;c<16;c++){
    size_t sb = ((size_t)(c*16+h))*16384 + flat;
    S[sb] = f2bf(cur);                     // state BEFORE chunk c
    float gd = __expf(cg[(size_t)(c*64+63)*2048 + h*128 + mdec]);
    cur = cur*gd + bf2f(DS[sb]);
  }
}

// ---------------- Phase C (MFMA): per-chunk outputs ----------------
__global__ __launch_bounds__(256)
void phaseC_k(const u16* __restrict__ q, const u16* __restrict__ k,
              const u16* __restrict__ v, const float* __restrict__ bw,
              const float* __restrict__ cg, const u16* __restrict__ SkT,
              const u16* __restrict__ SvT, float* __restrict__ o){
  __shared__ u16 Qb[64*132];     // Q, then A' (wave-private rows after prep)
  __shared__ u16 KV[8704];       // K[64][132], then VT[128][68]
  __shared__ u16 Bws[64*132];    // bw*e^{cgm-cg} natural [s][m]
  __shared__ u16 BwT[128*68];    // transposed [m][s]
  __shared__ u16 Ssb[64*68];     // sqk, then P (wave-private rows)
  __shared__ u16 SkL[128*132];   // Sk'^T * e^{cgm[m]}  [m][d]
  __shared__ u16 SvL[128*132];   // Sv'^T * e^{cgm[m]}  [v][m]
  __shared__ float cgm[128];
  __shared__ float ecgm[128];
  const int bx=blockIdx.x, h=bx&15, c=bx>>4, tid=threadIdx.x;
  const int w=tid>>6, lane=tid&63, lr=lane&15, kg=lane>>4;
  const float SCALE = 0.088388347648318447f;   // 128^-0.5
  const f32x4 vz = {0.f,0.f,0.f,0.f};
  if (tid<128){ float t=cg[(size_t)(c*64+31)*2048 + h*128 + tid]; cgm[tid]=t; ecgm[tid]=__expf(t); }
  __syncthreads();
#pragma unroll
  for (int j=0;j<8;j++){
    int f4=tid+j*256, r=f4>>5, c4=(f4&31)<<2;
    size_t g=(size_t)(c*64+r)*2048 + h*128 + c4;
    *(ushort4*)&Qb[r*132+c4] = *(const ushort4*)&q[g];
    *(ushort4*)&KV[r*132+c4] = *(const ushort4*)&k[g];
    float4 bv=*(const float4*)&bw[g];
    float4 cv=*(const float4*)&cg[g];
    float b0=bv.x*__expf(cgm[c4+0]-cv.x);
    float b1=bv.y*__expf(cgm[c4+1]-cv.y);
    float b2=bv.z*__expf(cgm[c4+2]-cv.z);
    float b3=bv.w*__expf(cgm[c4+3]-cv.w);
    bf16x4 bb = cvt4(b0,b1,b2,b3);
    *(bf16x4*)&Bws[r*132+c4] = bb;
    BwT[(c4+0)*68+r]=(u16)bb[0]; BwT[(c4+1)*68+r]=(u16)bb[1];
    BwT[(c4+2)*68+r]=(u16)bb[2]; BwT[(c4+3)*68+r]=(u16)bb[3];
  }
  __syncthreads();
  {
    f32x4 acc1[4];
#pragma unroll
    for (int a=0;a<4;a++) acc1[a]=vz;
#pragma unroll
    for (int ks=0;ks<4;ks++){
      bf16x8 aq = ldfrag(&Qb[(w*16+lr)*132 + ks*32+kg*8]);
#pragma unroll
      for (int ni=0;ni<4;ni++){
        bf16x8 bk = ldfrag(&KV[(ni*16+lr)*132 + ks*32+kg*8]);
        acc1[ni]=__builtin_amdgcn_mfma_f32_16x16x32_bf16(aq,bk,acc1[ni],0,0,0);
      }
    }
#pragma unroll
    for (int ni=0;ni<4;ni++)
#pragma unroll
      for (int vv2=0;vv2<4;vv2++){
        int row=w*16+kg*4+vv2, col=ni*16+lr;
        Ssb[row*68+col] = (col<=row) ? f2bf(acc1[ni][vv2]) : (u16)0;
      }
  }
  __syncthreads();   // all K reads done -> KV reusable for VT
#pragma unroll
  for (int j=0;j<8;j++){
    int f4=tid+j*256, r=f4>>5, c4=(f4&31)<<2;
    ushort4 vv=*(const ushort4*)&v[(size_t)(c*64+r)*2048 + h*128 + c4];
    KV[(c4+0)*68+r]=vv.x; KV[(c4+1)*68+r]=vv.y;
    KV[(c4+2)*68+r]=vv.z; KV[(c4+3)*68+r]=vv.w;
  }
#pragma unroll
  for (int j=0;j<16;j++){
    int f4=tid+j*256, r=f4>>5, c4=(f4&31)<<2;
    ushort4 s4=*(const ushort4*)&SkT[(size_t)bx*16384 + (size_t)r*128 + c4];
    float em=ecgm[r];
    *(bf16x4*)&SkL[r*132+c4]=cvt4(bf2f(s4.x)*em, bf2f(s4.y)*em, bf2f(s4.z)*em, bf2f(s4.w)*em);
  }
#pragma unroll
  for (int j=0;j<16;j++){
    int f4=tid+j*256, r=f4>>5, c4=(f4&31)<<2;
    ushort4 s4=*(const ushort4*)&SvT[(size_t)bx*16384 + (size_t)r*128 + c4];
    *(bf16x4*)&SvL[r*132+c4]=cvt4(bf2f(s4.x)*ecgm[c4+0], bf2f(s4.y)*ecgm[c4+1],
                                  bf2f(s4.z)*ecgm[c4+2], bf2f(s4.w)*ecgm[c4+3]);
  }
  f32x4 zac[8];
#pragma unroll
  for (int a=0;a<8;a++) zac[a]=vz;
#pragma unroll
  for (int ks=0;ks<2;ks++){
    bf16x8 as_ = ldfrag(&Ssb[(w*16+lr)*68 + ks*32+kg*8]);
#pragma unroll
    for (int ni=0;ni<8;ni++){
      bf16x8 bb = ldfrag(&BwT[(ni*16+lr)*68 + ks*32+kg*8]);
      zac[ni]=__builtin_amdgcn_mfma_f32_16x16x32_bf16(as_,bb,zac[ni],0,0,0);
    }
  }
  __syncthreads();   // SkL/SvL/VT staged & visible
#pragma unroll
  for (int dt=0;dt<4;dt++){
    bf16x8 aq = ldfrag(&Qb[(w*16+lr)*132 + dt*32+kg*8]);
#pragma unroll
    for (int ni=0;ni<8;ni++){
      bf16x8 bs = ldfrag(&SkL[(ni*16+lr)*132 + dt*32+kg*8]);
      zac[ni]=__builtin_amdgcn_mfma_f32_16x16x32_bf16(aq,bs,zac[ni],0,0,0);
    }
  }
  float dec[4][8], zz[4][8];
#pragma unroll
  for (int vv2=0;vv2<4;vv2++)
#pragma unroll
    for (int ni=0;ni<8;ni++) zz[vv2][ni]=zac[ni][vv2];
#pragma unroll
  for (int vv2=0;vv2<4;vv2++){
    size_t gr=(size_t)(c*64+w*16+kg*4+vv2)*2048 + h*128;
#pragma unroll
    for (int ni=0;ni<8;ni++){
      float cgv = cg[gr + ni*16+lr];
      dec[vv2][ni] = __expf(cgv - cgm[ni*16+lr]);
    }
  }
#pragma unroll
  for (int vv2=0;vv2<4;vv2++){
    float mx=-3.0e38f;
#pragma unroll
    for (int ni=0;ni<8;ni++){ zz[vv2][ni] *= SCALE*dec[vv2][ni]; mx=fmaxf(mx,zz[vv2][ni]); }
    mx=fmaxf(mx,__shfl_xor(mx,1)); mx=fmaxf(mx,__shfl_xor(mx,2));
    mx=fmaxf(mx,__shfl_xor(mx,4)); mx=fmaxf(mx,__shfl_xor(mx,8));
    float sum=0.f;
#pragma unroll
    for (int ni=0;ni<8;ni++){ zz[vv2][ni]=__expf(zz[vv2][ni]-mx); sum+=zz[vv2][ni]; }
    sum+=__shfl_xor(sum,1); sum+=__shfl_xor(sum,2);
    sum+=__shfl_xor(sum,4); sum+=__shfl_xor(sum,8);
    float inv=1.f/sum;
#pragma unroll
    for (int ni=0;ni<8;ni++) zz[vv2][ni] *= inv*dec[vv2][ni];   // A' = a * e^{cg-cgm}
  }
#pragma unroll
  for (int vv2=0;vv2<4;vv2++)
#pragma unroll
    for (int ni=0;ni<8;ni++)
      Qb[(w*16+kg*4+vv2)*132 + ni*16+lr] = f2bf(zz[vv2][ni]);
  {
    f32x4 acc4[4];
#pragma unroll
    for (int a=0;a<4;a++) acc4[a]=vz;
#pragma unroll
    for (int ks=0;ks<4;ks++){
      bf16x8 aa = ldfrag(&Qb[(w*16+lr)*132 + ks*32+kg*8]);
#pragma unroll
      for (int ni=0;ni<4;ni++){
        bf16x8 bb = ldfrag(&Bws[(ni*16+lr)*132 + ks*32+kg*8]);
        acc4[ni]=__builtin_amdgcn_mfma_f32_16x16x32_bf16(aa,bb,acc4[ni],0,0,0);
      }
    }
#pragma unroll
    for (int ni=0;ni<4;ni++)
#pragma unroll
      for (int vv2=0;vv2<4;vv2++){
        int row=w*16+kg*4+vv2, col=ni*16+lr;
        Ssb[row*68+col] = (col<=row) ? f2bf(acc4[ni][vv2]) : (u16)0;
      }
  }
  f32x4 oac[8];
#pragma unroll
  for (int a=0;a<8;a++) oac[a]=vz;
#pragma unroll
  for (int ks=0;ks<2;ks++){
    bf16x8 ap = ldfrag(&Ssb[(w*16+lr)*68 + ks*32+kg*8]);
#pragma unroll
    for (int ni=0;ni<8;ni++){
      bf16x8 bv2 = ldfrag(&KV[(ni*16+lr)*68 + ks*32+kg*8]);
      oac[ni]=__builtin_amdgcn_mfma_f32_16x16x32_bf16(ap,bv2,oac[ni],0,0,0);
    }
  }
#pragma unroll
  for (int mt=0;mt<4;mt++){
    bf16x8 aa = ldfrag(&Qb[(w*16+lr)*132 + mt*32+kg*8]);
#pragma unroll
    for (int ni=0;ni<8;ni++){
      bf16x8 bs = ldfrag(&SvL[(ni*16+lr)*132 + mt*32+kg*8]);
      oac[ni]=__builtin_amdgcn_mfma_f32_16x16x32_bf16(aa,bs,oac[ni],0,0,0);
    }
  }
#pragma unroll
  for (int ni=0;ni<8;ni++)
#pragma unroll
    for (int vv2=0;vv2<4;vv2++)
      o[(size_t)(c*64+w*16+kg*4+vv2)*2048 + h*128 + ni*16+lr] = oac[ni][vv2];
}

// ---------------- gated RMSNorm -> bf16 ----------------
__global__ __launch_bounds__(256)
void norm_k(const float* __restrict__ o, const float* __restrict__ gate,
            const float* __restrict__ bg2, const float* __restrict__ nw,
            u16* __restrict__ Obf){
  int row = blockIdx.x*4 + (threadIdx.x>>6);
  int lane = threadIdx.x & 63;
  int t = row >> 4, h = row & 15;
  size_t base = (size_t)t*2048 + h*128;
  float o0 = o[base+lane], o1 = o[base+64+lane];
  float ss = o0*o0 + o1*o1;
#pragma unroll
  for (int off=1;off<64;off<<=1) ss += __shfl_xor(ss, off);
  float r = rsqrtf(ss*(1.f/128.f) + 1e-5f);
  int hv0 = h*128+lane, hv1 = hv0+64;
  float g0 = gate[base+lane]    + bg2[hv0];
  float g1 = gate[base+64+lane] + bg2[hv1];
  float v0 = o0*r*nw[lane]   *(1.f/(1.f+__expf(-g0)));
  float v1 = o1*r*nw[lane+64]*(1.f/(1.f+__expf(-g1)));
  Obf[base+lane]    = f2bf(v0);
  Obf[base+64+lane] = f2bf(v1);
}

extern "C" void kernel_launch(void* const* d_in, const int* in_sizes, int n_in,
                              void* d_out, int out_size, void* d_ws, size_t ws_size,
                              hipStream_t stream){
  (void)in_sizes; (void)n_in; (void)out_size; (void)ws_size;
  const float* hX   = (const float*)d_in[0];
  const float* Wq   = (const float*)d_in[1];
  const float* Wk   = (const float*)d_in[2];
  const float* Wv   = (const float*)d_in[3];
  const float* Ww   = (const float*)d_in[4];
  const float* cq   = (const float*)d_in[5];
  const float* ck   = (const float*)d_in[6];
  const float* cv   = (const float*)d_in[7];
  const float* Wf1  = (const float*)d_in[8];
  const float* Wf2  = (const float*)d_in[9];
  const float* Wb   = (const float*)d_in[10];
  const float* Wg1  = (const float*)d_in[11];
  const float* Wg2  = (const float*)d_in[12];
  const float* bg2  = (const float*)d_in[13];
  const float* nw   = (const float*)d_in[14];
  const float* Wo   = (const float*)d_in[15];
  char* ws = (char*)d_ws;
  u16*   h_bf  = (u16*)  (ws + 0);
  u16*   WcatT = (u16*)  (ws + 4194304);
  u16*   Sk0   = (u16*)  (ws + 4194304);            // reuses WcatT after GEMMs (bf16)
  u16*   Sv0   = (u16*)  (ws + 20971520);
  u16*   WoT   = (u16*)  (ws + 37748736);
  u16*   WfgT  = (u16*)  (ws + 46137344);
  u16*   Wf2T  = (u16*)  (ws + 47185920);
  u16*   Wg2T  = (u16*)  (ws + 47710208);
  u16*   qkvw  = (u16*)  (ws + 48234496);           // bf16 [1024][8192]
  u16*   DSk   = (u16*)  (ws + 48234496);           // bf16, reuses qkvw after conv
  u16*   DSv   = (u16*)  (ws + 56623104);
  float* Pw    = (float*)(ws + 48234496);           // Wo split-K partials (after phaseB)
  u16*   qb    = (u16*)  (ws + 81788928);           // bf16 [1024][2048]
  u16*   kb    = (u16*)  (ws + 90177536);
  u16*   vb    = (u16*)  (ws + 98566144);
  float* wcv   = (float*)(ws + 106954752);
  float* P8    = wcv;                               // split-K partials (before conv)
  float* osc   = wcv;                               // reuses wconv after l2bw
  float* bwb   = (float*)(ws + 115343360);
  u16*   f1g1  = (u16*)  (ws + 123731968);
  float* gpre  = (float*)(ws + 124256256);
  float* gateb = gpre;                              // reuses gpre after cg
  float* cgb   = (float*)(ws + 132644864);
  float* betab = (float*)(ws + 141033472);
  u16*   Obf   = (u16*)  (ws + 141099008);
  float* outp  = (float*)d_out;

  // conversions
  f2bf_k<<<2048,256,0,stream>>>(hX, h_bf);
  transp64_k<<<dim3(32,32,5),256,0,stream>>>(Wq, Wk, Wv, Ww, Wo, WcatT, WoT);
  transp_k<<<dim3(4,64), 256,0,stream>>>(Wf1, WfgT, 2048, 128);
  transp_k<<<dim3(4,64), 256,0,stream>>>(Wg1, WfgT + (size_t)128*2048, 2048, 128);
  transp_k<<<dim3(64,4), 256,0,stream>>>(Wf2, Wf2T, 128, 2048);
  transp_k<<<dim3(64,4), 256,0,stream>>>(Wg2, Wg2T, 128, 2048);

  // projections
  gemm8_k<<<dim3(32,8),512,0,stream>>>(h_bf, WcatT, qkvw, 2048, 2048, 2048, 8192);
  gemmsk_k<<<dim3(2,8,8),256,0,stream>>>(h_bf, WfgT, P8, 2048, 2048);
  reduce8_k<<<256,256,0,stream>>>(P8, f1g1);
  gemm_k<false,1><<<dim3(16,8),256,0,stream>>>(f1g1, Wf2T, gpre, 128, 256, 128, 2048);
  beta_k<<<1024,256,0,stream>>>(hX, Wb, betab);

  // conv + silu, l2norm*beta, chunk cumsum
  conv_k<<<8192,256,0,stream>>>(qkvw, cq, ck, cv, qb, kb, vb, wcv);
  l2bw_k<<<4096,256,0,stream>>>(wcv, betab, bwb);
  cg_k<<<256,128,0,stream>>>(gpre, cgb);

  // gate GEMM (into gpre buffer, safe after cg)
  gemm_k<false,0><<<dim3(16,8),256,0,stream>>>(f1g1 + 128, Wg2T, gateb, 128, 256, 128, 2048);

  // chunked scan
  phaseA_k<<<256,256,0,stream>>>(kb, vb, bwb, cgb, DSk, DSv);
  phaseB_k<<<2048,256,0,stream>>>(DSk, DSv, cgb, Sk0, Sv0);
  phaseC_k<<<256,256,0,stream>>>(qb, kb, vb, bwb, cgb, Sk0, Sv0, osc);

  // gated RMSNorm + output projection (split-K=2, pipelined)
  norm_k<<<4096,256,0,stream>>>(osc, gateb, bg2, nw, Obf);
  gemm4sk_k<<<dim3(16,8,2),256,0,stream>>>(Obf, WoT, Pw, 1024, 2048, 2048, 2048);
  addout_k<<<2048,256,0,stream>>>(Pw, outp);
}

// Round 8
// 198.562 us; speedup vs baseline: 4.2423x; 1.0938x over previous
//
#include <hip/hip_runtime.h>
#include <hip/hip_bf16.h>
#include <stdint.h>

typedef unsigned short u16;
typedef __attribute__((ext_vector_type(8))) short bf16x8;
typedef __attribute__((ext_vector_type(4))) short bf16x4;
typedef __attribute__((ext_vector_type(4))) float f32x4;

#define DEV static __device__ __forceinline__

DEV u16 f2bf(float f){
  union { float f; unsigned u; } x; x.f = f;
  unsigned r = x.u + 0x7fffu + ((x.u >> 16) & 1u);
  return (u16)(r >> 16);
}

DEV float bf2f(u16 u){
  union { unsigned u; float f; } x; x.u = ((unsigned)u) << 16; return x.f;
}

DEV bf16x8 ldfrag(const u16* p){           // two ds_read_b64 (8B-aligned rows)
  bf16x4 a = *(const bf16x4*)p;
  bf16x4 b = *(const bf16x4*)(p+4);
  bf16x8 r;
  r[0]=a[0]; r[1]=a[1]; r[2]=a[2]; r[3]=a[3];
  r[4]=b[0]; r[5]=b[1]; r[6]=b[2]; r[7]=b[3];
  return r;
}

DEV bf16x4 cvt4(float a, float b, float c, float d){
  bf16x4 r; r[0]=(short)f2bf(a); r[1]=(short)f2bf(b); r[2]=(short)f2bf(c); r[3]=(short)f2bf(d);
  return r;
}

DEV void g2l16(const void* g, void* l){
  __builtin_amdgcn_global_load_lds((const __attribute__((address_space(1))) unsigned int*)g,
                                   (__attribute__((address_space(3))) unsigned int*)l,
                                   16, 0, 0);
}

// ---------------- fused: 2048x2048 f32->bf16 transposes (z=0..4) + hX convert (z=5) ----------------
__global__ __launch_bounds__(256)
void transp64_k(const float* __restrict__ Wq, const float* __restrict__ Wk,
                const float* __restrict__ Wv, const float* __restrict__ Ww,
                const float* __restrict__ Wo, u16* __restrict__ WcatT, u16* __restrict__ WoT,
                const float* __restrict__ hX, u16* __restrict__ h_bf){
  __shared__ float tile[64][65];
  const int z = blockIdx.z;
  if (z == 5){
    int idx = ((blockIdx.y*32 + blockIdx.x)*256 + threadIdx.x)*8;
    float4 v0 = *(const float4*)&hX[idx];
    float4 v1 = *(const float4*)&hX[idx+4];
    ushort4 o0, o1;
    o0.x=f2bf(v0.x); o0.y=f2bf(v0.y); o0.z=f2bf(v0.z); o0.w=f2bf(v0.w);
    o1.x=f2bf(v1.x); o1.y=f2bf(v1.y); o1.z=f2bf(v1.z); o1.w=f2bf(v1.w);
    *(ushort4*)&h_bf[idx]   = o0;
    *(ushort4*)&h_bf[idx+4] = o1;
    return;
  }
  const float* src = (z==0)?Wq:((z==1)?Wk:((z==2)?Wv:((z==3)?Ww:Wo)));
  u16* dst = (z<4) ? (WcatT + (size_t)z*4194304) : WoT;
  const int c0 = blockIdx.x*64, r0 = blockIdx.y*64;
#pragma unroll
  for (int p=0;p<4;p++){
    int i = threadIdx.x + p*256;
    int r = i>>4, c4 = (i&15)<<2;
    *(float4*)&tile[r][c4] = *(const float4*)&src[(size_t)(r0+r)*2048 + c0 + c4];
  }
  __syncthreads();
#pragma unroll
  for (int p=0;p<4;p++){
    int i = threadIdx.x + p*256;
    int cc = i>>4, r4 = (i&15)<<2;
    ushort4 o;
    o.x = f2bf(tile[r4+0][cc]); o.y = f2bf(tile[r4+1][cc]);
    o.z = f2bf(tile[r4+2][cc]); o.w = f2bf(tile[r4+3][cc]);
    *(ushort4*)&dst[(size_t)(c0+cc)*2048 + r0 + r4] = o;
  }
}

// ---------------- fused small transposes: Wf1,Wg1 (2048x128) ; Wf2,Wg2 (128x2048) ----------------
__global__ __launch_bounds__(256)
void transpsm_k(const float* __restrict__ Wf1, const float* __restrict__ Wg1,
                const float* __restrict__ Wf2, const float* __restrict__ Wg2,
                u16* __restrict__ WfgT, u16* __restrict__ Wf2T, u16* __restrict__ Wg2T){
  __shared__ float tile[32][33];
  const int bx = blockIdx.x;              // 0..1023
  const int z = bx >> 8, rem = bx & 255;
  const float* src; u16* dst; int R, C, cx, cy;
  if (z==0){      src=Wf1; dst=WfgT;                    R=2048; C=128;  cx=rem&3;  cy=rem>>2; }
  else if (z==1){ src=Wg1; dst=WfgT+(size_t)128*2048;   R=2048; C=128;  cx=rem&3;  cy=rem>>2; }
  else if (z==2){ src=Wf2; dst=Wf2T;                    R=128;  C=2048; cx=rem>>2; cy=rem&3; }
  else {          src=Wg2; dst=Wg2T;                    R=128;  C=2048; cx=rem>>2; cy=rem&3; }
  const int c0 = cx*32, r0 = cy*32;
  const int x = threadIdx.x & 31, y0 = threadIdx.x >> 5;
#pragma unroll
  for (int j=0;j<4;j++){
    int r = y0 + j*8;
    tile[r][x] = src[(size_t)(r0+r)*C + c0 + x];
  }
  __syncthreads();
#pragma unroll
  for (int j=0;j<4;j++){
    int cc = y0 + j*8;
    dst[(size_t)(c0+cc)*R + r0 + x] = f2bf(tile[x][cc]);
  }
}

// ---------------- pipelined GEMM: 128x128, BK=64, 4 waves, dbuf + counted vmcnt ----------------
// A[M,K] row (lda), B^T[N,K] row (ldb) -> C bf16 or f32 (ldc); 64KB LDS -> 2 blocks/CU
template<bool OBF>
__global__ __launch_bounds__(256)
void gemm4_k(const u16* __restrict__ A, const u16* __restrict__ B, void* __restrict__ Cp,
             int K, int lda, int ldb, int ldc){
  __shared__ u16 As[2][128*64];
  __shared__ u16 Bs[2][128*64];
  const int m0 = blockIdx.y*128, n0 = blockIdx.x*128;
  const int tid = threadIdx.x;
  const int wave = tid>>6, lane = tid&63, lr = lane&15, kg = lane>>4;
  const int wm = wave>>1, wn = wave&1;
  const f32x4 vz = {0.f,0.f,0.f,0.f};
  f32x4 acc[4][4];
#pragma unroll
  for (int a=0;a<4;a++)
#pragma unroll
    for (int b=0;b<4;b++) acc[a][b]=vz;

#define STAGE4(buf, k0) do { \
    _Pragma("unroll") \
    for (int p=0;p<4;p++){ \
      int chunk = tid + p*256, r_ = chunk>>3, ci = chunk&7; \
      g2l16(A + (size_t)(m0+r_)*lda + (k0) + ((ci^(r_&7))<<3), &As[buf][chunk*8]); \
    } \
    _Pragma("unroll") \
    for (int p=0;p<4;p++){ \
      int chunk = tid + p*256, r_ = chunk>>3, ci = chunk&7; \
      g2l16(B + (size_t)(n0+r_)*ldb + (k0) + ((ci^(r_&7))<<3), &Bs[buf][chunk*8]); \
    } \
  } while(0)

  const int nt = K>>6;          // >= 2 required
  STAGE4(0, 0);
  STAGE4(1, 64);
  for (int t=0; t<nt; ++t){
    const int buf = t&1;
    if (t < nt-1) asm volatile("s_waitcnt vmcnt(8)" ::: "memory");
    else          asm volatile("s_waitcnt vmcnt(0)" ::: "memory");
    asm volatile("s_barrier" ::: "memory");
#pragma unroll
    for (int ks=0; ks<2; ++ks){
      bf16x8 af[4], bfv[4];
#pragma unroll
      for (int mi=0;mi<4;mi++){
        int r = wm*64+mi*16+lr;
        af[mi] = *(const bf16x8*)&As[buf][r*64 + (((ks*4+kg)^(r&7))<<3)];
      }
#pragma unroll
      for (int ni=0;ni<4;ni++){
        int r = wn*64+ni*16+lr;
        bfv[ni] = *(const bf16x8*)&Bs[buf][r*64 + (((ks*4+kg)^(r&7))<<3)];
      }
      asm volatile("s_waitcnt lgkmcnt(0)" ::: "memory");
      __builtin_amdgcn_sched_barrier(0);
      __builtin_amdgcn_s_setprio(1);
#pragma unroll
      for (int mi=0;mi<4;mi++)
#pragma unroll
        for (int ni=0;ni<4;ni++)
          acc[mi][ni] = __builtin_amdgcn_mfma_f32_16x16x32_bf16(af[mi], bfv[ni], acc[mi][ni], 0, 0, 0);
      __builtin_amdgcn_s_setprio(0);
      __builtin_amdgcn_sched_barrier(0);
      asm volatile("s_barrier" ::: "memory");
    }
    if (t+2 < nt) STAGE4(buf, (t+2)<<6);
  }
#undef STAGE4
#pragma unroll
  for (int mi=0;mi<4;mi++)
#pragma unroll
    for (int ni=0;ni<4;ni++)
#pragma unroll
      for (int vv=0;vv<4;vv++){
        int row = m0 + wm*64 + mi*16 + kg*4 + vv;
        int col = n0 + wn*64 + ni*16 + lr;
        if (OBF) ((u16*)Cp)[(size_t)row*ldc + col] = f2bf(acc[mi][ni][vv]);
        else     ((float*)Cp)[(size_t)row*ldc + col] = acc[mi][ni][vv];
      }
}

// ---------------- split-K pipelined GEMM: 128x128, BK=64, 4 waves -> f32 partials ----------------
__global__ __launch_bounds__(256)
void gemm4sk_k(const u16* __restrict__ A, const u16* __restrict__ B, float* __restrict__ P,
               int Khalf, int lda, int ldb, int ldc){
  __shared__ u16 As[2][128*64];
  __shared__ u16 Bs[2][128*64];
  const int m0 = blockIdx.y*128, n0 = blockIdx.x*128;
  const int kbase = blockIdx.z*Khalf;
  const int tid = threadIdx.x;
  const int wave = tid>>6, lane = tid&63, lr = lane&15, kg = lane>>4;
  const int wm = wave>>1, wn = wave&1;
  const f32x4 vz = {0.f,0.f,0.f,0.f};
  f32x4 acc[4][4];
#pragma unroll
  for (int a=0;a<4;a++)
#pragma unroll
    for (int b=0;b<4;b++) acc[a][b]=vz;

#define STAGE4(buf, k0) do { \
    _Pragma("unroll") \
    for (int p=0;p<4;p++){ \
      int chunk = tid + p*256, r_ = chunk>>3, ci = chunk&7; \
      g2l16(A + (size_t)(m0+r_)*lda + (k0) + ((ci^(r_&7))<<3), &As[buf][chunk*8]); \
    } \
    _Pragma("unroll") \
    for (int p=0;p<4;p++){ \
      int chunk = tid + p*256, r_ = chunk>>3, ci = chunk&7; \
      g2l16(B + (size_t)(n0+r_)*ldb + (k0) + ((ci^(r_&7))<<3), &Bs[buf][chunk*8]); \
    } \
  } while(0)

  const int nt = Khalf>>6;      // >= 2 required
  STAGE4(0, kbase);
  STAGE4(1, kbase+64);
  for (int t=0; t<nt; ++t){
    const int buf = t&1;
    if (t < nt-1) asm volatile("s_waitcnt vmcnt(8)" ::: "memory");
    else          asm volatile("s_waitcnt vmcnt(0)" ::: "memory");
    asm volatile("s_barrier" ::: "memory");
#pragma unroll
    for (int ks=0; ks<2; ++ks){
      bf16x8 af[4], bfv[4];
#pragma unroll
      for (int mi=0;mi<4;mi++){
        int r = wm*64+mi*16+lr;
        af[mi] = *(const bf16x8*)&As[buf][r*64 + (((ks*4+kg)^(r&7))<<3)];
      }
#pragma unroll
      for (int ni=0;ni<4;ni++){
        int r = wn*64+ni*16+lr;
        bfv[ni] = *(const bf16x8*)&Bs[buf][r*64 + (((ks*4+kg)^(r&7))<<3)];
      }
      asm volatile("s_waitcnt lgkmcnt(0)" ::: "memory");
      __builtin_amdgcn_sched_barrier(0);
      __builtin_amdgcn_s_setprio(1);
#pragma unroll
      for (int mi=0;mi<4;mi++)
#pragma unroll
        for (int ni=0;ni<4;ni++)
          acc[mi][ni] = __builtin_amdgcn_mfma_f32_16x16x32_bf16(af[mi], bfv[ni], acc[mi][ni], 0, 0, 0);
      __builtin_amdgcn_s_setprio(0);
      __builtin_amdgcn_sched_barrier(0);
      asm volatile("s_barrier" ::: "memory");
    }
    if (t+2 < nt) STAGE4(buf, kbase + ((t+2)<<6));
  }
#undef STAGE4
#pragma unroll
  for (int mi=0;mi<4;mi++)
#pragma unroll
    for (int ni=0;ni<4;ni++)
#pragma unroll
      for (int vv=0;vv<4;vv++){
        int row = m0 + wm*64 + mi*16 + kg*4 + vv;
        int col = n0 + wn*64 + ni*16 + lr;
        P[(size_t)blockIdx.z*2097152 + (size_t)row*ldc + col] = acc[mi][ni][vv];
      }
}

__global__ __launch_bounds__(256)
void addout_k(const float* __restrict__ P, float* __restrict__ out){
  int i = (blockIdx.x*256 + threadIdx.x)*4;
  float4 a = *(const float4*)&P[i];
  float4 b = *(const float4*)&P[2097152 + i];
  float4 s = {a.x+b.x, a.y+b.y, a.z+b.z, a.w+b.w};
  *(float4*)&out[i] = s;
}

// ---------------- bf16 GEMM (128^2, BK=32): EPI 0=none 1=logsigmoid ----------------
template<bool OBF, int EPI>
__global__ __launch_bounds__(256)
void gemm_k(const u16* __restrict__ A, const u16* __restrict__ B, void* __restrict__ Cp,
            int K, int lda, int ldb, int ldc){
  __shared__ u16 As[128*32];
  __shared__ u16 Bs[128*32];
  const int m0 = blockIdx.y*128, n0 = blockIdx.x*128;
  const int tid = threadIdx.x;
  const int lane = tid & 63, wave = tid >> 6;
  const int wr = wave >> 1, wc = wave & 1;
  const int lr = lane & 15, kg = lane >> 4;
  const f32x4 vzero = {0.f,0.f,0.f,0.f};
  f32x4 acc[4][4];
#pragma unroll
  for (int a=0;a<4;a++)
#pragma unroll
    for (int b=0;b<4;b++) acc[a][b] = vzero;
  const int r0 = tid>>2, s0 = tid&3;
  for (int k0=0;k0<K;k0+=32){
    __syncthreads();
    g2l16(A + (size_t)(m0+r0)*lda + k0 + s0*8, (u16*)As + (size_t)tid*8);
    g2l16(B + (size_t)(n0+r0)*ldb + k0 + s0*8, (u16*)Bs + (size_t)tid*8);
    g2l16(A + (size_t)(m0+r0+64)*lda + k0 + s0*8, (u16*)As + (size_t)(tid+256)*8);
    g2l16(B + (size_t)(n0+r0+64)*ldb + k0 + s0*8, (u16*)Bs + (size_t)(tid+256)*8);
    __syncthreads();
    bf16x8 af[4], bfv[4];
#pragma unroll
    for (int mi=0;mi<4;mi++) af[mi]  = *(const bf16x8*)(As + (wr*64+mi*16+lr)*32 + kg*8);
#pragma unroll
    for (int ni=0;ni<4;ni++) bfv[ni] = *(const bf16x8*)(Bs + (wc*64+ni*16+lr)*32 + kg*8);
#pragma unroll
    for (int mi=0;mi<4;mi++)
#pragma unroll
      for (int ni=0;ni<4;ni++)
        acc[mi][ni] = __builtin_amdgcn_mfma_f32_16x16x32_bf16(af[mi], bfv[ni], acc[mi][ni], 0, 0, 0);
  }
#pragma unroll
  for (int mi=0;mi<4;mi++)
#pragma unroll
    for (int ni=0;ni<4;ni++)
#pragma unroll
      for (int vv=0;vv<4;vv++){
        int row = m0 + wr*64 + mi*16 + kg*4 + vv;
        int col = n0 + wc*64 + ni*16 + lr;
        float val = acc[mi][ni][vv];
        if (EPI==1) val = fminf(val,0.f) - __logf(1.f + __expf(-fabsf(val)));
        if (OBF) ((u16*)Cp)[(size_t)row*ldc + col] = f2bf(val);
        else     ((float*)Cp)[(size_t)row*ldc + col] = val;
      }
}

// ---------------- split-K GEMM for f1g1 (N=256, K=2048 in 8 chunks) ----------------
__global__ __launch_bounds__(256)
void gemmsk_k(const u16* __restrict__ A, const u16* __restrict__ B, float* __restrict__ P,
              int lda, int ldb){
  __shared__ u16 As[128*32];
  __shared__ u16 Bs[128*32];
  const int m0 = blockIdx.y*128, n0 = blockIdx.x*128;
  const int kbase = blockIdx.z*256;
  const int tid = threadIdx.x;
  const int lane = tid & 63, wave = tid >> 6;
  const int wr = wave >> 1, wc = wave & 1;
  const int lr = lane & 15, kg = lane >> 4;
  const f32x4 vzero = {0.f,0.f,0.f,0.f};
  f32x4 acc[4][4];
#pragma unroll
  for (int a=0;a<4;a++)
#pragma unroll
    for (int b=0;b<4;b++) acc[a][b] = vzero;
  const int r0 = tid>>2, s0 = tid&3;
  for (int k0=kbase;k0<kbase+256;k0+=32){
    __syncthreads();
    g2l16(A + (size_t)(m0+r0)*lda + k0 + s0*8, (u16*)As + (size_t)tid*8);
    g2l16(B + (size_t)(n0+r0)*ldb + k0 + s0*8, (u16*)Bs + (size_t)tid*8);
    g2l16(A + (size_t)(m0+r0+64)*lda + k0 + s0*8, (u16*)As + (size_t)(tid+256)*8);
    g2l16(B + (size_t)(n0+r0+64)*ldb + k0 + s0*8, (u16*)Bs + (size_t)(tid+256)*8);
    __syncthreads();
    bf16x8 af[4], bfv[4];
#pragma unroll
    for (int mi=0;mi<4;mi++) af[mi]  = *(const bf16x8*)(As + (wr*64+mi*16+lr)*32 + kg*8);
#pragma unroll
    for (int ni=0;ni<4;ni++) bfv[ni] = *(const bf16x8*)(Bs + (wc*64+ni*16+lr)*32 + kg*8);
#pragma unroll
    for (int mi=0;mi<4;mi++)
#pragma unroll
      for (int ni=0;ni<4;ni++)
        acc[mi][ni] = __builtin_amdgcn_mfma_f32_16x16x32_bf16(af[mi], bfv[ni], acc[mi][ni], 0, 0, 0);
  }
#pragma unroll
  for (int mi=0;mi<4;mi++)
#pragma unroll
    for (int ni=0;ni<4;ni++)
#pragma unroll
      for (int vv=0;vv<4;vv++){
        int row = m0 + wr*64 + mi*16 + kg*4 + vv;
        int col = n0 + wc*64 + ni*16 + lr;
        P[(size_t)blockIdx.z*262144 + (size_t)row*256 + col] = acc[mi][ni][vv];
      }
}

__global__ __launch_bounds__(256)
void reduce8_k(const float* __restrict__ P, u16* __restrict__ out){
  int i = (blockIdx.x*256 + threadIdx.x)*4;
  float4 s = *(const float4*)&P[i];
#pragma unroll
  for (int z=1;z<8;z++){
    float4 p = *(const float4*)&P[(size_t)z*262144 + i];
    s.x+=p.x; s.y+=p.y; s.z+=p.z; s.w+=p.w;
  }
  ushort4 o; o.x=f2bf(s.x); o.y=f2bf(s.y); o.z=f2bf(s.z); o.w=f2bf(s.w);
  *(ushort4*)&out[i] = o;
}

// ---------------- beta = sigmoid(h @ Wb), per-t block ----------------
__global__ __launch_bounds__(256)
void beta_k(const float* __restrict__ h, const float* __restrict__ Wb, float* __restrict__ betab){
  __shared__ float hrow[2048];
  __shared__ float red[16][5];
  const int t = blockIdx.x, tid = threadIdx.x;
#pragma unroll
  for (int j=0;j<8;j++) hrow[tid + j*256] = h[(size_t)t*2048 + tid + j*256];
  __syncthreads();
  float part[16];
#pragma unroll
  for (int n=0;n<16;n++) part[n]=0.f;
  for (int j=0;j<8;j++){
    int kk = tid + j*256;
    float hv = hrow[kk];
    const float4* wr4 = (const float4*)&Wb[(size_t)kk*16];
    float4 w0=wr4[0], w1=wr4[1], w2=wr4[2], w3=wr4[3];
    part[0]+=hv*w0.x; part[1]+=hv*w0.y; part[2]+=hv*w0.z; part[3]+=hv*w0.w;
    part[4]+=hv*w1.x; part[5]+=hv*w1.y; part[6]+=hv*w1.z; part[7]+=hv*w1.w;
    part[8]+=hv*w2.x; part[9]+=hv*w2.y; part[10]+=hv*w2.z; part[11]+=hv*w2.w;
    part[12]+=hv*w3.x; part[13]+=hv*w3.y; part[14]+=hv*w3.z; part[15]+=hv*w3.w;
  }
#pragma unroll
  for (int n=0;n<16;n++){
    float s = part[n];
#pragma unroll
    for (int off=1;off<64;off<<=1) s += __shfl_xor(s, off);
    if ((tid&63)==0) red[n][tid>>6] = s;
  }
  __syncthreads();
  if (tid < 16){
    float s = red[tid][0]+red[tid][1]+red[tid][2]+red[tid][3];
    betab[t*16+tid] = 1.f/(1.f+__expf(-s));
  }
}

// ---------------- causal conv4 + silu: q,k,v -> bf16 ; w -> f32 ----------------
__global__ __launch_bounds__(256)
void conv_k(const u16* __restrict__ raw, const float* __restrict__ cq,
            const float* __restrict__ ck, const float* __restrict__ cv,
            u16* __restrict__ qo, u16* __restrict__ ko,
            u16* __restrict__ vo, float* __restrict__ wo){
  int idx = blockIdx.x*256 + threadIdx.x;
  int cgl = idx & 8191, tb = idx >> 13;
  int which = cgl >> 11, cc = cgl & 2047;
  const float* wt = (which==0)?cq:((which==1)?ck:cv);   // w-branch (3) uses cv (faithful to ref)
  float4 w4 = *(const float4*)&wt[cc*4];
  u16* outb = (which==0)?qo:((which==1)?ko:vo);
  int t0 = tb*4;
  float x[7];
#pragma unroll
  for (int j=0;j<7;j++){
    int t = t0 - 3 + j;
    x[j] = (t >= 0) ? bf2f(raw[(size_t)t*8192 + cgl]) : 0.f;
  }
#pragma unroll
  for (int j=0;j<4;j++){
    float y = x[j]*w4.x + x[j+1]*w4.y + x[j+2]*w4.z + x[j+3]*w4.w;
    y = y / (1.f + __expf(-y));           // silu
    if (which==3) wo[(size_t)(t0+j)*2048 + cc] = y;
    else          outb[(size_t)(t0+j)*2048 + cc] = f2bf(y);
  }
}

// ---------------- l2norm over M + beta scale: bw ----------------
__global__ __launch_bounds__(256)
void l2bw_k(const float* __restrict__ wconv, const float* __restrict__ betab,
            float* __restrict__ bwout){
  int row = blockIdx.x*4 + (threadIdx.x>>6);
  int lane = threadIdx.x & 63;
  int t = row >> 4, h = row & 15;
  size_t base = (size_t)t*2048 + h*128;
  float a0 = wconv[base+lane], a1 = wconv[base+64+lane];
  float ss = a0*a0 + a1*a1;
#pragma unroll
  for (int off=1;off<64;off<<=1) ss += __shfl_xor(ss, off);
  float r = rsqrtf(ss + 1e-6f) * betab[t*16+h];
  bwout[base+lane]    = a0*r;
  bwout[base+64+lane] = a1*r;
}

// ---------------- per-chunk inclusive cumsum (gpre already = logsigmoid) ----------------
__global__ __launch_bounds__(128)
void cg_k(const float* __restrict__ gpre, float* __restrict__ cg){
  int idx = blockIdx.x*128 + threadIdx.x;   // 32768 = c*2048 + h*128 + m
  int c = idx >> 11;
  size_t base = (size_t)(idx & 2047);
  float run = 0.f;
  for (int i2=0;i2<64;i2++){
    size_t t = (size_t)c*64 + i2;
    run += gpre[t*2048 + base];
    cg[t*2048 + base] = run;
  }
}

// ---------------- Phase A (MFMA): DSkT[m][d] = U^T K ; DSvT[v][m] = V^T U (bf16 out) ----------------
__global__ __launch_bounds__(256)
void phaseA_k(const u16* __restrict__ k, const u16* __restrict__ v,
              const float* __restrict__ bw, const float* __restrict__ cg,
              u16* __restrict__ DSkT, u16* __restrict__ DSvT){
  __shared__ u16 UT[128*68];
  __shared__ u16 KT[128*68];
  __shared__ u16 VT[128*68];
  __shared__ float Gt[128];
  const int bx=blockIdx.x, h=bx&15, c=bx>>4, tid=threadIdx.x;
  const int w=tid>>6, lane=tid&63, lr=lane&15, kg=lane>>4;
  if (tid<128) Gt[tid] = cg[(size_t)(c*64+63)*2048 + h*128 + tid];
  __syncthreads();
#pragma unroll
  for (int j=0;j<8;j++){
    int f4=tid+j*256, r=f4>>5, c4=(f4&31)<<2;
    size_t g=(size_t)(c*64+r)*2048 + h*128 + c4;
    ushort4 kv=*(const ushort4*)&k[g];
    ushort4 vv=*(const ushort4*)&v[g];
    float4 bv=*(const float4*)&bw[g];
    float4 cv=*(const float4*)&cg[g];
    float u0=bv.x*__expf(Gt[c4+0]-cv.x);
    float u1=bv.y*__expf(Gt[c4+1]-cv.y);
    float u2=bv.z*__expf(Gt[c4+2]-cv.z);
    float u3=bv.w*__expf(Gt[c4+3]-cv.w);
    KT[(c4+0)*68+r]=kv.x; KT[(c4+1)*68+r]=kv.y;
    KT[(c4+2)*68+r]=kv.z; KT[(c4+3)*68+r]=kv.w;
    VT[(c4+0)*68+r]=vv.x; VT[(c4+1)*68+r]=vv.y;
    VT[(c4+2)*68+r]=vv.z; VT[(c4+3)*68+r]=vv.w;
    UT[(c4+0)*68+r]=f2bf(u0);   UT[(c4+1)*68+r]=f2bf(u1);
    UT[(c4+2)*68+r]=f2bf(u2);   UT[(c4+3)*68+r]=f2bf(u3);
  }
  __syncthreads();
  const f32x4 vz = {0.f,0.f,0.f,0.f};
  {
    f32x4 acc[2][8];
#pragma unroll
    for (int a=0;a<2;a++)
#pragma unroll
      for (int b=0;b<8;b++) acc[a][b]=vz;
#pragma unroll
    for (int ks=0;ks<2;ks++){
      bf16x8 a0=ldfrag(&UT[(w*32   +lr)*68 + ks*32+kg*8]);
      bf16x8 a1=ldfrag(&UT[(w*32+16+lr)*68 + ks*32+kg*8]);
#pragma unroll
      for (int nj=0;nj<8;nj++){
        bf16x8 b=ldfrag(&KT[(nj*16+lr)*68 + ks*32+kg*8]);
        acc[0][nj]=__builtin_amdgcn_mfma_f32_16x16x32_bf16(a0,b,acc[0][nj],0,0,0);
        acc[1][nj]=__builtin_amdgcn_mfma_f32_16x16x32_bf16(a1,b,acc[1][nj],0,0,0);
      }
    }
#pragma unroll
    for (int mi2=0;mi2<2;mi2++)
#pragma unroll
      for (int nj=0;nj<8;nj++)
#pragma unroll
        for (int vv2=0;vv2<4;vv2++)
          DSkT[(size_t)bx*16384 + (size_t)(w*32+mi2*16+kg*4+vv2)*128 + nj*16+lr] = f2bf(acc[mi2][nj][vv2]);
  }
  {
    f32x4 acc[2][8];
#pragma unroll
    for (int a=0;a<2;a++)
#pragma unroll
      for (int b=0;b<8;b++) acc[a][b]=vz;
#pragma unroll
    for (int ks=0;ks<2;ks++){
      bf16x8 a0=ldfrag(&VT[(w*32   +lr)*68 + ks*32+kg*8]);
      bf16x8 a1=ldfrag(&VT[(w*32+16+lr)*68 + ks*32+kg*8]);
#pragma unroll
      for (int nj=0;nj<8;nj++){
        bf16x8 b=ldfrag(&UT[(nj*16+lr)*68 + ks*32+kg*8]);
        acc[0][nj]=__builtin_amdgcn_mfma_f32_16x16x32_bf16(a0,b,acc[0][nj],0,0,0);
        acc[1][nj]=__builtin_amdgcn_mfma_f32_16x16x32_bf16(a1,b,acc[1][nj],0,0,0);
      }
    }
#pragma unroll
    for (int mi2=0;mi2<2;mi2++)
#pragma unroll
      for (int nj=0;nj<8;nj++)
#pragma unroll
        for (int vv2=0;vv2<4;vv2++)
          DSvT[(size_t)bx*16384 + (size_t)(w*32+mi2*16+kg*4+vv2)*128 + nj*16+lr] = f2bf(acc[mi2][nj][vv2]);
  }
}

// ---------------- Phase B: sequential cross-chunk combine (bf16 in/out) ----------------
__global__ __launch_bounds__(256)
void phaseB_k(const u16* __restrict__ DSk, const u16* __restrict__ DSv,
              const float* __restrict__ cg, u16* __restrict__ Sk0, u16* __restrict__ Sv0){
  unsigned idx = blockIdx.x*256u + threadIdx.x;   // 524288 total
  int sel  = idx >> 18;
  int h    = (idx >> 14) & 15;
  int flat = idx & 16383;                 // SkT: m*128+d ; SvT: v*128+m
  int mdec = sel ? (flat & 127) : (flat >> 7);
  const u16* DS = sel ? DSv : DSk;
  u16* S = sel ? Sv0 : Sk0;
  float cur = 0.f;
  for (int c=0;c<16;c++){
    size_t sb = ((size_t)(c*16+h))*16384 + flat;
    S[sb] = f2bf(cur);                     // state BEFORE chunk c
    float gd = __expf(cg[(size_t)(c*64+63)*2048 + h*128 + mdec]);
    cur = cur*gd + bf2f(DS[sb]);
  }
}

// ---------------- Phase C (MFMA): per-chunk outputs ----------------
__global__ __launch_bounds__(256)
void phaseC_k(const u16* __restrict__ q, const u16* __restrict__ k,
              const u16* __restrict__ v, const float* __restrict__ bw,
              const float* __restrict__ cg, const u16* __restrict__ SkT,
              const u16* __restrict__ SvT, float* __restrict__ o){
  __shared__ u16 Qb[64*132];     // Q, then A' (wave-private rows after prep)
  __shared__ u16 KV[8704];       // K[64][132], then VT[128][68]
  __shared__ u16 Bws[64*132];    // bw*e^{cgm-cg} natural [s][m]
  __shared__ u16 BwT[128*68];    // transposed [m][s]
  __shared__ u16 Ssb[64*68];     // sqk, then P (wave-private rows)
  __shared__ u16 SkL[128*132];   // Sk'^T * e^{cgm[m]}  [m][d]
  __shared__ u16 SvL[128*132];   // Sv'^T * e^{cgm[m]}  [v][m]
  __shared__ float cgm[128];
  __shared__ float ecgm[128];
  const int bx=blockIdx.x, h=bx&15, c=bx>>4, tid=threadIdx.x;
  const int w=tid>>6, lane=tid&63, lr=lane&15, kg=lane>>4;
  const float SCALE = 0.088388347648318447f;   // 128^-0.5
  const f32x4 vz = {0.f,0.f,0.f,0.f};
  if (tid<128){ float t=cg[(size_t)(c*64+31)*2048 + h*128 + tid]; cgm[tid]=t; ecgm[tid]=__expf(t); }
  __syncthreads();
#pragma unroll
  for (int j=0;j<8;j++){
    int f4=tid+j*256, r=f4>>5, c4=(f4&31)<<2;
    size_t g=(size_t)(c*64+r)*2048 + h*128 + c4;
    *(ushort4*)&Qb[r*132+c4] = *(const ushort4*)&q[g];
    *(ushort4*)&KV[r*132+c4] = *(const ushort4*)&k[g];
    float4 bv=*(const float4*)&bw[g];
    float4 cv=*(const float4*)&cg[g];
    float b0=bv.x*__expf(cgm[c4+0]-cv.x);
    float b1=bv.y*__expf(cgm[c4+1]-cv.y);
    float b2=bv.z*__expf(cgm[c4+2]-cv.z);
    float b3=bv.w*__expf(cgm[c4+3]-cv.w);
    bf16x4 bb = cvt4(b0,b1,b2,b3);
    *(bf16x4*)&Bws[r*132+c4] = bb;
    BwT[(c4+0)*68+r]=(u16)bb[0]; BwT[(c4+1)*68+r]=(u16)bb[1];
    BwT[(c4+2)*68+r]=(u16)bb[2]; BwT[(c4+3)*68+r]=(u16)bb[3];
  }
  __syncthreads();
  {
    f32x4 acc1[4];
#pragma unroll
    for (int a=0;a<4;a++) acc1[a]=vz;
#pragma unroll
    for (int ks=0;ks<4;ks++){
      bf16x8 aq = ldfrag(&Qb[(w*16+lr)*132 + ks*32+kg*8]);
#pragma unroll
      for (int ni=0;ni<4;ni++){
        bf16x8 bk = ldfrag(&KV[(ni*16+lr)*132 + ks*32+kg*8]);
        acc1[ni]=__builtin_amdgcn_mfma_f32_16x16x32_bf16(aq,bk,acc1[ni],0,0,0);
      }
    }
#pragma unroll
    for (int ni=0;ni<4;ni++)
#pragma unroll
      for (int vv2=0;vv2<4;vv2++){
        int row=w*16+kg*4+vv2, col=ni*16+lr;
        Ssb[row*68+col] = (col<=row) ? f2bf(acc1[ni][vv2]) : (u16)0;
      }
  }
  __syncthreads();   // all K reads done -> KV reusable for VT
#pragma unroll
  for (int j=0;j<8;j++){
    int f4=tid+j*256, r=f4>>5, c4=(f4&31)<<2;
    ushort4 vv=*(const ushort4*)&v[(size_t)(c*64+r)*2048 + h*128 + c4];
    KV[(c4+0)*68+r]=vv.x; KV[(c4+1)*68+r]=vv.y;
    KV[(c4+2)*68+r]=vv.z; KV[(c4+3)*68+r]=vv.w;
  }
#pragma unroll
  for (int j=0;j<16;j++){
    int f4=tid+j*256, r=f4>>5, c4=(f4&31)<<2;
    ushort4 s4=*(const ushort4*)&SkT[(size_t)bx*16384 + (size_t)r*128 + c4];
    float em=ecgm[r];
    *(bf16x4*)&SkL[r*132+c4]=cvt4(bf2f(s4.x)*em, bf2f(s4.y)*em, bf2f(s4.z)*em, bf2f(s4.w)*em);
  }
#pragma unroll
  for (int j=0;j<16;j++){
    int f4=tid+j*256, r=f4>>5, c4=(f4&31)<<2;
    ushort4 s4=*(const ushort4*)&SvT[(size_t)bx*16384 + (size_t)r*128 + c4];
    *(bf16x4*)&SvL[r*132+c4]=cvt4(bf2f(s4.x)*ecgm[c4+0], bf2f(s4.y)*ecgm[c4+1],
                                  bf2f(s4.z)*ecgm[c4+2], bf2f(s4.w)*ecgm[c4+3]);
  }
  f32x4 zac[8];
#pragma unroll
  for (int a=0;a<8;a++) zac[a]=vz;
#pragma unroll
  for (int ks=0;ks<2;ks++){
    bf16x8 as_ = ldfrag(&Ssb[(w*16+lr)*68 + ks*32+kg*8]);
#pragma unroll
    for (int ni=0;ni<8;ni++){
      bf16x8 bb = ldfrag(&BwT[(ni*16+lr)*68 + ks*32+kg*8]);
      zac[ni]=__builtin_amdgcn_mfma_f32_16x16x32_bf16(as_,bb,zac[ni],0,0,0);
    }
  }
  __syncthreads();   // SkL/SvL/VT staged & visible
#pragma unroll
  for (int dt=0;dt<4;dt++){
    bf16x8 aq = ldfrag(&Qb[(w*16+lr)*132 + dt*32+kg*8]);
#pragma unroll
    for (int ni=0;ni<8;ni++){
      bf16x8 bs = ldfrag(&SkL[(ni*16+lr)*132 + dt*32+kg*8]);
      zac[ni]=__builtin_amdgcn_mfma_f32_16x16x32_bf16(aq,bs,zac[ni],0,0,0);
    }
  }
  float dec[4][8], zz[4][8];
#pragma unroll
  for (int vv2=0;vv2<4;vv2++)
#pragma unroll
    for (int ni=0;ni<8;ni++) zz[vv2][ni]=zac[ni][vv2];
#pragma unroll
  for (int vv2=0;vv2<4;vv2++){
    size_t gr=(size_t)(c*64+w*16+kg*4+vv2)*2048 + h*128;
#pragma unroll
    for (int ni=0;ni<8;ni++){
      float cgv = cg[gr + ni*16+lr];
      dec[vv2][ni] = __expf(cgv - cgm[ni*16+lr]);
    }
  }
#pragma unroll
  for (int vv2=0;vv2<4;vv2++){
    float mx=-3.0e38f;
#pragma unroll
    for (int ni=0;ni<8;ni++){ zz[vv2][ni] *= SCALE*dec[vv2][ni]; mx=fmaxf(mx,zz[vv2][ni]); }
    mx=fmaxf(mx,__shfl_xor(mx,1)); mx=fmaxf(mx,__shfl_xor(mx,2));
    mx=fmaxf(mx,__shfl_xor(mx,4)); mx=fmaxf(mx,__shfl_xor(mx,8));
    float sum=0.f;
#pragma unroll
    for (int ni=0;ni<8;ni++){ zz[vv2][ni]=__expf(zz[vv2][ni]-mx); sum+=zz[vv2][ni]; }
    sum+=__shfl_xor(sum,1); sum+=__shfl_xor(sum,2);
    sum+=__shfl_xor(sum,4); sum+=__shfl_xor(sum,8);
    float inv=1.f/sum;
#pragma unroll
    for (int ni=0;ni<8;ni++) zz[vv2][ni] *= inv*dec[vv2][ni];   // A' = a * e^{cg-cgm}
  }
#pragma unroll
  for (int vv2=0;vv2<4;vv2++)
#pragma unroll
    for (int ni=0;ni<8;ni++)
      Qb[(w*16+kg*4+vv2)*132 + ni*16+lr] = f2bf(zz[vv2][ni]);
  {
    f32x4 acc4[4];
#pragma unroll
    for (int a=0;a<4;a++) acc4[a]=vz;
#pragma unroll
    for (int ks=0;ks<4;ks++){
      bf16x8 aa = ldfrag(&Qb[(w*16+lr)*132 + ks*32+kg*8]);
#pragma unroll
      for (int ni=0;ni<4;ni++){
        bf16x8 bb = ldfrag(&Bws[(ni*16+lr)*132 + ks*32+kg*8]);
        acc4[ni]=__builtin_amdgcn_mfma_f32_16x16x32_bf16(aa,bb,acc4[ni],0,0,0);
      }
    }
#pragma unroll
    for (int ni=0;ni<4;ni++)
#pragma unroll
      for (int vv2=0;vv2<4;vv2++){
        int row=w*16+kg*4+vv2, col=ni*16+lr;
        Ssb[row*68+col] = (col<=row) ? f2bf(acc4[ni][vv2]) : (u16)0;
      }
  }
  f32x4 oac[8];
#pragma unroll
  for (int a=0;a<8;a++) oac[a]=vz;
#pragma unroll
  for (int ks=0;ks<2;ks++){
    bf16x8 ap = ldfrag(&Ssb[(w*16+lr)*68 + ks*32+kg*8]);
#pragma unroll
    for (int ni=0;ni<8;ni++){
      bf16x8 bv2 = ldfrag(&KV[(ni*16+lr)*68 + ks*32+kg*8]);
      oac[ni]=__builtin_amdgcn_mfma_f32_16x16x32_bf16(ap,bv2,oac[ni],0,0,0);
    }
  }
#pragma unroll
  for (int mt=0;mt<4;mt++){
    bf16x8 aa = ldfrag(&Qb[(w*16+lr)*132 + mt*32+kg*8]);
#pragma unroll
    for (int ni=0;ni<8;ni++){
      bf16x8 bs = ldfrag(&SvL[(ni*16+lr)*132 + mt*32+kg*8]);
      oac[ni]=__builtin_amdgcn_mfma_f32_16x16x32_bf16(aa,bs,oac[ni],0,0,0);
    }
  }
#pragma unroll
  for (int ni=0;ni<8;ni++)
#pragma unroll
    for (int vv2=0;vv2<4;vv2++)
      o[(size_t)(c*64+w*16+kg*4+vv2)*2048 + h*128 + ni*16+lr] = oac[ni][vv2];
}

// ---------------- gated RMSNorm -> bf16 ----------------
__global__ __launch_bounds__(256)
void norm_k(const float* __restrict__ o, const float* __restrict__ gate,
            const float* __restrict__ bg2, const float* __restrict__ nw,
            u16* __restrict__ Obf){
  int row = blockIdx.x*4 + (threadIdx.x>>6);
  int lane = threadIdx.x & 63;
  int t = row >> 4, h = row & 15;
  size_t base = (size_t)t*2048 + h*128;
  float o0 = o[base+lane], o1 = o[base+64+lane];
  float ss = o0*o0 + o1*o1;
#pragma unroll
  for (int off=1;off<64;off<<=1) ss += __shfl_xor(ss, off);
  float r = rsqrtf(ss*(1.f/128.f) + 1e-5f);
  int hv0 = h*128+lane, hv1 = hv0+64;
  float g0 = gate[base+lane]    + bg2[hv0];
  float g1 = gate[base+64+lane] + bg2[hv1];
  float v0 = o0*r*nw[lane]   *(1.f/(1.f+__expf(-g0)));
  float v1 = o1*r*nw[lane+64]*(1.f/(1.f+__expf(-g1)));
  Obf[base+lane]    = f2bf(v0);
  Obf[base+64+lane] = f2bf(v1);
}

extern "C" void kernel_launch(void* const* d_in, const int* in_sizes, int n_in,
                              void* d_out, int out_size, void* d_ws, size_t ws_size,
                              hipStream_t stream){
  (void)in_sizes; (void)n_in; (void)out_size; (void)ws_size;
  const float* hX   = (const float*)d_in[0];
  const float* Wq   = (const float*)d_in[1];
  const float* Wk   = (const float*)d_in[2];
  const float* Wv   = (const float*)d_in[3];
  const float* Ww   = (const float*)d_in[4];
  const float* cq   = (const float*)d_in[5];
  const float* ck   = (const float*)d_in[6];
  const float* cv   = (const float*)d_in[7];
  const float* Wf1  = (const float*)d_in[8];
  const float* Wf2  = (const float*)d_in[9];
  const float* Wb   = (const float*)d_in[10];
  const float* Wg1  = (const float*)d_in[11];
  const float* Wg2  = (const float*)d_in[12];
  const float* bg2  = (const float*)d_in[13];
  const float* nw   = (const float*)d_in[14];
  const float* Wo   = (const float*)d_in[15];
  char* ws = (char*)d_ws;
  u16*   h_bf  = (u16*)  (ws + 0);
  u16*   WcatT = (u16*)  (ws + 4194304);
  u16*   Sk0   = (u16*)  (ws + 4194304);            // reuses WcatT after GEMMs (bf16)
  u16*   Sv0   = (u16*)  (ws + 20971520);
  u16*   WoT   = (u16*)  (ws + 37748736);
  u16*   WfgT  = (u16*)  (ws + 46137344);
  u16*   Wf2T  = (u16*)  (ws + 47185920);
  u16*   Wg2T  = (u16*)  (ws + 47710208);
  u16*   qkvw  = (u16*)  (ws + 48234496);           // bf16 [1024][8192]
  u16*   DSk   = (u16*)  (ws + 48234496);           // bf16, reuses qkvw after conv
  u16*   DSv   = (u16*)  (ws + 56623104);
  float* Pw    = (float*)(ws + 48234496);           // Wo split-K partials (after phaseB)
  u16*   qb    = (u16*)  (ws + 81788928);           // bf16 [1024][2048]
  u16*   kb    = (u16*)  (ws + 90177536);
  u16*   vb    = (u16*)  (ws + 98566144);
  float* wcv   = (float*)(ws + 106954752);
  float* P8    = wcv;                               // split-K partials (before conv)
  float* osc   = wcv;                               // reuses wconv after l2bw
  float* bwb   = (float*)(ws + 115343360);
  u16*   f1g1  = (u16*)  (ws + 123731968);
  float* gpre  = (float*)(ws + 124256256);
  float* gateb = gpre;                              // reuses gpre after cg
  float* cgb   = (float*)(ws + 132644864);
  float* betab = (float*)(ws + 141033472);
  u16*   Obf   = (u16*)  (ws + 141099008);
  float* outp  = (float*)d_out;

  // conversions (fused: 5 big transposes + hX convert in one launch, small transposes in one)
  transp64_k<<<dim3(32,32,6),256,0,stream>>>(Wq, Wk, Wv, Ww, Wo, WcatT, WoT, hX, h_bf);
  transpsm_k<<<1024,256,0,stream>>>(Wf1, Wg1, Wf2, Wg2, WfgT, Wf2T, Wg2T);

  // projections
  gemm4_k<true><<<dim3(64,8),256,0,stream>>>(h_bf, WcatT, qkvw, 2048, 2048, 2048, 8192);
  gemmsk_k<<<dim3(2,8,8),256,0,stream>>>(h_bf, WfgT, P8, 2048, 2048);
  reduce8_k<<<256,256,0,stream>>>(P8, f1g1);
  gemm_k<false,1><<<dim3(16,8),256,0,stream>>>(f1g1, Wf2T, gpre, 128, 256, 128, 2048);
  beta_k<<<1024,256,0,stream>>>(hX, Wb, betab);

  // conv + silu, l2norm*beta, chunk cumsum
  conv_k<<<8192,256,0,stream>>>(qkvw, cq, ck, cv, qb, kb, vb, wcv);
  l2bw_k<<<4096,256,0,stream>>>(wcv, betab, bwb);
  cg_k<<<256,128,0,stream>>>(gpre, cgb);

  // gate GEMM (into gpre buffer, safe after cg)
  gemm_k<false,0><<<dim3(16,8),256,0,stream>>>(f1g1 + 128, Wg2T, gateb, 128, 256, 128, 2048);

  // chunked scan
  phaseA_k<<<256,256,0,stream>>>(kb, vb, bwb, cgb, DSk, DSv);
  phaseB_k<<<2048,256,0,stream>>>(DSk, DSv, cgb, Sk0, Sv0);
  phaseC_k<<<256,256,0,stream>>>(qb, kb, vb, bwb, cgb, Sk0, Sv0, osc);

  // gated RMSNorm + output projection (split-K=2, pipelined)
  norm_k<<<4096,256,0,stream>>>(osc, gateb, bg2, nw, Obf);
  gemm4sk_k<<<dim3(16,8,2),256,0,stream>>>(Obf, WoT, Pw, 1024, 2048, 2048, 2048);
  addout_k<<<2048,256,0,stream>>>(Pw, outp);
}

// Round 9
// 191.840 us; speedup vs baseline: 4.3910x; 1.0350x over previous
//
#include <hip/hip_runtime.h>
#include <hip/hip_bf16.h>
#include <stdint.h>

typedef unsigned short u16;
typedef __attribute__((ext_vector_type(8))) short bf16x8;
typedef __attribute__((ext_vector_type(4))) short bf16x4;
typedef __attribute__((ext_vector_type(4))) float f32x4;

#define DEV static __device__ __forceinline__

DEV u16 f2bf(float f){
  union { float f; unsigned u; } x; x.f = f;
  unsigned r = x.u + 0x7fffu + ((x.u >> 16) & 1u);
  return (u16)(r >> 16);
}

DEV float bf2f(u16 u){
  union { unsigned u; float f; } x; x.u = ((unsigned)u) << 16; return x.f;
}

DEV bf16x8 ldfrag(const u16* p){           // two ds_read_b64 (8B-aligned rows)
  bf16x4 a = *(const bf16x4*)p;
  bf16x4 b = *(const bf16x4*)(p+4);
  bf16x8 r;
  r[0]=a[0]; r[1]=a[1]; r[2]=a[2]; r[3]=a[3];
  r[4]=b[0]; r[5]=b[1]; r[6]=b[2]; r[7]=b[3];
  return r;
}

DEV bf16x4 cvt4(float a, float b, float c, float d){
  bf16x4 r; r[0]=(short)f2bf(a); r[1]=(short)f2bf(b); r[2]=(short)f2bf(c); r[3]=(short)f2bf(d);
  return r;
}

DEV void g2l16(const void* g, void* l){
  __builtin_amdgcn_global_load_lds((const __attribute__((address_space(1))) unsigned int*)g,
                                   (__attribute__((address_space(3))) unsigned int*)l,
                                   16, 0, 0);
}

// ---- fused transposes: z=0..4 big 2048x2048, z=5 hX convert, z=6..9 small mats ----
__global__ __launch_bounds__(256)
void transp64_k(const float* __restrict__ Wq, const float* __restrict__ Wk,
                const float* __restrict__ Wv, const float* __restrict__ Ww,
                const float* __restrict__ Wo, u16* __restrict__ WcatT, u16* __restrict__ WoT,
                const float* __restrict__ hX, u16* __restrict__ h_bf,
                const float* __restrict__ Wf1, const float* __restrict__ Wg1,
                const float* __restrict__ Wf2, const float* __restrict__ Wg2,
                u16* __restrict__ WfgT, u16* __restrict__ Wf2T, u16* __restrict__ Wg2T){
  __shared__ float tile[64*65];
  const int z = blockIdx.z;
  if (z == 5){
    int idx = ((blockIdx.y*32 + blockIdx.x)*256 + threadIdx.x)*8;
    float4 v0 = *(const float4*)&hX[idx];
    float4 v1 = *(const float4*)&hX[idx+4];
    ushort4 o0, o1;
    o0.x=f2bf(v0.x); o0.y=f2bf(v0.y); o0.z=f2bf(v0.z); o0.w=f2bf(v0.w);
    o1.x=f2bf(v1.x); o1.y=f2bf(v1.y); o1.z=f2bf(v1.z); o1.w=f2bf(v1.w);
    *(ushort4*)&h_bf[idx]   = o0;
    *(ushort4*)&h_bf[idx+4] = o1;
    return;
  }
  if (z >= 6){
    int rem = blockIdx.y*32 + blockIdx.x;
    if (rem >= 256) return;
    const float* src; u16* dst; int R, C, cx, cy;
    if (z==6){      src=Wf1; dst=WfgT;                  R=2048; C=128;  cx=rem&3;  cy=rem>>2; }
    else if (z==7){ src=Wg1; dst=WfgT+(size_t)128*2048; R=2048; C=128;  cx=rem&3;  cy=rem>>2; }
    else if (z==8){ src=Wf2; dst=Wf2T;                  R=128;  C=2048; cx=rem>>2; cy=rem&3; }
    else {          src=Wg2; dst=Wg2T;                  R=128;  C=2048; cx=rem>>2; cy=rem&3; }
    const int c0 = cx*32, r0 = cy*32;
    const int x = threadIdx.x & 31, y0 = threadIdx.x >> 5;
#pragma unroll
    for (int j=0;j<4;j++){
      int r = y0 + j*8;
      tile[r*33 + x] = src[(size_t)(r0+r)*C + c0 + x];
    }
    __syncthreads();
#pragma unroll
    for (int j=0;j<4;j++){
      int cc = y0 + j*8;
      dst[(size_t)(c0+cc)*R + r0 + x] = f2bf(tile[x*33 + cc]);
    }
    return;
  }
  const float* src = (z==0)?Wq:((z==1)?Wk:((z==2)?Wv:((z==3)?Ww:Wo)));
  u16* dst = (z<4) ? (WcatT + (size_t)z*4194304) : WoT;
  const int c0 = blockIdx.x*64, r0 = blockIdx.y*64;
#pragma unroll
  for (int p=0;p<4;p++){
    int i = threadIdx.x + p*256;
    int r = i>>4, c4 = (i&15)<<2;
    *(float4*)&tile[r*65 + c4] = *(const float4*)&src[(size_t)(r0+r)*2048 + c0 + c4];
  }
  __syncthreads();
#pragma unroll
  for (int p=0;p<4;p++){
    int i = threadIdx.x + p*256;
    int cc = i>>4, r4 = (i&15)<<2;
    ushort4 o;
    o.x = f2bf(tile[(r4+0)*65 + cc]); o.y = f2bf(tile[(r4+1)*65 + cc]);
    o.z = f2bf(tile[(r4+2)*65 + cc]); o.w = f2bf(tile[(r4+3)*65 + cc]);
    *(ushort4*)&dst[(size_t)(c0+cc)*2048 + r0 + r4] = o;
  }
}

// ---------------- pipelined GEMM: 128x128, BK=64, 4 waves, dbuf + counted vmcnt ----------------
template<bool OBF>
__global__ __launch_bounds__(256)
void gemm4_k(const u16* __restrict__ A, const u16* __restrict__ B, void* __restrict__ Cp,
             int K, int lda, int ldb, int ldc){
  __shared__ u16 As[2][128*64];
  __shared__ u16 Bs[2][128*64];
  const int m0 = blockIdx.y*128, n0 = blockIdx.x*128;
  const int tid = threadIdx.x;
  const int wave = tid>>6, lane = tid&63, lr = lane&15, kg = lane>>4;
  const int wm = wave>>1, wn = wave&1;
  const f32x4 vz = {0.f,0.f,0.f,0.f};
  f32x4 acc[4][4];
#pragma unroll
  for (int a=0;a<4;a++)
#pragma unroll
    for (int b=0;b<4;b++) acc[a][b]=vz;

#define STAGE4(buf, k0) do { \
    _Pragma("unroll") \
    for (int p=0;p<4;p++){ \
      int chunk = tid + p*256, r_ = chunk>>3, ci = chunk&7; \
      g2l16(A + (size_t)(m0+r_)*lda + (k0) + ((ci^(r_&7))<<3), &As[buf][chunk*8]); \
    } \
    _Pragma("unroll") \
    for (int p=0;p<4;p++){ \
      int chunk = tid + p*256, r_ = chunk>>3, ci = chunk&7; \
      g2l16(B + (size_t)(n0+r_)*ldb + (k0) + ((ci^(r_&7))<<3), &Bs[buf][chunk*8]); \
    } \
  } while(0)

  const int nt = K>>6;          // >= 2 required
  STAGE4(0, 0);
  STAGE4(1, 64);
  for (int t=0; t<nt; ++t){
    const int buf = t&1;
    if (t < nt-1) asm volatile("s_waitcnt vmcnt(8)" ::: "memory");
    else          asm volatile("s_waitcnt vmcnt(0)" ::: "memory");
    asm volatile("s_barrier" ::: "memory");
#pragma unroll
    for (int ks=0; ks<2; ++ks){
      bf16x8 af[4], bfv[4];
#pragma unroll
      for (int mi=0;mi<4;mi++){
        int r = wm*64+mi*16+lr;
        af[mi] = *(const bf16x8*)&As[buf][r*64 + (((ks*4+kg)^(r&7))<<3)];
      }
#pragma unroll
      for (int ni=0;ni<4;ni++){
        int r = wn*64+ni*16+lr;
        bfv[ni] = *(const bf16x8*)&Bs[buf][r*64 + (((ks*4+kg)^(r&7))<<3)];
      }
      asm volatile("s_waitcnt lgkmcnt(0)" ::: "memory");
      __builtin_amdgcn_sched_barrier(0);
      __builtin_amdgcn_s_setprio(1);
#pragma unroll
      for (int mi=0;mi<4;mi++)
#pragma unroll
        for (int ni=0;ni<4;ni++)
          acc[mi][ni] = __builtin_amdgcn_mfma_f32_16x16x32_bf16(af[mi], bfv[ni], acc[mi][ni], 0, 0, 0);
      __builtin_amdgcn_s_setprio(0);
      __builtin_amdgcn_sched_barrier(0);
      asm volatile("s_barrier" ::: "memory");
    }
    if (t+2 < nt) STAGE4(buf, (t+2)<<6);
  }
#undef STAGE4
#pragma unroll
  for (int mi=0;mi<4;mi++)
#pragma unroll
    for (int ni=0;ni<4;ni++)
#pragma unroll
      for (int vv=0;vv<4;vv++){
        int row = m0 + wm*64 + mi*16 + kg*4 + vv;
        int col = n0 + wn*64 + ni*16 + lr;
        if (OBF) ((u16*)Cp)[(size_t)row*ldc + col] = f2bf(acc[mi][ni][vv]);
        else     ((float*)Cp)[(size_t)row*ldc + col] = acc[mi][ni][vv];
      }
}

// ---------------- split-K pipelined GEMM: 128x128, BK=64, 4 waves -> f32 partials ----------------
__global__ __launch_bounds__(256)
void gemm4sk_k(const u16* __restrict__ A, const u16* __restrict__ B, float* __restrict__ P,
               int Khalf, int lda, int ldb, int ldc){
  __shared__ u16 As[2][128*64];
  __shared__ u16 Bs[2][128*64];
  const int m0 = blockIdx.y*128, n0 = blockIdx.x*128;
  const int kbase = blockIdx.z*Khalf;
  const int tid = threadIdx.x;
  const int wave = tid>>6, lane = tid&63, lr = lane&15, kg = lane>>4;
  const int wm = wave>>1, wn = wave&1;
  const f32x4 vz = {0.f,0.f,0.f,0.f};
  f32x4 acc[4][4];
#pragma unroll
  for (int a=0;a<4;a++)
#pragma unroll
    for (int b=0;b<4;b++) acc[a][b]=vz;

#define STAGE4(buf, k0) do { \
    _Pragma("unroll") \
    for (int p=0;p<4;p++){ \
      int chunk = tid + p*256, r_ = chunk>>3, ci = chunk&7; \
      g2l16(A + (size_t)(m0+r_)*lda + (k0) + ((ci^(r_&7))<<3), &As[buf][chunk*8]); \
    } \
    _Pragma("unroll") \
    for (int p=0;p<4;p++){ \
      int chunk = tid + p*256, r_ = chunk>>3, ci = chunk&7; \
      g2l16(B + (size_t)(n0+r_)*ldb + (k0) + ((ci^(r_&7))<<3), &Bs[buf][chunk*8]); \
    } \
  } while(0)

  const int nt = Khalf>>6;      // >= 2 required
  STAGE4(0, kbase);
  STAGE4(1, kbase+64);
  for (int t=0; t<nt; ++t){
    const int buf = t&1;
    if (t < nt-1) asm volatile("s_waitcnt vmcnt(8)" ::: "memory");
    else          asm volatile("s_waitcnt vmcnt(0)" ::: "memory");
    asm volatile("s_barrier" ::: "memory");
#pragma unroll
    for (int ks=0; ks<2; ++ks){
      bf16x8 af[4], bfv[4];
#pragma unroll
      for (int mi=0;mi<4;mi++){
        int r = wm*64+mi*16+lr;
        af[mi] = *(const bf16x8*)&As[buf][r*64 + (((ks*4+kg)^(r&7))<<3)];
      }
#pragma unroll
      for (int ni=0;ni<4;ni++){
        int r = wn*64+ni*16+lr;
        bfv[ni] = *(const bf16x8*)&Bs[buf][r*64 + (((ks*4+kg)^(r&7))<<3)];
      }
      asm volatile("s_waitcnt lgkmcnt(0)" ::: "memory");
      __builtin_amdgcn_sched_barrier(0);
      __builtin_amdgcn_s_setprio(1);
#pragma unroll
      for (int mi=0;mi<4;mi++)
#pragma unroll
        for (int ni=0;ni<4;ni++)
          acc[mi][ni] = __builtin_amdgcn_mfma_f32_16x16x32_bf16(af[mi], bfv[ni], acc[mi][ni], 0, 0, 0);
      __builtin_amdgcn_s_setprio(0);
      __builtin_amdgcn_sched_barrier(0);
      asm volatile("s_barrier" ::: "memory");
    }
    if (t+2 < nt) STAGE4(buf, kbase + ((t+2)<<6));
  }
#undef STAGE4
#pragma unroll
  for (int mi=0;mi<4;mi++)
#pragma unroll
    for (int ni=0;ni<4;ni++)
#pragma unroll
      for (int vv=0;vv<4;vv++){
        int row = m0 + wm*64 + mi*16 + kg*4 + vv;
        int col = n0 + wn*64 + ni*16 + lr;
        P[(size_t)blockIdx.z*2097152 + (size_t)row*ldc + col] = acc[mi][ni][vv];
      }
}

__global__ __launch_bounds__(256)
void addout_k(const float* __restrict__ P, float* __restrict__ out){
  int i = (blockIdx.x*256 + threadIdx.x)*4;
  float4 a = *(const float4*)&P[i];
  float4 b = *(const float4*)&P[2097152 + i];
  float4 s = {a.x+b.x, a.y+b.y, a.z+b.z, a.w+b.w};
  *(float4*)&out[i] = s;
}

// ---- fused dual gate GEMM (128^2, K=128): z=0 -> logsigmoid->gpre, z=1 -> gate ----
__global__ __launch_bounds__(256)
void gemmg_k(const u16* __restrict__ f1g1, const u16* __restrict__ Bf, const u16* __restrict__ Bg,
             float* __restrict__ Cf, float* __restrict__ Cg){
  __shared__ u16 As[128*32];
  __shared__ u16 Bs[128*32];
  const int zz = blockIdx.z;
  const u16* A = f1g1 + zz*128;          // lda = 256
  const u16* B = zz ? Bg : Bf;           // ldb = 128
  float* C = zz ? Cg : Cf;               // ldc = 2048
  const int m0 = blockIdx.y*128, n0 = blockIdx.x*128;
  const int tid = threadIdx.x;
  const int lane = tid & 63, wave = tid >> 6;
  const int wr = wave >> 1, wc = wave & 1;
  const int lr = lane & 15, kg = lane >> 4;
  const f32x4 vzero = {0.f,0.f,0.f,0.f};
  f32x4 acc[4][4];
#pragma unroll
  for (int a=0;a<4;a++)
#pragma unroll
    for (int b=0;b<4;b++) acc[a][b] = vzero;
  const int r0 = tid>>2, s0 = tid&3;
  for (int k0=0;k0<128;k0+=32){
    __syncthreads();
    g2l16(A + (size_t)(m0+r0)*256 + k0 + s0*8, (u16*)As + (size_t)tid*8);
    g2l16(B + (size_t)(n0+r0)*128 + k0 + s0*8, (u16*)Bs + (size_t)tid*8);
    g2l16(A + (size_t)(m0+r0+64)*256 + k0 + s0*8, (u16*)As + (size_t)(tid+256)*8);
    g2l16(B + (size_t)(n0+r0+64)*128 + k0 + s0*8, (u16*)Bs + (size_t)(tid+256)*8);
    __syncthreads();
    bf16x8 af[4], bfv[4];
#pragma unroll
    for (int mi=0;mi<4;mi++) af[mi]  = *(const bf16x8*)(As + (wr*64+mi*16+lr)*32 + kg*8);
#pragma unroll
    for (int ni=0;ni<4;ni++) bfv[ni] = *(const bf16x8*)(Bs + (wc*64+ni*16+lr)*32 + kg*8);
#pragma unroll
    for (int mi=0;mi<4;mi++)
#pragma unroll
      for (int ni=0;ni<4;ni++)
        acc[mi][ni] = __builtin_amdgcn_mfma_f32_16x16x32_bf16(af[mi], bfv[ni], acc[mi][ni], 0, 0, 0);
  }
#pragma unroll
  for (int mi=0;mi<4;mi++)
#pragma unroll
    for (int ni=0;ni<4;ni++)
#pragma unroll
      for (int vv=0;vv<4;vv++){
        int row = m0 + wr*64 + mi*16 + kg*4 + vv;
        int col = n0 + wc*64 + ni*16 + lr;
        float val = acc[mi][ni][vv];
        if (zz==0) val = fminf(val,0.f) - __logf(1.f + __expf(-fabsf(val)));
        C[(size_t)row*2048 + col] = val;
      }
}

// ---------------- split-K GEMM for f1g1 (N=256, K=2048 in 16 chunks) ----------------
__global__ __launch_bounds__(256)
void gemmsk_k(const u16* __restrict__ A, const u16* __restrict__ B, float* __restrict__ P,
              int lda, int ldb){
  __shared__ u16 As[128*32];
  __shared__ u16 Bs[128*32];
  const int m0 = blockIdx.y*128, n0 = blockIdx.x*128;
  const int kbase = blockIdx.z*128;
  const int tid = threadIdx.x;
  const int lane = tid & 63, wave = tid >> 6;
  const int wr = wave >> 1, wc = wave & 1;
  const int lr = lane & 15, kg = lane >> 4;
  const f32x4 vzero = {0.f,0.f,0.f,0.f};
  f32x4 acc[4][4];
#pragma unroll
  for (int a=0;a<4;a++)
#pragma unroll
    for (int b=0;b<4;b++) acc[a][b] = vzero;
  const int r0 = tid>>2, s0 = tid&3;
  for (int k0=kbase;k0<kbase+128;k0+=32){
    __syncthreads();
    g2l16(A + (size_t)(m0+r0)*lda + k0 + s0*8, (u16*)As + (size_t)tid*8);
    g2l16(B + (size_t)(n0+r0)*ldb + k0 + s0*8, (u16*)Bs + (size_t)tid*8);
    g2l16(A + (size_t)(m0+r0+64)*lda + k0 + s0*8, (u16*)As + (size_t)(tid+256)*8);
    g2l16(B + (size_t)(n0+r0+64)*ldb + k0 + s0*8, (u16*)Bs + (size_t)(tid+256)*8);
    __syncthreads();
    bf16x8 af[4], bfv[4];
#pragma unroll
    for (int mi=0;mi<4;mi++) af[mi]  = *(const bf16x8*)(As + (wr*64+mi*16+lr)*32 + kg*8);
#pragma unroll
    for (int ni=0;ni<4;ni++) bfv[ni] = *(const bf16x8*)(Bs + (wc*64+ni*16+lr)*32 + kg*8);
#pragma unroll
    for (int mi=0;mi<4;mi++)
#pragma unroll
      for (int ni=0;ni<4;ni++)
        acc[mi][ni] = __builtin_amdgcn_mfma_f32_16x16x32_bf16(af[mi], bfv[ni], acc[mi][ni], 0, 0, 0);
  }
#pragma unroll
  for (int mi=0;mi<4;mi++)
#pragma unroll
    for (int ni=0;ni<4;ni++)
#pragma unroll
      for (int vv=0;vv<4;vv++){
        int row = m0 + wr*64 + mi*16 + kg*4 + vv;
        int col = n0 + wc*64 + ni*16 + lr;
        P[(size_t)blockIdx.z*262144 + (size_t)row*256 + col] = acc[mi][ni][vv];
      }
}

__global__ __launch_bounds__(256)
void reduce16_k(const float* __restrict__ P, u16* __restrict__ out){
  int i = (blockIdx.x*256 + threadIdx.x)*4;
  float4 s = *(const float4*)&P[i];
#pragma unroll
  for (int z=1;z<16;z++){
    float4 p = *(const float4*)&P[(size_t)z*262144 + i];
    s.x+=p.x; s.y+=p.y; s.z+=p.z; s.w+=p.w;
  }
  ushort4 o; o.x=f2bf(s.x); o.y=f2bf(s.y); o.z=f2bf(s.z); o.w=f2bf(s.w);
  *(ushort4*)&out[i] = o;
}

// ---------------- beta = sigmoid(h @ Wb), per-t block ----------------
__global__ __launch_bounds__(256)
void beta_k(const float* __restrict__ h, const float* __restrict__ Wb, float* __restrict__ betab){
  __shared__ float hrow[2048];
  __shared__ float red[16][5];
  const int t = blockIdx.x, tid = threadIdx.x;
#pragma unroll
  for (int j=0;j<8;j++) hrow[tid + j*256] = h[(size_t)t*2048 + tid + j*256];
  __syncthreads();
  float part[16];
#pragma unroll
  for (int n=0;n<16;n++) part[n]=0.f;
  for (int j=0;j<8;j++){
    int kk = tid + j*256;
    float hv = hrow[kk];
    const float4* wr4 = (const float4*)&Wb[(size_t)kk*16];
    float4 w0=wr4[0], w1=wr4[1], w2=wr4[2], w3=wr4[3];
    part[0]+=hv*w0.x; part[1]+=hv*w0.y; part[2]+=hv*w0.z; part[3]+=hv*w0.w;
    part[4]+=hv*w1.x; part[5]+=hv*w1.y; part[6]+=hv*w1.z; part[7]+=hv*w1.w;
    part[8]+=hv*w2.x; part[9]+=hv*w2.y; part[10]+=hv*w2.z; part[11]+=hv*w2.w;
    part[12]+=hv*w3.x; part[13]+=hv*w3.y; part[14]+=hv*w3.z; part[15]+=hv*w3.w;
  }
#pragma unroll
  for (int n=0;n<16;n++){
    float s = part[n];
#pragma unroll
    for (int off=1;off<64;off<<=1) s += __shfl_xor(s, off);
    if ((tid&63)==0) red[n][tid>>6] = s;
  }
  __syncthreads();
  if (tid < 16){
    float s = red[tid][0]+red[tid][1]+red[tid][2]+red[tid][3];
    betab[t*16+tid] = 1.f/(1.f+__expf(-s));
  }
}

// ---- causal conv4 + silu: q,k,v -> bf16 ; w-branch -> fused l2norm*beta -> bwb f32 ----
__global__ __launch_bounds__(256)
void conv_k(const u16* __restrict__ raw, const float* __restrict__ cq,
            const float* __restrict__ ck, const float* __restrict__ cv,
            const float* __restrict__ betab,
            u16* __restrict__ qo, u16* __restrict__ ko,
            u16* __restrict__ vo, float* __restrict__ bwout){
  __shared__ float red[2][2][4];
  int idx = blockIdx.x*256 + threadIdx.x;
  int cgl = idx & 8191, tb = idx >> 13;
  int which = cgl >> 11, cc = cgl & 2047;
  const float* wt = (which==0)?cq:((which==1)?ck:cv);   // w-branch (3) uses cv (faithful to ref)
  float4 w4 = *(const float4*)&wt[cc*4];
  int t0 = tb*4;
  float x[7];
#pragma unroll
  for (int j=0;j<7;j++){
    int t = t0 - 3 + j;
    x[j] = (t >= 0) ? bf2f(raw[(size_t)t*8192 + cgl]) : 0.f;
  }
  float y[4];
#pragma unroll
  for (int j=0;j<4;j++){
    float yy = x[j]*w4.x + x[j+1]*w4.y + x[j+2]*w4.z + x[j+3]*w4.w;
    y[j] = yy / (1.f + __expf(-yy));      // silu
  }
  if (which < 3){
    u16* outb = (which==0)?qo:((which==1)?ko:vo);
#pragma unroll
    for (int j=0;j<4;j++)
      outb[(size_t)(t0+j)*2048 + cc] = f2bf(y[j]);
  } else {
    // fused l2norm over m (128 threads = 2 waves per head) * beta
    const int hh = threadIdx.x >> 7;        // which head-half of block
    const int wh = (threadIdx.x >> 6) & 1;  // wave-half within head group
    float ss[4];
#pragma unroll
    for (int j=0;j<4;j++){
      float s = y[j]*y[j];
#pragma unroll
      for (int off=1;off<64;off<<=1) s += __shfl_xor(s, off);
      ss[j] = s;
    }
    if ((threadIdx.x & 63) == 0){
#pragma unroll
      for (int j=0;j<4;j++) red[hh][wh][j] = ss[j];
    }
    __syncthreads();
    const int h = cc >> 7;
#pragma unroll
    for (int j=0;j<4;j++){
      float tot = red[hh][0][j] + red[hh][1][j];
      float r = rsqrtf(tot + 1e-6f) * betab[(t0+j)*16 + h];
      bwout[(size_t)(t0+j)*2048 + cc] = y[j]*r;
    }
  }
}

// ---------------- per-chunk inclusive cumsum (gpre already = logsigmoid) ----------------
__global__ __launch_bounds__(128)
void cg_k(const float* __restrict__ gpre, float* __restrict__ cg){
  int idx = blockIdx.x*128 + threadIdx.x;   // 32768 = c*2048 + h*128 + m
  int c = idx >> 11;
  size_t base = (size_t)(idx & 2047);
  float run = 0.f;
  for (int i2=0;i2<64;i2++){
    size_t t = (size_t)c*64 + i2;
    run += gpre[t*2048 + base];
    cg[t*2048 + base] = run;
  }
}

// ---------------- Phase A (MFMA): DSkT[m][d] = U^T K ; DSvT[v][m] = V^T U (bf16 out) ----------------
__global__ __launch_bounds__(256)
void phaseA_k(const u16* __restrict__ k, const u16* __restrict__ v,
              const float* __restrict__ bw, const float* __restrict__ cg,
              u16* __restrict__ DSkT, u16* __restrict__ DSvT){
  __shared__ u16 UT[128*68];
  __shared__ u16 KT[128*68];
  __shared__ u16 VT[128*68];
  __shared__ float Gt[128];
  const int bx=blockIdx.x, h=bx&15, c=bx>>4, tid=threadIdx.x;
  const int w=tid>>6, lane=tid&63, lr=lane&15, kg=lane>>4;
  if (tid<128) Gt[tid] = cg[(size_t)(c*64+63)*2048 + h*128 + tid];
  __syncthreads();
#pragma unroll
  for (int j=0;j<8;j++){
    int f4=tid+j*256, r=f4>>5, c4=(f4&31)<<2;
    size_t g=(size_t)(c*64+r)*2048 + h*128 + c4;
    ushort4 kv=*(const ushort4*)&k[g];
    ushort4 vv=*(const ushort4*)&v[g];
    float4 bv=*(const float4*)&bw[g];
    float4 cv=*(const float4*)&cg[g];
    float u0=bv.x*__expf(Gt[c4+0]-cv.x);
    float u1=bv.y*__expf(Gt[c4+1]-cv.y);
    float u2=bv.z*__expf(Gt[c4+2]-cv.z);
    float u3=bv.w*__expf(Gt[c4+3]-cv.w);
    KT[(c4+0)*68+r]=kv.x; KT[(c4+1)*68+r]=kv.y;
    KT[(c4+2)*68+r]=kv.z; KT[(c4+3)*68+r]=kv.w;
    VT[(c4+0)*68+r]=vv.x; VT[(c4+1)*68+r]=vv.y;
    VT[(c4+2)*68+r]=vv.z; VT[(c4+3)*68+r]=vv.w;
    UT[(c4+0)*68+r]=f2bf(u0);   UT[(c4+1)*68+r]=f2bf(u1);
    UT[(c4+2)*68+r]=f2bf(u2);   UT[(c4+3)*68+r]=f2bf(u3);
  }
  __syncthreads();
  const f32x4 vz = {0.f,0.f,0.f,0.f};
  {
    f32x4 acc[2][8];
#pragma unroll
    for (int a=0;a<2;a++)
#pragma unroll
      for (int b=0;b<8;b++) acc[a][b]=vz;
#pragma unroll
    for (int ks=0;ks<2;ks++){
      bf16x8 a0=ldfrag(&UT[(w*32   +lr)*68 + ks*32+kg*8]);
      bf16x8 a1=ldfrag(&UT[(w*32+16+lr)*68 + ks*32+kg*8]);
#pragma unroll
      for (int nj=0;nj<8;nj++){
        bf16x8 b=ldfrag(&KT[(nj*16+lr)*68 + ks*32+kg*8]);
        acc[0][nj]=__builtin_amdgcn_mfma_f32_16x16x32_bf16(a0,b,acc[0][nj],0,0,0);
        acc[1][nj]=__builtin_amdgcn_mfma_f32_16x16x32_bf16(a1,b,acc[1][nj],0,0,0);
      }
    }
#pragma unroll
    for (int mi2=0;mi2<2;mi2++)
#pragma unroll
      for (int nj=0;nj<8;nj++)
#pragma unroll
        for (int vv2=0;vv2<4;vv2++)
          DSkT[(size_t)bx*16384 + (size_t)(w*32+mi2*16+kg*4+vv2)*128 + nj*16+lr] = f2bf(acc[mi2][nj][vv2]);
  }
  {
    f32x4 acc[2][8];
#pragma unroll
    for (int a=0;a<2;a++)
#pragma unroll
      for (int b=0;b<8;b++) acc[a][b]=vz;
#pragma unroll
    for (int ks=0;ks<2;ks++){
      bf16x8 a0=ldfrag(&VT[(w*32   +lr)*68 + ks*32+kg*8]);
      bf16x8 a1=ldfrag(&VT[(w*32+16+lr)*68 + ks*32+kg*8]);
#pragma unroll
      for (int nj=0;nj<8;nj++){
        bf16x8 b=ldfrag(&UT[(nj*16+lr)*68 + ks*32+kg*8]);
        acc[0][nj]=__builtin_amdgcn_mfma_f32_16x16x32_bf16(a0,b,acc[0][nj],0,0,0);
        acc[1][nj]=__builtin_amdgcn_mfma_f32_16x16x32_bf16(a1,b,acc[1][nj],0,0,0);
      }
    }
#pragma unroll
    for (int mi2=0;mi2<2;mi2++)
#pragma unroll
      for (int nj=0;nj<8;nj++)
#pragma unroll
        for (int vv2=0;vv2<4;vv2++)
          DSvT[(size_t)bx*16384 + (size_t)(w*32+mi2*16+kg*4+vv2)*128 + nj*16+lr] = f2bf(acc[mi2][nj][vv2]);
  }
}

// ---------------- Phase B: sequential cross-chunk combine (bf16 in/out) ----------------
__global__ __launch_bounds__(256)
void phaseB_k(const u16* __restrict__ DSk, const u16* __restrict__ DSv,
              const float* __restrict__ cg, u16* __restrict__ Sk0, u16* __restrict__ Sv0){
  unsigned idx = blockIdx.x*256u + threadIdx.x;   // 524288 total
  int sel  = idx >> 18;
  int h    = (idx >> 14) & 15;
  int flat = idx & 16383;                 // SkT: m*128+d ; SvT: v*128+m
  int mdec = sel ? (flat & 127) : (flat >> 7);
  const u16* DS = sel ? DSv : DSk;
  u16* S = sel ? Sv0 : Sk0;
  float cur = 0.f;
  for (int c=0;c<16;c++){
    size_t sb = ((size_t)(c*16+h))*16384 + flat;
    S[sb] = f2bf(cur);                     // state BEFORE chunk c
    float gd = __expf(cg[(size_t)(c*64+63)*2048 + h*128 + mdec]);
    cur = cur*gd + bf2f(DS[sb]);
  }
}

// ---------------- Phase C (MFMA): per-chunk outputs ----------------
__global__ __launch_bounds__(256)
void phaseC_k(const u16* __restrict__ q, const u16* __restrict__ k,
              const u16* __restrict__ v, const float* __restrict__ bw,
              const float* __restrict__ cg, const u16* __restrict__ SkT,
              const u16* __restrict__ SvT, float* __restrict__ o){
  __shared__ u16 Qb[64*132];     // Q, then A' (wave-private rows after prep)
  __shared__ u16 KV[8704];       // K[64][132], then VT[128][68]
  __shared__ u16 Bws[64*132];    // bw*e^{cgm-cg} natural [s][m]
  __shared__ u16 BwT[128*68];    // transposed [m][s]
  __shared__ u16 Ssb[64*68];     // sqk, then P (wave-private rows)
  __shared__ u16 SkL[128*132];   // Sk'^T * e^{cgm[m]}  [m][d]
  __shared__ u16 SvL[128*132];   // Sv'^T * e^{cgm[m]}  [v][m]
  __shared__ float cgm[128];
  __shared__ float ecgm[128];
  const int bx=blockIdx.x, h=bx&15, c=bx>>4, tid=threadIdx.x;
  const int w=tid>>6, lane=tid&63, lr=lane&15, kg=lane>>4;
  const float SCALE = 0.088388347648318447f;   // 128^-0.5
  const f32x4 vz = {0.f,0.f,0.f,0.f};
  if (tid<128){ float t=cg[(size_t)(c*64+31)*2048 + h*128 + tid]; cgm[tid]=t; ecgm[tid]=__expf(t); }
  __syncthreads();
#pragma unroll
  for (int j=0;j<8;j++){
    int f4=tid+j*256, r=f4>>5, c4=(f4&31)<<2;
    size_t g=(size_t)(c*64+r)*2048 + h*128 + c4;
    *(ushort4*)&Qb[r*132+c4] = *(const ushort4*)&q[g];
    *(ushort4*)&KV[r*132+c4] = *(const ushort4*)&k[g];
    float4 bv=*(const float4*)&bw[g];
    float4 cv=*(const float4*)&cg[g];
    float b0=bv.x*__expf(cgm[c4+0]-cv.x);
    float b1=bv.y*__expf(cgm[c4+1]-cv.y);
    float b2=bv.z*__expf(cgm[c4+2]-cv.z);
    float b3=bv.w*__expf(cgm[c4+3]-cv.w);
    bf16x4 bb = cvt4(b0,b1,b2,b3);
    *(bf16x4*)&Bws[r*132+c4] = bb;
    BwT[(c4+0)*68+r]=(u16)bb[0]; BwT[(c4+1)*68+r]=(u16)bb[1];
    BwT[(c4+2)*68+r]=(u16)bb[2]; BwT[(c4+3)*68+r]=(u16)bb[3];
  }
  __syncthreads();
  {
    f32x4 acc1[4];
#pragma unroll
    for (int a=0;a<4;a++) acc1[a]=vz;
#pragma unroll
    for (int ks=0;ks<4;ks++){
      bf16x8 aq = ldfrag(&Qb[(w*16+lr)*132 + ks*32+kg*8]);
#pragma unroll
      for (int ni=0;ni<4;ni++){
        bf16x8 bk = ldfrag(&KV[(ni*16+lr)*132 + ks*32+kg*8]);
        acc1[ni]=__builtin_amdgcn_mfma_f32_16x16x32_bf16(aq,bk,acc1[ni],0,0,0);
      }
    }
#pragma unroll
    for (int ni=0;ni<4;ni++)
#pragma unroll
      for (int vv2=0;vv2<4;vv2++){
        int row=w*16+kg*4+vv2, col=ni*16+lr;
        Ssb[row*68+col] = (col<=row) ? f2bf(acc1[ni][vv2]) : (u16)0;
      }
  }
  __syncthreads();   // all K reads done -> KV reusable for VT
#pragma unroll
  for (int j=0;j<8;j++){
    int f4=tid+j*256, r=f4>>5, c4=(f4&31)<<2;
    ushort4 vv=*(const ushort4*)&v[(size_t)(c*64+r)*2048 + h*128 + c4];
    KV[(c4+0)*68+r]=vv.x; KV[(c4+1)*68+r]=vv.y;
    KV[(c4+2)*68+r]=vv.z; KV[(c4+3)*68+r]=vv.w;
  }
#pragma unroll
  for (int j=0;j<16;j++){
    int f4=tid+j*256, r=f4>>5, c4=(f4&31)<<2;
    ushort4 s4=*(const ushort4*)&SkT[(size_t)bx*16384 + (size_t)r*128 + c4];
    float em=ecgm[r];
    *(bf16x4*)&SkL[r*132+c4]=cvt4(bf2f(s4.x)*em, bf2f(s4.y)*em, bf2f(s4.z)*em, bf2f(s4.w)*em);
  }
#pragma unroll
  for (int j=0;j<16;j++){
    int f4=tid+j*256, r=f4>>5, c4=(f4&31)<<2;
    ushort4 s4=*(const ushort4*)&SvT[(size_t)bx*16384 + (size_t)r*128 + c4];
    *(bf16x4*)&SvL[r*132+c4]=cvt4(bf2f(s4.x)*ecgm[c4+0], bf2f(s4.y)*ecgm[c4+1],
                                  bf2f(s4.z)*ecgm[c4+2], bf2f(s4.w)*ecgm[c4+3]);
  }
  f32x4 zac[8];
#pragma unroll
  for (int a=0;a<8;a++) zac[a]=vz;
#pragma unroll
  for (int ks=0;ks<2;ks++){
    bf16x8 as_ = ldfrag(&Ssb[(w*16+lr)*68 + ks*32+kg*8]);
#pragma unroll
    for (int ni=0;ni<8;ni++){
      bf16x8 bb = ldfrag(&BwT[(ni*16+lr)*68 + ks*32+kg*8]);
      zac[ni]=__builtin_amdgcn_mfma_f32_16x16x32_bf16(as_,bb,zac[ni],0,0,0);
    }
  }
  __syncthreads();   // SkL/SvL/VT staged & visible
#pragma unroll
  for (int dt=0;dt<4;dt++){
    bf16x8 aq = ldfrag(&Qb[(w*16+lr)*132 + dt*32+kg*8]);
#pragma unroll
    for (int ni=0;ni<8;ni++){
      bf16x8 bs = ldfrag(&SkL[(ni*16+lr)*132 + dt*32+kg*8]);
      zac[ni]=__builtin_amdgcn_mfma_f32_16x16x32_bf16(aq,bs,zac[ni],0,0,0);
    }
  }
  float dec[4][8], zz[4][8];
#pragma unroll
  for (int vv2=0;vv2<4;vv2++)
#pragma unroll
    for (int ni=0;ni<8;ni++) zz[vv2][ni]=zac[ni][vv2];
#pragma unroll
  for (int vv2=0;vv2<4;vv2++){
    size_t gr=(size_t)(c*64+w*16+kg*4+vv2)*2048 + h*128;
#pragma unroll
    for (int ni=0;ni<8;ni++){
      float cgv = cg[gr + ni*16+lr];
      dec[vv2][ni] = __expf(cgv - cgm[ni*16+lr]);
    }
  }
#pragma unroll
  for (int vv2=0;vv2<4;vv2++){
    float mx=-3.0e38f;
#pragma unroll
    for (int ni=0;ni<8;ni++){ zz[vv2][ni] *= SCALE*dec[vv2][ni]; mx=fmaxf(mx,zz[vv2][ni]); }
    mx=fmaxf(mx,__shfl_xor(mx,1)); mx=fmaxf(mx,__shfl_xor(mx,2));
    mx=fmaxf(mx,__shfl_xor(mx,4)); mx=fmaxf(mx,__shfl_xor(mx,8));
    float sum=0.f;
#pragma unroll
    for (int ni=0;ni<8;ni++){ zz[vv2][ni]=__expf(zz[vv2][ni]-mx); sum+=zz[vv2][ni]; }
    sum+=__shfl_xor(sum,1); sum+=__shfl_xor(sum,2);
    sum+=__shfl_xor(sum,4); sum+=__shfl_xor(sum,8);
    float inv=1.f/sum;
#pragma unroll
    for (int ni=0;ni<8;ni++) zz[vv2][ni] *= inv*dec[vv2][ni];   // A' = a * e^{cg-cgm}
  }
#pragma unroll
  for (int vv2=0;vv2<4;vv2++)
#pragma unroll
    for (int ni=0;ni<8;ni++)
      Qb[(w*16+kg*4+vv2)*132 + ni*16+lr] = f2bf(zz[vv2][ni]);
  {
    f32x4 acc4[4];
#pragma unroll
    for (int a=0;a<4;a++) acc4[a]=vz;
#pragma unroll
    for (int ks=0;ks<4;ks++){
      bf16x8 aa = ldfrag(&Qb[(w*16+lr)*132 + ks*32+kg*8]);
#pragma unroll
      for (int ni=0;ni<4;ni++){
        bf16x8 bb = ldfrag(&Bws[(ni*16+lr)*132 + ks*32+kg*8]);
        acc4[ni]=__builtin_amdgcn_mfma_f32_16x16x32_bf16(aa,bb,acc4[ni],0,0,0);
      }
    }
#pragma unroll
    for (int ni=0;ni<4;ni++)
#pragma unroll
      for (int vv2=0;vv2<4;vv2++){
        int row=w*16+kg*4+vv2, col=ni*16+lr;
        Ssb[row*68+col] = (col<=row) ? f2bf(acc4[ni][vv2]) : (u16)0;
      }
  }
  f32x4 oac[8];
#pragma unroll
  for (int a=0;a<8;a++) oac[a]=vz;
#pragma unroll
  for (int ks=0;ks<2;ks++){
    bf16x8 ap = ldfrag(&Ssb[(w*16+lr)*68 + ks*32+kg*8]);
#pragma unroll
    for (int ni=0;ni<8;ni++){
      bf16x8 bv2 = ldfrag(&KV[(ni*16+lr)*68 + ks*32+kg*8]);
      oac[ni]=__builtin_amdgcn_mfma_f32_16x16x32_bf16(ap,bv2,oac[ni],0,0,0);
    }
  }
#pragma unroll
  for (int mt=0;mt<4;mt++){
    bf16x8 aa = ldfrag(&Qb[(w*16+lr)*132 + mt*32+kg*8]);
#pragma unroll
    for (int ni=0;ni<8;ni++){
      bf16x8 bs = ldfrag(&SvL[(ni*16+lr)*132 + mt*32+kg*8]);
      oac[ni]=__builtin_amdgcn_mfma_f32_16x16x32_bf16(aa,bs,oac[ni],0,0,0);
    }
  }
#pragma unroll
  for (int ni=0;ni<8;ni++)
#pragma unroll
    for (int vv2=0;vv2<4;vv2++)
      o[(size_t)(c*64+w*16+kg*4+vv2)*2048 + h*128 + ni*16+lr] = oac[ni][vv2];
}

// ---------------- gated RMSNorm -> bf16 ----------------
__global__ __launch_bounds__(256)
void norm_k(const float* __restrict__ o, const float* __restrict__ gate,
            const float* __restrict__ bg2, const float* __restrict__ nw,
            u16* __restrict__ Obf){
  int row = blockIdx.x*4 + (threadIdx.x>>6);
  int lane = threadIdx.x & 63;
  int t = row >> 4, h = row & 15;
  size_t base = (size_t)t*2048 + h*128;
  float o0 = o[base+lane], o1 = o[base+64+lane];
  float ss = o0*o0 + o1*o1;
#pragma unroll
  for (int off=1;off<64;off<<=1) ss += __shfl_xor(ss, off);
  float r = rsqrtf(ss*(1.f/128.f) + 1e-5f);
  int hv0 = h*128+lane, hv1 = hv0+64;
  float g0 = gate[base+lane]    + bg2[hv0];
  float g1 = gate[base+64+lane] + bg2[hv1];
  float v0 = o0*r*nw[lane]   *(1.f/(1.f+__expf(-g0)));
  float v1 = o1*r*nw[lane+64]*(1.f/(1.f+__expf(-g1)));
  Obf[base+lane]    = f2bf(v0);
  Obf[base+64+lane] = f2bf(v1);
}

extern "C" void kernel_launch(void* const* d_in, const int* in_sizes, int n_in,
                              void* d_out, int out_size, void* d_ws, size_t ws_size,
                              hipStream_t stream){
  (void)in_sizes; (void)n_in; (void)out_size; (void)ws_size;
  const float* hX   = (const float*)d_in[0];
  const float* Wq   = (const float*)d_in[1];
  const float* Wk   = (const float*)d_in[2];
  const float* Wv   = (const float*)d_in[3];
  const float* Ww   = (const float*)d_in[4];
  const float* cq   = (const float*)d_in[5];
  const float* ck   = (const float*)d_in[6];
  const float* cv   = (const float*)d_in[7];
  const float* Wf1  = (const float*)d_in[8];
  const float* Wf2  = (const float*)d_in[9];
  const float* Wb   = (const float*)d_in[10];
  const float* Wg1  = (const float*)d_in[11];
  const float* Wg2  = (const float*)d_in[12];
  const float* bg2  = (const float*)d_in[13];
  const float* nw   = (const float*)d_in[14];
  const float* Wo   = (const float*)d_in[15];
  char* ws = (char*)d_ws;
  u16*   h_bf  = (u16*)  (ws + 0);
  u16*   WcatT = (u16*)  (ws + 4194304);
  u16*   Sk0   = (u16*)  (ws + 4194304);            // reuses WcatT after GEMMs (bf16)
  u16*   Sv0   = (u16*)  (ws + 20971520);
  u16*   WoT   = (u16*)  (ws + 37748736);
  u16*   WfgT  = (u16*)  (ws + 46137344);
  u16*   Wf2T  = (u16*)  (ws + 47185920);
  u16*   Wg2T  = (u16*)  (ws + 47710208);
  u16*   qkvw  = (u16*)  (ws + 48234496);           // bf16 [1024][8192] -> ends 65011712
  u16*   DSk   = (u16*)  (ws + 48234496);           // bf16, reuses qkvw after conv
  u16*   DSv   = (u16*)  (ws + 56623104);
  float* Pw    = (float*)(ws + 48234496);           // Wo split-K partials (after phaseB)
  float* gateb = (float*)(ws + 65011712);           // f32 [1024][2048] (free region)
  u16*   qb    = (u16*)  (ws + 81788928);           // bf16 [1024][2048]
  u16*   kb    = (u16*)  (ws + 90177536);
  u16*   vb    = (u16*)  (ws + 98566144);
  float* P8    = (float*)(ws + 106954752);          // f1g1 split-K partials (16 x 1MB)
  float* osc   = (float*)(ws + 106954752);          // phaseC out (after P8 dead)
  float* bwb   = (float*)(ws + 115343360);          // conv-fused l2bw out (after P8 dead)
  u16*   f1g1  = (u16*)  (ws + 123731968);
  float* gpre  = (float*)(ws + 124256256);
  float* cgb   = (float*)(ws + 132644864);
  float* betab = (float*)(ws + 141033472);
  u16*   Obf   = (u16*)  (ws + 141099008);
  float* outp  = (float*)d_out;

  // conversions: all transposes + hX convert in ONE launch
  transp64_k<<<dim3(32,32,10),256,0,stream>>>(Wq, Wk, Wv, Ww, Wo, WcatT, WoT, hX, h_bf,
                                              Wf1, Wg1, Wf2, Wg2, WfgT, Wf2T, Wg2T);

  // projections
  gemm4_k<true><<<dim3(64,8),256,0,stream>>>(h_bf, WcatT, qkvw, 2048, 2048, 2048, 8192);
  gemmsk_k<<<dim3(2,8,16),256,0,stream>>>(h_bf, WfgT, P8, 2048, 2048);
  reduce16_k<<<256,256,0,stream>>>(P8, f1g1);
  gemmg_k<<<dim3(16,8,2),256,0,stream>>>(f1g1, Wf2T, Wg2T, gpre, gateb);
  beta_k<<<1024,256,0,stream>>>(hX, Wb, betab);

  // conv + silu (+fused l2norm*beta on w-branch), chunk cumsum
  conv_k<<<8192,256,0,stream>>>(qkvw, cq, ck, cv, betab, qb, kb, vb, bwb);
  cg_k<<<256,128,0,stream>>>(gpre, cgb);

  // chunked scan
  phaseA_k<<<256,256,0,stream>>>(kb, vb, bwb, cgb, DSk, DSv);
  phaseB_k<<<2048,256,0,stream>>>(DSk, DSv, cgb, Sk0, Sv0);
  phaseC_k<<<256,256,0,stream>>>(qb, kb, vb, bwb, cgb, Sk0, Sv0, osc);

  // gated RMSNorm + output projection (split-K=2, pipelined)
  norm_k<<<4096,256,0,stream>>>(osc, gateb, bg2, nw, Obf);
  gemm4sk_k<<<dim3(16,8,2),256,0,stream>>>(Obf, WoT, Pw, 1024, 2048, 2048, 2048);
  addout_k<<<2048,256,0,stream>>>(Pw, outp);
}

// Round 10
// 180.804 us; speedup vs baseline: 4.6590x; 1.0610x over previous
//
#include <hip/hip_runtime.h>
#include <hip/hip_bf16.h>
#include <stdint.h>

typedef unsigned short u16;
typedef __attribute__((ext_vector_type(8))) short bf16x8;
typedef __attribute__((ext_vector_type(4))) short bf16x4;
typedef __attribute__((ext_vector_type(4))) float f32x4;

#define DEV static __device__ __forceinline__

DEV u16 f2bf(float f){
  union { float f; unsigned u; } x; x.f = f;
  unsigned r = x.u + 0x7fffu + ((x.u >> 16) & 1u);
  return (u16)(r >> 16);
}

DEV float bf2f(u16 u){
  union { unsigned u; float f; } x; x.u = ((unsigned)u) << 16; return x.f;
}

DEV bf16x8 ldfrag(const u16* p){           // two ds_read_b64 (8B-aligned rows)
  bf16x4 a = *(const bf16x4*)p;
  bf16x4 b = *(const bf16x4*)(p+4);
  bf16x8 r;
  r[0]=a[0]; r[1]=a[1]; r[2]=a[2]; r[3]=a[3];
  r[4]=b[0]; r[5]=b[1]; r[6]=b[2]; r[7]=b[3];
  return r;
}

DEV bf16x4 cvt4(float a, float b, float c, float d){
  bf16x4 r; r[0]=(short)f2bf(a); r[1]=(short)f2bf(b); r[2]=(short)f2bf(c); r[3]=(short)f2bf(d);
  return r;
}

DEV void g2l16(const void* g, void* l){
  __builtin_amdgcn_global_load_lds((const __attribute__((address_space(1))) unsigned int*)g,
                                   (__attribute__((address_space(3))) unsigned int*)l,
                                   16, 0, 0);
}

// ---- fused transposes: z=0..4 big 2048x2048, z=5 hX convert, z=6..9 small mats ----
__global__ __launch_bounds__(256)
void transp64_k(const float* __restrict__ Wq, const float* __restrict__ Wk,
                const float* __restrict__ Wv, const float* __restrict__ Ww,
                const float* __restrict__ Wo, u16* __restrict__ WcatT, u16* __restrict__ WoT,
                const float* __restrict__ hX, u16* __restrict__ h_bf,
                const float* __restrict__ Wf1, const float* __restrict__ Wg1,
                const float* __restrict__ Wf2, const float* __restrict__ Wg2,
                u16* __restrict__ WfgT, u16* __restrict__ Wf2T, u16* __restrict__ Wg2T){
  __shared__ float tile[64*65];
  const int z = blockIdx.z;
  if (z == 5){
    int idx = ((blockIdx.y*32 + blockIdx.x)*256 + threadIdx.x)*8;
    float4 v0 = *(const float4*)&hX[idx];
    float4 v1 = *(const float4*)&hX[idx+4];
    ushort4 o0, o1;
    o0.x=f2bf(v0.x); o0.y=f2bf(v0.y); o0.z=f2bf(v0.z); o0.w=f2bf(v0.w);
    o1.x=f2bf(v1.x); o1.y=f2bf(v1.y); o1.z=f2bf(v1.z); o1.w=f2bf(v1.w);
    *(ushort4*)&h_bf[idx]   = o0;
    *(ushort4*)&h_bf[idx+4] = o1;
    return;
  }
  if (z >= 6){
    int rem = blockIdx.y*32 + blockIdx.x;
    if (rem >= 256) return;
    const float* src; u16* dst; int R, C, cx, cy;
    if (z==6){      src=Wf1; dst=WfgT;                  R=2048; C=128;  cx=rem&3;  cy=rem>>2; }
    else if (z==7){ src=Wg1; dst=WfgT+(size_t)128*2048; R=2048; C=128;  cx=rem&3;  cy=rem>>2; }
    else if (z==8){ src=Wf2; dst=Wf2T;                  R=128;  C=2048; cx=rem>>2; cy=rem&3; }
    else {          src=Wg2; dst=Wg2T;                  R=128;  C=2048; cx=rem>>2; cy=rem&3; }
    const int c0 = cx*32, r0 = cy*32;
    const int x = threadIdx.x & 31, y0 = threadIdx.x >> 5;
#pragma unroll
    for (int j=0;j<4;j++){
      int r = y0 + j*8;
      tile[r*33 + x] = src[(size_t)(r0+r)*C + c0 + x];
    }
    __syncthreads();
#pragma unroll
    for (int j=0;j<4;j++){
      int cc = y0 + j*8;
      dst[(size_t)(c0+cc)*R + r0 + x] = f2bf(tile[x*33 + cc]);
    }
    return;
  }
  const float* src = (z==0)?Wq:((z==1)?Wk:((z==2)?Wv:((z==3)?Ww:Wo)));
  u16* dst = (z<4) ? (WcatT + (size_t)z*4194304) : WoT;
  const int c0 = blockIdx.x*64, r0 = blockIdx.y*64;
#pragma unroll
  for (int p=0;p<4;p++){
    int i = threadIdx.x + p*256;
    int r = i>>4, c4 = (i&15)<<2;
    *(float4*)&tile[r*65 + c4] = *(const float4*)&src[(size_t)(r0+r)*2048 + c0 + c4];
  }
  __syncthreads();
#pragma unroll
  for (int p=0;p<4;p++){
    int i = threadIdx.x + p*256;
    int cc = i>>4, r4 = (i&15)<<2;
    ushort4 o;
    o.x = f2bf(tile[(r4+0)*65 + cc]); o.y = f2bf(tile[(r4+1)*65 + cc]);
    o.z = f2bf(tile[(r4+2)*65 + cc]); o.w = f2bf(tile[(r4+3)*65 + cc]);
    *(ushort4*)&dst[(size_t)(c0+cc)*2048 + r0 + r4] = o;
  }
}

// ---------------- pipelined GEMM: 128x128, BK=64, 4 waves, dbuf + counted vmcnt ----------------
template<bool OBF>
__global__ __launch_bounds__(256)
void gemm4_k(const u16* __restrict__ A, const u16* __restrict__ B, void* __restrict__ Cp,
             int K, int lda, int ldb, int ldc){
  __shared__ u16 As[2][128*64];
  __shared__ u16 Bs[2][128*64];
  const int m0 = blockIdx.y*128, n0 = blockIdx.x*128;
  const int tid = threadIdx.x;
  const int wave = tid>>6, lane = tid&63, lr = lane&15, kg = lane>>4;
  const int wm = wave>>1, wn = wave&1;
  const f32x4 vz = {0.f,0.f,0.f,0.f};
  f32x4 acc[4][4];
#pragma unroll
  for (int a=0;a<4;a++)
#pragma unroll
    for (int b=0;b<4;b++) acc[a][b]=vz;

#define STAGE4(buf, k0) do { \
    _Pragma("unroll") \
    for (int p=0;p<4;p++){ \
      int chunk = tid + p*256, r_ = chunk>>3, ci = chunk&7; \
      g2l16(A + (size_t)(m0+r_)*lda + (k0) + ((ci^(r_&7))<<3), &As[buf][chunk*8]); \
    } \
    _Pragma("unroll") \
    for (int p=0;p<4;p++){ \
      int chunk = tid + p*256, r_ = chunk>>3, ci = chunk&7; \
      g2l16(B + (size_t)(n0+r_)*ldb + (k0) + ((ci^(r_&7))<<3), &Bs[buf][chunk*8]); \
    } \
  } while(0)

  const int nt = K>>6;          // >= 2 required
  STAGE4(0, 0);
  STAGE4(1, 64);
  for (int t=0; t<nt; ++t){
    const int buf = t&1;
    if (t < nt-1) asm volatile("s_waitcnt vmcnt(8)" ::: "memory");
    else          asm volatile("s_waitcnt vmcnt(0)" ::: "memory");
    asm volatile("s_barrier" ::: "memory");
#pragma unroll
    for (int ks=0; ks<2; ++ks){
      bf16x8 af[4], bfv[4];
#pragma unroll
      for (int mi=0;mi<4;mi++){
        int r = wm*64+mi*16+lr;
        af[mi] = *(const bf16x8*)&As[buf][r*64 + (((ks*4+kg)^(r&7))<<3)];
      }
#pragma unroll
      for (int ni=0;ni<4;ni++){
        int r = wn*64+ni*16+lr;
        bfv[ni] = *(const bf16x8*)&Bs[buf][r*64 + (((ks*4+kg)^(r&7))<<3)];
      }
      asm volatile("s_waitcnt lgkmcnt(0)" ::: "memory");
      __builtin_amdgcn_sched_barrier(0);
      __builtin_amdgcn_s_setprio(1);
#pragma unroll
      for (int mi=0;mi<4;mi++)
#pragma unroll
        for (int ni=0;ni<4;ni++)
          acc[mi][ni] = __builtin_amdgcn_mfma_f32_16x16x32_bf16(af[mi], bfv[ni], acc[mi][ni], 0, 0, 0);
      __builtin_amdgcn_s_setprio(0);
      __builtin_amdgcn_sched_barrier(0);
      asm volatile("s_barrier" ::: "memory");
    }
    if (t+2 < nt) STAGE4(buf, (t+2)<<6);
  }
#undef STAGE4
#pragma unroll
  for (int mi=0;mi<4;mi++)
#pragma unroll
    for (int ni=0;ni<4;ni++)
#pragma unroll
      for (int vv=0;vv<4;vv++){
        int row = m0 + wm*64 + mi*16 + kg*4 + vv;
        int col = n0 + wn*64 + ni*16 + lr;
        if (OBF) ((u16*)Cp)[(size_t)row*ldc + col] = f2bf(acc[mi][ni][vv]);
        else     ((float*)Cp)[(size_t)row*ldc + col] = acc[mi][ni][vv];
      }
}

// ---------------- split-K pipelined GEMM: 128x128, BK=64, 4 waves -> f32 partials ----------------
__global__ __launch_bounds__(256)
void gemm4sk_k(const u16* __restrict__ A, const u16* __restrict__ B, float* __restrict__ P,
               int Khalf, int lda, int ldb, int ldc){
  __shared__ u16 As[2][128*64];
  __shared__ u16 Bs[2][128*64];
  const int m0 = blockIdx.y*128, n0 = blockIdx.x*128;
  const int kbase = blockIdx.z*Khalf;
  const int tid = threadIdx.x;
  const int wave = tid>>6, lane = tid&63, lr = lane&15, kg = lane>>4;
  const int wm = wave>>1, wn = wave&1;
  const f32x4 vz = {0.f,0.f,0.f,0.f};
  f32x4 acc[4][4];
#pragma unroll
  for (int a=0;a<4;a++)
#pragma unroll
    for (int b=0;b<4;b++) acc[a][b]=vz;

#define STAGE4(buf, k0) do { \
    _Pragma("unroll") \
    for (int p=0;p<4;p++){ \
      int chunk = tid + p*256, r_ = chunk>>3, ci = chunk&7; \
      g2l16(A + (size_t)(m0+r_)*lda + (k0) + ((ci^(r_&7))<<3), &As[buf][chunk*8]); \
    } \
    _Pragma("unroll") \
    for (int p=0;p<4;p++){ \
      int chunk = tid + p*256, r_ = chunk>>3, ci = chunk&7; \
      g2l16(B + (size_t)(n0+r_)*ldb + (k0) + ((ci^(r_&7))<<3), &Bs[buf][chunk*8]); \
    } \
  } while(0)

  const int nt = Khalf>>6;      // >= 2 required
  STAGE4(0, kbase);
  STAGE4(1, kbase+64);
  for (int t=0; t<nt; ++t){
    const int buf = t&1;
    if (t < nt-1) asm volatile("s_waitcnt vmcnt(8)" ::: "memory");
    else          asm volatile("s_waitcnt vmcnt(0)" ::: "memory");
    asm volatile("s_barrier" ::: "memory");
#pragma unroll
    for (int ks=0; ks<2; ++ks){
      bf16x8 af[4], bfv[4];
#pragma unroll
      for (int mi=0;mi<4;mi++){
        int r = wm*64+mi*16+lr;
        af[mi] = *(const bf16x8*)&As[buf][r*64 + (((ks*4+kg)^(r&7))<<3)];
      }
#pragma unroll
      for (int ni=0;ni<4;ni++){
        int r = wn*64+ni*16+lr;
        bfv[ni] = *(const bf16x8*)&Bs[buf][r*64 + (((ks*4+kg)^(r&7))<<3)];
      }
      asm volatile("s_waitcnt lgkmcnt(0)" ::: "memory");
      __builtin_amdgcn_sched_barrier(0);
      __builtin_amdgcn_s_setprio(1);
#pragma unroll
      for (int mi=0;mi<4;mi++)
#pragma unroll
        for (int ni=0;ni<4;ni++)
          acc[mi][ni] = __builtin_amdgcn_mfma_f32_16x16x32_bf16(af[mi], bfv[ni], acc[mi][ni], 0, 0, 0);
      __builtin_amdgcn_s_setprio(0);
      __builtin_amdgcn_sched_barrier(0);
      asm volatile("s_barrier" ::: "memory");
    }
    if (t+2 < nt) STAGE4(buf, kbase + ((t+2)<<6));
  }
#undef STAGE4
#pragma unroll
  for (int mi=0;mi<4;mi++)
#pragma unroll
    for (int ni=0;ni<4;ni++)
#pragma unroll
      for (int vv=0;vv<4;vv++){
        int row = m0 + wm*64 + mi*16 + kg*4 + vv;
        int col = n0 + wn*64 + ni*16 + lr;
        P[(size_t)blockIdx.z*2097152 + (size_t)row*ldc + col] = acc[mi][ni][vv];
      }
}

__global__ __launch_bounds__(256)
void addout_k(const float* __restrict__ P, float* __restrict__ out){
  int i = (blockIdx.x*256 + threadIdx.x)*4;
  float4 a = *(const float4*)&P[i];
  float4 b = *(const float4*)&P[2097152 + i];
  float4 s = {a.x+b.x, a.y+b.y, a.z+b.z, a.w+b.w};
  *(float4*)&out[i] = s;
}

// ---- fused dual gate GEMM (128^2, K=128): z=0 -> logsigmoid+chunk-cumsum -> cgb f32 ;
//      z=1 -> gate -> bf16 ----
__global__ __launch_bounds__(256)
void gemmg_k(const u16* __restrict__ f1g1, const u16* __restrict__ Bf, const u16* __restrict__ Bg,
             float* __restrict__ Ccg, u16* __restrict__ Cgate){
  __shared__ u16 As[128*32];
  __shared__ u16 Bs[128*32];
  const int zz = blockIdx.z;
  const u16* A = f1g1 + zz*128;          // lda = 256
  const u16* B = zz ? Bg : Bf;           // ldb = 128
  const int m0 = blockIdx.y*128, n0 = blockIdx.x*128;
  const int tid = threadIdx.x;
  const int lane = tid & 63, wave = tid >> 6;
  const int wr = wave >> 1, wc = wave & 1;
  const int lr = lane & 15, kg = lane >> 4;
  const f32x4 vzero = {0.f,0.f,0.f,0.f};
  f32x4 acc[4][4];
#pragma unroll
  for (int a=0;a<4;a++)
#pragma unroll
    for (int b=0;b<4;b++) acc[a][b] = vzero;
  const int r0 = tid>>2, s0 = tid&3;
  for (int k0=0;k0<128;k0+=32){
    __syncthreads();
    g2l16(A + (size_t)(m0+r0)*256 + k0 + s0*8, (u16*)As + (size_t)tid*8);
    g2l16(B + (size_t)(n0+r0)*128 + k0 + s0*8, (u16*)Bs + (size_t)tid*8);
    g2l16(A + (size_t)(m0+r0+64)*256 + k0 + s0*8, (u16*)As + (size_t)(tid+256)*8);
    g2l16(B + (size_t)(n0+r0+64)*128 + k0 + s0*8, (u16*)Bs + (size_t)(tid+256)*8);
    __syncthreads();
    bf16x8 af[4], bfv[4];
#pragma unroll
    for (int mi=0;mi<4;mi++) af[mi]  = *(const bf16x8*)(As + (wr*64+mi*16+lr)*32 + kg*8);
#pragma unroll
    for (int ni=0;ni<4;ni++) bfv[ni] = *(const bf16x8*)(Bs + (wc*64+ni*16+lr)*32 + kg*8);
#pragma unroll
    for (int mi=0;mi<4;mi++)
#pragma unroll
      for (int ni=0;ni<4;ni++)
        acc[mi][ni] = __builtin_amdgcn_mfma_f32_16x16x32_bf16(af[mi], bfv[ni], acc[mi][ni], 0, 0, 0);
  }
  if (zz == 0){
    // logsigmoid + inclusive cumsum over the 64-row chunk (wr-aligned) per column
#pragma unroll
    for (int ni=0;ni<4;ni++){
      float p[4][4]; float s[4];
#pragma unroll
      for (int mi=0;mi<4;mi++){
        float run = 0.f;
#pragma unroll
        for (int vv=0;vv<4;vv++){
          float v = acc[mi][ni][vv];
          v = fminf(v,0.f) - __logf(1.f + __expf(-fabsf(v)));
          run += v; p[mi][vv] = run;
        }
        s[mi] = run;
      }
      float M = 0.f; float base[4];
#pragma unroll
      for (int mi=0;mi<4;mi++){
        float a0 = __shfl(s[mi], lr);
        float a1 = __shfl(s[mi], lr+16);
        float a2 = __shfl(s[mi], lr+32);
        float a3 = __shfl(s[mi], lr+48);
        float before = 0.f;
        if (kg>0) before += a0;
        if (kg>1) before += a1;
        if (kg>2) before += a2;
        base[mi] = M + before;
        M += a0+a1+a2+a3;
      }
#pragma unroll
      for (int mi=0;mi<4;mi++)
#pragma unroll
        for (int vv=0;vv<4;vv++){
          int row = m0 + wr*64 + mi*16 + kg*4 + vv;
          int col = n0 + wc*64 + ni*16 + lr;
          Ccg[(size_t)row*2048 + col] = base[mi] + p[mi][vv];
        }
    }
  } else {
#pragma unroll
    for (int mi=0;mi<4;mi++)
#pragma unroll
      for (int ni=0;ni<4;ni++)
#pragma unroll
        for (int vv=0;vv<4;vv++){
          int row = m0 + wr*64 + mi*16 + kg*4 + vv;
          int col = n0 + wc*64 + ni*16 + lr;
          Cgate[(size_t)row*2048 + col] = f2bf(acc[mi][ni][vv]);
        }
  }
}

// ---------------- split-K GEMM for f1g1 (N=256, K=2048 in 16 chunks) ----------------
__global__ __launch_bounds__(256)
void gemmsk_k(const u16* __restrict__ A, const u16* __restrict__ B, float* __restrict__ P,
              int lda, int ldb){
  __shared__ u16 As[128*32];
  __shared__ u16 Bs[128*32];
  const int m0 = blockIdx.y*128, n0 = blockIdx.x*128;
  const int kbase = blockIdx.z*128;
  const int tid = threadIdx.x;
  const int lane = tid & 63, wave = tid >> 6;
  const int wr = wave >> 1, wc = wave & 1;
  const int lr = lane & 15, kg = lane >> 4;
  const f32x4 vzero = {0.f,0.f,0.f,0.f};
  f32x4 acc[4][4];
#pragma unroll
  for (int a=0;a<4;a++)
#pragma unroll
    for (int b=0;b<4;b++) acc[a][b] = vzero;
  const int r0 = tid>>2, s0 = tid&3;
  for (int k0=kbase;k0<kbase+128;k0+=32){
    __syncthreads();
    g2l16(A + (size_t)(m0+r0)*lda + k0 + s0*8, (u16*)As + (size_t)tid*8);
    g2l16(B + (size_t)(n0+r0)*ldb + k0 + s0*8, (u16*)Bs + (size_t)tid*8);
    g2l16(A + (size_t)(m0+r0+64)*lda + k0 + s0*8, (u16*)As + (size_t)(tid+256)*8);
    g2l16(B + (size_t)(n0+r0+64)*ldb + k0 + s0*8, (u16*)Bs + (size_t)(tid+256)*8);
    __syncthreads();
    bf16x8 af[4], bfv[4];
#pragma unroll
    for (int mi=0;mi<4;mi++) af[mi]  = *(const bf16x8*)(As + (wr*64+mi*16+lr)*32 + kg*8);
#pragma unroll
    for (int ni=0;ni<4;ni++) bfv[ni] = *(const bf16x8*)(Bs + (wc*64+ni*16+lr)*32 + kg*8);
#pragma unroll
    for (int mi=0;mi<4;mi++)
#pragma unroll
      for (int ni=0;ni<4;ni++)
        acc[mi][ni] = __builtin_amdgcn_mfma_f32_16x16x32_bf16(af[mi], bfv[ni], acc[mi][ni], 0, 0, 0);
  }
#pragma unroll
  for (int mi=0;mi<4;mi++)
#pragma unroll
    for (int ni=0;ni<4;ni++)
#pragma unroll
      for (int vv=0;vv<4;vv++){
        int row = m0 + wr*64 + mi*16 + kg*4 + vv;
        int col = n0 + wc*64 + ni*16 + lr;
        P[(size_t)blockIdx.z*262144 + (size_t)row*256 + col] = acc[mi][ni][vv];
      }
}

__global__ __launch_bounds__(256)
void reduce16_k(const float* __restrict__ P, u16* __restrict__ out){
  int i = (blockIdx.x*256 + threadIdx.x)*4;
  float4 s = *(const float4*)&P[i];
#pragma unroll
  for (int z=1;z<16;z++){
    float4 p = *(const float4*)&P[(size_t)z*262144 + i];
    s.x+=p.x; s.y+=p.y; s.z+=p.z; s.w+=p.w;
  }
  ushort4 o; o.x=f2bf(s.x); o.y=f2bf(s.y); o.z=f2bf(s.z); o.w=f2bf(s.w);
  *(ushort4*)&out[i] = o;
}

// ---------------- beta = sigmoid(h @ Wb), per-t block (bf16 h) ----------------
__global__ __launch_bounds__(256)
void beta_k(const u16* __restrict__ h, const float* __restrict__ Wb, float* __restrict__ betab){
  __shared__ float hrow[2048];
  __shared__ float red[16][5];
  const int t = blockIdx.x, tid = threadIdx.x;
  {
    int b8 = tid*8;
    ushort4 a = *(const ushort4*)&h[(size_t)t*2048 + b8];
    ushort4 b = *(const ushort4*)&h[(size_t)t*2048 + b8 + 4];
    hrow[b8+0]=bf2f(a.x); hrow[b8+1]=bf2f(a.y); hrow[b8+2]=bf2f(a.z); hrow[b8+3]=bf2f(a.w);
    hrow[b8+4]=bf2f(b.x); hrow[b8+5]=bf2f(b.y); hrow[b8+6]=bf2f(b.z); hrow[b8+7]=bf2f(b.w);
  }
  __syncthreads();
  float part[16];
#pragma unroll
  for (int n=0;n<16;n++) part[n]=0.f;
  for (int j=0;j<8;j++){
    int kk = tid + j*256;
    float hv = hrow[kk];
    const float4* wr4 = (const float4*)&Wb[(size_t)kk*16];
    float4 w0=wr4[0], w1=wr4[1], w2=wr4[2], w3=wr4[3];
    part[0]+=hv*w0.x; part[1]+=hv*w0.y; part[2]+=hv*w0.z; part[3]+=hv*w0.w;
    part[4]+=hv*w1.x; part[5]+=hv*w1.y; part[6]+=hv*w1.z; part[7]+=hv*w1.w;
    part[8]+=hv*w2.x; part[9]+=hv*w2.y; part[10]+=hv*w2.z; part[11]+=hv*w2.w;
    part[12]+=hv*w3.x; part[13]+=hv*w3.y; part[14]+=hv*w3.z; part[15]+=hv*w3.w;
  }
#pragma unroll
  for (int n=0;n<16;n++){
    float s = part[n];
#pragma unroll
    for (int off=1;off<64;off<<=1) s += __shfl_xor(s, off);
    if ((tid&63)==0) red[n][tid>>6] = s;
  }
  __syncthreads();
  if (tid < 16){
    float s = red[tid][0]+red[tid][1]+red[tid][2]+red[tid][3];
    betab[t*16+tid] = 1.f/(1.f+__expf(-s));
  }
}

// ---- causal conv4 + silu: q,k,v -> bf16 ; w-branch -> fused l2norm*beta -> bwb f32 ----
__global__ __launch_bounds__(256)
void conv_k(const u16* __restrict__ raw, const float* __restrict__ cq,
            const float* __restrict__ ck, const float* __restrict__ cv,
            const float* __restrict__ betab,
            u16* __restrict__ qo, u16* __restrict__ ko,
            u16* __restrict__ vo, float* __restrict__ bwout){
  __shared__ float red[2][2][4];
  int idx = blockIdx.x*256 + threadIdx.x;
  int cgl = idx & 8191, tb = idx >> 13;
  int which = cgl >> 11, cc = cgl & 2047;
  const float* wt = (which==0)?cq:((which==1)?ck:cv);   // w-branch (3) uses cv (faithful to ref)
  float4 w4 = *(const float4*)&wt[cc*4];
  int t0 = tb*4;
  float x[7];
#pragma unroll
  for (int j=0;j<7;j++){
    int t = t0 - 3 + j;
    x[j] = (t >= 0) ? bf2f(raw[(size_t)t*8192 + cgl]) : 0.f;
  }
  float y[4];
#pragma unroll
  for (int j=0;j<4;j++){
    float yy = x[j]*w4.x + x[j+1]*w4.y + x[j+2]*w4.z + x[j+3]*w4.w;
    y[j] = yy / (1.f + __expf(-yy));      // silu
  }
  if (which < 3){
    u16* outb = (which==0)?qo:((which==1)?ko:vo);
#pragma unroll
    for (int j=0;j<4;j++)
      outb[(size_t)(t0+j)*2048 + cc] = f2bf(y[j]);
  } else {
    // fused l2norm over m (128 threads = 2 waves per head) * beta
    const int hh = threadIdx.x >> 7;        // which head-half of block
    const int wh = (threadIdx.x >> 6) & 1;  // wave-half within head group
    float ss[4];
#pragma unroll
    for (int j=0;j<4;j++){
      float s = y[j]*y[j];
#pragma unroll
      for (int off=1;off<64;off<<=1) s += __shfl_xor(s, off);
      ss[j] = s;
    }
    if ((threadIdx.x & 63) == 0){
#pragma unroll
      for (int j=0;j<4;j++) red[hh][wh][j] = ss[j];
    }
    __syncthreads();
    const int h = cc >> 7;
#pragma unroll
    for (int j=0;j<4;j++){
      float tot = red[hh][0][j] + red[hh][1][j];
      float r = rsqrtf(tot + 1e-6f) * betab[(t0+j)*16 + h];
      bwout[(size_t)(t0+j)*2048 + cc] = y[j]*r;
    }
  }
}

// ---------------- Phase A (MFMA): DSkT[m][d] = U^T K ; DSvT[v][m] = V^T U (bf16 out) ----------------
__global__ __launch_bounds__(256)
void phaseA_k(const u16* __restrict__ k, const u16* __restrict__ v,
              const float* __restrict__ bw, const float* __restrict__ cg,
              u16* __restrict__ DSkT, u16* __restrict__ DSvT){
  __shared__ u16 UT[128*68];
  __shared__ u16 KT[128*68];
  __shared__ u16 VT[128*68];
  __shared__ float Gt[128];
  const int bx=blockIdx.x, h=bx&15, c=bx>>4, tid=threadIdx.x;
  const int w=tid>>6, lane=tid&63, lr=lane&15, kg=lane>>4;
  if (tid<128) Gt[tid] = cg[(size_t)(c*64+63)*2048 + h*128 + tid];
  __syncthreads();
#pragma unroll
  for (int j=0;j<8;j++){
    int f4=tid+j*256, r=f4>>5, c4=(f4&31)<<2;
    size_t g=(size_t)(c*64+r)*2048 + h*128 + c4;
    ushort4 kv=*(const ushort4*)&k[g];
    ushort4 vv=*(const ushort4*)&v[g];
    float4 bv=*(const float4*)&bw[g];
    float4 cv=*(const float4*)&cg[g];
    float u0=bv.x*__expf(Gt[c4+0]-cv.x);
    float u1=bv.y*__expf(Gt[c4+1]-cv.y);
    float u2=bv.z*__expf(Gt[c4+2]-cv.z);
    float u3=bv.w*__expf(Gt[c4+3]-cv.w);
    KT[(c4+0)*68+r]=kv.x; KT[(c4+1)*68+r]=kv.y;
    KT[(c4+2)*68+r]=kv.z; KT[(c4+3)*68+r]=kv.w;
    VT[(c4+0)*68+r]=vv.x; VT[(c4+1)*68+r]=vv.y;
    VT[(c4+2)*68+r]=vv.z; VT[(c4+3)*68+r]=vv.w;
    UT[(c4+0)*68+r]=f2bf(u0);   UT[(c4+1)*68+r]=f2bf(u1);
    UT[(c4+2)*68+r]=f2bf(u2);   UT[(c4+3)*68+r]=f2bf(u3);
  }
  __syncthreads();
  const f32x4 vz = {0.f,0.f,0.f,0.f};
  {
    f32x4 acc[2][8];
#pragma unroll
    for (int a=0;a<2;a++)
#pragma unroll
      for (int b=0;b<8;b++) acc[a][b]=vz;
#pragma unroll
    for (int ks=0;ks<2;ks++){
      bf16x8 a0=ldfrag(&UT[(w*32   +lr)*68 + ks*32+kg*8]);
      bf16x8 a1=ldfrag(&UT[(w*32+16+lr)*68 + ks*32+kg*8]);
#pragma unroll
      for (int nj=0;nj<8;nj++){
        bf16x8 b=ldfrag(&KT[(nj*16+lr)*68 + ks*32+kg*8]);
        acc[0][nj]=__builtin_amdgcn_mfma_f32_16x16x32_bf16(a0,b,acc[0][nj],0,0,0);
        acc[1][nj]=__builtin_amdgcn_mfma_f32_16x16x32_bf16(a1,b,acc[1][nj],0,0,0);
      }
    }
#pragma unroll
    for (int mi2=0;mi2<2;mi2++)
#pragma unroll
      for (int nj=0;nj<8;nj++)
#pragma unroll
        for (int vv2=0;vv2<4;vv2++)
          DSkT[(size_t)bx*16384 + (size_t)(w*32+mi2*16+kg*4+vv2)*128 + nj*16+lr] = f2bf(acc[mi2][nj][vv2]);
  }
  {
    f32x4 acc[2][8];
#pragma unroll
    for (int a=0;a<2;a++)
#pragma unroll
      for (int b=0;b<8;b++) acc[a][b]=vz;
#pragma unroll
    for (int ks=0;ks<2;ks++){
      bf16x8 a0=ldfrag(&VT[(w*32   +lr)*68 + ks*32+kg*8]);
      bf16x8 a1=ldfrag(&VT[(w*32+16+lr)*68 + ks*32+kg*8]);
#pragma unroll
      for (int nj=0;nj<8;nj++){
        bf16x8 b=ldfrag(&UT[(nj*16+lr)*68 + ks*32+kg*8]);
        acc[0][nj]=__builtin_amdgcn_mfma_f32_16x16x32_bf16(a0,b,acc[0][nj],0,0,0);
        acc[1][nj]=__builtin_amdgcn_mfma_f32_16x16x32_bf16(a1,b,acc[1][nj],0,0,0);
      }
    }
#pragma unroll
    for (int mi2=0;mi2<2;mi2++)
#pragma unroll
      for (int nj=0;nj<8;nj++)
#pragma unroll
        for (int vv2=0;vv2<4;vv2++)
          DSvT[(size_t)bx*16384 + (size_t)(w*32+mi2*16+kg*4+vv2)*128 + nj*16+lr] = f2bf(acc[mi2][nj][vv2]);
  }
}

// ---------------- Phase B: sequential cross-chunk combine (bf16 in/out) ----------------
__global__ __launch_bounds__(256)
void phaseB_k(const u16* __restrict__ DSk, const u16* __restrict__ DSv,
              const float* __restrict__ cg, u16* __restrict__ Sk0, u16* __restrict__ Sv0){
  unsigned idx = blockIdx.x*256u + threadIdx.x;   // 524288 total
  int sel  = idx >> 18;
  int h    = (idx >> 14) & 15;
  int flat = idx & 16383;                 // SkT: m*128+d ; SvT: v*128+m
  int mdec = sel ? (flat & 127) : (flat >> 7);
  const u16* DS = sel ? DSv : DSk;
  u16* S = sel ? Sv0 : Sk0;
  float cur = 0.f;
  for (int c=0;c<16;c++){
    size_t sb = ((size_t)(c*16+h))*16384 + flat;
    S[sb] = f2bf(cur);                     // state BEFORE chunk c
    float gd = __expf(cg[(size_t)(c*64+63)*2048 + h*128 + mdec]);
    cur = cur*gd + bf2f(DS[sb]);
  }
}

// ---------------- Phase C (MFMA): per-chunk outputs + fused gated RMSNorm -> Obf ----------------
__global__ __launch_bounds__(256)
void phaseC_k(const u16* __restrict__ q, const u16* __restrict__ k,
              const u16* __restrict__ v, const float* __restrict__ bw,
              const float* __restrict__ cg, const u16* __restrict__ SkT,
              const u16* __restrict__ SvT, const u16* __restrict__ gate,
              const float* __restrict__ bg2, const float* __restrict__ nw,
              u16* __restrict__ Obf){
  __shared__ u16 Qb[64*132];     // Q, then A' (wave-private rows after prep)
  __shared__ u16 KV[8704];       // K[64][132], then VT[128][68]
  __shared__ u16 Bws[64*132];    // bw*e^{cgm-cg} natural [s][m]
  __shared__ u16 BwT[128*68];    // transposed [m][s]
  __shared__ u16 Ssb[64*68];     // sqk, then P (wave-private rows)
  __shared__ u16 SkL[128*132];   // Sk'^T * e^{cgm[m]}  [m][d]
  __shared__ u16 SvL[128*132];   // Sv'^T * e^{cgm[m]}  [v][m]
  __shared__ float cgm[128];
  __shared__ float ecgm[128];
  const int bx=blockIdx.x, h=bx&15, c=bx>>4, tid=threadIdx.x;
  const int w=tid>>6, lane=tid&63, lr=lane&15, kg=lane>>4;
  const float SCALE = 0.088388347648318447f;   // 128^-0.5
  const f32x4 vz = {0.f,0.f,0.f,0.f};
  if (tid<128){ float t=cg[(size_t)(c*64+31)*2048 + h*128 + tid]; cgm[tid]=t; ecgm[tid]=__expf(t); }
  __syncthreads();
#pragma unroll
  for (int j=0;j<8;j++){
    int f4=tid+j*256, r=f4>>5, c4=(f4&31)<<2;
    size_t g=(size_t)(c*64+r)*2048 + h*128 + c4;
    *(ushort4*)&Qb[r*132+c4] = *(const ushort4*)&q[g];
    *(ushort4*)&KV[r*132+c4] = *(const ushort4*)&k[g];
    float4 bv=*(const float4*)&bw[g];
    float4 cv=*(const float4*)&cg[g];
    float b0=bv.x*__expf(cgm[c4+0]-cv.x);
    float b1=bv.y*__expf(cgm[c4+1]-cv.y);
    float b2=bv.z*__expf(cgm[c4+2]-cv.z);
    float b3=bv.w*__expf(cgm[c4+3]-cv.w);
    bf16x4 bb = cvt4(b0,b1,b2,b3);
    *(bf16x4*)&Bws[r*132+c4] = bb;
    BwT[(c4+0)*68+r]=(u16)bb[0]; BwT[(c4+1)*68+r]=(u16)bb[1];
    BwT[(c4+2)*68+r]=(u16)bb[2]; BwT[(c4+3)*68+r]=(u16)bb[3];
  }
  __syncthreads();
  {
    f32x4 acc1[4];
#pragma unroll
    for (int a=0;a<4;a++) acc1[a]=vz;
#pragma unroll
    for (int ks=0;ks<4;ks++){
      bf16x8 aq = ldfrag(&Qb[(w*16+lr)*132 + ks*32+kg*8]);
#pragma unroll
      for (int ni=0;ni<4;ni++){
        bf16x8 bk = ldfrag(&KV[(ni*16+lr)*132 + ks*32+kg*8]);
        acc1[ni]=__builtin_amdgcn_mfma_f32_16x16x32_bf16(aq,bk,acc1[ni],0,0,0);
      }
    }
#pragma unroll
    for (int ni=0;ni<4;ni++)
#pragma unroll
      for (int vv2=0;vv2<4;vv2++){
        int row=w*16+kg*4+vv2, col=ni*16+lr;
        Ssb[row*68+col] = (col<=row) ? f2bf(acc1[ni][vv2]) : (u16)0;
      }
  }
  __syncthreads();   // all K reads done -> KV reusable for VT
#pragma unroll
  for (int j=0;j<8;j++){
    int f4=tid+j*256, r=f4>>5, c4=(f4&31)<<2;
    ushort4 vv=*(const ushort4*)&v[(size_t)(c*64+r)*2048 + h*128 + c4];
    KV[(c4+0)*68+r]=vv.x; KV[(c4+1)*68+r]=vv.y;
    KV[(c4+2)*68+r]=vv.z; KV[(c4+3)*68+r]=vv.w;
  }
#pragma unroll
  for (int j=0;j<16;j++){
    int f4=tid+j*256, r=f4>>5, c4=(f4&31)<<2;
    ushort4 s4=*(const ushort4*)&SkT[(size_t)bx*16384 + (size_t)r*128 + c4];
    float em=ecgm[r];
    *(bf16x4*)&SkL[r*132+c4]=cvt4(bf2f(s4.x)*em, bf2f(s4.y)*em, bf2f(s4.z)*em, bf2f(s4.w)*em);
  }
#pragma unroll
  for (int j=0;j<16;j++){
    int f4=tid+j*256, r=f4>>5, c4=(f4&31)<<2;
    ushort4 s4=*(const ushort4*)&SvT[(size_t)bx*16384 + (size_t)r*128 + c4];
    *(bf16x4*)&SvL[r*132+c4]=cvt4(bf2f(s4.x)*ecgm[c4+0], bf2f(s4.y)*ecgm[c4+1],
                                  bf2f(s4.z)*ecgm[c4+2], bf2f(s4.w)*ecgm[c4+3]);
  }
  f32x4 zac[8];
#pragma unroll
  for (int a=0;a<8;a++) zac[a]=vz;
#pragma unroll
  for (int ks=0;ks<2;ks++){
    bf16x8 as_ = ldfrag(&Ssb[(w*16+lr)*68 + ks*32+kg*8]);
#pragma unroll
    for (int ni=0;ni<8;ni++){
      bf16x8 bb = ldfrag(&BwT[(ni*16+lr)*68 + ks*32+kg*8]);
      zac[ni]=__builtin_amdgcn_mfma_f32_16x16x32_bf16(as_,bb,zac[ni],0,0,0);
    }
  }
  __syncthreads();   // SkL/SvL/VT staged & visible
#pragma unroll
  for (int dt=0;dt<4;dt++){
    bf16x8 aq = ldfrag(&Qb[(w*16+lr)*132 + dt*32+kg*8]);
#pragma unroll
    for (int ni=0;ni<8;ni++){
      bf16x8 bs = ldfrag(&SkL[(ni*16+lr)*132 + dt*32+kg*8]);
      zac[ni]=__builtin_amdgcn_mfma_f32_16x16x32_bf16(aq,bs,zac[ni],0,0,0);
    }
  }
  float dec[4][8], zz[4][8];
#pragma unroll
  for (int vv2=0;vv2<4;vv2++)
#pragma unroll
    for (int ni=0;ni<8;ni++) zz[vv2][ni]=zac[ni][vv2];
#pragma unroll
  for (int vv2=0;vv2<4;vv2++){
    size_t gr=(size_t)(c*64+w*16+kg*4+vv2)*2048 + h*128;
#pragma unroll
    for (int ni=0;ni<8;ni++){
      float cgv = cg[gr + ni*16+lr];
      dec[vv2][ni] = __expf(cgv - cgm[ni*16+lr]);
    }
  }
#pragma unroll
  for (int vv2=0;vv2<4;vv2++){
    float mx=-3.0e38f;
#pragma unroll
    for (int ni=0;ni<8;ni++){ zz[vv2][ni] *= SCALE*dec[vv2][ni]; mx=fmaxf(mx,zz[vv2][ni]); }
    mx=fmaxf(mx,__shfl_xor(mx,1)); mx=fmaxf(mx,__shfl_xor(mx,2));
    mx=fmaxf(mx,__shfl_xor(mx,4)); mx=fmaxf(mx,__shfl_xor(mx,8));
    float sum=0.f;
#pragma unroll
    for (int ni=0;ni<8;ni++){ zz[vv2][ni]=__expf(zz[vv2][ni]-mx); sum+=zz[vv2][ni]; }
    sum+=__shfl_xor(sum,1); sum+=__shfl_xor(sum,2);
    sum+=__shfl_xor(sum,4); sum+=__shfl_xor(sum,8);
    float inv=1.f/sum;
#pragma unroll
    for (int ni=0;ni<8;ni++) zz[vv2][ni] *= inv*dec[vv2][ni];   // A' = a * e^{cg-cgm}
  }
#pragma unroll
  for (int vv2=0;vv2<4;vv2++)
#pragma unroll
    for (int ni=0;ni<8;ni++)
      Qb[(w*16+kg*4+vv2)*132 + ni*16+lr] = f2bf(zz[vv2][ni]);
  {
    f32x4 acc4[4];
#pragma unroll
    for (int a=0;a<4;a++) acc4[a]=vz;
#pragma unroll
    for (int ks=0;ks<4;ks++){
      bf16x8 aa = ldfrag(&Qb[(w*16+lr)*132 + ks*32+kg*8]);
#pragma unroll
      for (int ni=0;ni<4;ni++){
        bf16x8 bb = ldfrag(&Bws[(ni*16+lr)*132 + ks*32+kg*8]);
        acc4[ni]=__builtin_amdgcn_mfma_f32_16x16x32_bf16(aa,bb,acc4[ni],0,0,0);
      }
    }
#pragma unroll
    for (int ni=0;ni<4;ni++)
#pragma unroll
      for (int vv2=0;vv2<4;vv2++){
        int row=w*16+kg*4+vv2, col=ni*16+lr;
        Ssb[row*68+col] = (col<=row) ? f2bf(acc4[ni][vv2]) : (u16)0;
      }
  }
  f32x4 oac[8];
#pragma unroll
  for (int a=0;a<8;a++) oac[a]=vz;
#pragma unroll
  for (int ks=0;ks<2;ks++){
    bf16x8 ap = ldfrag(&Ssb[(w*16+lr)*68 + ks*32+kg*8]);
#pragma unroll
    for (int ni=0;ni<8;ni++){
      bf16x8 bv2 = ldfrag(&KV[(ni*16+lr)*68 + ks*32+kg*8]);
      oac[ni]=__builtin_amdgcn_mfma_f32_16x16x32_bf16(ap,bv2,oac[ni],0,0,0);
    }
  }
#pragma unroll
  for (int mt=0;mt<4;mt++){
    bf16x8 aa = ldfrag(&Qb[(w*16+lr)*132 + mt*32+kg*8]);
#pragma unroll
    for (int ni=0;ni<8;ni++){
      bf16x8 bs = ldfrag(&SvL[(ni*16+lr)*132 + mt*32+kg*8]);
      oac[ni]=__builtin_amdgcn_mfma_f32_16x16x32_bf16(aa,bs,oac[ni],0,0,0);
    }
  }
  // ---- fused gated RMSNorm epilogue -> Obf bf16
#pragma unroll
  for (int vv2=0;vv2<4;vv2++){
    float ss = 0.f;
#pragma unroll
    for (int ni=0;ni<8;ni++) ss += oac[ni][vv2]*oac[ni][vv2];
    ss += __shfl_xor(ss,1); ss += __shfl_xor(ss,2);
    ss += __shfl_xor(ss,4); ss += __shfl_xor(ss,8);
    float rr = rsqrtf(ss*(1.f/128.f) + 1e-5f);
    int row = c*64 + w*16 + kg*4 + vv2;
#pragma unroll
    for (int ni=0;ni<8;ni++){
      int colh = ni*16+lr;
      int col  = h*128 + colh;
      float g = bf2f(gate[(size_t)row*2048 + col]) + bg2[col];
      float val = oac[ni][vv2]*rr*nw[colh]*(1.f/(1.f+__expf(-g)));
      Obf[(size_t)row*2048 + col] = f2bf(val);
    }
  }
}

extern "C" void kernel_launch(void* const* d_in, const int* in_sizes, int n_in,
                              void* d_out, int out_size, void* d_ws, size_t ws_size,
                              hipStream_t stream){
  (void)in_sizes; (void)n_in; (void)out_size; (void)ws_size;
  const float* hX   = (const float*)d_in[0];
  const float* Wq   = (const float*)d_in[1];
  const float* Wk   = (const float*)d_in[2];
  const float* Wv   = (const float*)d_in[3];
  const float* Ww   = (const float*)d_in[4];
  const float* cq   = (const float*)d_in[5];
  const float* ck   = (const float*)d_in[6];
  const float* cv   = (const float*)d_in[7];
  const float* Wf1  = (const float*)d_in[8];
  const float* Wf2  = (const float*)d_in[9];
  const float* Wb   = (const float*)d_in[10];
  const float* Wg1  = (const float*)d_in[11];
  const float* Wg2  = (const float*)d_in[12];
  const float* bg2  = (const float*)d_in[13];
  const float* nw   = (const float*)d_in[14];
  const float* Wo   = (const float*)d_in[15];
  char* ws = (char*)d_ws;
  u16*   h_bf  = (u16*)  (ws + 0);
  u16*   WcatT = (u16*)  (ws + 4194304);
  u16*   Sk0   = (u16*)  (ws + 4194304);            // reuses WcatT after GEMMs (bf16)
  u16*   Sv0   = (u16*)  (ws + 20971520);
  u16*   WoT   = (u16*)  (ws + 37748736);
  u16*   WfgT  = (u16*)  (ws + 46137344);
  u16*   Wf2T  = (u16*)  (ws + 47185920);
  u16*   Wg2T  = (u16*)  (ws + 47710208);
  u16*   qkvw  = (u16*)  (ws + 48234496);           // bf16 [1024][8192] -> ends 65011712
  u16*   DSk   = (u16*)  (ws + 48234496);           // bf16, reuses qkvw after conv
  u16*   DSv   = (u16*)  (ws + 56623104);
  float* Pw    = (float*)(ws + 48234496);           // Wo split-K partials (after phaseB)
  u16*   gateb = (u16*)  (ws + 65011712);           // bf16 [1024][2048]
  u16*   qb    = (u16*)  (ws + 81788928);           // bf16 [1024][2048]
  u16*   kb    = (u16*)  (ws + 90177536);
  u16*   vb    = (u16*)  (ws + 98566144);
  float* P8    = (float*)(ws + 106954752);          // f1g1 split-K partials (16 x 1MB)
  float* bwb   = (float*)(ws + 115343360);          // conv-fused l2bw out (after P8 dead? no: separate)
  u16*   f1g1  = (u16*)  (ws + 123731968);
  float* cgb   = (float*)(ws + 132644864);
  float* betab = (float*)(ws + 141033472);
  u16*   Obf   = (u16*)  (ws + 141099008);
  float* outp  = (float*)d_out;

  // conversions: all transposes + hX convert in ONE launch
  transp64_k<<<dim3(32,32,10),256,0,stream>>>(Wq, Wk, Wv, Ww, Wo, WcatT, WoT, hX, h_bf,
                                              Wf1, Wg1, Wf2, Wg2, WfgT, Wf2T, Wg2T);

  // projections
  gemm4_k<true><<<dim3(64,8),256,0,stream>>>(h_bf, WcatT, qkvw, 2048, 2048, 2048, 8192);
  gemmsk_k<<<dim3(2,8,16),256,0,stream>>>(h_bf, WfgT, P8, 2048, 2048);
  reduce16_k<<<256,256,0,stream>>>(P8, f1g1);
  gemmg_k<<<dim3(16,8,2),256,0,stream>>>(f1g1, Wf2T, Wg2T, cgb, gateb);   // cg + gate directly
  beta_k<<<1024,256,0,stream>>>(h_bf, Wb, betab);

  // conv + silu (+fused l2norm*beta on w-branch)
  conv_k<<<8192,256,0,stream>>>(qkvw, cq, ck, cv, betab, qb, kb, vb, bwb);

  // chunked scan (phaseC fuses gated RMSNorm -> Obf)
  phaseA_k<<<256,256,0,stream>>>(kb, vb, bwb, cgb, DSk, DSv);
  phaseB_k<<<2048,256,0,stream>>>(DSk, DSv, cgb, Sk0, Sv0);
  phaseC_k<<<256,256,0,stream>>>(qb, kb, vb, bwb, cgb, Sk0, Sv0, gateb, bg2, nw, Obf);

  // output projection (split-K=2, pipelined)
  gemm4sk_k<<<dim3(16,8,2),256,0,stream>>>(Obf, WoT, Pw, 1024, 2048, 2048, 2048);
  addout_k<<<2048,256,0,stream>>>(Pw, outp);
}

// Round 11
// 177.110 us; speedup vs baseline: 4.7562x; 1.0209x over previous
//
#include <hip/hip_runtime.h>
#include <hip/hip_bf16.h>
#include <stdint.h>

typedef unsigned short u16;
typedef __attribute__((ext_vector_type(8))) short bf16x8;
typedef __attribute__((ext_vector_type(4))) short bf16x4;
typedef __attribute__((ext_vector_type(4))) float f32x4;

#define DEV static __device__ __forceinline__

DEV u16 f2bf(float f){
  union { float f; unsigned u; } x; x.f = f;
  unsigned r = x.u + 0x7fffu + ((x.u >> 16) & 1u);
  return (u16)(r >> 16);
}

DEV float bf2f(u16 u){
  union { unsigned u; float f; } x; x.u = ((unsigned)u) << 16; return x.f;
}

DEV bf16x8 ldfrag(const u16* p){           // two ds_read_b64 (8B-aligned rows)
  bf16x4 a = *(const bf16x4*)p;
  bf16x4 b = *(const bf16x4*)(p+4);
  bf16x8 r;
  r[0]=a[0]; r[1]=a[1]; r[2]=a[2]; r[3]=a[3];
  r[4]=b[0]; r[5]=b[1]; r[6]=b[2]; r[7]=b[3];
  return r;
}

DEV bf16x4 cvt4(float a, float b, float c, float d){
  bf16x4 r; r[0]=(short)f2bf(a); r[1]=(short)f2bf(b); r[2]=(short)f2bf(c); r[3]=(short)f2bf(d);
  return r;
}

DEV void g2l16(const void* g, void* l){
  __builtin_amdgcn_global_load_lds((const __attribute__((address_space(1))) unsigned int*)g,
                                   (__attribute__((address_space(3))) unsigned int*)l,
                                   16, 0, 0);
}

// ---- fused transposes: z=0..4 big 2048x2048, z=5 hX convert, z=6..9 small mats,
// ---- z=10 WbT rows 256..383 of WfgT (rows>=16 zero-padded) ----
__global__ __launch_bounds__(256)
void transp64_k(const float* __restrict__ Wq, const float* __restrict__ Wk,
                const float* __restrict__ Wv, const float* __restrict__ Ww,
                const float* __restrict__ Wo, u16* __restrict__ WcatT, u16* __restrict__ WoT,
                const float* __restrict__ hX, u16* __restrict__ h_bf,
                const float* __restrict__ Wf1, const float* __restrict__ Wg1,
                const float* __restrict__ Wf2, const float* __restrict__ Wg2,
                const float* __restrict__ Wb,
                u16* __restrict__ WfgT, u16* __restrict__ Wf2T, u16* __restrict__ Wg2T){
  __shared__ float tile[64*65];
  const int z = blockIdx.z;
  if (z == 5){
    int idx = ((blockIdx.y*32 + blockIdx.x)*256 + threadIdx.x)*8;
    float4 v0 = *(const float4*)&hX[idx];
    float4 v1 = *(const float4*)&hX[idx+4];
    ushort4 o0, o1;
    o0.x=f2bf(v0.x); o0.y=f2bf(v0.y); o0.z=f2bf(v0.z); o0.w=f2bf(v0.w);
    o1.x=f2bf(v1.x); o1.y=f2bf(v1.y); o1.z=f2bf(v1.z); o1.w=f2bf(v1.w);
    *(ushort4*)&h_bf[idx]   = o0;
    *(ushort4*)&h_bf[idx+4] = o1;
    return;
  }
  if (z == 10){
    int rem = blockIdx.y*32 + blockIdx.x;
    if (rem >= 256) return;
    int cx = rem & 63, cy = rem >> 6;     // k-tile (2048/32), row-tile (128/32)
    const int x = threadIdx.x & 31, y0 = threadIdx.x >> 5;
    int k = cx*32 + x;
#pragma unroll
    for (int j=0;j<4;j++){
      int rpad = cy*32 + y0 + j*8;        // 0..127 -> WfgT row 256+rpad
      float v = (rpad < 16) ? Wb[(size_t)k*16 + rpad] : 0.f;
      WfgT[(size_t)(256+rpad)*2048 + k] = f2bf(v);
    }
    return;
  }
  if (z >= 6){
    int rem = blockIdx.y*32 + blockIdx.x;
    if (rem >= 256) return;
    const float* src; u16* dst; int R, C, cx, cy;
    if (z==6){      src=Wf1; dst=WfgT;                  R=2048; C=128;  cx=rem&3;  cy=rem>>2; }
    else if (z==7){ src=Wg1; dst=WfgT+(size_t)128*2048; R=2048; C=128;  cx=rem&3;  cy=rem>>2; }
    else if (z==8){ src=Wf2; dst=Wf2T;                  R=128;  C=2048; cx=rem>>2; cy=rem&3; }
    else {          src=Wg2; dst=Wg2T;                  R=128;  C=2048; cx=rem>>2; cy=rem&3; }
    const int c0 = cx*32, r0 = cy*32;
    const int x = threadIdx.x & 31, y0 = threadIdx.x >> 5;
#pragma unroll
    for (int j=0;j<4;j++){
      int r = y0 + j*8;
      tile[r*33 + x] = src[(size_t)(r0+r)*C + c0 + x];
    }
    __syncthreads();
#pragma unroll
    for (int j=0;j<4;j++){
      int cc = y0 + j*8;
      dst[(size_t)(c0+cc)*R + r0 + x] = f2bf(tile[x*33 + cc]);
    }
    return;
  }
  const float* src = (z==0)?Wq:((z==1)?Wk:((z==2)?Wv:((z==3)?Ww:Wo)));
  u16* dst = (z<4) ? (WcatT + (size_t)z*4194304) : WoT;
  const int c0 = blockIdx.x*64, r0 = blockIdx.y*64;
#pragma unroll
  for (int p=0;p<4;p++){
    int i = threadIdx.x + p*256;
    int r = i>>4, c4 = (i&15)<<2;
    *(float4*)&tile[r*65 + c4] = *(const float4*)&src[(size_t)(r0+r)*2048 + c0 + c4];
  }
  __syncthreads();
#pragma unroll
  for (int p=0;p<4;p++){
    int i = threadIdx.x + p*256;
    int cc = i>>4, r4 = (i&15)<<2;
    ushort4 o;
    o.x = f2bf(tile[(r4+0)*65 + cc]); o.y = f2bf(tile[(r4+1)*65 + cc]);
    o.z = f2bf(tile[(r4+2)*65 + cc]); o.w = f2bf(tile[(r4+3)*65 + cc]);
    *(ushort4*)&dst[(size_t)(c0+cc)*2048 + r0 + r4] = o;
  }
}

// ---------------- pipelined GEMM: 128x128, BK=64, 4 waves, dbuf + counted vmcnt ----------------
template<bool OBF>
__global__ __launch_bounds__(256)
void gemm4_k(const u16* __restrict__ A, const u16* __restrict__ B, void* __restrict__ Cp,
             int K, int lda, int ldb, int ldc){
  __shared__ u16 As[2][128*64];
  __shared__ u16 Bs[2][128*64];
  const int m0 = blockIdx.y*128, n0 = blockIdx.x*128;
  const int tid = threadIdx.x;
  const int wave = tid>>6, lane = tid&63, lr = lane&15, kg = lane>>4;
  const int wm = wave>>1, wn = wave&1;
  const f32x4 vz = {0.f,0.f,0.f,0.f};
  f32x4 acc[4][4];
#pragma unroll
  for (int a=0;a<4;a++)
#pragma unroll
    for (int b=0;b<4;b++) acc[a][b]=vz;

#define STAGE4(buf, k0) do { \
    _Pragma("unroll") \
    for (int p=0;p<4;p++){ \
      int chunk = tid + p*256, r_ = chunk>>3, ci = chunk&7; \
      g2l16(A + (size_t)(m0+r_)*lda + (k0) + ((ci^(r_&7))<<3), &As[buf][chunk*8]); \
    } \
    _Pragma("unroll") \
    for (int p=0;p<4;p++){ \
      int chunk = tid + p*256, r_ = chunk>>3, ci = chunk&7; \
      g2l16(B + (size_t)(n0+r_)*ldb + (k0) + ((ci^(r_&7))<<3), &Bs[buf][chunk*8]); \
    } \
  } while(0)

  const int nt = K>>6;          // >= 2 required
  STAGE4(0, 0);
  STAGE4(1, 64);
  for (int t=0; t<nt; ++t){
    const int buf = t&1;
    if (t < nt-1) asm volatile("s_waitcnt vmcnt(8)" ::: "memory");
    else          asm volatile("s_waitcnt vmcnt(0)" ::: "memory");
    asm volatile("s_barrier" ::: "memory");
#pragma unroll
    for (int ks=0; ks<2; ++ks){
      bf16x8 af[4], bfv[4];
#pragma unroll
      for (int mi=0;mi<4;mi++){
        int r = wm*64+mi*16+lr;
        af[mi] = *(const bf16x8*)&As[buf][r*64 + (((ks*4+kg)^(r&7))<<3)];
      }
#pragma unroll
      for (int ni=0;ni<4;ni++){
        int r = wn*64+ni*16+lr;
        bfv[ni] = *(const bf16x8*)&Bs[buf][r*64 + (((ks*4+kg)^(r&7))<<3)];
      }
      asm volatile("s_waitcnt lgkmcnt(0)" ::: "memory");
      __builtin_amdgcn_sched_barrier(0);
      __builtin_amdgcn_s_setprio(1);
#pragma unroll
      for (int mi=0;mi<4;mi++)
#pragma unroll
        for (int ni=0;ni<4;ni++)
          acc[mi][ni] = __builtin_amdgcn_mfma_f32_16x16x32_bf16(af[mi], bfv[ni], acc[mi][ni], 0, 0, 0);
      __builtin_amdgcn_s_setprio(0);
      __builtin_amdgcn_sched_barrier(0);
      asm volatile("s_barrier" ::: "memory");
    }
    if (t+2 < nt) STAGE4(buf, (t+2)<<6);
  }
#undef STAGE4
#pragma unroll
  for (int mi=0;mi<4;mi++)
#pragma unroll
    for (int ni=0;ni<4;ni++)
#pragma unroll
      for (int vv=0;vv<4;vv++){
        int row = m0 + wm*64 + mi*16 + kg*4 + vv;
        int col = n0 + wn*64 + ni*16 + lr;
        if (OBF) ((u16*)Cp)[(size_t)row*ldc + col] = f2bf(acc[mi][ni][vv]);
        else     ((float*)Cp)[(size_t)row*ldc + col] = acc[mi][ni][vv];
      }
}

// ---- split-K pipelined GEMM: 128x128, BK=64 -> atomic f32 accumulate into out ----
__global__ __launch_bounds__(256)
void gemm4sk_k(const u16* __restrict__ A, const u16* __restrict__ B, float* __restrict__ out,
               int Khalf, int lda, int ldb, int ldc){
  __shared__ u16 As[2][128*64];
  __shared__ u16 Bs[2][128*64];
  const int m0 = blockIdx.y*128, n0 = blockIdx.x*128;
  const int kbase = blockIdx.z*Khalf;
  const int tid = threadIdx.x;
  const int wave = tid>>6, lane = tid&63, lr = lane&15, kg = lane>>4;
  const int wm = wave>>1, wn = wave&1;
  const f32x4 vz = {0.f,0.f,0.f,0.f};
  f32x4 acc[4][4];
#pragma unroll
  for (int a=0;a<4;a++)
#pragma unroll
    for (int b=0;b<4;b++) acc[a][b]=vz;

#define STAGE4(buf, k0) do { \
    _Pragma("unroll") \
    for (int p=0;p<4;p++){ \
      int chunk = tid + p*256, r_ = chunk>>3, ci = chunk&7; \
      g2l16(A + (size_t)(m0+r_)*lda + (k0) + ((ci^(r_&7))<<3), &As[buf][chunk*8]); \
    } \
    _Pragma("unroll") \
    for (int p=0;p<4;p++){ \
      int chunk = tid + p*256, r_ = chunk>>3, ci = chunk&7; \
      g2l16(B + (size_t)(n0+r_)*ldb + (k0) + ((ci^(r_&7))<<3), &Bs[buf][chunk*8]); \
    } \
  } while(0)

  const int nt = Khalf>>6;      // >= 2 required
  STAGE4(0, kbase);
  STAGE4(1, kbase+64);
  for (int t=0; t<nt; ++t){
    const int buf = t&1;
    if (t < nt-1) asm volatile("s_waitcnt vmcnt(8)" ::: "memory");
    else          asm volatile("s_waitcnt vmcnt(0)" ::: "memory");
    asm volatile("s_barrier" ::: "memory");
#pragma unroll
    for (int ks=0; ks<2; ++ks){
      bf16x8 af[4], bfv[4];
#pragma unroll
      for (int mi=0;mi<4;mi++){
        int r = wm*64+mi*16+lr;
        af[mi] = *(const bf16x8*)&As[buf][r*64 + (((ks*4+kg)^(r&7))<<3)];
      }
#pragma unroll
      for (int ni=0;ni<4;ni++){
        int r = wn*64+ni*16+lr;
        bfv[ni] = *(const bf16x8*)&Bs[buf][r*64 + (((ks*4+kg)^(r&7))<<3)];
      }
      asm volatile("s_waitcnt lgkmcnt(0)" ::: "memory");
      __builtin_amdgcn_sched_barrier(0);
      __builtin_amdgcn_s_setprio(1);
#pragma unroll
      for (int mi=0;mi<4;mi++)
#pragma unroll
        for (int ni=0;ni<4;ni++)
          acc[mi][ni] = __builtin_amdgcn_mfma_f32_16x16x32_bf16(af[mi], bfv[ni], acc[mi][ni], 0, 0, 0);
      __builtin_amdgcn_s_setprio(0);
      __builtin_amdgcn_sched_barrier(0);
      asm volatile("s_barrier" ::: "memory");
    }
    if (t+2 < nt) STAGE4(buf, kbase + ((t+2)<<6));
  }
#undef STAGE4
  // 2 contributions per address (z=0,1); f32 add is commutative -> deterministic
#pragma unroll
  for (int mi=0;mi<4;mi++)
#pragma unroll
    for (int ni=0;ni<4;ni++)
#pragma unroll
      for (int vv=0;vv<4;vv++){
        int row = m0 + wm*64 + mi*16 + kg*4 + vv;
        int col = n0 + wn*64 + ni*16 + lr;
        unsafeAtomicAdd(&out[(size_t)row*ldc + col], acc[mi][ni][vv]);
      }
}

// ---- fused dual gate GEMM (128^2, K=128): z=0 -> logsigmoid+chunk-cumsum -> cgb f32 ;
//      z=1 -> gate -> bf16 ----
__global__ __launch_bounds__(256)
void gemmg_k(const u16* __restrict__ f1g1, const u16* __restrict__ Bf, const u16* __restrict__ Bg,
             float* __restrict__ Ccg, u16* __restrict__ Cgate){
  __shared__ u16 As[128*32];
  __shared__ u16 Bs[128*32];
  const int zz = blockIdx.z;
  const u16* A = f1g1 + zz*128;          // lda = 384
  const u16* B = zz ? Bg : Bf;           // ldb = 128
  const int m0 = blockIdx.y*128, n0 = blockIdx.x*128;
  const int tid = threadIdx.x;
  const int lane = tid & 63, wave = tid >> 6;
  const int wr = wave >> 1, wc = wave & 1;
  const int lr = lane & 15, kg = lane >> 4;
  const f32x4 vzero = {0.f,0.f,0.f,0.f};
  f32x4 acc[4][4];
#pragma unroll
  for (int a=0;a<4;a++)
#pragma unroll
    for (int b=0;b<4;b++) acc[a][b] = vzero;
  const int r0 = tid>>2, s0 = tid&3;
  for (int k0=0;k0<128;k0+=32){
    __syncthreads();
    g2l16(A + (size_t)(m0+r0)*384 + k0 + s0*8, (u16*)As + (size_t)tid*8);
    g2l16(B + (size_t)(n0+r0)*128 + k0 + s0*8, (u16*)Bs + (size_t)tid*8);
    g2l16(A + (size_t)(m0+r0+64)*384 + k0 + s0*8, (u16*)As + (size_t)(tid+256)*8);
    g2l16(B + (size_t)(n0+r0+64)*128 + k0 + s0*8, (u16*)Bs + (size_t)(tid+256)*8);
    __syncthreads();
    bf16x8 af[4], bfv[4];
#pragma unroll
    for (int mi=0;mi<4;mi++) af[mi]  = *(const bf16x8*)(As + (wr*64+mi*16+lr)*32 + kg*8);
#pragma unroll
    for (int ni=0;ni<4;ni++) bfv[ni] = *(const bf16x8*)(Bs + (wc*64+ni*16+lr)*32 + kg*8);
#pragma unroll
    for (int mi=0;mi<4;mi++)
#pragma unroll
      for (int ni=0;ni<4;ni++)
        acc[mi][ni] = __builtin_amdgcn_mfma_f32_16x16x32_bf16(af[mi], bfv[ni], acc[mi][ni], 0, 0, 0);
  }
  if (zz == 0){
    // logsigmoid + inclusive cumsum over the 64-row chunk (wr-aligned) per column
#pragma unroll
    for (int ni=0;ni<4;ni++){
      float p[4][4]; float s[4];
#pragma unroll
      for (int mi=0;mi<4;mi++){
        float run = 0.f;
#pragma unroll
        for (int vv=0;vv<4;vv++){
          float v = acc[mi][ni][vv];
          v = fminf(v,0.f) - __logf(1.f + __expf(-fabsf(v)));
          run += v; p[mi][vv] = run;
        }
        s[mi] = run;
      }
      float M = 0.f; float base[4];
#pragma unroll
      for (int mi=0;mi<4;mi++){
        float a0 = __shfl(s[mi], lr);
        float a1 = __shfl(s[mi], lr+16);
        float a2 = __shfl(s[mi], lr+32);
        float a3 = __shfl(s[mi], lr+48);
        float before = 0.f;
        if (kg>0) before += a0;
        if (kg>1) before += a1;
        if (kg>2) before += a2;
        base[mi] = M + before;
        M += a0+a1+a2+a3;
      }
#pragma unroll
      for (int mi=0;mi<4;mi++)
#pragma unroll
        for (int vv=0;vv<4;vv++){
          int row = m0 + wr*64 + mi*16 + kg*4 + vv;
          int col = n0 + wc*64 + ni*16 + lr;
          Ccg[(size_t)row*2048 + col] = base[mi] + p[mi][vv];
        }
    }
  } else {
#pragma unroll
    for (int mi=0;mi<4;mi++)
#pragma unroll
      for (int ni=0;ni<4;ni++)
#pragma unroll
        for (int vv=0;vv<4;vv++){
          int row = m0 + wr*64 + mi*16 + kg*4 + vv;
          int col = n0 + wc*64 + ni*16 + lr;
          Cgate[(size_t)row*2048 + col] = f2bf(acc[mi][ni][vv]);
        }
  }
}

// ---------------- split-K GEMM for f1g1+beta (N=384, K=2048 in 16 chunks, bf16 partials) ----------------
__global__ __launch_bounds__(256)
void gemmsk_k(const u16* __restrict__ A, const u16* __restrict__ B, u16* __restrict__ P,
              int lda, int ldb){
  __shared__ u16 As[128*32];
  __shared__ u16 Bs[128*32];
  const int m0 = blockIdx.y*128, n0 = blockIdx.x*128;
  const int kbase = blockIdx.z*128;
  const int tid = threadIdx.x;
  const int lane = tid & 63, wave = tid >> 6;
  const int wr = wave >> 1, wc = wave & 1;
  const int lr = lane & 15, kg = lane >> 4;
  const f32x4 vzero = {0.f,0.f,0.f,0.f};
  f32x4 acc[4][4];
#pragma unroll
  for (int a=0;a<4;a++)
#pragma unroll
    for (int b=0;b<4;b++) acc[a][b] = vzero;
  const int r0 = tid>>2, s0 = tid&3;
  for (int k0=kbase;k0<kbase+128;k0+=32){
    __syncthreads();
    g2l16(A + (size_t)(m0+r0)*lda + k0 + s0*8, (u16*)As + (size_t)tid*8);
    g2l16(B + (size_t)(n0+r0)*ldb + k0 + s0*8, (u16*)Bs + (size_t)tid*8);
    g2l16(A + (size_t)(m0+r0+64)*lda + k0 + s0*8, (u16*)As + (size_t)(tid+256)*8);
    g2l16(B + (size_t)(n0+r0+64)*ldb + k0 + s0*8, (u16*)Bs + (size_t)(tid+256)*8);
    __syncthreads();
    bf16x8 af[4], bfv[4];
#pragma unroll
    for (int mi=0;mi<4;mi++) af[mi]  = *(const bf16x8*)(As + (wr*64+mi*16+lr)*32 + kg*8);
#pragma unroll
    for (int ni=0;ni<4;ni++) bfv[ni] = *(const bf16x8*)(Bs + (wc*64+ni*16+lr)*32 + kg*8);
#pragma unroll
    for (int mi=0;mi<4;mi++)
#pragma unroll
      for (int ni=0;ni<4;ni++)
        acc[mi][ni] = __builtin_amdgcn_mfma_f32_16x16x32_bf16(af[mi], bfv[ni], acc[mi][ni], 0, 0, 0);
  }
#pragma unroll
  for (int mi=0;mi<4;mi++)
#pragma unroll
    for (int ni=0;ni<4;ni++)
#pragma unroll
      for (int vv=0;vv<4;vv++){
        int row = m0 + wr*64 + mi*16 + kg*4 + vv;
        int col = n0 + wc*64 + ni*16 + lr;
        P[(size_t)blockIdx.z*393216 + (size_t)row*384 + col] = f2bf(acc[mi][ni][vv]);
      }
}

// ---- reduce 16 bf16 partials -> f1g1 bf16 [1024][384]; cols 256..271 -> sigmoid -> betab ----
__global__ __launch_bounds__(256)
void reduceb_k(const u16* __restrict__ P, u16* __restrict__ out, float* __restrict__ betab){
  int i4 = (blockIdx.x*256 + threadIdx.x)*4;
  float s0=0.f, s1=0.f, s2=0.f, s3=0.f;
#pragma unroll
  for (int z=0;z<16;z++){
    ushort4 p = *(const ushort4*)&P[(size_t)z*393216 + i4];
    s0+=bf2f(p.x); s1+=bf2f(p.y); s2+=bf2f(p.z); s3+=bf2f(p.w);
  }
  ushort4 o; o.x=f2bf(s0); o.y=f2bf(s1); o.z=f2bf(s2); o.w=f2bf(s3);
  *(ushort4*)&out[i4] = o;
  int col = i4 % 384;
  if (col >= 256 && col < 272){
    int row = i4 / 384;
    float* bp = &betab[row*16 + (col-256)];
    bp[0] = 1.f/(1.f+__expf(-s0));
    bp[1] = 1.f/(1.f+__expf(-s1));
    bp[2] = 1.f/(1.f+__expf(-s2));
    bp[3] = 1.f/(1.f+__expf(-s3));
  }
}

// ---- causal conv4 + silu: q,k,v -> bf16 ; w-branch -> fused l2norm*beta -> bwb bf16 ----
__global__ __launch_bounds__(256)
void conv_k(const u16* __restrict__ raw, const float* __restrict__ cq,
            const float* __restrict__ ck, const float* __restrict__ cv,
            const float* __restrict__ betab,
            u16* __restrict__ qo, u16* __restrict__ ko,
            u16* __restrict__ vo, u16* __restrict__ bwout){
  __shared__ float red[2][2][4];
  int idx = blockIdx.x*256 + threadIdx.x;
  int cgl = idx & 8191, tb = idx >> 13;
  int which = cgl >> 11, cc = cgl & 2047;
  const float* wt = (which==0)?cq:((which==1)?ck:cv);   // w-branch (3) uses cv (faithful to ref)
  float4 w4 = *(const float4*)&wt[cc*4];
  int t0 = tb*4;
  float x[7];
#pragma unroll
  for (int j=0;j<7;j++){
    int t = t0 - 3 + j;
    x[j] = (t >= 0) ? bf2f(raw[(size_t)t*8192 + cgl]) : 0.f;
  }
  float y[4];
#pragma unroll
  for (int j=0;j<4;j++){
    float yy = x[j]*w4.x + x[j+1]*w4.y + x[j+2]*w4.z + x[j+3]*w4.w;
    y[j] = yy / (1.f + __expf(-yy));      // silu
  }
  if (which < 3){
    u16* outb = (which==0)?qo:((which==1)?ko:vo);
#pragma unroll
    for (int j=0;j<4;j++)
      outb[(size_t)(t0+j)*2048 + cc] = f2bf(y[j]);
  } else {
    // fused l2norm over m (128 threads = 2 waves per head) * beta
    const int hh = threadIdx.x >> 7;        // which head-half of block
    const int wh = (threadIdx.x >> 6) & 1;  // wave-half within head group
    float ss[4];
#pragma unroll
    for (int j=0;j<4;j++){
      float s = y[j]*y[j];
#pragma unroll
      for (int off=1;off<64;off<<=1) s += __shfl_xor(s, off);
      ss[j] = s;
    }
    if ((threadIdx.x & 63) == 0){
#pragma unroll
      for (int j=0;j<4;j++) red[hh][wh][j] = ss[j];
    }
    __syncthreads();
    const int h = cc >> 7;
#pragma unroll
    for (int j=0;j<4;j++){
      float tot = red[hh][0][j] + red[hh][1][j];
      float r = rsqrtf(tot + 1e-6f) * betab[(t0+j)*16 + h];
      bwout[(size_t)(t0+j)*2048 + cc] = f2bf(y[j]*r);
    }
  }
}

// ---------------- Phase A (MFMA): DSkT[m][d] = U^T K ; DSvT[v][m] = V^T U (bf16 out) ----------------
__global__ __launch_bounds__(256)
void phaseA_k(const u16* __restrict__ k, const u16* __restrict__ v,
              const u16* __restrict__ bw, const float* __restrict__ cg,
              u16* __restrict__ DSkT, u16* __restrict__ DSvT){
  __shared__ u16 UT[128*68];
  __shared__ u16 KT[128*68];
  __shared__ u16 VT[128*68];
  __shared__ float Gt[128];
  const int bx=blockIdx.x, h=bx&15, c=bx>>4, tid=threadIdx.x;
  const int w=tid>>6, lane=tid&63, lr=lane&15, kg=lane>>4;
  if (tid<128) Gt[tid] = cg[(size_t)(c*64+63)*2048 + h*128 + tid];
  __syncthreads();
#pragma unroll
  for (int j=0;j<8;j++){
    int f4=tid+j*256, r=f4>>5, c4=(f4&31)<<2;
    size_t g=(size_t)(c*64+r)*2048 + h*128 + c4;
    ushort4 kv=*(const ushort4*)&k[g];
    ushort4 vv=*(const ushort4*)&v[g];
    ushort4 bv=*(const ushort4*)&bw[g];
    float4 cv=*(const float4*)&cg[g];
    float u0=bf2f(bv.x)*__expf(Gt[c4+0]-cv.x);
    float u1=bf2f(bv.y)*__expf(Gt[c4+1]-cv.y);
    float u2=bf2f(bv.z)*__expf(Gt[c4+2]-cv.z);
    float u3=bf2f(bv.w)*__expf(Gt[c4+3]-cv.w);
    KT[(c4+0)*68+r]=kv.x; KT[(c4+1)*68+r]=kv.y;
    KT[(c4+2)*68+r]=kv.z; KT[(c4+3)*68+r]=kv.w;
    VT[(c4+0)*68+r]=vv.x; VT[(c4+1)*68+r]=vv.y;
    VT[(c4+2)*68+r]=vv.z; VT[(c4+3)*68+r]=vv.w;
    UT[(c4+0)*68+r]=f2bf(u0);   UT[(c4+1)*68+r]=f2bf(u1);
    UT[(c4+2)*68+r]=f2bf(u2);   UT[(c4+3)*68+r]=f2bf(u3);
  }
  __syncthreads();
  const f32x4 vz = {0.f,0.f,0.f,0.f};
  {
    f32x4 acc[2][8];
#pragma unroll
    for (int a=0;a<2;a++)
#pragma unroll
      for (int b=0;b<8;b++) acc[a][b]=vz;
#pragma unroll
    for (int ks=0;ks<2;ks++){
      bf16x8 a0=ldfrag(&UT[(w*32   +lr)*68 + ks*32+kg*8]);
      bf16x8 a1=ldfrag(&UT[(w*32+16+lr)*68 + ks*32+kg*8]);
#pragma unroll
      for (int nj=0;nj<8;nj++){
        bf16x8 b=ldfrag(&KT[(nj*16+lr)*68 + ks*32+kg*8]);
        acc[0][nj]=__builtin_amdgcn_mfma_f32_16x16x32_bf16(a0,b,acc[0][nj],0,0,0);
        acc[1][nj]=__builtin_amdgcn_mfma_f32_16x16x32_bf16(a1,b,acc[1][nj],0,0,0);
      }
    }
#pragma unroll
    for (int mi2=0;mi2<2;mi2++)
#pragma unroll
      for (int nj=0;nj<8;nj++)
#pragma unroll
        for (int vv2=0;vv2<4;vv2++)
          DSkT[(size_t)bx*16384 + (size_t)(w*32+mi2*16+kg*4+vv2)*128 + nj*16+lr] = f2bf(acc[mi2][nj][vv2]);
  }
  {
    f32x4 acc[2][8];
#pragma unroll
    for (int a=0;a<2;a++)
#pragma unroll
      for (int b=0;b<8;b++) acc[a][b]=vz;
#pragma unroll
    for (int ks=0;ks<2;ks++){
      bf16x8 a0=ldfrag(&VT[(w*32   +lr)*68 + ks*32+kg*8]);
      bf16x8 a1=ldfrag(&VT[(w*32+16+lr)*68 + ks*32+kg*8]);
#pragma unroll
      for (int nj=0;nj<8;nj++){
        bf16x8 b=ldfrag(&UT[(nj*16+lr)*68 + ks*32+kg*8]);
        acc[0][nj]=__builtin_amdgcn_mfma_f32_16x16x32_bf16(a0,b,acc[0][nj],0,0,0);
        acc[1][nj]=__builtin_amdgcn_mfma_f32_16x16x32_bf16(a1,b,acc[1][nj],0,0,0);
      }
    }
#pragma unroll
    for (int mi2=0;mi2<2;mi2++)
#pragma unroll
      for (int nj=0;nj<8;nj++)
#pragma unroll
        for (int vv2=0;vv2<4;vv2++)
          DSvT[(size_t)bx*16384 + (size_t)(w*32+mi2*16+kg*4+vv2)*128 + nj*16+lr] = f2bf(acc[mi2][nj][vv2]);
  }
}

// ---------------- Phase B: sequential cross-chunk combine (bf16 in/out) ----------------
__global__ __launch_bounds__(256)
void phaseB_k(const u16* __restrict__ DSk, const u16* __restrict__ DSv,
              const float* __restrict__ cg, u16* __restrict__ Sk0, u16* __restrict__ Sv0){
  unsigned idx = blockIdx.x*256u + threadIdx.x;   // 524288 total
  int sel  = idx >> 18;
  int h    = (idx >> 14) & 15;
  int flat = idx & 16383;                 // SkT: m*128+d ; SvT: v*128+m
  int mdec = sel ? (flat & 127) : (flat >> 7);
  const u16* DS = sel ? DSv : DSk;
  u16* S = sel ? Sv0 : Sk0;
  float cur = 0.f;
  for (int c=0;c<16;c++){
    size_t sb = ((size_t)(c*16+h))*16384 + flat;
    S[sb] = f2bf(cur);                     // state BEFORE chunk c
    float gd = __expf(cg[(size_t)(c*64+63)*2048 + h*128 + mdec]);
    cur = cur*gd + bf2f(DS[sb]);
  }
}

// ---------------- Phase C (MFMA): per-chunk outputs + fused gated RMSNorm -> Obf ----------------
__global__ __launch_bounds__(256)
void phaseC_k(const u16* __restrict__ q, const u16* __restrict__ k,
              const u16* __restrict__ v, const u16* __restrict__ bw,
              const float* __restrict__ cg, const u16* __restrict__ SkT,
              const u16* __restrict__ SvT, const u16* __restrict__ gate,
              const float* __restrict__ bg2, const float* __restrict__ nw,
              u16* __restrict__ Obf){
  __shared__ u16 Qb[64*132];     // Q, then A' (wave-private rows after prep)
  __shared__ u16 KV[8704];       // K[64][132], then VT[128][68]
  __shared__ u16 Bws[64*132];    // bw*e^{cgm-cg} natural [s][m]
  __shared__ u16 BwT[128*68];    // transposed [m][s]
  __shared__ u16 Ssb[64*68];     // sqk, then P (wave-private rows)
  __shared__ u16 SkL[128*132];   // Sk'^T * e^{cgm[m]}  [m][d]
  __shared__ u16 SvL[128*132];   // Sv'^T * e^{cgm[m]}  [v][m]
  __shared__ float cgm[128];
  __shared__ float ecgm[128];
  const int bx=blockIdx.x, h=bx&15, c=bx>>4, tid=threadIdx.x;
  const int w=tid>>6, lane=tid&63, lr=lane&15, kg=lane>>4;
  const float SCALE = 0.088388347648318447f;   // 128^-0.5
  const f32x4 vz = {0.f,0.f,0.f,0.f};
  if (tid<128){ float t=cg[(size_t)(c*64+31)*2048 + h*128 + tid]; cgm[tid]=t; ecgm[tid]=__expf(t); }
  __syncthreads();
#pragma unroll
  for (int j=0;j<8;j++){
    int f4=tid+j*256, r=f4>>5, c4=(f4&31)<<2;
    size_t g=(size_t)(c*64+r)*2048 + h*128 + c4;
    *(ushort4*)&Qb[r*132+c4] = *(const ushort4*)&q[g];
    *(ushort4*)&KV[r*132+c4] = *(const ushort4*)&k[g];
    ushort4 bv=*(const ushort4*)&bw[g];
    float4 cv=*(const float4*)&cg[g];
    float b0=bf2f(bv.x)*__expf(cgm[c4+0]-cv.x);
    float b1=bf2f(bv.y)*__expf(cgm[c4+1]-cv.y);
    float b2=bf2f(bv.z)*__expf(cgm[c4+2]-cv.z);
    float b3=bf2f(bv.w)*__expf(cgm[c4+3]-cv.w);
    bf16x4 bb = cvt4(b0,b1,b2,b3);
    *(bf16x4*)&Bws[r*132+c4] = bb;
    BwT[(c4+0)*68+r]=(u16)bb[0]; BwT[(c4+1)*68+r]=(u16)bb[1];
    BwT[(c4+2)*68+r]=(u16)bb[2]; BwT[(c4+3)*68+r]=(u16)bb[3];
  }
  __syncthreads();
  {
    f32x4 acc1[4];
#pragma unroll
    for (int a=0;a<4;a++) acc1[a]=vz;
#pragma unroll
    for (int ks=0;ks<4;ks++){
      bf16x8 aq = ldfrag(&Qb[(w*16+lr)*132 + ks*32+kg*8]);
#pragma unroll
      for (int ni=0;ni<4;ni++){
        bf16x8 bk = ldfrag(&KV[(ni*16+lr)*132 + ks*32+kg*8]);
        acc1[ni]=__builtin_amdgcn_mfma_f32_16x16x32_bf16(aq,bk,acc1[ni],0,0,0);
      }
    }
#pragma unroll
    for (int ni=0;ni<4;ni++)
#pragma unroll
      for (int vv2=0;vv2<4;vv2++){
        int row=w*16+kg*4+vv2, col=ni*16+lr;
        Ssb[row*68+col] = (col<=row) ? f2bf(acc1[ni][vv2]) : (u16)0;
      }
  }
  __syncthreads();   // all K reads done -> KV reusable for VT
#pragma unroll
  for (int j=0;j<8;j++){
    int f4=tid+j*256, r=f4>>5, c4=(f4&31)<<2;
    ushort4 vv=*(const ushort4*)&v[(size_t)(c*64+r)*2048 + h*128 + c4];
    KV[(c4+0)*68+r]=vv.x; KV[(c4+1)*68+r]=vv.y;
    KV[(c4+2)*68+r]=vv.z; KV[(c4+3)*68+r]=vv.w;
  }
#pragma unroll
  for (int j=0;j<16;j++){
    int f4=tid+j*256, r=f4>>5, c4=(f4&31)<<2;
    ushort4 s4=*(const ushort4*)&SkT[(size_t)bx*16384 + (size_t)r*128 + c4];
    float em=ecgm[r];
    *(bf16x4*)&SkL[r*132+c4]=cvt4(bf2f(s4.x)*em, bf2f(s4.y)*em, bf2f(s4.z)*em, bf2f(s4.w)*em);
  }
#pragma unroll
  for (int j=0;j<16;j++){
    int f4=tid+j*256, r=f4>>5, c4=(f4&31)<<2;
    ushort4 s4=*(const ushort4*)&SvT[(size_t)bx*16384 + (size_t)r*128 + c4];
    *(bf16x4*)&SvL[r*132+c4]=cvt4(bf2f(s4.x)*ecgm[c4+0], bf2f(s4.y)*ecgm[c4+1],
                                  bf2f(s4.z)*ecgm[c4+2], bf2f(s4.w)*ecgm[c4+3]);
  }
  f32x4 zac[8];
#pragma unroll
  for (int a=0;a<8;a++) zac[a]=vz;
#pragma unroll
  for (int ks=0;ks<2;ks++){
    bf16x8 as_ = ldfrag(&Ssb[(w*16+lr)*68 + ks*32+kg*8]);
#pragma unroll
    for (int ni=0;ni<8;ni++){
      bf16x8 bb = ldfrag(&BwT[(ni*16+lr)*68 + ks*32+kg*8]);
      zac[ni]=__builtin_amdgcn_mfma_f32_16x16x32_bf16(as_,bb,zac[ni],0,0,0);
    }
  }
  __syncthreads();   // SkL/SvL/VT staged & visible
#pragma unroll
  for (int dt=0;dt<4;dt++){
    bf16x8 aq = ldfrag(&Qb[(w*16+lr)*132 + dt*32+kg*8]);
#pragma unroll
    for (int ni=0;ni<8;ni++){
      bf16x8 bs = ldfrag(&SkL[(ni*16+lr)*132 + dt*32+kg*8]);
      zac[ni]=__builtin_amdgcn_mfma_f32_16x16x32_bf16(aq,bs,zac[ni],0,0,0);
    }
  }
  float dec[4][8], zz[4][8];
#pragma unroll
  for (int vv2=0;vv2<4;vv2++)
#pragma unroll
    for (int ni=0;ni<8;ni++) zz[vv2][ni]=zac[ni][vv2];
#pragma unroll
  for (int vv2=0;vv2<4;vv2++){
    size_t gr=(size_t)(c*64+w*16+kg*4+vv2)*2048 + h*128;
#pragma unroll
    for (int ni=0;ni<8;ni++){
      float cgv = cg[gr + ni*16+lr];
      dec[vv2][ni] = __expf(cgv - cgm[ni*16+lr]);
    }
  }
#pragma unroll
  for (int vv2=0;vv2<4;vv2++){
    float mx=-3.0e38f;
#pragma unroll
    for (int ni=0;ni<8;ni++){ zz[vv2][ni] *= SCALE*dec[vv2][ni]; mx=fmaxf(mx,zz[vv2][ni]); }
    mx=fmaxf(mx,__shfl_xor(mx,1)); mx=fmaxf(mx,__shfl_xor(mx,2));
    mx=fmaxf(mx,__shfl_xor(mx,4)); mx=fmaxf(mx,__shfl_xor(mx,8));
    float sum=0.f;
#pragma unroll
    for (int ni=0;ni<8;ni++){ zz[vv2][ni]=__expf(zz[vv2][ni]-mx); sum+=zz[vv2][ni]; }
    sum+=__shfl_xor(sum,1); sum+=__shfl_xor(sum,2);
    sum+=__shfl_xor(sum,4); sum+=__shfl_xor(sum,8);
    float inv=1.f/sum;
#pragma unroll
    for (int ni=0;ni<8;ni++) zz[vv2][ni] *= inv*dec[vv2][ni];   // A' = a * e^{cg-cgm}
  }
#pragma unroll
  for (int vv2=0;vv2<4;vv2++)
#pragma unroll
    for (int ni=0;ni<8;ni++)
      Qb[(w*16+kg*4+vv2)*132 + ni*16+lr] = f2bf(zz[vv2][ni]);
  {
    f32x4 acc4[4];
#pragma unroll
    for (int a=0;a<4;a++) acc4[a]=vz;
#pragma unroll
    for (int ks=0;ks<4;ks++){
      bf16x8 aa = ldfrag(&Qb[(w*16+lr)*132 + ks*32+kg*8]);
#pragma unroll
      for (int ni=0;ni<4;ni++){
        bf16x8 bb = ldfrag(&Bws[(ni*16+lr)*132 + ks*32+kg*8]);
        acc4[ni]=__builtin_amdgcn_mfma_f32_16x16x32_bf16(aa,bb,acc4[ni],0,0,0);
      }
    }
#pragma unroll
    for (int ni=0;ni<4;ni++)
#pragma unroll
      for (int vv2=0;vv2<4;vv2++){
        int row=w*16+kg*4+vv2, col=ni*16+lr;
        Ssb[row*68+col] = (col<=row) ? f2bf(acc4[ni][vv2]) : (u16)0;
      }
  }
  f32x4 oac[8];
#pragma unroll
  for (int a=0;a<8;a++) oac[a]=vz;
#pragma unroll
  for (int ks=0;ks<2;ks++){
    bf16x8 ap = ldfrag(&Ssb[(w*16+lr)*68 + ks*32+kg*8]);
#pragma unroll
    for (int ni=0;ni<8;ni++){
      bf16x8 bv2 = ldfrag(&KV[(ni*16+lr)*68 + ks*32+kg*8]);
      oac[ni]=__builtin_amdgcn_mfma_f32_16x16x32_bf16(ap,bv2,oac[ni],0,0,0);
    }
  }
#pragma unroll
  for (int mt=0;mt<4;mt++){
    bf16x8 aa = ldfrag(&Qb[(w*16+lr)*132 + mt*32+kg*8]);
#pragma unroll
    for (int ni=0;ni<8;ni++){
      bf16x8 bs = ldfrag(&SvL[(ni*16+lr)*132 + mt*32+kg*8]);
      oac[ni]=__builtin_amdgcn_mfma_f32_16x16x32_bf16(aa,bs,oac[ni],0,0,0);
    }
  }
  // ---- fused gated RMSNorm epilogue -> Obf bf16
#pragma unroll
  for (int vv2=0;vv2<4;vv2++){
    float ss = 0.f;
#pragma unroll
    for (int ni=0;ni<8;ni++) ss += oac[ni][vv2]*oac[ni][vv2];
    ss += __shfl_xor(ss,1); ss += __shfl_xor(ss,2);
    ss += __shfl_xor(ss,4); ss += __shfl_xor(ss,8);
    float rr = rsqrtf(ss*(1.f/128.f) + 1e-5f);
    int row = c*64 + w*16 + kg*4 + vv2;
#pragma unroll
    for (int ni=0;ni<8;ni++){
      int colh = ni*16+lr;
      int col  = h*128 + colh;
      float g = bf2f(gate[(size_t)row*2048 + col]) + bg2[col];
      float val = oac[ni][vv2]*rr*nw[colh]*(1.f/(1.f+__expf(-g)));
      Obf[(size_t)row*2048 + col] = f2bf(val);
    }
  }
}

extern "C" void kernel_launch(void* const* d_in, const int* in_sizes, int n_in,
                              void* d_out, int out_size, void* d_ws, size_t ws_size,
                              hipStream_t stream){
  (void)in_sizes; (void)n_in; (void)out_size; (void)ws_size;
  const float* hX   = (const float*)d_in[0];
  const float* Wq   = (const float*)d_in[1];
  const float* Wk   = (const float*)d_in[2];
  const float* Wv   = (const float*)d_in[3];
  const float* Ww   = (const float*)d_in[4];
  const float* cq   = (const float*)d_in[5];
  const float* ck   = (const float*)d_in[6];
  const float* cv   = (const float*)d_in[7];
  const float* Wf1  = (const float*)d_in[8];
  const float* Wf2  = (const float*)d_in[9];
  const float* Wb   = (const float*)d_in[10];
  const float* Wg1  = (const float*)d_in[11];
  const float* Wg2  = (const float*)d_in[12];
  const float* bg2  = (const float*)d_in[13];
  const float* nw   = (const float*)d_in[14];
  const float* Wo   = (const float*)d_in[15];
  char* ws = (char*)d_ws;
  u16*   h_bf  = (u16*)  (ws + 0);
  u16*   WcatT = (u16*)  (ws + 4194304);
  u16*   Sk0   = (u16*)  (ws + 4194304);            // reuses WcatT after GEMMs (bf16)
  u16*   Sv0   = (u16*)  (ws + 20971520);
  u16*   WoT   = (u16*)  (ws + 37748736);
  u16*   Wf2T  = (u16*)  (ws + 47185920);
  u16*   Wg2T  = (u16*)  (ws + 47710208);
  u16*   qkvw  = (u16*)  (ws + 48234496);           // bf16 [1024][8192] -> ends 65011712
  u16*   DSk   = (u16*)  (ws + 48234496);           // bf16, reuses qkvw after conv
  u16*   DSv   = (u16*)  (ws + 56623104);
  u16*   gateb = (u16*)  (ws + 65011712);           // bf16 [1024][2048]
  u16*   qb    = (u16*)  (ws + 81788928);           // bf16 [1024][2048]
  u16*   kb    = (u16*)  (ws + 90177536);
  u16*   vb    = (u16*)  (ws + 98566144);
  u16*   P8    = (u16*)  (ws + 106954752);          // f1g1 split-K bf16 partials (16 x 768KB)
  u16*   bwb   = (u16*)  (ws + 119537664);          // bf16 [1024][2048] (after P8)
  u16*   f1g1  = (u16*)  (ws + 123731968);          // bf16 [1024][384]
  u16*   WfgT  = (u16*)  (ws + 124518400);          // bf16 [384][2048]
  float* cgb   = (float*)(ws + 132644864);
  float* betab = (float*)(ws + 141033472);
  u16*   Obf   = (u16*)  (ws + 141099008);
  float* outp  = (float*)d_out;

  // conversions: all transposes + hX convert + WbT in ONE launch
  transp64_k<<<dim3(32,32,11),256,0,stream>>>(Wq, Wk, Wv, Ww, Wo, WcatT, WoT, hX, h_bf,
                                              Wf1, Wg1, Wf2, Wg2, Wb, WfgT, Wf2T, Wg2T);

  // projections
  gemm4_k<true><<<dim3(64,8),256,0,stream>>>(h_bf, WcatT, qkvw, 2048, 2048, 2048, 8192);
  gemmsk_k<<<dim3(3,8,16),256,0,stream>>>(h_bf, WfgT, P8, 2048, 2048);
  reduceb_k<<<384,256,0,stream>>>(P8, f1g1, betab);
  gemmg_k<<<dim3(16,8,2),256,0,stream>>>(f1g1, Wf2T, Wg2T, cgb, gateb);   // cg + gate directly

  // conv + silu (+fused l2norm*beta on w-branch)
  conv_k<<<8192,256,0,stream>>>(qkvw, cq, ck, cv, betab, qb, kb, vb, bwb);

  // chunked scan (phaseC fuses gated RMSNorm -> Obf)
  phaseA_k<<<256,256,0,stream>>>(kb, vb, bwb, cgb, DSk, DSv);
  phaseB_k<<<2048,256,0,stream>>>(DSk, DSv, cgb, Sk0, Sv0);
  phaseC_k<<<256,256,0,stream>>>(qb, kb, vb, bwb, cgb, Sk0, Sv0, gateb, bg2, nw, Obf);

  // output projection: zero + split-K=2 atomic accumulate (2 commutative adds -> deterministic)
  hipMemsetAsync(outp, 0, (size_t)1024*2048*4, stream);
  gemm4sk_k<<<dim3(16,8,2),256,0,stream>>>(Obf, WoT, outp, 1024, 2048, 2048, 2048);
}